// Round 11
// baseline (449.677 us; speedup 1.0000x reference)
//
#include <hip/hip_runtime.h>

// N = 32768 (runtime), C = 64, K = 16, CS = 8, SHARE = 8

enum {
  S_SC1 = 0,    S_SH1 = 64,
  S_LPSC = 128, S_LPSH = 132,
  S_M2S1 = 136, S_M2H1 = 200,
  S_M2S2 = 264, S_M2H2 = 272,
  S_SC2 = 280,  S_SH2 = 344,
  S_SC3 = 408,  S_SH3 = 472,
  S_LPW2S = 536, S_LPB2S = 584,
  S_QW = 600, S_QB = 612,
  S_G = 640,        // 64x16 c-major
  S_HC = 1664,      // 64x4 c-major
  S_HB = 1920,      // 64
  CONST_FLOATS = 2048
};

__device__ __forceinline__ int pidx(int a, int b) {  // a<=b, 20-dim sym
  return a * 20 - (a * (a - 1)) / 2 + (b - a);
}
__device__ __forceinline__ unsigned short bf16r(float f) {
  unsigned u = __float_as_uint(f);
  u = u + 0x7fffu + ((u >> 16) & 1u);
  return (unsigned short)(u >> 16);
}
__device__ __forceinline__ unsigned short f2h(float f) {
  _Float16 h = (_Float16)f;
  unsigned short u;
  __builtin_memcpy(&u, &h, 2);
  return u;
}
__device__ __forceinline__ float h2f(unsigned short u) {
  _Float16 h;
  __builtin_memcpy(&h, &u, 2);
  return (float)h;
}
__device__ __forceinline__ unsigned packh2(float a, float b) {
  return (unsigned)f2h(a) | ((unsigned)f2h(b) << 16);
}
__device__ __forceinline__ float lo16(unsigned u) { return h2f((unsigned short)(u & 0xffffu)); }
__device__ __forceinline__ float hi16(unsigned u) { return h2f((unsigned short)(u >> 16)); }

// ---------------- fused partial-reduce + BN finalize ----------------
__global__ __launch_bounds__(256) void k_rbn(
    const float* __restrict__ partial, int nb, int nch,
    const float* __restrict__ g, const float* __restrict__ b,
    float* __restrict__ scale, float* __restrict__ shift, float inv_count)
{
  const int c = blockIdx.x;
  const int tid = threadIdx.x;
  float s = 0.f, q = 0.f;
  for (int i = tid; i < nb; i += 256) {
    s += partial[(size_t)c * nb + i];
    q += partial[(size_t)(c + nch) * nb + i];
  }
  #pragma unroll
  for (int m = 1; m < 64; m <<= 1) { s += __shfl_xor(s, m); q += __shfl_xor(q, m); }
  __shared__ float ws[4], wq[4];
  if ((tid & 63) == 0) { ws[tid >> 6] = s; wq[tid >> 6] = q; }
  __syncthreads();
  if (tid == 0) {
    float S = ws[0] + ws[1] + ws[2] + ws[3];
    float Q = wq[0] + wq[1] + wq[2] + wq[3];
    float m = S * inv_count;
    float v = Q * inv_count - m * m;
    float rs = rsqrtf(v + 1e-5f);
    float sc = g[c] * rs;
    scale[c] = sc;
    shift[c] = fmaf(-m, sc, b[c]);
  }
}

// ---------------- generic 64x64 GEMM (f32 out) ----------------
__global__ __launch_bounds__(256) void k_gemm64(
    const float* __restrict__ in, const float* __restrict__ w,
    const float* __restrict__ bias,
    const float* __restrict__ sc, const float* __restrict__ sh,
    float* __restrict__ out,
    float* __restrict__ partial, int n)
{
  __shared__ float scsh[64], shsh[64];
  __shared__ float bsum[64], bsq[64];
  const int tid = threadIdx.x;
  const int lane = tid & 63;
  const int wave = tid >> 6;
  if (sc != nullptr && tid < 64) { scsh[tid] = sc[tid]; shsh[tid] = sh[tid]; }
  if (tid < 64) { bsum[tid] = 0.f; bsq[tid] = 0.f; }
  __syncthreads();

  float wreg[64];
  #pragma unroll
  for (int k = 0; k < 64; ++k) wreg[k] = w[k * 64 + lane];
  const float bz = bias ? bias[lane] : 0.f;

  float lsum = 0.f, lsq = 0.f;
  const int row0 = (blockIdx.x * 4 + wave) * 16;
  for (int r = 0; r < 16; ++r) {
    const int row = row0 + r;
    const float* xr = in + (size_t)row * 64;
    float acc = bz;
    if (sc != nullptr) {
      #pragma unroll
      for (int k = 0; k < 64; k += 4) {
        float4 xv = *(const float4*)(xr + k);
        float x0 = fmaxf(fmaf(xv.x, scsh[k + 0], shsh[k + 0]), 0.f);
        float x1 = fmaxf(fmaf(xv.y, scsh[k + 1], shsh[k + 1]), 0.f);
        float x2 = fmaxf(fmaf(xv.z, scsh[k + 2], shsh[k + 2]), 0.f);
        float x3 = fmaxf(fmaf(xv.w, scsh[k + 3], shsh[k + 3]), 0.f);
        acc = fmaf(x0, wreg[k + 0], acc);
        acc = fmaf(x1, wreg[k + 1], acc);
        acc = fmaf(x2, wreg[k + 2], acc);
        acc = fmaf(x3, wreg[k + 3], acc);
      }
    } else {
      #pragma unroll
      for (int k = 0; k < 64; k += 4) {
        float4 xv = *(const float4*)(xr + k);
        acc = fmaf(xv.x, wreg[k + 0], acc);
        acc = fmaf(xv.y, wreg[k + 1], acc);
        acc = fmaf(xv.z, wreg[k + 2], acc);
        acc = fmaf(xv.w, wreg[k + 3], acc);
      }
    }
    out[(size_t)row * 64 + lane] = acc;
    lsum += acc;
    lsq = fmaf(acc, acc, lsq);
  }
  if (partial != nullptr) {
    atomicAdd(&bsum[lane], lsum);
    atomicAdd(&bsq[lane], lsq);
    __syncthreads();
    if (tid < 64) {
      partial[(size_t)tid * gridDim.x + blockIdx.x] = bsum[tid];
      partial[(size_t)(tid + 64) * gridDim.x + blockIdx.x] = bsq[tid];
    }
  }
}

// ---------------- fused: z (bf16) = nr(y1)@m3w+m3b ; y16 = nr(y1)@m1w1[3:] ----------------
__global__ __launch_bounds__(256) void k_gemmzy(
    const float* __restrict__ in, const float* __restrict__ w,
    const float* __restrict__ bias, const float* __restrict__ w16,
    const float* __restrict__ sc, const float* __restrict__ sh,
    unsigned short* __restrict__ outz, float* __restrict__ out16)
{
  __shared__ float xn[64][68];
  __shared__ float w16sh[1024];
  __shared__ float scsh[64], shsh[64];
  const int tid = threadIdx.x;
  if (tid < 64) { scsh[tid] = sc[tid]; shsh[tid] = sh[tid]; }
  for (int i2 = tid; i2 < 1024; i2 += 256) w16sh[i2] = w16[i2];
  __syncthreads();
  const int row0 = blockIdx.x * 64;
  for (int idx = tid; idx < 4096; idx += 256) {
    int r = idx >> 6, c = idx & 63;
    float v = in[(size_t)(row0 + r) * 64 + c];
    xn[r][c] = fmaxf(fmaf(v, scsh[c], shsh[c]), 0.f);
  }
  __syncthreads();

  const int lane = tid & 63;
  const int wave = tid >> 6;
  float wreg[64];
  #pragma unroll
  for (int k = 0; k < 64; ++k) wreg[k] = w[k * 64 + lane];
  const float bz = bias[lane];
  for (int r = wave * 16; r < wave * 16 + 16; ++r) {
    float acc = bz;
    #pragma unroll
    for (int k = 0; k < 64; k += 4) {
      float4 xv = *(const float4*)(&xn[r][k]);
      acc = fmaf(xv.x, wreg[k + 0], acc);
      acc = fmaf(xv.y, wreg[k + 1], acc);
      acc = fmaf(xv.z, wreg[k + 2], acc);
      acc = fmaf(xv.w, wreg[k + 3], acc);
    }
    outz[(size_t)(row0 + r) * 64 + lane] = bf16r(acc);
  }
  for (int idx = tid; idx < 1024; idx += 256) {
    int r = idx >> 4, t = idx & 15;
    float acc = 0.f;
    #pragma unroll
    for (int c = 0; c < 64; c += 4) {
      float4 xv = *(const float4*)(&xn[r][c]);
      acc = fmaf(xv.x, w16sh[(c + 0) * 16 + t], acc);
      acc = fmaf(xv.y, w16sh[(c + 1) * 16 + t], acc);
      acc = fmaf(xv.z, w16sh[(c + 2) * 16 + t], acc);
      acc = fmaf(xv.w, w16sh[(c + 3) * 16 + t], acc);
    }
    out16[(size_t)(row0 + r) * 16 + t] = acc;
  }
}

// ---------------- K1: p_r, lp partials, histogram + rank ----------------
__global__ __launch_bounds__(256) void k_prhist(
    const float* __restrict__ p, const int* __restrict__ knn,
    const float* __restrict__ lpw1, const float* __restrict__ lpb1,
    float* __restrict__ p_r, float* __restrict__ plp,
    int* __restrict__ cnt, int* __restrict__ rank)
{
  __shared__ float lpw1sh[9], lpb1sh[3];
  __shared__ float lpsh[4][8];
  const int tid = threadIdx.x;
  if (tid < 9) lpw1sh[tid] = lpw1[tid];
  if (tid < 3) lpb1sh[tid] = lpb1[tid];
  __syncthreads();

  const size_t g = (size_t)blockIdx.x * 256 + tid;
  const int i = (int)(g >> 4);
  const int j = knn[g];
  const float pr0 = p[j * 3 + 0] - p[i * 3 + 0];
  const float pr1 = p[j * 3 + 1] - p[i * 3 + 1];
  const float pr2 = p[j * 3 + 2] - p[i * 3 + 2];
  p_r[g * 3 + 0] = pr0; p_r[g * 3 + 1] = pr1; p_r[g * 3 + 2] = pr2;
  rank[g] = atomicAdd(&cnt[j], 1);

  float q0 = fmaf(pr2, lpw1sh[6], fmaf(pr1, lpw1sh[3], fmaf(pr0, lpw1sh[0], lpb1sh[0])));
  float q1 = fmaf(pr2, lpw1sh[7], fmaf(pr1, lpw1sh[4], fmaf(pr0, lpw1sh[1], lpb1sh[1])));
  float q2 = fmaf(pr2, lpw1sh[8], fmaf(pr1, lpw1sh[5], fmaf(pr0, lpw1sh[2], lpb1sh[2])));
  float s0 = q0, s1 = q1, s2 = q2, qq0 = q0 * q0, qq1 = q1 * q1, qq2 = q2 * q2;
  #pragma unroll
  for (int m = 1; m < 64; m <<= 1) {
    s0 += __shfl_xor(s0, m); s1 += __shfl_xor(s1, m); s2 += __shfl_xor(s2, m);
    qq0 += __shfl_xor(qq0, m); qq1 += __shfl_xor(qq1, m); qq2 += __shfl_xor(qq2, m);
  }
  if ((tid & 63) == 0) {
    const int w = tid >> 6;
    lpsh[w][0] = s0; lpsh[w][1] = s1; lpsh[w][2] = s2; lpsh[w][3] = 0.f;
    lpsh[w][4] = qq0; lpsh[w][5] = qq1; lpsh[w][6] = qq2; lpsh[w][7] = 0.f;
  }
  __syncthreads();
  if (tid < 8) {
    float v = lpsh[0][tid] + lpsh[1][tid] + lpsh[2][tid] + lpsh[3][tid];
    plp[(size_t)tid * gridDim.x + blockIdx.x] = v;
  }
}

// ---------------- merged: CSR scan + lp finalize + weight folding ----------------
__global__ __launch_bounds__(1024) void k_scan_mid(
    const int* __restrict__ cnt, int* __restrict__ rowstart, int n,
    const float* __restrict__ plp, int nbplp,
    const float* __restrict__ lpg, const float* __restrict__ lpbt,
    const float* __restrict__ lpw1, const float* __restrict__ lpb1,
    const float* __restrict__ lpw2, const float* __restrict__ lpb2,
    const float* __restrict__ m1w2, const float* __restrict__ m2w1,
    const float* __restrict__ m1b2,
    float* __restrict__ cst, float inv_count)
{
  __shared__ int tsum[1024];
  __shared__ float Ssh[8];
  const int tid = threadIdx.x;
  const int per = n >> 10;
  const int base = tid * per;
  int local[32];
  int s = 0;
  for (int u = 0; u < per; ++u) { local[u] = cnt[base + u]; s += local[u]; }
  tsum[tid] = s;
  __syncthreads();
  for (int off = 1; off < 1024; off <<= 1) {
    int v = (tid >= off) ? tsum[tid - off] : 0;
    __syncthreads();
    tsum[tid] += v;
    __syncthreads();
  }
  int run = tsum[tid] - s;
  for (int u = 0; u < per; ++u) { rowstart[base + u] = run; run += local[u]; }
  if (tid == 1023) rowstart[n] = run;

  if (tid < 256) {
    const int row = tid >> 5, l32 = tid & 31;
    float ls = 0.f;
    for (int i = l32; i < nbplp; i += 32) ls += plp[(size_t)row * nbplp + i];
    #pragma unroll
    for (int m = 1; m < 32; m <<= 1) ls += __shfl_xor(ls, m);
    if (l32 == 0) Ssh[row] = ls;
  }
  __syncthreads();
  if (tid < 3) {
    float m = Ssh[tid] * inv_count;
    float v = Ssh[4 + tid] * inv_count - m * m;
    float rs = rsqrtf(v + 1e-5f);
    float sc = lpg[tid] * rs;
    cst[S_LPSC + tid] = sc;
    cst[S_LPSH + tid] = fmaf(-m, sc, lpbt[tid]);
  }
  __syncthreads();
  if (tid < 9)  cst[S_QW + tid] = lpw1[tid] * cst[S_LPSC + (tid % 3)];
  if (tid < 3)  cst[S_QB + tid] = fmaf(lpb1[tid], cst[S_LPSC + tid], cst[S_LPSH + tid]);
  if (tid < 16) {
    float b = 0.f;
    for (int c2 = 0; c2 < 4; ++c2) b += lpb2[c2 * 16 + tid];
    cst[S_LPB2S + tid] = b;
    for (int r = 0; r < 3; ++r) {
      float w = 0.f;
      for (int c2 = 0; c2 < 4; ++c2) w += lpw2[r * 64 + c2 * 16 + tid];
      cst[S_LPW2S + r * 16 + tid] = w;
    }
  }
  __syncthreads();
  if (tid < 256) {
    #pragma unroll
    for (int q = 0; q < 4; ++q) {
      int ee = tid * 4 + q;
      int c = ee >> 4, u = ee & 15;
      float sg = 0.f;
      #pragma unroll
      for (int t = 0; t < 16; ++t) sg = fmaf(m1w2[u * 16 + t], m2w1[t * 64 + c], sg);
      cst[S_G + c * 16 + u] = sg;
    }
  }
  if (tid < 192) {
    int c = tid / 3, r = tid - c * 3;
    float sh = 0.f;
    #pragma unroll
    for (int t = 0; t < 16; ++t) sh = fmaf(cst[S_LPW2S + r * 16 + t], m2w1[(16 + t) * 64 + c], sh);
    cst[S_HC + c * 4 + r] = sh;
  }
  if (tid < 64) {
    cst[S_HC + tid * 4 + 3] = 0.f;
    float sb = 0.f;
    #pragma unroll
    for (int t = 0; t < 16; ++t) {
      sb = fmaf(m1b2[t], m2w1[t * 64 + tid], sb);
      sb = fmaf(cst[S_LPB2S + t], m2w1[(16 + t) * 64 + tid], sb);
    }
    cst[S_HB + tid] = sb;
  }
}

// ---------------- K2: u-moment accumulation + uq/uqn/pos store ----------------
__global__ __launch_bounds__(256) void k_moment(
    const float* __restrict__ y16, const float* __restrict__ p_r,
    const int* __restrict__ knn, const float* __restrict__ m1w1,
    const float* __restrict__ m1b1, const float* __restrict__ cst,
    const int* __restrict__ rowstart, const int* __restrict__ rank,
    float* __restrict__ pmom,   // [210 * gridDim.x] channel-major
    unsigned* __restrict__ uq,  // [nk * 8] packed fp16 t1[16]
    unsigned* __restrict__ uqn, // [nk * 2] packed fp16 qn[3]
    int* __restrict__ posbuf)   // [nk]
{
  __shared__ float ush[256 * 21];
  const int tid = threadIdx.x;
  const size_t g = (size_t)blockIdx.x * 256 + tid;
  const int j = knn[g];
  const float pr0 = p_r[g * 3 + 0], pr1 = p_r[g * 3 + 1], pr2 = p_r[g * 3 + 2];
  const float* yj = y16 + (size_t)j * 16;
  float4 ya = *(const float4*)(yj);
  float4 yb = *(const float4*)(yj + 4);
  float4 yc = *(const float4*)(yj + 8);
  float4 yd = *(const float4*)(yj + 12);
  float t1[16] = {ya.x, ya.y, ya.z, ya.w, yb.x, yb.y, yb.z, yb.w,
                  yc.x, yc.y, yc.z, yc.w, yd.x, yd.y, yd.z, yd.w};
  #pragma unroll
  for (int u = 0; u < 16; ++u)
    t1[u] = fmaxf(fmaf(pr2, m1w1[32 + u], fmaf(pr1, m1w1[16 + u],
                  fmaf(pr0, m1w1[u], t1[u] + m1b1[u]))), 0.f);
  const float qn0 = fmaxf(fmaf(pr2, cst[S_QW + 6], fmaf(pr1, cst[S_QW + 3], fmaf(pr0, cst[S_QW + 0], cst[S_QB + 0]))), 0.f);
  const float qn1 = fmaxf(fmaf(pr2, cst[S_QW + 7], fmaf(pr1, cst[S_QW + 4], fmaf(pr0, cst[S_QW + 1], cst[S_QB + 1]))), 0.f);
  const float qn2 = fmaxf(fmaf(pr2, cst[S_QW + 8], fmaf(pr1, cst[S_QW + 5], fmaf(pr0, cst[S_QW + 2], cst[S_QB + 2]))), 0.f);

  posbuf[g] = rowstart[j] + rank[g];

  uint4 ua, ub;
  ua.x = packh2(t1[0], t1[1]);   ua.y = packh2(t1[2], t1[3]);
  ua.z = packh2(t1[4], t1[5]);   ua.w = packh2(t1[6], t1[7]);
  ub.x = packh2(t1[8], t1[9]);   ub.y = packh2(t1[10], t1[11]);
  ub.z = packh2(t1[12], t1[13]); ub.w = packh2(t1[14], t1[15]);
  *(uint4*)(uq + g * 8)     = ua;
  *(uint4*)(uq + g * 8 + 4) = ub;
  uint2 uc;
  uc.x = packh2(qn0, qn1);
  uc.y = packh2(qn2, 0.f);
  *(uint2*)(uqn + g * 2) = uc;

  float* ur = ush + tid * 21;
  #pragma unroll
  for (int u = 0; u < 16; ++u) ur[u] = t1[u];
  ur[16] = qn0; ur[17] = qn1; ur[18] = qn2; ur[19] = 1.f;
  __syncthreads();

  if (tid < 210) {
    int a = 0, t = tid;
    while (t >= 20 - a) { t -= 20 - a; ++a; }
    const int b = a + t;
    float s = 0.f;
    for (int it = 0; it < 256; ++it) {
      const int r = (it + tid) & 255;
      const float* u = ush + r * 21;
      s = fmaf(u[a], u[b], s);
    }
    pmom[(size_t)tid * gridDim.x + blockIdx.x] = s;
  }
}

// ---------------- parallel moment reduce ----------------
__global__ __launch_bounds__(256) void k_mred(
    const float* __restrict__ pmom, float* __restrict__ S2, int nb)
{
  const int c = blockIdx.x;
  const int tid = threadIdx.x;
  float s = 0.f;
  for (int i = tid; i < nb; i += 256) s += pmom[(size_t)c * nb + i];
  #pragma unroll
  for (int m = 1; m < 64; m <<= 1) s += __shfl_xor(s, m);
  __shared__ float ws[4];
  if ((tid & 63) == 0) ws[tid >> 6] = s;
  __syncthreads();
  if (tid == 0) S2[c] = ws[0] + ws[1] + ws[2] + ws[3];
}

// ---------------- moment finalize ----------------
__global__ __launch_bounds__(64) void k_mfin(
    const float* __restrict__ S2in,
    const float* __restrict__ g, const float* __restrict__ b,
    float* __restrict__ cst, float inv_count)
{
  __shared__ float S2[210];
  const int tid = threadIdx.x;
  for (int i = tid; i < 210; i += 64) S2[i] = S2in[i];
  __syncthreads();
  const int c = tid;
  float w[20];
  #pragma unroll
  for (int u = 0; u < 16; ++u) w[u] = cst[S_G + c * 16 + u];
  w[16] = cst[S_HC + c * 4 + 0];
  w[17] = cst[S_HC + c * 4 + 1];
  w[18] = cst[S_HC + c * 4 + 2];
  w[19] = cst[S_HB + c];
  float m2 = 0.f, m1 = 0.f;
  for (int a = 0; a < 20; ++a) {
    const float wa = w[a];
    m2 = fmaf(wa * wa, S2[pidx(a, a)], m2);
    float cross = 0.f;
    for (int bb = a + 1; bb < 20; ++bb) cross = fmaf(w[bb], S2[pidx(a, bb)], cross);
    m2 = fmaf(2.f * wa, cross, m2);
    m1 = fmaf(wa, S2[pidx(a, 19)], m1);
  }
  const float mean = m1 * inv_count;
  const float var = m2 * inv_count - mean * mean;
  const float rs = rsqrtf(var + 1e-5f);
  const float sc = g[c] * rs;
  cst[S_M2S1 + c] = sc;
  cst[S_M2H1 + c] = fmaf(-mean, sc, b[c]);
}

// ---------------- K3: h2(bf16) from packed uq/uqn via folded G/H ----------------
__global__ __launch_bounds__(256) void k_h2(
    const unsigned* __restrict__ uq, const unsigned* __restrict__ uqn,
    const float* __restrict__ cst, const float* __restrict__ m2w2,
    unsigned short* __restrict__ h2out,
    float* __restrict__ partial)   // [16 * gridDim.x]
{
  __shared__ float Gsh[1024], Hsh[256], hbsh[64];
  __shared__ float w2m[512];
  __shared__ float scsh[64], shsh[64];
  __shared__ float redsh[4][16];
  const int tid = threadIdx.x;
  for (int i = tid; i < 1024; i += 256) Gsh[i] = cst[S_G + i];
  Hsh[tid] = cst[S_HC + tid];
  for (int i = tid; i < 512; i += 256) w2m[i] = m2w2[i];
  if (tid < 64) { hbsh[tid] = cst[S_HB + tid]; scsh[tid] = cst[S_M2S1 + tid]; shsh[tid] = cst[S_M2H1 + tid]; }
  __syncthreads();

  const size_t g0 = ((size_t)blockIdx.x * 256 + tid) * 2;
  float t1[2][16], qn[2][3];
  #pragma unroll
  for (int gg = 0; gg < 2; ++gg) {
    const size_t g = g0 + gg;
    uint4 ua = *(const uint4*)(uq + g * 8);
    uint4 ub = *(const uint4*)(uq + g * 8 + 4);
    uint2 uc = *(const uint2*)(uqn + g * 2);
    t1[gg][0] = lo16(ua.x);  t1[gg][1] = hi16(ua.x);
    t1[gg][2] = lo16(ua.y);  t1[gg][3] = hi16(ua.y);
    t1[gg][4] = lo16(ua.z);  t1[gg][5] = hi16(ua.z);
    t1[gg][6] = lo16(ua.w);  t1[gg][7] = hi16(ua.w);
    t1[gg][8] = lo16(ub.x);  t1[gg][9] = hi16(ub.x);
    t1[gg][10] = lo16(ub.y); t1[gg][11] = hi16(ub.y);
    t1[gg][12] = lo16(ub.z); t1[gg][13] = hi16(ub.z);
    t1[gg][14] = lo16(ub.w); t1[gg][15] = hi16(ub.w);
    qn[gg][0] = lo16(uc.x); qn[gg][1] = hi16(uc.x); qn[gg][2] = lo16(uc.y);
  }

  float a0[8], a1[8];
  #pragma unroll
  for (int t = 0; t < 8; ++t) { a0[t] = 0.f; a1[t] = 0.f; }
  for (int c = 0; c < 64; ++c) {
    float4 g0v = *(const float4*)(Gsh + c * 16);
    float4 g1v = *(const float4*)(Gsh + c * 16 + 4);
    float4 g2v = *(const float4*)(Gsh + c * 16 + 8);
    float4 g3v = *(const float4*)(Gsh + c * 16 + 12);
    float4 hv = *(const float4*)(Hsh + c * 4);
    float h_0 = hbsh[c], h_1 = hbsh[c];
    h_0 = fmaf(t1[0][0], g0v.x, h_0); h_0 = fmaf(t1[0][1], g0v.y, h_0); h_0 = fmaf(t1[0][2], g0v.z, h_0); h_0 = fmaf(t1[0][3], g0v.w, h_0);
    h_0 = fmaf(t1[0][4], g1v.x, h_0); h_0 = fmaf(t1[0][5], g1v.y, h_0); h_0 = fmaf(t1[0][6], g1v.z, h_0); h_0 = fmaf(t1[0][7], g1v.w, h_0);
    h_0 = fmaf(t1[0][8], g2v.x, h_0); h_0 = fmaf(t1[0][9], g2v.y, h_0); h_0 = fmaf(t1[0][10], g2v.z, h_0); h_0 = fmaf(t1[0][11], g2v.w, h_0);
    h_0 = fmaf(t1[0][12], g3v.x, h_0); h_0 = fmaf(t1[0][13], g3v.y, h_0); h_0 = fmaf(t1[0][14], g3v.z, h_0); h_0 = fmaf(t1[0][15], g3v.w, h_0);
    h_0 = fmaf(qn[0][0], hv.x, fmaf(qn[0][1], hv.y, fmaf(qn[0][2], hv.z, h_0)));
    h_1 = fmaf(t1[1][0], g0v.x, h_1); h_1 = fmaf(t1[1][1], g0v.y, h_1); h_1 = fmaf(t1[1][2], g0v.z, h_1); h_1 = fmaf(t1[1][3], g0v.w, h_1);
    h_1 = fmaf(t1[1][4], g1v.x, h_1); h_1 = fmaf(t1[1][5], g1v.y, h_1); h_1 = fmaf(t1[1][6], g1v.z, h_1); h_1 = fmaf(t1[1][7], g1v.w, h_1);
    h_1 = fmaf(t1[1][8], g2v.x, h_1); h_1 = fmaf(t1[1][9], g2v.y, h_1); h_1 = fmaf(t1[1][10], g2v.z, h_1); h_1 = fmaf(t1[1][11], g2v.w, h_1);
    h_1 = fmaf(t1[1][12], g3v.x, h_1); h_1 = fmaf(t1[1][13], g3v.y, h_1); h_1 = fmaf(t1[1][14], g3v.z, h_1); h_1 = fmaf(t1[1][15], g3v.w, h_1);
    h_1 = fmaf(qn[1][0], hv.x, fmaf(qn[1][1], hv.y, fmaf(qn[1][2], hv.z, h_1)));
    float x0 = fmaxf(fmaf(h_0, scsh[c], shsh[c]), 0.f);
    float x1 = fmaxf(fmaf(h_1, scsh[c], shsh[c]), 0.f);
    float4 wa = *(const float4*)(w2m + c * 8);
    float4 wb = *(const float4*)(w2m + c * 8 + 4);
    a0[0] = fmaf(x0, wa.x, a0[0]); a0[1] = fmaf(x0, wa.y, a0[1]); a0[2] = fmaf(x0, wa.z, a0[2]); a0[3] = fmaf(x0, wa.w, a0[3]);
    a0[4] = fmaf(x0, wb.x, a0[4]); a0[5] = fmaf(x0, wb.y, a0[5]); a0[6] = fmaf(x0, wb.z, a0[6]); a0[7] = fmaf(x0, wb.w, a0[7]);
    a1[0] = fmaf(x1, wa.x, a1[0]); a1[1] = fmaf(x1, wa.y, a1[1]); a1[2] = fmaf(x1, wa.z, a1[2]); a1[3] = fmaf(x1, wa.w, a1[3]);
    a1[4] = fmaf(x1, wb.x, a1[4]); a1[5] = fmaf(x1, wb.y, a1[5]); a1[6] = fmaf(x1, wb.z, a1[6]); a1[7] = fmaf(x1, wb.w, a1[7]);
  }
  uint4 pa, pb;
  pa.x = bf16r(a0[0]) | ((unsigned)bf16r(a0[1]) << 16);
  pa.y = bf16r(a0[2]) | ((unsigned)bf16r(a0[3]) << 16);
  pa.z = bf16r(a0[4]) | ((unsigned)bf16r(a0[5]) << 16);
  pa.w = bf16r(a0[6]) | ((unsigned)bf16r(a0[7]) << 16);
  pb.x = bf16r(a1[0]) | ((unsigned)bf16r(a1[1]) << 16);
  pb.y = bf16r(a1[2]) | ((unsigned)bf16r(a1[3]) << 16);
  pb.z = bf16r(a1[4]) | ((unsigned)bf16r(a1[5]) << 16);
  pb.w = bf16r(a1[6]) | ((unsigned)bf16r(a1[7]) << 16);
  *(uint4*)(h2out + g0 * 8) = pa;
  *(uint4*)(h2out + g0 * 8 + 8) = pb;

  float st[8], sq[8];
  #pragma unroll
  for (int t = 0; t < 8; ++t) {
    st[t] = a0[t] + a1[t];
    sq[t] = fmaf(a0[t], a0[t], a1[t] * a1[t]);
  }
  #pragma unroll
  for (int m = 1; m < 64; m <<= 1) {
    #pragma unroll
    for (int t = 0; t < 8; ++t) { st[t] += __shfl_xor(st[t], m); sq[t] += __shfl_xor(sq[t], m); }
  }
  if ((tid & 63) == 0) {
    const int w = tid >> 6;
    #pragma unroll
    for (int t = 0; t < 8; ++t) { redsh[w][t] = st[t]; redsh[w][8 + t] = sq[t]; }
  }
  __syncthreads();
  if (tid < 16) {
    float v = redsh[0][tid] + redsh[1][tid] + redsh[2][tid] + redsh[3][tid];
    partial[(size_t)tid * gridDim.x + blockIdx.x] = v;
  }
}

// ---------------- K4: fused softmax + xk + x_intra + exv(fp16) ----------------
__global__ __launch_bounds__(256, 6) void k_intra(
    const unsigned short* __restrict__ zb, const unsigned* __restrict__ uqn,
    const int* __restrict__ knn, const float* __restrict__ cst,
    const float* __restrict__ lpw2, const float* __restrict__ lpb2,
    const float* __restrict__ iw, const float* __restrict__ ib,
    const float* __restrict__ ixw, const float* __restrict__ ixb,
    const unsigned short* __restrict__ h2b, const float* __restrict__ m2w3,
    const float* __restrict__ m2b3,
    const int* __restrict__ posbuf,
    float* __restrict__ x_intra, unsigned* __restrict__ exv)
{
  __shared__ float lpw2sh[192], lpb2sh[64];
  __shared__ float iwsh[512], ixwsh[512];
  __shared__ float ibsh[8], ixbsh[8];
  __shared__ float w3sh[64], b3sh[8], s2sh[8], h2ssh[8];
  const int tid = threadIdx.x;
  if (tid < 192) lpw2sh[tid] = lpw2[tid];
  if (tid < 64) { lpb2sh[tid] = lpb2[tid]; w3sh[tid] = m2w3[tid]; }
  for (int idx = tid; idx < 512; idx += 256) { iwsh[idx] = iw[idx]; ixwsh[idx] = ixw[idx]; }
  if (tid < 8) {
    ibsh[tid] = ib[tid]; ixbsh[tid] = ixb[tid];
    b3sh[tid] = m2b3[tid]; s2sh[tid] = cst[S_M2S2 + tid]; h2ssh[tid] = cst[S_M2H2 + tid];
  }
  __syncthreads();

  const size_t g = (size_t)blockIdx.x * 256 + tid;
  const int j = knn[g];
  const int own = tid & 15;
  const unsigned* zr = (const unsigned*)(zb + (size_t)j * 64);
  const int pos = posbuf[g];

  uint2 uc = *(const uint2*)(uqn + g * 2);
  const float qn0 = lo16(uc.x), qn1 = hi16(uc.x), qn2 = lo16(uc.y);

  // fused k-softmax from bf16 h2
  uint4 hu = *(const uint4*)(h2b + g * 8);
  float hn[8];
  hn[0] = fmaxf(fmaf(__uint_as_float(hu.x << 16),        s2sh[0], h2ssh[0]), 0.f);
  hn[1] = fmaxf(fmaf(__uint_as_float(hu.x & 0xffff0000u), s2sh[1], h2ssh[1]), 0.f);
  hn[2] = fmaxf(fmaf(__uint_as_float(hu.y << 16),        s2sh[2], h2ssh[2]), 0.f);
  hn[3] = fmaxf(fmaf(__uint_as_float(hu.y & 0xffff0000u), s2sh[3], h2ssh[3]), 0.f);
  hn[4] = fmaxf(fmaf(__uint_as_float(hu.z << 16),        s2sh[4], h2ssh[4]), 0.f);
  hn[5] = fmaxf(fmaf(__uint_as_float(hu.z & 0xffff0000u), s2sh[5], h2ssh[5]), 0.f);
  hn[6] = fmaxf(fmaf(__uint_as_float(hu.w << 16),        s2sh[6], h2ssh[6]), 0.f);
  hn[7] = fmaxf(fmaf(__uint_as_float(hu.w & 0xffff0000u), s2sh[7], h2ssh[7]), 0.f);
  float wk[8];
  #pragma unroll
  for (int t = 0; t < 8; ++t) {
    float a = b3sh[t];
    #pragma unroll
    for (int u = 0; u < 8; ++u) a = fmaf(hn[u], w3sh[u * 8 + t], a);
    wk[t] = a;
  }
  #pragma unroll
  for (int t = 0; t < 8; ++t) {
    float m = wk[t];
    m = fmaxf(m, __shfl_xor(m, 1));
    m = fmaxf(m, __shfl_xor(m, 2));
    m = fmaxf(m, __shfl_xor(m, 4));
    m = fmaxf(m, __shfl_xor(m, 8));
    float ex = __expf(wk[t] - m);
    float s = ex;
    s += __shfl_xor(s, 1);
    s += __shfl_xor(s, 2);
    s += __shfl_xor(s, 4);
    s += __shfl_xor(s, 8);
    wk[t] = ex / s;
  }

  float sacc[8], vacc[8];
  #pragma unroll
  for (int t = 0; t < 8; ++t) { sacc[t] = ibsh[t]; vacc[t] = ixbsh[t]; }
  float4 o = make_float4(0.f, 0.f, 0.f, 0.f);
  uint4 zq;
  #pragma unroll
  for (int c = 0; c < 64; c += 4) {
    if ((c & 7) == 0) zq = *(const uint4*)(zr + (c >> 1));
    const unsigned u0 = ((c & 7) == 0) ? zq.x : zq.z;
    const unsigned u1 = ((c & 7) == 0) ? zq.y : zq.w;
    const float z0 = __uint_as_float(u0 << 16);
    const float z1 = __uint_as_float(u0 & 0xffff0000u);
    const float z2 = __uint_as_float(u1 << 16);
    const float z3 = __uint_as_float(u1 & 0xffff0000u);
    float4 l0 = *(const float4*)(lpw2sh + c);
    float4 l1 = *(const float4*)(lpw2sh + 64 + c);
    float4 l2 = *(const float4*)(lpw2sh + 128 + c);
    float4 lb = *(const float4*)(lpb2sh + c);
    float xkv[4];
    xkv[0] = (z0 + fmaf(qn2, l2.x, fmaf(qn1, l1.x, fmaf(qn0, l0.x, lb.x)))) * wk[(c + 0) & 7];
    xkv[1] = (z1 + fmaf(qn2, l2.y, fmaf(qn1, l1.y, fmaf(qn0, l0.y, lb.y)))) * wk[(c + 1) & 7];
    xkv[2] = (z2 + fmaf(qn2, l2.z, fmaf(qn1, l1.z, fmaf(qn0, l0.z, lb.z)))) * wk[(c + 2) & 7];
    xkv[3] = (z3 + fmaf(qn2, l2.w, fmaf(qn1, l1.w, fmaf(qn0, l0.w, lb.w)))) * wk[(c + 3) & 7];
    float r0 = xkv[0], r1 = xkv[1], r2 = xkv[2], r3 = xkv[3];
    #pragma unroll
    for (int m = 1; m < 16; m <<= 1) {
      r0 += __shfl_xor(r0, m);
      r1 += __shfl_xor(r1, m);
      r2 += __shfl_xor(r2, m);
      r3 += __shfl_xor(r3, m);
    }
    if (own == (c >> 2)) o = make_float4(r0, r1, r2, r3);
    #pragma unroll
    for (int d = 0; d < 4; ++d) {
      const float xk = xkv[d];
      const float* iwc = iwsh + (c + d) * 8;
      const float* ixwc = ixwsh + (c + d) * 8;
      float4 a0 = *(const float4*)(iwc);
      float4 a1 = *(const float4*)(iwc + 4);
      float4 b0 = *(const float4*)(ixwc);
      float4 b1 = *(const float4*)(ixwc + 4);
      sacc[0] = fmaf(xk, a0.x, sacc[0]); sacc[1] = fmaf(xk, a0.y, sacc[1]); sacc[2] = fmaf(xk, a0.z, sacc[2]); sacc[3] = fmaf(xk, a0.w, sacc[3]);
      sacc[4] = fmaf(xk, a1.x, sacc[4]); sacc[5] = fmaf(xk, a1.y, sacc[5]); sacc[6] = fmaf(xk, a1.z, sacc[6]); sacc[7] = fmaf(xk, a1.w, sacc[7]);
      vacc[0] = fmaf(xk, b0.x, vacc[0]); vacc[1] = fmaf(xk, b0.y, vacc[1]); vacc[2] = fmaf(xk, b0.z, vacc[2]); vacc[3] = fmaf(xk, b0.w, vacc[3]);
      vacc[4] = fmaf(xk, b1.x, vacc[4]); vacc[5] = fmaf(xk, b1.y, vacc[5]); vacc[6] = fmaf(xk, b1.z, vacc[6]); vacc[7] = fmaf(xk, b1.w, vacc[7]);
    }
  }
  float ex[8];
  #pragma unroll
  for (int t = 0; t < 8; ++t) ex[t] = __expf(sacc[t]);
  uint4 ea, eb;
  ea.x = packh2(ex[0], ex[1]); ea.y = packh2(ex[2], ex[3]);
  ea.z = packh2(ex[4], ex[5]); ea.w = packh2(ex[6], ex[7]);
  eb.x = packh2(ex[0] * vacc[0], ex[1] * vacc[1]);
  eb.y = packh2(ex[2] * vacc[2], ex[3] * vacc[3]);
  eb.z = packh2(ex[4] * vacc[4], ex[5] * vacc[5]);
  eb.w = packh2(ex[6] * vacc[6], ex[7] * vacc[7]);
  *(uint4*)(exv + (size_t)pos * 8) = ea;
  *(uint4*)(exv + (size_t)pos * 8 + 4) = eb;

  const size_t i = g >> 4;
  *(float4*)(x_intra + i * 64 + own * 4) = o;
}

// ---------------- K5: streaming segment reduce (fp16) + x2 + bn2 partials ----------------
__global__ __launch_bounds__(256) void k_inter_x2(
    const int* __restrict__ rowstart, const unsigned* __restrict__ exv,
    float* __restrict__ xi, float* __restrict__ partial)
{
  __shared__ float bsum[64], bsq[64];
  const int tid = threadIdx.x;
  if (tid < 64) { bsum[tid] = 0.f; bsq[tid] = 0.f; }
  __syncthreads();
  const int t = tid & 15;
  const int j = blockIdx.x * 16 + (tid >> 4);
  const int s0 = rowstart[j];
  const int e0 = rowstart[j + 1];
  const unsigned short* eh = (const unsigned short*)exv;
  float acc = 0.f;
  for (int e = s0; e < e0; ++e) acc += h2f(eh[(size_t)e * 16 + t]);
  const float other = __shfl_xor(acc, 8);
  float r = (t < 8) ? ((acc > 0.f) ? other / acc : 0.f)
                    : ((other > 0.f) ? acc / other : 0.f);
  float4 xv = *(const float4*)(xi + (size_t)j * 64 + t * 4);
  float v0 = xv.x + __shfl(r, (4 * t + 0) & 7, 16);
  float v1 = xv.y + __shfl(r, (4 * t + 1) & 7, 16);
  float v2 = xv.z + __shfl(r, (4 * t + 2) & 7, 16);
  float v3 = xv.w + __shfl(r, (4 * t + 3) & 7, 16);
  *(float4*)(xi + (size_t)j * 64 + t * 4) = make_float4(v0, v1, v2, v3);
  float s_[4] = {v0, v1, v2, v3};
  float q_[4] = {v0 * v0, v1 * v1, v2 * v2, v3 * v3};
  #pragma unroll
  for (int d = 0; d < 4; ++d) {
    s_[d] += __shfl_xor(s_[d], 16); s_[d] += __shfl_xor(s_[d], 32);
    q_[d] += __shfl_xor(q_[d], 16); q_[d] += __shfl_xor(q_[d], 32);
  }
  if ((tid & 63) < 16) {
    #pragma unroll
    for (int d = 0; d < 4; ++d) {
      atomicAdd(&bsum[4 * t + d], s_[d]);
      atomicAdd(&bsq[4 * t + d], q_[d]);
    }
  }
  __syncthreads();
  if (tid < 64) {
    partial[(size_t)tid * gridDim.x + blockIdx.x] = bsum[tid];
    partial[(size_t)(tid + 64) * gridDim.x + blockIdx.x] = bsq[tid];
  }
}

// ---------------- K6: final bn3 + residual + relu ----------------
__global__ __launch_bounds__(256) void k_out(
    const float* __restrict__ y3, const float* __restrict__ x0,
    const float* __restrict__ cst, float* __restrict__ out)
{
  __shared__ float scsh[64], shsh[64];
  const int tid = threadIdx.x;
  if (tid < 64) { scsh[tid] = cst[S_SC3 + tid]; shsh[tid] = cst[S_SH3 + tid]; }
  __syncthreads();
  const size_t i = ((size_t)blockIdx.x * 256 + tid) * 4;
  float4 y = *(const float4*)(y3 + i);
  float4 x = *(const float4*)(x0 + i);
  const int c = (int)(i & 63);
  float4 o;
  o.x = fmaxf(fmaf(y.x, scsh[c + 0], shsh[c + 0]) + x.x, 0.f);
  o.y = fmaxf(fmaf(y.y, scsh[c + 1], shsh[c + 1]) + x.y, 0.f);
  o.z = fmaxf(fmaf(y.z, scsh[c + 2], shsh[c + 2]) + x.z, 0.f);
  o.w = fmaxf(fmaf(y.w, scsh[c + 3], shsh[c + 3]) + x.w, 0.f);
  *(float4*)(out + i) = o;
}

// ---------------- launch ----------------
extern "C" void kernel_launch(void* const* d_in, const int* in_sizes, int n_in,
                              void* d_out, int out_size, void* d_ws, size_t ws_size,
                              hipStream_t stream)
{
  (void)n_in; (void)out_size; (void)ws_size;
  const float* p    = (const float*)d_in[0];
  const float* x    = (const float*)d_in[1];
  const int*   knn  = (const int*)d_in[2];
  const float* w1   = (const float*)d_in[3];
  const float* g1   = (const float*)d_in[4];
  const float* b1   = (const float*)d_in[5];
  const float* m1w1 = (const float*)d_in[6];
  const float* m1b1 = (const float*)d_in[7];
  const float* m1w2 = (const float*)d_in[8];
  const float* m1b2 = (const float*)d_in[9];
  const float* lpw1 = (const float*)d_in[10];
  const float* lpb1 = (const float*)d_in[11];
  const float* lpg  = (const float*)d_in[12];
  const float* lpbt = (const float*)d_in[13];
  const float* lpw2 = (const float*)d_in[14];
  const float* lpb2 = (const float*)d_in[15];
  const float* m2w1 = (const float*)d_in[16];
  const float* m2g1 = (const float*)d_in[17];
  const float* m2bt1= (const float*)d_in[18];
  const float* m2w2 = (const float*)d_in[19];
  const float* m2g2 = (const float*)d_in[20];
  const float* m2bt2= (const float*)d_in[21];
  const float* m2w3 = (const float*)d_in[22];
  const float* m2b3 = (const float*)d_in[23];
  const float* m3w  = (const float*)d_in[24];
  const float* m3b  = (const float*)d_in[25];
  const float* iw   = (const float*)d_in[26];
  const float* ib   = (const float*)d_in[27];
  const float* ixw  = (const float*)d_in[28];
  const float* ixb  = (const float*)d_in[29];
  const float* g2   = (const float*)d_in[30];
  const float* b2   = (const float*)d_in[31];
  const float* w3   = (const float*)d_in[32];
  const float* g3   = (const float*)d_in[33];
  const float* b3   = (const float*)d_in[34];
  float* out = (float*)d_out;
  float* ws  = (float*)d_ws;

  const int n = in_sizes[1] / 64;                // 32768
  const long long nk = (long long)n * 16;        // 524288

  float* cst  = ws;
  int* cnt      = (int*)(ws + CONST_FLOATS);    // n ints (zeroed with cst)
  int* rowstart = cnt + n;                      // n+1 ints (+pad)
  int* rank     = rowstart + n + 16;            // nk ints
  int* posb     = rank + nk;                    // nk ints
  unsigned short* zb = (unsigned short*)(posb + nk);  // 64n bf16 = 32n words
  float* y1 = (float*)(zb + 64LL * n);          // 64n, reused as y3
  float* xi = y1 + 64LL * n;                    // 64n
  float* pr = xi + 64LL * n;                    // 48n
  float* y16 = pr + 48LL * n;                   // 16n
  unsigned short* h2b = (unsigned short*)(y16 + 16LL * n);  // 128n ushorts
  unsigned* exv = (unsigned*)(h2b + 128LL * n); // 128n uints

  const int gB   = n / 64;            // 512
  const int nkB  = (int)(nk / 256);   // 2048
  const int nkB2 = (int)(nk / 512);   // 1024
  const int jB   = n / 16;            // 2048

  float* pbn1  = (float*)(exv + 128LL * n);      // 128 * gB
  float* plp   = pbn1 + 128LL * gB;              // 8 * nkB
  float* pmom  = plp + 8LL * nkB;                // 210 * nkB
  float* s2buf = pmom + 210LL * nkB;             // 256
  float* pm2b2 = s2buf + 256;                    // 16 * nkB2
  float* pbn2  = pm2b2 + 16LL * nkB2;            // 128 * jB
  float* pbn3  = pbn2 + 128LL * jB;              // 128 * gB
  unsigned* uq = (unsigned*)(pbn3 + 128LL * gB); // 8 * nk uints
  unsigned* uqn = uq + 8LL * nk;                 // 2 * nk uints

  hipMemsetAsync(d_ws, 0, (size_t)CONST_FLOATS * sizeof(float) + (size_t)n * sizeof(int), stream);

  k_prhist<<<nkB, 256, 0, stream>>>(p, knn, lpw1, lpb1, pr, plp, cnt, rank);
  k_gemm64<<<gB, 256, 0, stream>>>(x, w1, nullptr, nullptr, nullptr, y1, pbn1, n);
  k_scan_mid<<<1, 1024, 0, stream>>>(cnt, rowstart, n, plp, nkB,
                                     lpg, lpbt, lpw1, lpb1, lpw2, lpb2,
                                     m1w2, m2w1, m1b2, cst, 1.f / (float)nk);
  k_rbn<<<64, 256, 0, stream>>>(pbn1, gB, 64, g1, b1, cst + S_SC1, cst + S_SH1, 1.f / (float)n);
  // z(bf16) + y16 in one pass
  k_gemmzy<<<gB, 256, 0, stream>>>(y1, m3w, m3b, m1w1 + 48, cst + S_SC1, cst + S_SH1, zb, y16);
  // h1 BN stats via u-moments; also emits uq/uqn/pos
  k_moment<<<nkB, 256, 0, stream>>>(y16, pr, knn, m1w1, m1b1, cst, rowstart, rank,
                                    pmom, uq, uqn, posb);
  k_mred<<<210, 256, 0, stream>>>(pmom, s2buf, nkB);
  k_mfin<<<1, 64, 0, stream>>>(s2buf, m2g1, m2bt1, cst, 1.f / (float)nk);
  // h2 (bf16) from uq/uqn + stats
  k_h2<<<nkB2, 256, 0, stream>>>(uq, uqn, cst, m2w2, h2b, pm2b2);
  k_rbn<<<8, 256, 0, stream>>>(pm2b2, nkB2, 8, m2g2, m2bt2, cst + S_M2S2, cst + S_M2H2, 1.f / (float)nk);
  // fused softmax + xk + x_intra + exv
  k_intra<<<nkB, 256, 0, stream>>>(zb, uqn, knn, cst, lpw2, lpb2, iw, ib, ixw, ixb,
                                   h2b, m2w3, m2b3, posb, xi, exv);
  // streaming segment reduce + x2 + bn2 partials
  k_inter_x2<<<jB, 256, 0, stream>>>(rowstart, exv, xi, pbn2);
  k_rbn<<<64, 256, 0, stream>>>(pbn2, jB, 64, g2, b2, cst + S_SC2, cst + S_SH2, 1.f / (float)n);
  // y3 = relu(bn2(x2)) @ w3, bn3
  k_gemm64<<<gB, 256, 0, stream>>>(xi, w3, nullptr, cst + S_SC2, cst + S_SH2, y1, pbn3, n);
  k_rbn<<<64, 256, 0, stream>>>(pbn3, gB, 64, g3, b3, cst + S_SC3, cst + S_SH3, 1.f / (float)n);
  // out = relu(bn3(y3) + x)
  k_out<<<(int)((long long)n * 64 / 1024), 256, 0, stream>>>(y1, x, cst, out);
}

// Round 12
// 361.152 us; speedup vs baseline: 1.2451x; 1.2451x over previous
//
#include <hip/hip_runtime.h>

// N = 32768 (runtime), C = 64, K = 16, CS = 8, SHARE = 8

enum {
  S_SC1 = 0,    S_SH1 = 64,
  S_LPSC = 128, S_LPSH = 132,
  S_M2S1 = 136, S_M2H1 = 200,
  S_M2S2 = 264, S_M2H2 = 272,
  S_SC2 = 280,  S_SH2 = 344,
  S_SC3 = 408,  S_SH3 = 472,
  S_LPW2S = 536, S_LPB2S = 584,
  S_QW = 600, S_QB = 612,
  S_G = 640,        // 64x16 c-major
  S_HC = 1664,      // 64x4 c-major
  S_HB = 1920,      // 64
  CONST_FLOATS = 2048
};

__device__ __forceinline__ int pidx(int a, int b) {  // a<=b, 20-dim sym
  return a * 20 - (a * (a - 1)) / 2 + (b - a);
}
__device__ __forceinline__ unsigned short bf16r(float f) {
  unsigned u = __float_as_uint(f);
  u = u + 0x7fffu + ((u >> 16) & 1u);
  return (unsigned short)(u >> 16);
}
__device__ __forceinline__ unsigned short f2h(float f) {
  _Float16 h = (_Float16)f;
  unsigned short u;
  __builtin_memcpy(&u, &h, 2);
  return u;
}
__device__ __forceinline__ float h2f(unsigned short u) {
  _Float16 h;
  __builtin_memcpy(&h, &u, 2);
  return (float)h;
}
__device__ __forceinline__ unsigned packh2(float a, float b) {
  return (unsigned)f2h(a) | ((unsigned)f2h(b) << 16);
}
__device__ __forceinline__ float lo16(unsigned u) { return h2f((unsigned short)(u & 0xffffu)); }
__device__ __forceinline__ float hi16(unsigned u) { return h2f((unsigned short)(u >> 16)); }

// ---------------- fused partial-reduce + BN finalize ----------------
__global__ __launch_bounds__(256) void k_rbn(
    const float* __restrict__ partial, int nb, int nch,
    const float* __restrict__ g, const float* __restrict__ b,
    float* __restrict__ scale, float* __restrict__ shift, float inv_count)
{
  const int c = blockIdx.x;
  const int tid = threadIdx.x;
  float s = 0.f, q = 0.f;
  for (int i = tid; i < nb; i += 256) {
    s += partial[(size_t)c * nb + i];
    q += partial[(size_t)(c + nch) * nb + i];
  }
  #pragma unroll
  for (int m = 1; m < 64; m <<= 1) { s += __shfl_xor(s, m); q += __shfl_xor(q, m); }
  __shared__ float ws[4], wq[4];
  if ((tid & 63) == 0) { ws[tid >> 6] = s; wq[tid >> 6] = q; }
  __syncthreads();
  if (tid == 0) {
    float S = ws[0] + ws[1] + ws[2] + ws[3];
    float Q = wq[0] + wq[1] + wq[2] + wq[3];
    float m = S * inv_count;
    float v = Q * inv_count - m * m;
    float rs = rsqrtf(v + 1e-5f);
    float sc = g[c] * rs;
    scale[c] = sc;
    shift[c] = fmaf(-m, sc, b[c]);
  }
}

// ---------------- generic 64x64 GEMM (f32 out) ----------------
__global__ __launch_bounds__(256) void k_gemm64(
    const float* __restrict__ in, const float* __restrict__ w,
    const float* __restrict__ bias,
    const float* __restrict__ sc, const float* __restrict__ sh,
    float* __restrict__ out,
    float* __restrict__ partial, int n)
{
  __shared__ float scsh[64], shsh[64];
  __shared__ float bsum[64], bsq[64];
  const int tid = threadIdx.x;
  const int lane = tid & 63;
  const int wave = tid >> 6;
  if (sc != nullptr && tid < 64) { scsh[tid] = sc[tid]; shsh[tid] = sh[tid]; }
  if (tid < 64) { bsum[tid] = 0.f; bsq[tid] = 0.f; }
  __syncthreads();

  float wreg[64];
  #pragma unroll
  for (int k = 0; k < 64; ++k) wreg[k] = w[k * 64 + lane];
  const float bz = bias ? bias[lane] : 0.f;

  float lsum = 0.f, lsq = 0.f;
  const int row0 = (blockIdx.x * 4 + wave) * 16;
  for (int r = 0; r < 16; ++r) {
    const int row = row0 + r;
    const float* xr = in + (size_t)row * 64;
    float acc = bz;
    if (sc != nullptr) {
      #pragma unroll
      for (int k = 0; k < 64; k += 4) {
        float4 xv = *(const float4*)(xr + k);
        float x0 = fmaxf(fmaf(xv.x, scsh[k + 0], shsh[k + 0]), 0.f);
        float x1 = fmaxf(fmaf(xv.y, scsh[k + 1], shsh[k + 1]), 0.f);
        float x2 = fmaxf(fmaf(xv.z, scsh[k + 2], shsh[k + 2]), 0.f);
        float x3 = fmaxf(fmaf(xv.w, scsh[k + 3], shsh[k + 3]), 0.f);
        acc = fmaf(x0, wreg[k + 0], acc);
        acc = fmaf(x1, wreg[k + 1], acc);
        acc = fmaf(x2, wreg[k + 2], acc);
        acc = fmaf(x3, wreg[k + 3], acc);
      }
    } else {
      #pragma unroll
      for (int k = 0; k < 64; k += 4) {
        float4 xv = *(const float4*)(xr + k);
        acc = fmaf(xv.x, wreg[k + 0], acc);
        acc = fmaf(xv.y, wreg[k + 1], acc);
        acc = fmaf(xv.z, wreg[k + 2], acc);
        acc = fmaf(xv.w, wreg[k + 3], acc);
      }
    }
    out[(size_t)row * 64 + lane] = acc;
    lsum += acc;
    lsq = fmaf(acc, acc, lsq);
  }
  if (partial != nullptr) {
    atomicAdd(&bsum[lane], lsum);
    atomicAdd(&bsq[lane], lsq);
    __syncthreads();
    if (tid < 64) {
      partial[(size_t)tid * gridDim.x + blockIdx.x] = bsum[tid];
      partial[(size_t)(tid + 64) * gridDim.x + blockIdx.x] = bsq[tid];
    }
  }
}

// ---------------- fused: z (bf16) = nr(y1)@m3w+m3b ; y16 = nr(y1)@m1w1[3:] ----------------
__global__ __launch_bounds__(256) void k_gemmzy(
    const float* __restrict__ in, const float* __restrict__ w,
    const float* __restrict__ bias, const float* __restrict__ w16,
    const float* __restrict__ sc, const float* __restrict__ sh,
    unsigned short* __restrict__ outz, float* __restrict__ out16)
{
  __shared__ float xn[64][68];
  __shared__ float w16sh[1024];
  __shared__ float scsh[64], shsh[64];
  const int tid = threadIdx.x;
  if (tid < 64) { scsh[tid] = sc[tid]; shsh[tid] = sh[tid]; }
  for (int i2 = tid; i2 < 1024; i2 += 256) w16sh[i2] = w16[i2];
  __syncthreads();
  const int row0 = blockIdx.x * 64;
  for (int idx = tid; idx < 4096; idx += 256) {
    int r = idx >> 6, c = idx & 63;
    float v = in[(size_t)(row0 + r) * 64 + c];
    xn[r][c] = fmaxf(fmaf(v, scsh[c], shsh[c]), 0.f);
  }
  __syncthreads();

  const int lane = tid & 63;
  const int wave = tid >> 6;
  float wreg[64];
  #pragma unroll
  for (int k = 0; k < 64; ++k) wreg[k] = w[k * 64 + lane];
  const float bz = bias[lane];
  for (int r = wave * 16; r < wave * 16 + 16; ++r) {
    float acc = bz;
    #pragma unroll
    for (int k = 0; k < 64; k += 4) {
      float4 xv = *(const float4*)(&xn[r][k]);
      acc = fmaf(xv.x, wreg[k + 0], acc);
      acc = fmaf(xv.y, wreg[k + 1], acc);
      acc = fmaf(xv.z, wreg[k + 2], acc);
      acc = fmaf(xv.w, wreg[k + 3], acc);
    }
    outz[(size_t)(row0 + r) * 64 + lane] = bf16r(acc);
  }
  for (int idx = tid; idx < 1024; idx += 256) {
    int r = idx >> 4, t = idx & 15;
    float acc = 0.f;
    #pragma unroll
    for (int c = 0; c < 64; c += 4) {
      float4 xv = *(const float4*)(&xn[r][c]);
      acc = fmaf(xv.x, w16sh[(c + 0) * 16 + t], acc);
      acc = fmaf(xv.y, w16sh[(c + 1) * 16 + t], acc);
      acc = fmaf(xv.z, w16sh[(c + 2) * 16 + t], acc);
      acc = fmaf(xv.w, w16sh[(c + 3) * 16 + t], acc);
    }
    out16[(size_t)(row0 + r) * 16 + t] = acc;
  }
}

// ---------------- K1: p_r, lp partials, histogram + rank ----------------
__global__ __launch_bounds__(256) void k_prhist(
    const float* __restrict__ p, const int* __restrict__ knn,
    const float* __restrict__ lpw1, const float* __restrict__ lpb1,
    float* __restrict__ p_r, float* __restrict__ plp,
    int* __restrict__ cnt, int* __restrict__ rank)
{
  __shared__ float lpw1sh[9], lpb1sh[3];
  __shared__ float lpsh[4][8];
  const int tid = threadIdx.x;
  if (tid < 9) lpw1sh[tid] = lpw1[tid];
  if (tid < 3) lpb1sh[tid] = lpb1[tid];
  __syncthreads();

  const size_t g = (size_t)blockIdx.x * 256 + tid;
  const int i = (int)(g >> 4);
  const int j = knn[g];
  const float pr0 = p[j * 3 + 0] - p[i * 3 + 0];
  const float pr1 = p[j * 3 + 1] - p[i * 3 + 1];
  const float pr2 = p[j * 3 + 2] - p[i * 3 + 2];
  p_r[g * 3 + 0] = pr0; p_r[g * 3 + 1] = pr1; p_r[g * 3 + 2] = pr2;
  rank[g] = atomicAdd(&cnt[j], 1);

  float q0 = fmaf(pr2, lpw1sh[6], fmaf(pr1, lpw1sh[3], fmaf(pr0, lpw1sh[0], lpb1sh[0])));
  float q1 = fmaf(pr2, lpw1sh[7], fmaf(pr1, lpw1sh[4], fmaf(pr0, lpw1sh[1], lpb1sh[1])));
  float q2 = fmaf(pr2, lpw1sh[8], fmaf(pr1, lpw1sh[5], fmaf(pr0, lpw1sh[2], lpb1sh[2])));
  float s0 = q0, s1 = q1, s2 = q2, qq0 = q0 * q0, qq1 = q1 * q1, qq2 = q2 * q2;
  #pragma unroll
  for (int m = 1; m < 64; m <<= 1) {
    s0 += __shfl_xor(s0, m); s1 += __shfl_xor(s1, m); s2 += __shfl_xor(s2, m);
    qq0 += __shfl_xor(qq0, m); qq1 += __shfl_xor(qq1, m); qq2 += __shfl_xor(qq2, m);
  }
  if ((tid & 63) == 0) {
    const int w = tid >> 6;
    lpsh[w][0] = s0; lpsh[w][1] = s1; lpsh[w][2] = s2; lpsh[w][3] = 0.f;
    lpsh[w][4] = qq0; lpsh[w][5] = qq1; lpsh[w][6] = qq2; lpsh[w][7] = 0.f;
  }
  __syncthreads();
  if (tid < 8) {
    float v = lpsh[0][tid] + lpsh[1][tid] + lpsh[2][tid] + lpsh[3][tid];
    plp[(size_t)tid * gridDim.x + blockIdx.x] = v;
  }
}

// ---------------- merged: CSR scan + lp finalize + weight folding ----------------
__global__ __launch_bounds__(1024) void k_scan_mid(
    const int* __restrict__ cnt, int* __restrict__ rowstart, int n,
    const float* __restrict__ plp, int nbplp,
    const float* __restrict__ lpg, const float* __restrict__ lpbt,
    const float* __restrict__ lpw1, const float* __restrict__ lpb1,
    const float* __restrict__ lpw2, const float* __restrict__ lpb2,
    const float* __restrict__ m1w2, const float* __restrict__ m2w1,
    const float* __restrict__ m1b2,
    float* __restrict__ cst, float inv_count)
{
  __shared__ int tsum[1024];
  __shared__ float Ssh[8];
  const int tid = threadIdx.x;
  const int per = n >> 10;
  const int base = tid * per;
  int local[32];
  int s = 0;
  for (int u = 0; u < per; ++u) { local[u] = cnt[base + u]; s += local[u]; }
  tsum[tid] = s;
  __syncthreads();
  for (int off = 1; off < 1024; off <<= 1) {
    int v = (tid >= off) ? tsum[tid - off] : 0;
    __syncthreads();
    tsum[tid] += v;
    __syncthreads();
  }
  int run = tsum[tid] - s;
  for (int u = 0; u < per; ++u) { rowstart[base + u] = run; run += local[u]; }
  if (tid == 1023) rowstart[n] = run;

  if (tid < 256) {
    const int row = tid >> 5, l32 = tid & 31;
    float ls = 0.f;
    for (int i = l32; i < nbplp; i += 32) ls += plp[(size_t)row * nbplp + i];
    #pragma unroll
    for (int m = 1; m < 32; m <<= 1) ls += __shfl_xor(ls, m);
    if (l32 == 0) Ssh[row] = ls;
  }
  __syncthreads();
  if (tid < 3) {
    float m = Ssh[tid] * inv_count;
    float v = Ssh[4 + tid] * inv_count - m * m;
    float rs = rsqrtf(v + 1e-5f);
    float sc = lpg[tid] * rs;
    cst[S_LPSC + tid] = sc;
    cst[S_LPSH + tid] = fmaf(-m, sc, lpbt[tid]);
  }
  __syncthreads();
  if (tid < 9)  cst[S_QW + tid] = lpw1[tid] * cst[S_LPSC + (tid % 3)];
  if (tid < 3)  cst[S_QB + tid] = fmaf(lpb1[tid], cst[S_LPSC + tid], cst[S_LPSH + tid]);
  if (tid < 16) {
    float b = 0.f;
    for (int c2 = 0; c2 < 4; ++c2) b += lpb2[c2 * 16 + tid];
    cst[S_LPB2S + tid] = b;
    for (int r = 0; r < 3; ++r) {
      float w = 0.f;
      for (int c2 = 0; c2 < 4; ++c2) w += lpw2[r * 64 + c2 * 16 + tid];
      cst[S_LPW2S + r * 16 + tid] = w;
    }
  }
  __syncthreads();
  if (tid < 256) {
    #pragma unroll
    for (int q = 0; q < 4; ++q) {
      int ee = tid * 4 + q;
      int c = ee >> 4, u = ee & 15;
      float sg = 0.f;
      #pragma unroll
      for (int t = 0; t < 16; ++t) sg = fmaf(m1w2[u * 16 + t], m2w1[t * 64 + c], sg);
      cst[S_G + c * 16 + u] = sg;
    }
  }
  if (tid < 192) {
    int c = tid / 3, r = tid - c * 3;
    float sh = 0.f;
    #pragma unroll
    for (int t = 0; t < 16; ++t) sh = fmaf(cst[S_LPW2S + r * 16 + t], m2w1[(16 + t) * 64 + c], sh);
    cst[S_HC + c * 4 + r] = sh;
  }
  if (tid < 64) {
    cst[S_HC + tid * 4 + 3] = 0.f;
    float sb = 0.f;
    #pragma unroll
    for (int t = 0; t < 16; ++t) {
      sb = fmaf(m1b2[t], m2w1[t * 64 + tid], sb);
      sb = fmaf(cst[S_LPB2S + t], m2w1[(16 + t) * 64 + tid], sb);
    }
    cst[S_HB + tid] = sb;
  }
}

// ---------------- K2: u-moment accumulation + uq/uqn/pos store ----------------
__global__ __launch_bounds__(256) void k_moment(
    const float* __restrict__ y16, const float* __restrict__ p_r,
    const int* __restrict__ knn, const float* __restrict__ m1w1,
    const float* __restrict__ m1b1, const float* __restrict__ cst,
    const int* __restrict__ rowstart, const int* __restrict__ rank,
    float* __restrict__ pmom,   // [210 * gridDim.x] channel-major
    unsigned* __restrict__ uq,  // [nk * 8] packed fp16 t1[16]
    unsigned* __restrict__ uqn, // [nk * 2] packed fp16 qn[3]
    int* __restrict__ posbuf)   // [nk]
{
  __shared__ float ush[256 * 21];
  const int tid = threadIdx.x;
  const size_t g = (size_t)blockIdx.x * 256 + tid;
  const int j = knn[g];
  const float pr0 = p_r[g * 3 + 0], pr1 = p_r[g * 3 + 1], pr2 = p_r[g * 3 + 2];
  const float* yj = y16 + (size_t)j * 16;
  float4 ya = *(const float4*)(yj);
  float4 yb = *(const float4*)(yj + 4);
  float4 yc = *(const float4*)(yj + 8);
  float4 yd = *(const float4*)(yj + 12);
  float t1[16] = {ya.x, ya.y, ya.z, ya.w, yb.x, yb.y, yb.z, yb.w,
                  yc.x, yc.y, yc.z, yc.w, yd.x, yd.y, yd.z, yd.w};
  #pragma unroll
  for (int u = 0; u < 16; ++u)
    t1[u] = fmaxf(fmaf(pr2, m1w1[32 + u], fmaf(pr1, m1w1[16 + u],
                  fmaf(pr0, m1w1[u], t1[u] + m1b1[u]))), 0.f);
  const float qn0 = fmaxf(fmaf(pr2, cst[S_QW + 6], fmaf(pr1, cst[S_QW + 3], fmaf(pr0, cst[S_QW + 0], cst[S_QB + 0]))), 0.f);
  const float qn1 = fmaxf(fmaf(pr2, cst[S_QW + 7], fmaf(pr1, cst[S_QW + 4], fmaf(pr0, cst[S_QW + 1], cst[S_QB + 1]))), 0.f);
  const float qn2 = fmaxf(fmaf(pr2, cst[S_QW + 8], fmaf(pr1, cst[S_QW + 5], fmaf(pr0, cst[S_QW + 2], cst[S_QB + 2]))), 0.f);

  posbuf[g] = rowstart[j] + rank[g];

  uint4 ua, ub;
  ua.x = packh2(t1[0], t1[1]);   ua.y = packh2(t1[2], t1[3]);
  ua.z = packh2(t1[4], t1[5]);   ua.w = packh2(t1[6], t1[7]);
  ub.x = packh2(t1[8], t1[9]);   ub.y = packh2(t1[10], t1[11]);
  ub.z = packh2(t1[12], t1[13]); ub.w = packh2(t1[14], t1[15]);
  *(uint4*)(uq + g * 8)     = ua;
  *(uint4*)(uq + g * 8 + 4) = ub;
  uint2 uc;
  uc.x = packh2(qn0, qn1);
  uc.y = packh2(qn2, 0.f);
  *(uint2*)(uqn + g * 2) = uc;

  float* ur = ush + tid * 21;
  #pragma unroll
  for (int u = 0; u < 16; ++u) ur[u] = t1[u];
  ur[16] = qn0; ur[17] = qn1; ur[18] = qn2; ur[19] = 1.f;
  __syncthreads();

  if (tid < 210) {
    int a = 0, t = tid;
    while (t >= 20 - a) { t -= 20 - a; ++a; }
    const int b = a + t;
    float s = 0.f;
    for (int it = 0; it < 256; ++it) {
      const int r = (it + tid) & 255;
      const float* u = ush + r * 21;
      s = fmaf(u[a], u[b], s);
    }
    pmom[(size_t)tid * gridDim.x + blockIdx.x] = s;
  }
}

// ---------------- parallel moment reduce ----------------
__global__ __launch_bounds__(256) void k_mred(
    const float* __restrict__ pmom, float* __restrict__ S2, int nb)
{
  const int c = blockIdx.x;
  const int tid = threadIdx.x;
  float s = 0.f;
  for (int i = tid; i < nb; i += 256) s += pmom[(size_t)c * nb + i];
  #pragma unroll
  for (int m = 1; m < 64; m <<= 1) s += __shfl_xor(s, m);
  __shared__ float ws[4];
  if ((tid & 63) == 0) ws[tid >> 6] = s;
  __syncthreads();
  if (tid == 0) S2[c] = ws[0] + ws[1] + ws[2] + ws[3];
}

// ---------------- moment finalize ----------------
__global__ __launch_bounds__(64) void k_mfin(
    const float* __restrict__ S2in,
    const float* __restrict__ g, const float* __restrict__ b,
    float* __restrict__ cst, float inv_count)
{
  __shared__ float S2[210];
  const int tid = threadIdx.x;
  for (int i = tid; i < 210; i += 64) S2[i] = S2in[i];
  __syncthreads();
  const int c = tid;
  float w[20];
  #pragma unroll
  for (int u = 0; u < 16; ++u) w[u] = cst[S_G + c * 16 + u];
  w[16] = cst[S_HC + c * 4 + 0];
  w[17] = cst[S_HC + c * 4 + 1];
  w[18] = cst[S_HC + c * 4 + 2];
  w[19] = cst[S_HB + c];
  float m2 = 0.f, m1 = 0.f;
  for (int a = 0; a < 20; ++a) {
    const float wa = w[a];
    m2 = fmaf(wa * wa, S2[pidx(a, a)], m2);
    float cross = 0.f;
    for (int bb = a + 1; bb < 20; ++bb) cross = fmaf(w[bb], S2[pidx(a, bb)], cross);
    m2 = fmaf(2.f * wa, cross, m2);
    m1 = fmaf(wa, S2[pidx(a, 19)], m1);
  }
  const float mean = m1 * inv_count;
  const float var = m2 * inv_count - mean * mean;
  const float rs = rsqrtf(var + 1e-5f);
  const float sc = g[c] * rs;
  cst[S_M2S1 + c] = sc;
  cst[S_M2H1 + c] = fmaf(-mean, sc, b[c]);
}

// ---------------- K3: h2(bf16) from packed uq/uqn via folded G/H ----------------
__global__ __launch_bounds__(256) void k_h2(
    const unsigned* __restrict__ uq, const unsigned* __restrict__ uqn,
    const float* __restrict__ cst, const float* __restrict__ m2w2,
    unsigned short* __restrict__ h2out,
    float* __restrict__ partial)   // [16 * gridDim.x]
{
  __shared__ float Gsh[1024], Hsh[256], hbsh[64];
  __shared__ float w2m[512];
  __shared__ float scsh[64], shsh[64];
  __shared__ float redsh[4][16];
  const int tid = threadIdx.x;
  for (int i = tid; i < 1024; i += 256) Gsh[i] = cst[S_G + i];
  Hsh[tid] = cst[S_HC + tid];
  for (int i = tid; i < 512; i += 256) w2m[i] = m2w2[i];
  if (tid < 64) { hbsh[tid] = cst[S_HB + tid]; scsh[tid] = cst[S_M2S1 + tid]; shsh[tid] = cst[S_M2H1 + tid]; }
  __syncthreads();

  const size_t g0 = ((size_t)blockIdx.x * 256 + tid) * 2;
  float t1[2][16], qn[2][3];
  #pragma unroll
  for (int gg = 0; gg < 2; ++gg) {
    const size_t g = g0 + gg;
    uint4 ua = *(const uint4*)(uq + g * 8);
    uint4 ub = *(const uint4*)(uq + g * 8 + 4);
    uint2 uc = *(const uint2*)(uqn + g * 2);
    t1[gg][0] = lo16(ua.x);  t1[gg][1] = hi16(ua.x);
    t1[gg][2] = lo16(ua.y);  t1[gg][3] = hi16(ua.y);
    t1[gg][4] = lo16(ua.z);  t1[gg][5] = hi16(ua.z);
    t1[gg][6] = lo16(ua.w);  t1[gg][7] = hi16(ua.w);
    t1[gg][8] = lo16(ub.x);  t1[gg][9] = hi16(ub.x);
    t1[gg][10] = lo16(ub.y); t1[gg][11] = hi16(ub.y);
    t1[gg][12] = lo16(ub.z); t1[gg][13] = hi16(ub.z);
    t1[gg][14] = lo16(ub.w); t1[gg][15] = hi16(ub.w);
    qn[gg][0] = lo16(uc.x); qn[gg][1] = hi16(uc.x); qn[gg][2] = lo16(uc.y);
  }

  float a0[8], a1[8];
  #pragma unroll
  for (int t = 0; t < 8; ++t) { a0[t] = 0.f; a1[t] = 0.f; }
  for (int c = 0; c < 64; ++c) {
    float4 g0v = *(const float4*)(Gsh + c * 16);
    float4 g1v = *(const float4*)(Gsh + c * 16 + 4);
    float4 g2v = *(const float4*)(Gsh + c * 16 + 8);
    float4 g3v = *(const float4*)(Gsh + c * 16 + 12);
    float4 hv = *(const float4*)(Hsh + c * 4);
    float h_0 = hbsh[c], h_1 = hbsh[c];
    h_0 = fmaf(t1[0][0], g0v.x, h_0); h_0 = fmaf(t1[0][1], g0v.y, h_0); h_0 = fmaf(t1[0][2], g0v.z, h_0); h_0 = fmaf(t1[0][3], g0v.w, h_0);
    h_0 = fmaf(t1[0][4], g1v.x, h_0); h_0 = fmaf(t1[0][5], g1v.y, h_0); h_0 = fmaf(t1[0][6], g1v.z, h_0); h_0 = fmaf(t1[0][7], g1v.w, h_0);
    h_0 = fmaf(t1[0][8], g2v.x, h_0); h_0 = fmaf(t1[0][9], g2v.y, h_0); h_0 = fmaf(t1[0][10], g2v.z, h_0); h_0 = fmaf(t1[0][11], g2v.w, h_0);
    h_0 = fmaf(t1[0][12], g3v.x, h_0); h_0 = fmaf(t1[0][13], g3v.y, h_0); h_0 = fmaf(t1[0][14], g3v.z, h_0); h_0 = fmaf(t1[0][15], g3v.w, h_0);
    h_0 = fmaf(qn[0][0], hv.x, fmaf(qn[0][1], hv.y, fmaf(qn[0][2], hv.z, h_0)));
    h_1 = fmaf(t1[1][0], g0v.x, h_1); h_1 = fmaf(t1[1][1], g0v.y, h_1); h_1 = fmaf(t1[1][2], g0v.z, h_1); h_1 = fmaf(t1[1][3], g0v.w, h_1);
    h_1 = fmaf(t1[1][4], g1v.x, h_1); h_1 = fmaf(t1[1][5], g1v.y, h_1); h_1 = fmaf(t1[1][6], g1v.z, h_1); h_1 = fmaf(t1[1][7], g1v.w, h_1);
    h_1 = fmaf(t1[1][8], g2v.x, h_1); h_1 = fmaf(t1[1][9], g2v.y, h_1); h_1 = fmaf(t1[1][10], g2v.z, h_1); h_1 = fmaf(t1[1][11], g2v.w, h_1);
    h_1 = fmaf(t1[1][12], g3v.x, h_1); h_1 = fmaf(t1[1][13], g3v.y, h_1); h_1 = fmaf(t1[1][14], g3v.z, h_1); h_1 = fmaf(t1[1][15], g3v.w, h_1);
    h_1 = fmaf(qn[1][0], hv.x, fmaf(qn[1][1], hv.y, fmaf(qn[1][2], hv.z, h_1)));
    float x0 = fmaxf(fmaf(h_0, scsh[c], shsh[c]), 0.f);
    float x1 = fmaxf(fmaf(h_1, scsh[c], shsh[c]), 0.f);
    float4 wa = *(const float4*)(w2m + c * 8);
    float4 wb = *(const float4*)(w2m + c * 8 + 4);
    a0[0] = fmaf(x0, wa.x, a0[0]); a0[1] = fmaf(x0, wa.y, a0[1]); a0[2] = fmaf(x0, wa.z, a0[2]); a0[3] = fmaf(x0, wa.w, a0[3]);
    a0[4] = fmaf(x0, wb.x, a0[4]); a0[5] = fmaf(x0, wb.y, a0[5]); a0[6] = fmaf(x0, wb.z, a0[6]); a0[7] = fmaf(x0, wb.w, a0[7]);
    a1[0] = fmaf(x1, wa.x, a1[0]); a1[1] = fmaf(x1, wa.y, a1[1]); a1[2] = fmaf(x1, wa.z, a1[2]); a1[3] = fmaf(x1, wa.w, a1[3]);
    a1[4] = fmaf(x1, wb.x, a1[4]); a1[5] = fmaf(x1, wb.y, a1[5]); a1[6] = fmaf(x1, wb.z, a1[6]); a1[7] = fmaf(x1, wb.w, a1[7]);
  }
  uint4 pa, pb;
  pa.x = bf16r(a0[0]) | ((unsigned)bf16r(a0[1]) << 16);
  pa.y = bf16r(a0[2]) | ((unsigned)bf16r(a0[3]) << 16);
  pa.z = bf16r(a0[4]) | ((unsigned)bf16r(a0[5]) << 16);
  pa.w = bf16r(a0[6]) | ((unsigned)bf16r(a0[7]) << 16);
  pb.x = bf16r(a1[0]) | ((unsigned)bf16r(a1[1]) << 16);
  pb.y = bf16r(a1[2]) | ((unsigned)bf16r(a1[3]) << 16);
  pb.z = bf16r(a1[4]) | ((unsigned)bf16r(a1[5]) << 16);
  pb.w = bf16r(a1[6]) | ((unsigned)bf16r(a1[7]) << 16);
  *(uint4*)(h2out + g0 * 8) = pa;
  *(uint4*)(h2out + g0 * 8 + 8) = pb;

  float st[8], sq[8];
  #pragma unroll
  for (int t = 0; t < 8; ++t) {
    st[t] = a0[t] + a1[t];
    sq[t] = fmaf(a0[t], a0[t], a1[t] * a1[t]);
  }
  #pragma unroll
  for (int m = 1; m < 64; m <<= 1) {
    #pragma unroll
    for (int t = 0; t < 8; ++t) { st[t] += __shfl_xor(st[t], m); sq[t] += __shfl_xor(sq[t], m); }
  }
  if ((tid & 63) == 0) {
    const int w = tid >> 6;
    #pragma unroll
    for (int t = 0; t < 8; ++t) { redsh[w][t] = st[t]; redsh[w][8 + t] = sq[t]; }
  }
  __syncthreads();
  if (tid < 16) {
    float v = redsh[0][tid] + redsh[1][tid] + redsh[2][tid] + redsh[3][tid];
    partial[(size_t)tid * gridDim.x + blockIdx.x] = v;
  }
}

// ---------------- K4: fused softmax + xk + x_intra + exv(fp16) ----------------
__global__ __launch_bounds__(256) void k_intra(
    const unsigned short* __restrict__ zb, const unsigned* __restrict__ uqn,
    const int* __restrict__ knn, const float* __restrict__ cst,
    const float* __restrict__ lpw2, const float* __restrict__ lpb2,
    const float* __restrict__ iw, const float* __restrict__ ib,
    const float* __restrict__ ixw, const float* __restrict__ ixb,
    const unsigned short* __restrict__ h2b, const float* __restrict__ m2w3,
    const float* __restrict__ m2b3,
    const int* __restrict__ posbuf,
    float* __restrict__ x_intra, unsigned* __restrict__ exv)
{
  __shared__ float lpw2sh[192], lpb2sh[64];
  __shared__ float iwsh[512], ixwsh[512];
  __shared__ float ibsh[8], ixbsh[8];
  __shared__ float w3sh[64], b3sh[8], s2sh[8], h2ssh[8];
  const int tid = threadIdx.x;
  if (tid < 192) lpw2sh[tid] = lpw2[tid];
  if (tid < 64) { lpb2sh[tid] = lpb2[tid]; w3sh[tid] = m2w3[tid]; }
  for (int idx = tid; idx < 512; idx += 256) { iwsh[idx] = iw[idx]; ixwsh[idx] = ixw[idx]; }
  if (tid < 8) {
    ibsh[tid] = ib[tid]; ixbsh[tid] = ixb[tid];
    b3sh[tid] = m2b3[tid]; s2sh[tid] = cst[S_M2S2 + tid]; h2ssh[tid] = cst[S_M2H2 + tid];
  }
  __syncthreads();

  const size_t g = (size_t)blockIdx.x * 256 + tid;
  const int j = knn[g];
  const int own = tid & 15;
  const unsigned* zr = (const unsigned*)(zb + (size_t)j * 64);
  const int pos = posbuf[g];

  uint2 uc = *(const uint2*)(uqn + g * 2);
  const float qn0 = lo16(uc.x), qn1 = hi16(uc.x), qn2 = lo16(uc.y);

  // fused k-softmax from bf16 h2
  uint4 hu = *(const uint4*)(h2b + g * 8);
  float hn[8];
  hn[0] = fmaxf(fmaf(__uint_as_float(hu.x << 16),        s2sh[0], h2ssh[0]), 0.f);
  hn[1] = fmaxf(fmaf(__uint_as_float(hu.x & 0xffff0000u), s2sh[1], h2ssh[1]), 0.f);
  hn[2] = fmaxf(fmaf(__uint_as_float(hu.y << 16),        s2sh[2], h2ssh[2]), 0.f);
  hn[3] = fmaxf(fmaf(__uint_as_float(hu.y & 0xffff0000u), s2sh[3], h2ssh[3]), 0.f);
  hn[4] = fmaxf(fmaf(__uint_as_float(hu.z << 16),        s2sh[4], h2ssh[4]), 0.f);
  hn[5] = fmaxf(fmaf(__uint_as_float(hu.z & 0xffff0000u), s2sh[5], h2ssh[5]), 0.f);
  hn[6] = fmaxf(fmaf(__uint_as_float(hu.w << 16),        s2sh[6], h2ssh[6]), 0.f);
  hn[7] = fmaxf(fmaf(__uint_as_float(hu.w & 0xffff0000u), s2sh[7], h2ssh[7]), 0.f);
  float wk[8];
  #pragma unroll
  for (int t = 0; t < 8; ++t) {
    float a = b3sh[t];
    #pragma unroll
    for (int u = 0; u < 8; ++u) a = fmaf(hn[u], w3sh[u * 8 + t], a);
    wk[t] = a;
  }
  #pragma unroll
  for (int t = 0; t < 8; ++t) {
    float m = wk[t];
    m = fmaxf(m, __shfl_xor(m, 1));
    m = fmaxf(m, __shfl_xor(m, 2));
    m = fmaxf(m, __shfl_xor(m, 4));
    m = fmaxf(m, __shfl_xor(m, 8));
    float ex = __expf(wk[t] - m);
    float s = ex;
    s += __shfl_xor(s, 1);
    s += __shfl_xor(s, 2);
    s += __shfl_xor(s, 4);
    s += __shfl_xor(s, 8);
    wk[t] = ex / s;
  }

  float sacc[8], vacc[8];
  #pragma unroll
  for (int t = 0; t < 8; ++t) { sacc[t] = ibsh[t]; vacc[t] = ixbsh[t]; }
  float4 o = make_float4(0.f, 0.f, 0.f, 0.f);
  uint4 zq;
  #pragma unroll
  for (int c = 0; c < 64; c += 4) {
    if ((c & 7) == 0) zq = *(const uint4*)(zr + (c >> 1));
    const unsigned u0 = ((c & 7) == 0) ? zq.x : zq.z;
    const unsigned u1 = ((c & 7) == 0) ? zq.y : zq.w;
    const float z0 = __uint_as_float(u0 << 16);
    const float z1 = __uint_as_float(u0 & 0xffff0000u);
    const float z2 = __uint_as_float(u1 << 16);
    const float z3 = __uint_as_float(u1 & 0xffff0000u);
    float4 l0 = *(const float4*)(lpw2sh + c);
    float4 l1 = *(const float4*)(lpw2sh + 64 + c);
    float4 l2 = *(const float4*)(lpw2sh + 128 + c);
    float4 lb = *(const float4*)(lpb2sh + c);
    float xkv[4];
    xkv[0] = (z0 + fmaf(qn2, l2.x, fmaf(qn1, l1.x, fmaf(qn0, l0.x, lb.x)))) * wk[(c + 0) & 7];
    xkv[1] = (z1 + fmaf(qn2, l2.y, fmaf(qn1, l1.y, fmaf(qn0, l0.y, lb.y)))) * wk[(c + 1) & 7];
    xkv[2] = (z2 + fmaf(qn2, l2.z, fmaf(qn1, l1.z, fmaf(qn0, l0.z, lb.z)))) * wk[(c + 2) & 7];
    xkv[3] = (z3 + fmaf(qn2, l2.w, fmaf(qn1, l1.w, fmaf(qn0, l0.w, lb.w)))) * wk[(c + 3) & 7];
    float r0 = xkv[0], r1 = xkv[1], r2 = xkv[2], r3 = xkv[3];
    #pragma unroll
    for (int m = 1; m < 16; m <<= 1) {
      r0 += __shfl_xor(r0, m);
      r1 += __shfl_xor(r1, m);
      r2 += __shfl_xor(r2, m);
      r3 += __shfl_xor(r3, m);
    }
    if (own == (c >> 2)) o = make_float4(r0, r1, r2, r3);
    #pragma unroll
    for (int d = 0; d < 4; ++d) {
      const float xk = xkv[d];
      const float* iwc = iwsh + (c + d) * 8;
      const float* ixwc = ixwsh + (c + d) * 8;
      float4 a0 = *(const float4*)(iwc);
      float4 a1 = *(const float4*)(iwc + 4);
      float4 b0 = *(const float4*)(ixwc);
      float4 b1 = *(const float4*)(ixwc + 4);
      sacc[0] = fmaf(xk, a0.x, sacc[0]); sacc[1] = fmaf(xk, a0.y, sacc[1]); sacc[2] = fmaf(xk, a0.z, sacc[2]); sacc[3] = fmaf(xk, a0.w, sacc[3]);
      sacc[4] = fmaf(xk, a1.x, sacc[4]); sacc[5] = fmaf(xk, a1.y, sacc[5]); sacc[6] = fmaf(xk, a1.z, sacc[6]); sacc[7] = fmaf(xk, a1.w, sacc[7]);
      vacc[0] = fmaf(xk, b0.x, vacc[0]); vacc[1] = fmaf(xk, b0.y, vacc[1]); vacc[2] = fmaf(xk, b0.z, vacc[2]); vacc[3] = fmaf(xk, b0.w, vacc[3]);
      vacc[4] = fmaf(xk, b1.x, vacc[4]); vacc[5] = fmaf(xk, b1.y, vacc[5]); vacc[6] = fmaf(xk, b1.z, vacc[6]); vacc[7] = fmaf(xk, b1.w, vacc[7]);
    }
  }
  float ex[8];
  #pragma unroll
  for (int t = 0; t < 8; ++t) ex[t] = __expf(sacc[t]);
  uint4 ea, eb;
  ea.x = packh2(ex[0], ex[1]); ea.y = packh2(ex[2], ex[3]);
  ea.z = packh2(ex[4], ex[5]); ea.w = packh2(ex[6], ex[7]);
  eb.x = packh2(ex[0] * vacc[0], ex[1] * vacc[1]);
  eb.y = packh2(ex[2] * vacc[2], ex[3] * vacc[3]);
  eb.z = packh2(ex[4] * vacc[4], ex[5] * vacc[5]);
  eb.w = packh2(ex[6] * vacc[6], ex[7] * vacc[7]);
  *(uint4*)(exv + (size_t)pos * 8) = ea;
  *(uint4*)(exv + (size_t)pos * 8 + 4) = eb;

  const size_t i = g >> 4;
  *(float4*)(x_intra + i * 64 + own * 4) = o;
}

// ---------------- K5: streaming segment reduce (fp16) + x2 + bn2 partials ----------------
__global__ __launch_bounds__(256) void k_inter_x2(
    const int* __restrict__ rowstart, const unsigned* __restrict__ exv,
    float* __restrict__ xi, float* __restrict__ partial)
{
  __shared__ float bsum[64], bsq[64];
  const int tid = threadIdx.x;
  if (tid < 64) { bsum[tid] = 0.f; bsq[tid] = 0.f; }
  __syncthreads();
  const int t = tid & 15;
  const int j = blockIdx.x * 16 + (tid >> 4);
  const int s0 = rowstart[j];
  const int e0 = rowstart[j + 1];
  const unsigned short* eh = (const unsigned short*)exv;
  float acc = 0.f;
  for (int e = s0; e < e0; ++e) acc += h2f(eh[(size_t)e * 16 + t]);
  const float other = __shfl_xor(acc, 8);
  float r = (t < 8) ? ((acc > 0.f) ? other / acc : 0.f)
                    : ((other > 0.f) ? acc / other : 0.f);
  float4 xv = *(const float4*)(xi + (size_t)j * 64 + t * 4);
  float v0 = xv.x + __shfl(r, (4 * t + 0) & 7, 16);
  float v1 = xv.y + __shfl(r, (4 * t + 1) & 7, 16);
  float v2 = xv.z + __shfl(r, (4 * t + 2) & 7, 16);
  float v3 = xv.w + __shfl(r, (4 * t + 3) & 7, 16);
  *(float4*)(xi + (size_t)j * 64 + t * 4) = make_float4(v0, v1, v2, v3);
  float s_[4] = {v0, v1, v2, v3};
  float q_[4] = {v0 * v0, v1 * v1, v2 * v2, v3 * v3};
  #pragma unroll
  for (int d = 0; d < 4; ++d) {
    s_[d] += __shfl_xor(s_[d], 16); s_[d] += __shfl_xor(s_[d], 32);
    q_[d] += __shfl_xor(q_[d], 16); q_[d] += __shfl_xor(q_[d], 32);
  }
  if ((tid & 63) < 16) {
    #pragma unroll
    for (int d = 0; d < 4; ++d) {
      atomicAdd(&bsum[4 * t + d], s_[d]);
      atomicAdd(&bsq[4 * t + d], q_[d]);
    }
  }
  __syncthreads();
  if (tid < 64) {
    partial[(size_t)tid * gridDim.x + blockIdx.x] = bsum[tid];
    partial[(size_t)(tid + 64) * gridDim.x + blockIdx.x] = bsq[tid];
  }
}

// ---------------- K6: final bn3 + residual + relu ----------------
__global__ __launch_bounds__(256) void k_out(
    const float* __restrict__ y3, const float* __restrict__ x0,
    const float* __restrict__ cst, float* __restrict__ out)
{
  __shared__ float scsh[64], shsh[64];
  const int tid = threadIdx.x;
  if (tid < 64) { scsh[tid] = cst[S_SC3 + tid]; shsh[tid] = cst[S_SH3 + tid]; }
  __syncthreads();
  const size_t i = ((size_t)blockIdx.x * 256 + tid) * 4;
  float4 y = *(const float4*)(y3 + i);
  float4 x = *(const float4*)(x0 + i);
  const int c = (int)(i & 63);
  float4 o;
  o.x = fmaxf(fmaf(y.x, scsh[c + 0], shsh[c + 0]) + x.x, 0.f);
  o.y = fmaxf(fmaf(y.y, scsh[c + 1], shsh[c + 1]) + x.y, 0.f);
  o.z = fmaxf(fmaf(y.z, scsh[c + 2], shsh[c + 2]) + x.z, 0.f);
  o.w = fmaxf(fmaf(y.w, scsh[c + 3], shsh[c + 3]) + x.w, 0.f);
  *(float4*)(out + i) = o;
}

// ---------------- launch ----------------
extern "C" void kernel_launch(void* const* d_in, const int* in_sizes, int n_in,
                              void* d_out, int out_size, void* d_ws, size_t ws_size,
                              hipStream_t stream)
{
  (void)n_in; (void)out_size; (void)ws_size;
  const float* p    = (const float*)d_in[0];
  const float* x    = (const float*)d_in[1];
  const int*   knn  = (const int*)d_in[2];
  const float* w1   = (const float*)d_in[3];
  const float* g1   = (const float*)d_in[4];
  const float* b1   = (const float*)d_in[5];
  const float* m1w1 = (const float*)d_in[6];
  const float* m1b1 = (const float*)d_in[7];
  const float* m1w2 = (const float*)d_in[8];
  const float* m1b2 = (const float*)d_in[9];
  const float* lpw1 = (const float*)d_in[10];
  const float* lpb1 = (const float*)d_in[11];
  const float* lpg  = (const float*)d_in[12];
  const float* lpbt = (const float*)d_in[13];
  const float* lpw2 = (const float*)d_in[14];
  const float* lpb2 = (const float*)d_in[15];
  const float* m2w1 = (const float*)d_in[16];
  const float* m2g1 = (const float*)d_in[17];
  const float* m2bt1= (const float*)d_in[18];
  const float* m2w2 = (const float*)d_in[19];
  const float* m2g2 = (const float*)d_in[20];
  const float* m2bt2= (const float*)d_in[21];
  const float* m2w3 = (const float*)d_in[22];
  const float* m2b3 = (const float*)d_in[23];
  const float* m3w  = (const float*)d_in[24];
  const float* m3b  = (const float*)d_in[25];
  const float* iw   = (const float*)d_in[26];
  const float* ib   = (const float*)d_in[27];
  const float* ixw  = (const float*)d_in[28];
  const float* ixb  = (const float*)d_in[29];
  const float* g2   = (const float*)d_in[30];
  const float* b2   = (const float*)d_in[31];
  const float* w3   = (const float*)d_in[32];
  const float* g3   = (const float*)d_in[33];
  const float* b3   = (const float*)d_in[34];
  float* out = (float*)d_out;
  float* ws  = (float*)d_ws;

  const int n = in_sizes[1] / 64;                // 32768
  const long long nk = (long long)n * 16;        // 524288

  float* cst  = ws;
  int* cnt      = (int*)(ws + CONST_FLOATS);    // n ints (zeroed with cst)
  int* rowstart = cnt + n;                      // n+1 ints (+pad)
  int* rank     = rowstart + n + 16;            // nk ints
  int* posb     = rank + nk;                    // nk ints
  unsigned short* zb = (unsigned short*)(posb + nk);  // 64n bf16 = 32n words
  float* y1 = (float*)(zb + 64LL * n);          // 64n, reused as y3
  float* xi = y1 + 64LL * n;                    // 64n
  float* pr = xi + 64LL * n;                    // 48n
  float* y16 = pr + 48LL * n;                   // 16n
  unsigned short* h2b = (unsigned short*)(y16 + 16LL * n);  // 128n ushorts
  unsigned* exv = (unsigned*)(h2b + 128LL * n); // 128n uints

  const int gB   = n / 64;            // 512
  const int nkB  = (int)(nk / 256);   // 2048
  const int nkB2 = (int)(nk / 512);   // 1024
  const int jB   = n / 16;            // 2048

  float* pbn1  = (float*)(exv + 128LL * n);      // 128 * gB
  float* plp   = pbn1 + 128LL * gB;              // 8 * nkB
  float* pmom  = plp + 8LL * nkB;                // 210 * nkB
  float* s2buf = pmom + 210LL * nkB;             // 256
  float* pm2b2 = s2buf + 256;                    // 16 * nkB2
  float* pbn2  = pm2b2 + 16LL * nkB2;            // 128 * jB
  float* pbn3  = pbn2 + 128LL * jB;              // 128 * gB
  unsigned* uq = (unsigned*)(pbn3 + 128LL * gB); // 8 * nk uints
  unsigned* uqn = uq + 8LL * nk;                 // 2 * nk uints

  hipMemsetAsync(d_ws, 0, (size_t)CONST_FLOATS * sizeof(float) + (size_t)n * sizeof(int), stream);

  k_prhist<<<nkB, 256, 0, stream>>>(p, knn, lpw1, lpb1, pr, plp, cnt, rank);
  k_gemm64<<<gB, 256, 0, stream>>>(x, w1, nullptr, nullptr, nullptr, y1, pbn1, n);
  k_scan_mid<<<1, 1024, 0, stream>>>(cnt, rowstart, n, plp, nkB,
                                     lpg, lpbt, lpw1, lpb1, lpw2, lpb2,
                                     m1w2, m2w1, m1b2, cst, 1.f / (float)nk);
  k_rbn<<<64, 256, 0, stream>>>(pbn1, gB, 64, g1, b1, cst + S_SC1, cst + S_SH1, 1.f / (float)n);
  // z(bf16) + y16 in one pass
  k_gemmzy<<<gB, 256, 0, stream>>>(y1, m3w, m3b, m1w1 + 48, cst + S_SC1, cst + S_SH1, zb, y16);
  // h1 BN stats via u-moments; also emits uq/uqn/pos
  k_moment<<<nkB, 256, 0, stream>>>(y16, pr, knn, m1w1, m1b1, cst, rowstart, rank,
                                    pmom, uq, uqn, posb);
  k_mred<<<210, 256, 0, stream>>>(pmom, s2buf, nkB);
  k_mfin<<<1, 64, 0, stream>>>(s2buf, m2g1, m2bt1, cst, 1.f / (float)nk);
  // h2 (bf16) from uq/uqn + stats
  k_h2<<<nkB2, 256, 0, stream>>>(uq, uqn, cst, m2w2, h2b, pm2b2);
  k_rbn<<<8, 256, 0, stream>>>(pm2b2, nkB2, 8, m2g2, m2bt2, cst + S_M2S2, cst + S_M2H2, 1.f / (float)nk);
  // fused softmax + xk + x_intra + exv
  k_intra<<<nkB, 256, 0, stream>>>(zb, uqn, knn, cst, lpw2, lpb2, iw, ib, ixw, ixb,
                                   h2b, m2w3, m2b3, posb, xi, exv);
  // streaming segment reduce + x2 + bn2 partials
  k_inter_x2<<<jB, 256, 0, stream>>>(rowstart, exv, xi, pbn2);
  k_rbn<<<64, 256, 0, stream>>>(pbn2, jB, 64, g2, b2, cst + S_SC2, cst + S_SH2, 1.f / (float)n);
  // y3 = relu(bn2(x2)) @ w3, bn3
  k_gemm64<<<gB, 256, 0, stream>>>(xi, w3, nullptr, cst + S_SC2, cst + S_SH2, y1, pbn3, n);
  k_rbn<<<64, 256, 0, stream>>>(pbn3, gB, 64, g3, b3, cst + S_SC3, cst + S_SH3, 1.f / (float)n);
  // out = relu(bn3(y3) + x)
  k_out<<<(int)((long long)n * 64 / 1024), 256, 0, stream>>>(y1, x, cst, out);
}

// Round 13
// 337.801 us; speedup vs baseline: 1.3312x; 1.0691x over previous
//
#include <hip/hip_runtime.h>

// N = 32768 (runtime), C = 64, K = 16, CS = 8, SHARE = 8

enum {
  S_SC1 = 0,    S_SH1 = 64,
  S_LPSC = 128, S_LPSH = 132,
  S_M2S1 = 136, S_M2H1 = 200,
  S_M2S2 = 264, S_M2H2 = 272,
  S_SC2 = 280,  S_SH2 = 344,
  S_SC3 = 408,  S_SH3 = 472,
  S_LPW2S = 536, S_LPB2S = 584,
  S_QW = 600, S_QB = 612,
  S_G = 640,        // 64x16 c-major
  S_HC = 1664,      // 64x4 c-major
  S_HB = 1920,      // 64
  CONST_FLOATS = 2048
};

__device__ __forceinline__ int pidx(int a, int b) {  // a<=b, 20-dim sym
  return a * 20 - (a * (a - 1)) / 2 + (b - a);
}
__device__ __forceinline__ unsigned short bf16r(float f) {
  unsigned u = __float_as_uint(f);
  u = u + 0x7fffu + ((u >> 16) & 1u);
  return (unsigned short)(u >> 16);
}
__device__ __forceinline__ unsigned short f2h(float f) {
  _Float16 h = (_Float16)f;
  unsigned short u;
  __builtin_memcpy(&u, &h, 2);
  return u;
}
__device__ __forceinline__ float h2f(unsigned short u) {
  _Float16 h;
  __builtin_memcpy(&h, &u, 2);
  return (float)h;
}
__device__ __forceinline__ unsigned packh2(float a, float b) {
  return (unsigned)f2h(a) | ((unsigned)f2h(b) << 16);
}
__device__ __forceinline__ float lo16(unsigned u) { return h2f((unsigned short)(u & 0xffffu)); }
__device__ __forceinline__ float hi16(unsigned u) { return h2f((unsigned short)(u >> 16)); }

// ---------------- fused partial-reduce + BN finalize ----------------
__global__ __launch_bounds__(256) void k_rbn(
    const float* __restrict__ partial, int nb, int nch,
    const float* __restrict__ g, const float* __restrict__ b,
    float* __restrict__ scale, float* __restrict__ shift, float inv_count)
{
  const int c = blockIdx.x;
  const int tid = threadIdx.x;
  float s = 0.f, q = 0.f;
  for (int i = tid; i < nb; i += 256) {
    s += partial[(size_t)c * nb + i];
    q += partial[(size_t)(c + nch) * nb + i];
  }
  #pragma unroll
  for (int m = 1; m < 64; m <<= 1) { s += __shfl_xor(s, m); q += __shfl_xor(q, m); }
  __shared__ float ws[4], wq[4];
  if ((tid & 63) == 0) { ws[tid >> 6] = s; wq[tid >> 6] = q; }
  __syncthreads();
  if (tid == 0) {
    float S = ws[0] + ws[1] + ws[2] + ws[3];
    float Q = wq[0] + wq[1] + wq[2] + wq[3];
    float m = S * inv_count;
    float v = Q * inv_count - m * m;
    float rs = rsqrtf(v + 1e-5f);
    float sc = g[c] * rs;
    scale[c] = sc;
    shift[c] = fmaf(-m, sc, b[c]);
  }
}

// ---------------- generic 64x64 GEMM (f32 out) ----------------
__global__ __launch_bounds__(256) void k_gemm64(
    const float* __restrict__ in, const float* __restrict__ w,
    const float* __restrict__ bias,
    const float* __restrict__ sc, const float* __restrict__ sh,
    float* __restrict__ out,
    float* __restrict__ partial, int n)
{
  __shared__ float scsh[64], shsh[64];
  __shared__ float bsum[64], bsq[64];
  const int tid = threadIdx.x;
  const int lane = tid & 63;
  const int wave = tid >> 6;
  if (sc != nullptr && tid < 64) { scsh[tid] = sc[tid]; shsh[tid] = sh[tid]; }
  if (tid < 64) { bsum[tid] = 0.f; bsq[tid] = 0.f; }
  __syncthreads();

  float wreg[64];
  #pragma unroll
  for (int k = 0; k < 64; ++k) wreg[k] = w[k * 64 + lane];
  const float bz = bias ? bias[lane] : 0.f;

  float lsum = 0.f, lsq = 0.f;
  const int row0 = (blockIdx.x * 4 + wave) * 16;
  for (int r = 0; r < 16; ++r) {
    const int row = row0 + r;
    const float* xr = in + (size_t)row * 64;
    float acc = bz;
    if (sc != nullptr) {
      #pragma unroll
      for (int k = 0; k < 64; k += 4) {
        float4 xv = *(const float4*)(xr + k);
        float x0 = fmaxf(fmaf(xv.x, scsh[k + 0], shsh[k + 0]), 0.f);
        float x1 = fmaxf(fmaf(xv.y, scsh[k + 1], shsh[k + 1]), 0.f);
        float x2 = fmaxf(fmaf(xv.z, scsh[k + 2], shsh[k + 2]), 0.f);
        float x3 = fmaxf(fmaf(xv.w, scsh[k + 3], shsh[k + 3]), 0.f);
        acc = fmaf(x0, wreg[k + 0], acc);
        acc = fmaf(x1, wreg[k + 1], acc);
        acc = fmaf(x2, wreg[k + 2], acc);
        acc = fmaf(x3, wreg[k + 3], acc);
      }
    } else {
      #pragma unroll
      for (int k = 0; k < 64; k += 4) {
        float4 xv = *(const float4*)(xr + k);
        acc = fmaf(xv.x, wreg[k + 0], acc);
        acc = fmaf(xv.y, wreg[k + 1], acc);
        acc = fmaf(xv.z, wreg[k + 2], acc);
        acc = fmaf(xv.w, wreg[k + 3], acc);
      }
    }
    out[(size_t)row * 64 + lane] = acc;
    lsum += acc;
    lsq = fmaf(acc, acc, lsq);
  }
  if (partial != nullptr) {
    atomicAdd(&bsum[lane], lsum);
    atomicAdd(&bsq[lane], lsq);
    __syncthreads();
    if (tid < 64) {
      partial[(size_t)tid * gridDim.x + blockIdx.x] = bsum[tid];
      partial[(size_t)(tid + 64) * gridDim.x + blockIdx.x] = bsq[tid];
    }
  }
}

// ---------------- fused: z (bf16) = nr(y1)@m3w+m3b ; y16 = nr(y1)@m1w1[3:] ----------------
__global__ __launch_bounds__(256) void k_gemmzy(
    const float* __restrict__ in, const float* __restrict__ w,
    const float* __restrict__ bias, const float* __restrict__ w16,
    const float* __restrict__ sc, const float* __restrict__ sh,
    unsigned short* __restrict__ outz, float* __restrict__ out16)
{
  __shared__ float xn[64][68];
  __shared__ float w16sh[1024];
  __shared__ float scsh[64], shsh[64];
  const int tid = threadIdx.x;
  if (tid < 64) { scsh[tid] = sc[tid]; shsh[tid] = sh[tid]; }
  for (int i2 = tid; i2 < 1024; i2 += 256) w16sh[i2] = w16[i2];
  __syncthreads();
  const int row0 = blockIdx.x * 64;
  for (int idx = tid; idx < 4096; idx += 256) {
    int r = idx >> 6, c = idx & 63;
    float v = in[(size_t)(row0 + r) * 64 + c];
    xn[r][c] = fmaxf(fmaf(v, scsh[c], shsh[c]), 0.f);
  }
  __syncthreads();

  const int lane = tid & 63;
  const int wave = tid >> 6;
  float wreg[64];
  #pragma unroll
  for (int k = 0; k < 64; ++k) wreg[k] = w[k * 64 + lane];
  const float bz = bias[lane];
  for (int r = wave * 16; r < wave * 16 + 16; ++r) {
    float acc = bz;
    #pragma unroll
    for (int k = 0; k < 64; k += 4) {
      float4 xv = *(const float4*)(&xn[r][k]);
      acc = fmaf(xv.x, wreg[k + 0], acc);
      acc = fmaf(xv.y, wreg[k + 1], acc);
      acc = fmaf(xv.z, wreg[k + 2], acc);
      acc = fmaf(xv.w, wreg[k + 3], acc);
    }
    outz[(size_t)(row0 + r) * 64 + lane] = bf16r(acc);
  }
  for (int idx = tid; idx < 1024; idx += 256) {
    int r = idx >> 4, t = idx & 15;
    float acc = 0.f;
    #pragma unroll
    for (int c = 0; c < 64; c += 4) {
      float4 xv = *(const float4*)(&xn[r][c]);
      acc = fmaf(xv.x, w16sh[(c + 0) * 16 + t], acc);
      acc = fmaf(xv.y, w16sh[(c + 1) * 16 + t], acc);
      acc = fmaf(xv.z, w16sh[(c + 2) * 16 + t], acc);
      acc = fmaf(xv.w, w16sh[(c + 3) * 16 + t], acc);
    }
    out16[(size_t)(row0 + r) * 16 + t] = acc;
  }
}

// ---------------- K1: p_r, lp partials, histogram + rank ----------------
__global__ __launch_bounds__(256) void k_prhist(
    const float* __restrict__ p, const int* __restrict__ knn,
    const float* __restrict__ lpw1, const float* __restrict__ lpb1,
    float* __restrict__ p_r, float* __restrict__ plp,
    int* __restrict__ cnt, int* __restrict__ rank)
{
  __shared__ float lpw1sh[9], lpb1sh[3];
  __shared__ float lpsh[4][8];
  const int tid = threadIdx.x;
  if (tid < 9) lpw1sh[tid] = lpw1[tid];
  if (tid < 3) lpb1sh[tid] = lpb1[tid];
  __syncthreads();

  const size_t g = (size_t)blockIdx.x * 256 + tid;
  const int i = (int)(g >> 4);
  const int j = knn[g];
  const float pr0 = p[j * 3 + 0] - p[i * 3 + 0];
  const float pr1 = p[j * 3 + 1] - p[i * 3 + 1];
  const float pr2 = p[j * 3 + 2] - p[i * 3 + 2];
  p_r[g * 3 + 0] = pr0; p_r[g * 3 + 1] = pr1; p_r[g * 3 + 2] = pr2;
  rank[g] = atomicAdd(&cnt[j], 1);

  float q0 = fmaf(pr2, lpw1sh[6], fmaf(pr1, lpw1sh[3], fmaf(pr0, lpw1sh[0], lpb1sh[0])));
  float q1 = fmaf(pr2, lpw1sh[7], fmaf(pr1, lpw1sh[4], fmaf(pr0, lpw1sh[1], lpb1sh[1])));
  float q2 = fmaf(pr2, lpw1sh[8], fmaf(pr1, lpw1sh[5], fmaf(pr0, lpw1sh[2], lpb1sh[2])));
  float s0 = q0, s1 = q1, s2 = q2, qq0 = q0 * q0, qq1 = q1 * q1, qq2 = q2 * q2;
  #pragma unroll
  for (int m = 1; m < 64; m <<= 1) {
    s0 += __shfl_xor(s0, m); s1 += __shfl_xor(s1, m); s2 += __shfl_xor(s2, m);
    qq0 += __shfl_xor(qq0, m); qq1 += __shfl_xor(qq1, m); qq2 += __shfl_xor(qq2, m);
  }
  if ((tid & 63) == 0) {
    const int w = tid >> 6;
    lpsh[w][0] = s0; lpsh[w][1] = s1; lpsh[w][2] = s2; lpsh[w][3] = 0.f;
    lpsh[w][4] = qq0; lpsh[w][5] = qq1; lpsh[w][6] = qq2; lpsh[w][7] = 0.f;
  }
  __syncthreads();
  if (tid < 8) {
    float v = lpsh[0][tid] + lpsh[1][tid] + lpsh[2][tid] + lpsh[3][tid];
    plp[(size_t)tid * gridDim.x + blockIdx.x] = v;
  }
}

// ---------------- merged: CSR scan + lp finalize + weight folding ----------------
__global__ __launch_bounds__(1024) void k_scan_mid(
    const int* __restrict__ cnt, int* __restrict__ rowstart, int n,
    const float* __restrict__ plp, int nbplp,
    const float* __restrict__ lpg, const float* __restrict__ lpbt,
    const float* __restrict__ lpw1, const float* __restrict__ lpb1,
    const float* __restrict__ lpw2, const float* __restrict__ lpb2,
    const float* __restrict__ m1w2, const float* __restrict__ m2w1,
    const float* __restrict__ m1b2,
    float* __restrict__ cst, float inv_count)
{
  __shared__ int tsum[1024];
  __shared__ float Ssh[8];
  const int tid = threadIdx.x;
  const int per = n >> 10;
  const int base = tid * per;
  int local[32];
  int s = 0;
  for (int u = 0; u < per; ++u) { local[u] = cnt[base + u]; s += local[u]; }
  tsum[tid] = s;
  __syncthreads();
  for (int off = 1; off < 1024; off <<= 1) {
    int v = (tid >= off) ? tsum[tid - off] : 0;
    __syncthreads();
    tsum[tid] += v;
    __syncthreads();
  }
  int run = tsum[tid] - s;
  for (int u = 0; u < per; ++u) { rowstart[base + u] = run; run += local[u]; }
  if (tid == 1023) rowstart[n] = run;

  if (tid < 256) {
    const int row = tid >> 5, l32 = tid & 31;
    float ls = 0.f;
    for (int i = l32; i < nbplp; i += 32) ls += plp[(size_t)row * nbplp + i];
    #pragma unroll
    for (int m = 1; m < 32; m <<= 1) ls += __shfl_xor(ls, m);
    if (l32 == 0) Ssh[row] = ls;
  }
  __syncthreads();
  if (tid < 3) {
    float m = Ssh[tid] * inv_count;
    float v = Ssh[4 + tid] * inv_count - m * m;
    float rs = rsqrtf(v + 1e-5f);
    float sc = lpg[tid] * rs;
    cst[S_LPSC + tid] = sc;
    cst[S_LPSH + tid] = fmaf(-m, sc, lpbt[tid]);
  }
  __syncthreads();
  if (tid < 9)  cst[S_QW + tid] = lpw1[tid] * cst[S_LPSC + (tid % 3)];
  if (tid < 3)  cst[S_QB + tid] = fmaf(lpb1[tid], cst[S_LPSC + tid], cst[S_LPSH + tid]);
  if (tid < 16) {
    float b = 0.f;
    for (int c2 = 0; c2 < 4; ++c2) b += lpb2[c2 * 16 + tid];
    cst[S_LPB2S + tid] = b;
    for (int r = 0; r < 3; ++r) {
      float w = 0.f;
      for (int c2 = 0; c2 < 4; ++c2) w += lpw2[r * 64 + c2 * 16 + tid];
      cst[S_LPW2S + r * 16 + tid] = w;
    }
  }
  __syncthreads();
  if (tid < 256) {
    #pragma unroll
    for (int q = 0; q < 4; ++q) {
      int ee = tid * 4 + q;
      int c = ee >> 4, u = ee & 15;
      float sg = 0.f;
      #pragma unroll
      for (int t = 0; t < 16; ++t) sg = fmaf(m1w2[u * 16 + t], m2w1[t * 64 + c], sg);
      cst[S_G + c * 16 + u] = sg;
    }
  }
  if (tid < 192) {
    int c = tid / 3, r = tid - c * 3;
    float sh = 0.f;
    #pragma unroll
    for (int t = 0; t < 16; ++t) sh = fmaf(cst[S_LPW2S + r * 16 + t], m2w1[(16 + t) * 64 + c], sh);
    cst[S_HC + c * 4 + r] = sh;
  }
  if (tid < 64) {
    cst[S_HC + tid * 4 + 3] = 0.f;
    float sb = 0.f;
    #pragma unroll
    for (int t = 0; t < 16; ++t) {
      sb = fmaf(m1b2[t], m2w1[t * 64 + tid], sb);
      sb = fmaf(cst[S_LPB2S + t], m2w1[(16 + t) * 64 + tid], sb);
    }
    cst[S_HB + tid] = sb;
  }
}

// ---------------- K2: u-moment accumulation + uq/uqn/pos store ----------------
__global__ __launch_bounds__(256) void k_moment(
    const float* __restrict__ y16, const float* __restrict__ p_r,
    const int* __restrict__ knn, const float* __restrict__ m1w1,
    const float* __restrict__ m1b1, const float* __restrict__ cst,
    const int* __restrict__ rowstart, const int* __restrict__ rank,
    float* __restrict__ pmom,   // [210 * gridDim.x] channel-major
    unsigned* __restrict__ uq,  // [nk * 8] packed fp16 t1[16]
    unsigned* __restrict__ uqn, // [nk * 2] packed fp16 qn[3]
    int* __restrict__ posbuf)   // [nk]
{
  __shared__ float ush[256 * 21];
  const int tid = threadIdx.x;
  const size_t g = (size_t)blockIdx.x * 256 + tid;
  const int j = knn[g];
  const float pr0 = p_r[g * 3 + 0], pr1 = p_r[g * 3 + 1], pr2 = p_r[g * 3 + 2];
  const float* yj = y16 + (size_t)j * 16;
  float4 ya = *(const float4*)(yj);
  float4 yb = *(const float4*)(yj + 4);
  float4 yc = *(const float4*)(yj + 8);
  float4 yd = *(const float4*)(yj + 12);
  float t1[16] = {ya.x, ya.y, ya.z, ya.w, yb.x, yb.y, yb.z, yb.w,
                  yc.x, yc.y, yc.z, yc.w, yd.x, yd.y, yd.z, yd.w};
  #pragma unroll
  for (int u = 0; u < 16; ++u)
    t1[u] = fmaxf(fmaf(pr2, m1w1[32 + u], fmaf(pr1, m1w1[16 + u],
                  fmaf(pr0, m1w1[u], t1[u] + m1b1[u]))), 0.f);
  const float qn0 = fmaxf(fmaf(pr2, cst[S_QW + 6], fmaf(pr1, cst[S_QW + 3], fmaf(pr0, cst[S_QW + 0], cst[S_QB + 0]))), 0.f);
  const float qn1 = fmaxf(fmaf(pr2, cst[S_QW + 7], fmaf(pr1, cst[S_QW + 4], fmaf(pr0, cst[S_QW + 1], cst[S_QB + 1]))), 0.f);
  const float qn2 = fmaxf(fmaf(pr2, cst[S_QW + 8], fmaf(pr1, cst[S_QW + 5], fmaf(pr0, cst[S_QW + 2], cst[S_QB + 2]))), 0.f);

  posbuf[g] = rowstart[j] + rank[g];

  uint4 ua, ub;
  ua.x = packh2(t1[0], t1[1]);   ua.y = packh2(t1[2], t1[3]);
  ua.z = packh2(t1[4], t1[5]);   ua.w = packh2(t1[6], t1[7]);
  ub.x = packh2(t1[8], t1[9]);   ub.y = packh2(t1[10], t1[11]);
  ub.z = packh2(t1[12], t1[13]); ub.w = packh2(t1[14], t1[15]);
  *(uint4*)(uq + g * 8)     = ua;
  *(uint4*)(uq + g * 8 + 4) = ub;
  uint2 uc;
  uc.x = packh2(qn0, qn1);
  uc.y = packh2(qn2, 0.f);
  *(uint2*)(uqn + g * 2) = uc;

  float* ur = ush + tid * 21;
  #pragma unroll
  for (int u = 0; u < 16; ++u) ur[u] = t1[u];
  ur[16] = qn0; ur[17] = qn1; ur[18] = qn2; ur[19] = 1.f;
  __syncthreads();

  if (tid < 210) {
    int a = 0, t = tid;
    while (t >= 20 - a) { t -= 20 - a; ++a; }
    const int b = a + t;
    float s = 0.f;
    for (int it = 0; it < 256; ++it) {
      const int r = (it + tid) & 255;
      const float* u = ush + r * 21;
      s = fmaf(u[a], u[b], s);
    }
    pmom[(size_t)tid * gridDim.x + blockIdx.x] = s;
  }
}

// ---------------- parallel moment reduce ----------------
__global__ __launch_bounds__(256) void k_mred(
    const float* __restrict__ pmom, float* __restrict__ S2, int nb)
{
  const int c = blockIdx.x;
  const int tid = threadIdx.x;
  float s = 0.f;
  for (int i = tid; i < nb; i += 256) s += pmom[(size_t)c * nb + i];
  #pragma unroll
  for (int m = 1; m < 64; m <<= 1) s += __shfl_xor(s, m);
  __shared__ float ws[4];
  if ((tid & 63) == 0) ws[tid >> 6] = s;
  __syncthreads();
  if (tid == 0) S2[c] = ws[0] + ws[1] + ws[2] + ws[3];
}

// ---------------- moment finalize ----------------
__global__ __launch_bounds__(64) void k_mfin(
    const float* __restrict__ S2in,
    const float* __restrict__ g, const float* __restrict__ b,
    float* __restrict__ cst, float inv_count)
{
  __shared__ float S2[210];
  const int tid = threadIdx.x;
  for (int i = tid; i < 210; i += 64) S2[i] = S2in[i];
  __syncthreads();
  const int c = tid;
  float w[20];
  #pragma unroll
  for (int u = 0; u < 16; ++u) w[u] = cst[S_G + c * 16 + u];
  w[16] = cst[S_HC + c * 4 + 0];
  w[17] = cst[S_HC + c * 4 + 1];
  w[18] = cst[S_HC + c * 4 + 2];
  w[19] = cst[S_HB + c];
  float m2 = 0.f, m1 = 0.f;
  for (int a = 0; a < 20; ++a) {
    const float wa = w[a];
    m2 = fmaf(wa * wa, S2[pidx(a, a)], m2);
    float cross = 0.f;
    for (int bb = a + 1; bb < 20; ++bb) cross = fmaf(w[bb], S2[pidx(a, bb)], cross);
    m2 = fmaf(2.f * wa, cross, m2);
    m1 = fmaf(wa, S2[pidx(a, 19)], m1);
  }
  const float mean = m1 * inv_count;
  const float var = m2 * inv_count - mean * mean;
  const float rs = rsqrtf(var + 1e-5f);
  const float sc = g[c] * rs;
  cst[S_M2S1 + c] = sc;
  cst[S_M2H1 + c] = fmaf(-mean, sc, b[c]);
}

// ---------------- K3: h2(bf16) from packed uq/uqn via folded G/H ----------------
__global__ __launch_bounds__(256) void k_h2(
    const unsigned* __restrict__ uq, const unsigned* __restrict__ uqn,
    const float* __restrict__ cst, const float* __restrict__ m2w2,
    unsigned short* __restrict__ h2out,
    float* __restrict__ partial)   // [16 * gridDim.x]
{
  __shared__ float Gsh[1024], Hsh[256], hbsh[64];
  __shared__ float w2m[512];
  __shared__ float scsh[64], shsh[64];
  __shared__ float redsh[4][16];
  const int tid = threadIdx.x;
  for (int i = tid; i < 1024; i += 256) Gsh[i] = cst[S_G + i];
  Hsh[tid] = cst[S_HC + tid];
  for (int i = tid; i < 512; i += 256) w2m[i] = m2w2[i];
  if (tid < 64) { hbsh[tid] = cst[S_HB + tid]; scsh[tid] = cst[S_M2S1 + tid]; shsh[tid] = cst[S_M2H1 + tid]; }
  __syncthreads();

  const size_t g0 = ((size_t)blockIdx.x * 256 + tid) * 2;
  float t1[2][16], qn[2][3];
  #pragma unroll
  for (int gg = 0; gg < 2; ++gg) {
    const size_t g = g0 + gg;
    uint4 ua = *(const uint4*)(uq + g * 8);
    uint4 ub = *(const uint4*)(uq + g * 8 + 4);
    uint2 uc = *(const uint2*)(uqn + g * 2);
    t1[gg][0] = lo16(ua.x);  t1[gg][1] = hi16(ua.x);
    t1[gg][2] = lo16(ua.y);  t1[gg][3] = hi16(ua.y);
    t1[gg][4] = lo16(ua.z);  t1[gg][5] = hi16(ua.z);
    t1[gg][6] = lo16(ua.w);  t1[gg][7] = hi16(ua.w);
    t1[gg][8] = lo16(ub.x);  t1[gg][9] = hi16(ub.x);
    t1[gg][10] = lo16(ub.y); t1[gg][11] = hi16(ub.y);
    t1[gg][12] = lo16(ub.z); t1[gg][13] = hi16(ub.z);
    t1[gg][14] = lo16(ub.w); t1[gg][15] = hi16(ub.w);
    qn[gg][0] = lo16(uc.x); qn[gg][1] = hi16(uc.x); qn[gg][2] = lo16(uc.y);
  }

  float a0[8], a1[8];
  #pragma unroll
  for (int t = 0; t < 8; ++t) { a0[t] = 0.f; a1[t] = 0.f; }
  for (int c = 0; c < 64; ++c) {
    float4 g0v = *(const float4*)(Gsh + c * 16);
    float4 g1v = *(const float4*)(Gsh + c * 16 + 4);
    float4 g2v = *(const float4*)(Gsh + c * 16 + 8);
    float4 g3v = *(const float4*)(Gsh + c * 16 + 12);
    float4 hv = *(const float4*)(Hsh + c * 4);
    float h_0 = hbsh[c], h_1 = hbsh[c];
    h_0 = fmaf(t1[0][0], g0v.x, h_0); h_0 = fmaf(t1[0][1], g0v.y, h_0); h_0 = fmaf(t1[0][2], g0v.z, h_0); h_0 = fmaf(t1[0][3], g0v.w, h_0);
    h_0 = fmaf(t1[0][4], g1v.x, h_0); h_0 = fmaf(t1[0][5], g1v.y, h_0); h_0 = fmaf(t1[0][6], g1v.z, h_0); h_0 = fmaf(t1[0][7], g1v.w, h_0);
    h_0 = fmaf(t1[0][8], g2v.x, h_0); h_0 = fmaf(t1[0][9], g2v.y, h_0); h_0 = fmaf(t1[0][10], g2v.z, h_0); h_0 = fmaf(t1[0][11], g2v.w, h_0);
    h_0 = fmaf(t1[0][12], g3v.x, h_0); h_0 = fmaf(t1[0][13], g3v.y, h_0); h_0 = fmaf(t1[0][14], g3v.z, h_0); h_0 = fmaf(t1[0][15], g3v.w, h_0);
    h_0 = fmaf(qn[0][0], hv.x, fmaf(qn[0][1], hv.y, fmaf(qn[0][2], hv.z, h_0)));
    h_1 = fmaf(t1[1][0], g0v.x, h_1); h_1 = fmaf(t1[1][1], g0v.y, h_1); h_1 = fmaf(t1[1][2], g0v.z, h_1); h_1 = fmaf(t1[1][3], g0v.w, h_1);
    h_1 = fmaf(t1[1][4], g1v.x, h_1); h_1 = fmaf(t1[1][5], g1v.y, h_1); h_1 = fmaf(t1[1][6], g1v.z, h_1); h_1 = fmaf(t1[1][7], g1v.w, h_1);
    h_1 = fmaf(t1[1][8], g2v.x, h_1); h_1 = fmaf(t1[1][9], g2v.y, h_1); h_1 = fmaf(t1[1][10], g2v.z, h_1); h_1 = fmaf(t1[1][11], g2v.w, h_1);
    h_1 = fmaf(t1[1][12], g3v.x, h_1); h_1 = fmaf(t1[1][13], g3v.y, h_1); h_1 = fmaf(t1[1][14], g3v.z, h_1); h_1 = fmaf(t1[1][15], g3v.w, h_1);
    h_1 = fmaf(qn[1][0], hv.x, fmaf(qn[1][1], hv.y, fmaf(qn[1][2], hv.z, h_1)));
    float x0 = fmaxf(fmaf(h_0, scsh[c], shsh[c]), 0.f);
    float x1 = fmaxf(fmaf(h_1, scsh[c], shsh[c]), 0.f);
    float4 wa = *(const float4*)(w2m + c * 8);
    float4 wb = *(const float4*)(w2m + c * 8 + 4);
    a0[0] = fmaf(x0, wa.x, a0[0]); a0[1] = fmaf(x0, wa.y, a0[1]); a0[2] = fmaf(x0, wa.z, a0[2]); a0[3] = fmaf(x0, wa.w, a0[3]);
    a0[4] = fmaf(x0, wb.x, a0[4]); a0[5] = fmaf(x0, wb.y, a0[5]); a0[6] = fmaf(x0, wb.z, a0[6]); a0[7] = fmaf(x0, wb.w, a0[7]);
    a1[0] = fmaf(x1, wa.x, a1[0]); a1[1] = fmaf(x1, wa.y, a1[1]); a1[2] = fmaf(x1, wa.z, a1[2]); a1[3] = fmaf(x1, wa.w, a1[3]);
    a1[4] = fmaf(x1, wb.x, a1[4]); a1[5] = fmaf(x1, wb.y, a1[5]); a1[6] = fmaf(x1, wb.z, a1[6]); a1[7] = fmaf(x1, wb.w, a1[7]);
  }
  uint4 pa, pb;
  pa.x = bf16r(a0[0]) | ((unsigned)bf16r(a0[1]) << 16);
  pa.y = bf16r(a0[2]) | ((unsigned)bf16r(a0[3]) << 16);
  pa.z = bf16r(a0[4]) | ((unsigned)bf16r(a0[5]) << 16);
  pa.w = bf16r(a0[6]) | ((unsigned)bf16r(a0[7]) << 16);
  pb.x = bf16r(a1[0]) | ((unsigned)bf16r(a1[1]) << 16);
  pb.y = bf16r(a1[2]) | ((unsigned)bf16r(a1[3]) << 16);
  pb.z = bf16r(a1[4]) | ((unsigned)bf16r(a1[5]) << 16);
  pb.w = bf16r(a1[6]) | ((unsigned)bf16r(a1[7]) << 16);
  *(uint4*)(h2out + g0 * 8) = pa;
  *(uint4*)(h2out + g0 * 8 + 8) = pb;

  float st[8], sq[8];
  #pragma unroll
  for (int t = 0; t < 8; ++t) {
    st[t] = a0[t] + a1[t];
    sq[t] = fmaf(a0[t], a0[t], a1[t] * a1[t]);
  }
  #pragma unroll
  for (int m = 1; m < 64; m <<= 1) {
    #pragma unroll
    for (int t = 0; t < 8; ++t) { st[t] += __shfl_xor(st[t], m); sq[t] += __shfl_xor(sq[t], m); }
  }
  if ((tid & 63) == 0) {
    const int w = tid >> 6;
    #pragma unroll
    for (int t = 0; t < 8; ++t) { redsh[w][t] = st[t]; redsh[w][8 + t] = sq[t]; }
  }
  __syncthreads();
  if (tid < 16) {
    float v = redsh[0][tid] + redsh[1][tid] + redsh[2][tid] + redsh[3][tid];
    partial[(size_t)tid * gridDim.x + blockIdx.x] = v;
  }
}

// ---------------- K4: fused softmax + xk + x_intra (LDS reduce) + exv(fp16) ----------------
__global__ __launch_bounds__(256) void k_intra(
    const unsigned short* __restrict__ zb, const unsigned* __restrict__ uqn,
    const int* __restrict__ knn, const float* __restrict__ cst,
    const float* __restrict__ lpw2, const float* __restrict__ lpb2,
    const float* __restrict__ iw, const float* __restrict__ ib,
    const float* __restrict__ ixw, const float* __restrict__ ixb,
    const unsigned short* __restrict__ h2b, const float* __restrict__ m2w3,
    const float* __restrict__ m2b3,
    const int* __restrict__ posbuf,
    float* __restrict__ x_intra, unsigned* __restrict__ exv)
{
  __shared__ uint2 xksh[256][17];   // 64 fp16 per row (16 quads), padded row = 34 dwords
  __shared__ float lpw2sh[192], lpb2sh[64];
  __shared__ float iwsh[512], ixwsh[512];
  __shared__ float ibsh[8], ixbsh[8];
  __shared__ float w3sh[64], b3sh[8], s2sh[8], h2ssh[8];
  const int tid = threadIdx.x;
  if (tid < 192) lpw2sh[tid] = lpw2[tid];
  if (tid < 64) { lpb2sh[tid] = lpb2[tid]; w3sh[tid] = m2w3[tid]; }
  for (int idx = tid; idx < 512; idx += 256) { iwsh[idx] = iw[idx]; ixwsh[idx] = ixw[idx]; }
  if (tid < 8) {
    ibsh[tid] = ib[tid]; ixbsh[tid] = ixb[tid];
    b3sh[tid] = m2b3[tid]; s2sh[tid] = cst[S_M2S2 + tid]; h2ssh[tid] = cst[S_M2H2 + tid];
  }
  __syncthreads();

  const size_t g = (size_t)blockIdx.x * 256 + tid;
  const int j = knn[g];
  const unsigned* zr = (const unsigned*)(zb + (size_t)j * 64);
  const int pos = posbuf[g];

  uint2 uc = *(const uint2*)(uqn + g * 2);
  const float qn0 = lo16(uc.x), qn1 = hi16(uc.x), qn2 = lo16(uc.y);

  // fused k-softmax from bf16 h2
  uint4 hu = *(const uint4*)(h2b + g * 8);
  float hn[8];
  hn[0] = fmaxf(fmaf(__uint_as_float(hu.x << 16),        s2sh[0], h2ssh[0]), 0.f);
  hn[1] = fmaxf(fmaf(__uint_as_float(hu.x & 0xffff0000u), s2sh[1], h2ssh[1]), 0.f);
  hn[2] = fmaxf(fmaf(__uint_as_float(hu.y << 16),        s2sh[2], h2ssh[2]), 0.f);
  hn[3] = fmaxf(fmaf(__uint_as_float(hu.y & 0xffff0000u), s2sh[3], h2ssh[3]), 0.f);
  hn[4] = fmaxf(fmaf(__uint_as_float(hu.z << 16),        s2sh[4], h2ssh[4]), 0.f);
  hn[5] = fmaxf(fmaf(__uint_as_float(hu.z & 0xffff0000u), s2sh[5], h2ssh[5]), 0.f);
  hn[6] = fmaxf(fmaf(__uint_as_float(hu.w << 16),        s2sh[6], h2ssh[6]), 0.f);
  hn[7] = fmaxf(fmaf(__uint_as_float(hu.w & 0xffff0000u), s2sh[7], h2ssh[7]), 0.f);
  float wk[8];
  #pragma unroll
  for (int t = 0; t < 8; ++t) {
    float a = b3sh[t];
    #pragma unroll
    for (int u = 0; u < 8; ++u) a = fmaf(hn[u], w3sh[u * 8 + t], a);
    wk[t] = a;
  }
  #pragma unroll
  for (int t = 0; t < 8; ++t) {
    float m = wk[t];
    m = fmaxf(m, __shfl_xor(m, 1));
    m = fmaxf(m, __shfl_xor(m, 2));
    m = fmaxf(m, __shfl_xor(m, 4));
    m = fmaxf(m, __shfl_xor(m, 8));
    float ex = __expf(wk[t] - m);
    float s = ex;
    s += __shfl_xor(s, 1);
    s += __shfl_xor(s, 2);
    s += __shfl_xor(s, 4);
    s += __shfl_xor(s, 8);
    wk[t] = ex / s;
  }

  float sacc[8], vacc[8];
  #pragma unroll
  for (int t = 0; t < 8; ++t) { sacc[t] = ibsh[t]; vacc[t] = ixbsh[t]; }
  uint4 zq;
  #pragma unroll
  for (int c = 0; c < 64; c += 4) {
    if ((c & 7) == 0) zq = *(const uint4*)(zr + (c >> 1));
    const unsigned u0 = ((c & 7) == 0) ? zq.x : zq.z;
    const unsigned u1 = ((c & 7) == 0) ? zq.y : zq.w;
    const float z0 = __uint_as_float(u0 << 16);
    const float z1 = __uint_as_float(u0 & 0xffff0000u);
    const float z2 = __uint_as_float(u1 << 16);
    const float z3 = __uint_as_float(u1 & 0xffff0000u);
    float4 l0 = *(const float4*)(lpw2sh + c);
    float4 l1 = *(const float4*)(lpw2sh + 64 + c);
    float4 l2 = *(const float4*)(lpw2sh + 128 + c);
    float4 lb = *(const float4*)(lpb2sh + c);
    float xkv[4];
    xkv[0] = (z0 + fmaf(qn2, l2.x, fmaf(qn1, l1.x, fmaf(qn0, l0.x, lb.x)))) * wk[(c + 0) & 7];
    xkv[1] = (z1 + fmaf(qn2, l2.y, fmaf(qn1, l1.y, fmaf(qn0, l0.y, lb.y)))) * wk[(c + 1) & 7];
    xkv[2] = (z2 + fmaf(qn2, l2.z, fmaf(qn1, l1.z, fmaf(qn0, l0.z, lb.z)))) * wk[(c + 2) & 7];
    xkv[3] = (z3 + fmaf(qn2, l2.w, fmaf(qn1, l1.w, fmaf(qn0, l0.w, lb.w)))) * wk[(c + 3) & 7];
    xksh[tid][c >> 2] = make_uint2(packh2(xkv[0], xkv[1]), packh2(xkv[2], xkv[3]));
    #pragma unroll
    for (int d = 0; d < 4; ++d) {
      const float xk = xkv[d];
      const float* iwc = iwsh + (c + d) * 8;
      const float* ixwc = ixwsh + (c + d) * 8;
      float4 a0 = *(const float4*)(iwc);
      float4 a1 = *(const float4*)(iwc + 4);
      float4 b0 = *(const float4*)(ixwc);
      float4 b1 = *(const float4*)(ixwc + 4);
      sacc[0] = fmaf(xk, a0.x, sacc[0]); sacc[1] = fmaf(xk, a0.y, sacc[1]); sacc[2] = fmaf(xk, a0.z, sacc[2]); sacc[3] = fmaf(xk, a0.w, sacc[3]);
      sacc[4] = fmaf(xk, a1.x, sacc[4]); sacc[5] = fmaf(xk, a1.y, sacc[5]); sacc[6] = fmaf(xk, a1.z, sacc[6]); sacc[7] = fmaf(xk, a1.w, sacc[7]);
      vacc[0] = fmaf(xk, b0.x, vacc[0]); vacc[1] = fmaf(xk, b0.y, vacc[1]); vacc[2] = fmaf(xk, b0.z, vacc[2]); vacc[3] = fmaf(xk, b0.w, vacc[3]);
      vacc[4] = fmaf(xk, b1.x, vacc[4]); vacc[5] = fmaf(xk, b1.y, vacc[5]); vacc[6] = fmaf(xk, b1.z, vacc[6]); vacc[7] = fmaf(xk, b1.w, vacc[7]);
    }
  }
  float ex[8];
  #pragma unroll
  for (int t = 0; t < 8; ++t) ex[t] = __expf(sacc[t]);
  uint4 ea, eb;
  ea.x = packh2(ex[0], ex[1]); ea.y = packh2(ex[2], ex[3]);
  ea.z = packh2(ex[4], ex[5]); ea.w = packh2(ex[6], ex[7]);
  eb.x = packh2(ex[0] * vacc[0], ex[1] * vacc[1]);
  eb.y = packh2(ex[2] * vacc[2], ex[3] * vacc[3]);
  eb.z = packh2(ex[4] * vacc[4], ex[5] * vacc[5]);
  eb.w = packh2(ex[6] * vacc[6], ex[7] * vacc[7]);
  *(uint4*)(exv + (size_t)pos * 8) = ea;
  *(uint4*)(exv + (size_t)pos * 8 + 4) = eb;

  // x_intra: LDS-staged reduce over the 16 edges of each node
  __syncthreads();
  const int base = tid & ~15;
  const int own = tid & 15;
  float o0 = 0.f, o1 = 0.f, o2 = 0.f, o3 = 0.f;
  #pragma unroll
  for (int k = 0; k < 16; ++k) {
    uint2 v = xksh[base + k][own];
    o0 += lo16(v.x); o1 += hi16(v.x);
    o2 += lo16(v.y); o3 += hi16(v.y);
  }
  const size_t i = g >> 4;
  *(float4*)(x_intra + i * 64 + own * 4) = make_float4(o0, o1, o2, o3);
}

// ---------------- K5: streaming segment reduce (fp16) + x2 + bn2 partials ----------------
__global__ __launch_bounds__(256) void k_inter_x2(
    const int* __restrict__ rowstart, const unsigned* __restrict__ exv,
    float* __restrict__ xi, float* __restrict__ partial)
{
  __shared__ float bsum[64], bsq[64];
  const int tid = threadIdx.x;
  if (tid < 64) { bsum[tid] = 0.f; bsq[tid] = 0.f; }
  __syncthreads();
  const int t = tid & 15;
  const int j = blockIdx.x * 16 + (tid >> 4);
  const int s0 = rowstart[j];
  const int e0 = rowstart[j + 1];
  const unsigned short* eh = (const unsigned short*)exv;
  float acc = 0.f;
  for (int e = s0; e < e0; ++e) acc += h2f(eh[(size_t)e * 16 + t]);
  const float other = __shfl_xor(acc, 8);
  float r = (t < 8) ? ((acc > 0.f) ? other / acc : 0.f)
                    : ((other > 0.f) ? acc / other : 0.f);
  float4 xv = *(const float4*)(xi + (size_t)j * 64 + t * 4);
  float v0 = xv.x + __shfl(r, (4 * t + 0) & 7, 16);
  float v1 = xv.y + __shfl(r, (4 * t + 1) & 7, 16);
  float v2 = xv.z + __shfl(r, (4 * t + 2) & 7, 16);
  float v3 = xv.w + __shfl(r, (4 * t + 3) & 7, 16);
  *(float4*)(xi + (size_t)j * 64 + t * 4) = make_float4(v0, v1, v2, v3);
  float s_[4] = {v0, v1, v2, v3};
  float q_[4] = {v0 * v0, v1 * v1, v2 * v2, v3 * v3};
  #pragma unroll
  for (int d = 0; d < 4; ++d) {
    s_[d] += __shfl_xor(s_[d], 16); s_[d] += __shfl_xor(s_[d], 32);
    q_[d] += __shfl_xor(q_[d], 16); q_[d] += __shfl_xor(q_[d], 32);
  }
  if ((tid & 63) < 16) {
    #pragma unroll
    for (int d = 0; d < 4; ++d) {
      atomicAdd(&bsum[4 * t + d], s_[d]);
      atomicAdd(&bsq[4 * t + d], q_[d]);
    }
  }
  __syncthreads();
  if (tid < 64) {
    partial[(size_t)tid * gridDim.x + blockIdx.x] = bsum[tid];
    partial[(size_t)(tid + 64) * gridDim.x + blockIdx.x] = bsq[tid];
  }
}

// ---------------- K6: final bn3 + residual + relu ----------------
__global__ __launch_bounds__(256) void k_out(
    const float* __restrict__ y3, const float* __restrict__ x0,
    const float* __restrict__ cst, float* __restrict__ out)
{
  __shared__ float scsh[64], shsh[64];
  const int tid = threadIdx.x;
  if (tid < 64) { scsh[tid] = cst[S_SC3 + tid]; shsh[tid] = cst[S_SH3 + tid]; }
  __syncthreads();
  const size_t i = ((size_t)blockIdx.x * 256 + tid) * 4;
  float4 y = *(const float4*)(y3 + i);
  float4 x = *(const float4*)(x0 + i);
  const int c = (int)(i & 63);
  float4 o;
  o.x = fmaxf(fmaf(y.x, scsh[c + 0], shsh[c + 0]) + x.x, 0.f);
  o.y = fmaxf(fmaf(y.y, scsh[c + 1], shsh[c + 1]) + x.y, 0.f);
  o.z = fmaxf(fmaf(y.z, scsh[c + 2], shsh[c + 2]) + x.z, 0.f);
  o.w = fmaxf(fmaf(y.w, scsh[c + 3], shsh[c + 3]) + x.w, 0.f);
  *(float4*)(out + i) = o;
}

// ---------------- launch ----------------
extern "C" void kernel_launch(void* const* d_in, const int* in_sizes, int n_in,
                              void* d_out, int out_size, void* d_ws, size_t ws_size,
                              hipStream_t stream)
{
  (void)n_in; (void)out_size; (void)ws_size;
  const float* p    = (const float*)d_in[0];
  const float* x    = (const float*)d_in[1];
  const int*   knn  = (const int*)d_in[2];
  const float* w1   = (const float*)d_in[3];
  const float* g1   = (const float*)d_in[4];
  const float* b1   = (const float*)d_in[5];
  const float* m1w1 = (const float*)d_in[6];
  const float* m1b1 = (const float*)d_in[7];
  const float* m1w2 = (const float*)d_in[8];
  const float* m1b2 = (const float*)d_in[9];
  const float* lpw1 = (const float*)d_in[10];
  const float* lpb1 = (const float*)d_in[11];
  const float* lpg  = (const float*)d_in[12];
  const float* lpbt = (const float*)d_in[13];
  const float* lpw2 = (const float*)d_in[14];
  const float* lpb2 = (const float*)d_in[15];
  const float* m2w1 = (const float*)d_in[16];
  const float* m2g1 = (const float*)d_in[17];
  const float* m2bt1= (const float*)d_in[18];
  const float* m2w2 = (const float*)d_in[19];
  const float* m2g2 = (const float*)d_in[20];
  const float* m2bt2= (const float*)d_in[21];
  const float* m2w3 = (const float*)d_in[22];
  const float* m2b3 = (const float*)d_in[23];
  const float* m3w  = (const float*)d_in[24];
  const float* m3b  = (const float*)d_in[25];
  const float* iw   = (const float*)d_in[26];
  const float* ib   = (const float*)d_in[27];
  const float* ixw  = (const float*)d_in[28];
  const float* ixb  = (const float*)d_in[29];
  const float* g2   = (const float*)d_in[30];
  const float* b2   = (const float*)d_in[31];
  const float* w3   = (const float*)d_in[32];
  const float* g3   = (const float*)d_in[33];
  const float* b3   = (const float*)d_in[34];
  float* out = (float*)d_out;
  float* ws  = (float*)d_ws;

  const int n = in_sizes[1] / 64;                // 32768
  const long long nk = (long long)n * 16;        // 524288

  float* cst  = ws;
  int* cnt      = (int*)(ws + CONST_FLOATS);    // n ints (zeroed with cst)
  int* rowstart = cnt + n;                      // n+1 ints (+pad)
  int* rank     = rowstart + n + 16;            // nk ints
  int* posb     = rank + nk;                    // nk ints
  unsigned short* zb = (unsigned short*)(posb + nk);  // 64n bf16 = 32n words
  float* y1 = (float*)(zb + 64LL * n);          // 64n, reused as y3
  float* xi = y1 + 64LL * n;                    // 64n
  float* pr = xi + 64LL * n;                    // 48n
  float* y16 = pr + 48LL * n;                   // 16n
  unsigned short* h2b = (unsigned short*)(y16 + 16LL * n);  // 128n ushorts
  unsigned* exv = (unsigned*)(h2b + 128LL * n); // 128n uints

  const int gB   = n / 64;            // 512
  const int nkB  = (int)(nk / 256);   // 2048
  const int nkB2 = (int)(nk / 512);   // 1024
  const int jB   = n / 16;            // 2048

  float* pbn1  = (float*)(exv + 128LL * n);      // 128 * gB
  float* plp   = pbn1 + 128LL * gB;              // 8 * nkB
  float* pmom  = plp + 8LL * nkB;                // 210 * nkB
  float* s2buf = pmom + 210LL * nkB;             // 256
  float* pm2b2 = s2buf + 256;                    // 16 * nkB2
  float* pbn2  = pm2b2 + 16LL * nkB2;            // 128 * jB
  float* pbn3  = pbn2 + 128LL * jB;              // 128 * gB
  unsigned* uq = (unsigned*)(pbn3 + 128LL * gB); // 8 * nk uints
  unsigned* uqn = uq + 8LL * nk;                 // 2 * nk uints

  hipMemsetAsync(d_ws, 0, (size_t)CONST_FLOATS * sizeof(float) + (size_t)n * sizeof(int), stream);

  k_prhist<<<nkB, 256, 0, stream>>>(p, knn, lpw1, lpb1, pr, plp, cnt, rank);
  k_gemm64<<<gB, 256, 0, stream>>>(x, w1, nullptr, nullptr, nullptr, y1, pbn1, n);
  k_scan_mid<<<1, 1024, 0, stream>>>(cnt, rowstart, n, plp, nkB,
                                     lpg, lpbt, lpw1, lpb1, lpw2, lpb2,
                                     m1w2, m2w1, m1b2, cst, 1.f / (float)nk);
  k_rbn<<<64, 256, 0, stream>>>(pbn1, gB, 64, g1, b1, cst + S_SC1, cst + S_SH1, 1.f / (float)n);
  // z(bf16) + y16 in one pass
  k_gemmzy<<<gB, 256, 0, stream>>>(y1, m3w, m3b, m1w1 + 48, cst + S_SC1, cst + S_SH1, zb, y16);
  // h1 BN stats via u-moments; also emits uq/uqn/pos
  k_moment<<<nkB, 256, 0, stream>>>(y16, pr, knn, m1w1, m1b1, cst, rowstart, rank,
                                    pmom, uq, uqn, posb);
  k_mred<<<210, 256, 0, stream>>>(pmom, s2buf, nkB);
  k_mfin<<<1, 64, 0, stream>>>(s2buf, m2g1, m2bt1, cst, 1.f / (float)nk);
  // h2 (bf16) from uq/uqn + stats
  k_h2<<<nkB2, 256, 0, stream>>>(uq, uqn, cst, m2w2, h2b, pm2b2);
  k_rbn<<<8, 256, 0, stream>>>(pm2b2, nkB2, 8, m2g2, m2bt2, cst + S_M2S2, cst + S_M2H2, 1.f / (float)nk);
  // fused softmax + xk + x_intra + exv
  k_intra<<<nkB, 256, 0, stream>>>(zb, uqn, knn, cst, lpw2, lpb2, iw, ib, ixw, ixb,
                                   h2b, m2w3, m2b3, posb, xi, exv);
  // streaming segment reduce + x2 + bn2 partials
  k_inter_x2<<<jB, 256, 0, stream>>>(rowstart, exv, xi, pbn2);
  k_rbn<<<64, 256, 0, stream>>>(pbn2, jB, 64, g2, b2, cst + S_SC2, cst + S_SH2, 1.f / (float)n);
  // y3 = relu(bn2(x2)) @ w3, bn3
  k_gemm64<<<gB, 256, 0, stream>>>(xi, w3, nullptr, cst + S_SC2, cst + S_SH2, y1, pbn3, n);
  k_rbn<<<64, 256, 0, stream>>>(pbn3, gB, 64, g3, b3, cst + S_SC3, cst + S_SH3, 1.f / (float)n);
  // out = relu(bn3(y3) + x)
  k_out<<<(int)((long long)n * 64 / 1024), 256, 0, stream>>>(y1, x, cst, out);
}

// Round 14
// 300.406 us; speedup vs baseline: 1.4969x; 1.1245x over previous
//
#include <hip/hip_runtime.h>

// N = 32768 (runtime), C = 64, K = 16, CS = 8, SHARE = 8

enum {
  S_SC1 = 0,    S_SH1 = 64,
  S_LPSC = 128, S_LPSH = 132,
  S_M2S1 = 136, S_M2H1 = 200,
  S_M2S2 = 264, S_M2H2 = 272,
  S_SC2 = 280,  S_SH2 = 344,
  S_SC3 = 408,  S_SH3 = 472,
  S_LPW2S = 536, S_LPB2S = 584,
  S_QW = 600, S_QB = 612,
  S_G = 640,        // 64x16 c-major
  S_HC = 1664,      // 64x4 c-major
  S_HB = 1920,      // 64
  CONST_FLOATS = 2048
};

typedef _Float16 h2 __attribute__((ext_vector_type(2)));

__device__ __forceinline__ int pidx(int a, int b) {  // a<=b, 20-dim sym
  return a * 20 - (a * (a - 1)) / 2 + (b - a);
}
__device__ __forceinline__ unsigned short bf16r(float f) {
  unsigned u = __float_as_uint(f);
  u = u + 0x7fffu + ((u >> 16) & 1u);
  return (unsigned short)(u >> 16);
}
__device__ __forceinline__ unsigned short f2h(float f) {
  _Float16 h = (_Float16)f;
  unsigned short u;
  __builtin_memcpy(&u, &h, 2);
  return u;
}
__device__ __forceinline__ float h2f(unsigned short u) {
  _Float16 h;
  __builtin_memcpy(&h, &u, 2);
  return (float)h;
}
__device__ __forceinline__ unsigned packh2(float a, float b) {
  return (unsigned)f2h(a) | ((unsigned)f2h(b) << 16);
}
__device__ __forceinline__ float lo16(unsigned u) { return h2f((unsigned short)(u & 0xffffu)); }
__device__ __forceinline__ float hi16(unsigned u) { return h2f((unsigned short)(u >> 16)); }
__device__ __forceinline__ h2 mkh2(float a, float b) {
  h2 v; v[0] = (_Float16)a; v[1] = (_Float16)b; return v;
}

// ---------------- fused partial-reduce + BN finalize ----------------
__global__ __launch_bounds__(256) void k_rbn(
    const float* __restrict__ partial, int nb, int nch,
    const float* __restrict__ g, const float* __restrict__ b,
    float* __restrict__ scale, float* __restrict__ shift, float inv_count)
{
  const int c = blockIdx.x;
  const int tid = threadIdx.x;
  float s = 0.f, q = 0.f;
  for (int i = tid; i < nb; i += 256) {
    s += partial[(size_t)c * nb + i];
    q += partial[(size_t)(c + nch) * nb + i];
  }
  #pragma unroll
  for (int m = 1; m < 64; m <<= 1) { s += __shfl_xor(s, m); q += __shfl_xor(q, m); }
  __shared__ float ws[4], wq[4];
  if ((tid & 63) == 0) { ws[tid >> 6] = s; wq[tid >> 6] = q; }
  __syncthreads();
  if (tid == 0) {
    float S = ws[0] + ws[1] + ws[2] + ws[3];
    float Q = wq[0] + wq[1] + wq[2] + wq[3];
    float m = S * inv_count;
    float v = Q * inv_count - m * m;
    float rs = rsqrtf(v + 1e-5f);
    float sc = g[c] * rs;
    scale[c] = sc;
    shift[c] = fmaf(-m, sc, b[c]);
  }
}

// ---------------- generic 64x64 GEMM (f32 out) ----------------
__global__ __launch_bounds__(256) void k_gemm64(
    const float* __restrict__ in, const float* __restrict__ w,
    const float* __restrict__ bias,
    const float* __restrict__ sc, const float* __restrict__ sh,
    float* __restrict__ out,
    float* __restrict__ partial, int n)
{
  __shared__ float scsh[64], shsh[64];
  __shared__ float bsum[64], bsq[64];
  const int tid = threadIdx.x;
  const int lane = tid & 63;
  const int wave = tid >> 6;
  if (sc != nullptr && tid < 64) { scsh[tid] = sc[tid]; shsh[tid] = sh[tid]; }
  if (tid < 64) { bsum[tid] = 0.f; bsq[tid] = 0.f; }
  __syncthreads();

  float wreg[64];
  #pragma unroll
  for (int k = 0; k < 64; ++k) wreg[k] = w[k * 64 + lane];
  const float bz = bias ? bias[lane] : 0.f;

  float lsum = 0.f, lsq = 0.f;
  const int row0 = (blockIdx.x * 4 + wave) * 16;
  for (int r = 0; r < 16; ++r) {
    const int row = row0 + r;
    const float* xr = in + (size_t)row * 64;
    float acc = bz;
    if (sc != nullptr) {
      #pragma unroll
      for (int k = 0; k < 64; k += 4) {
        float4 xv = *(const float4*)(xr + k);
        float x0 = fmaxf(fmaf(xv.x, scsh[k + 0], shsh[k + 0]), 0.f);
        float x1 = fmaxf(fmaf(xv.y, scsh[k + 1], shsh[k + 1]), 0.f);
        float x2 = fmaxf(fmaf(xv.z, scsh[k + 2], shsh[k + 2]), 0.f);
        float x3 = fmaxf(fmaf(xv.w, scsh[k + 3], shsh[k + 3]), 0.f);
        acc = fmaf(x0, wreg[k + 0], acc);
        acc = fmaf(x1, wreg[k + 1], acc);
        acc = fmaf(x2, wreg[k + 2], acc);
        acc = fmaf(x3, wreg[k + 3], acc);
      }
    } else {
      #pragma unroll
      for (int k = 0; k < 64; k += 4) {
        float4 xv = *(const float4*)(xr + k);
        acc = fmaf(xv.x, wreg[k + 0], acc);
        acc = fmaf(xv.y, wreg[k + 1], acc);
        acc = fmaf(xv.z, wreg[k + 2], acc);
        acc = fmaf(xv.w, wreg[k + 3], acc);
      }
    }
    out[(size_t)row * 64 + lane] = acc;
    lsum += acc;
    lsq = fmaf(acc, acc, lsq);
  }
  if (partial != nullptr) {
    atomicAdd(&bsum[lane], lsum);
    atomicAdd(&bsq[lane], lsq);
    __syncthreads();
    if (tid < 64) {
      partial[(size_t)tid * gridDim.x + blockIdx.x] = bsum[tid];
      partial[(size_t)(tid + 64) * gridDim.x + blockIdx.x] = bsq[tid];
    }
  }
}

// ---------------- fused: z (bf16) = nr(y1)@m3w+m3b ; y16 = nr(y1)@m1w1[3:] ----------------
__global__ __launch_bounds__(256) void k_gemmzy(
    const float* __restrict__ in, const float* __restrict__ w,
    const float* __restrict__ bias, const float* __restrict__ w16,
    const float* __restrict__ sc, const float* __restrict__ sh,
    unsigned short* __restrict__ outz, float* __restrict__ out16)
{
  __shared__ float xn[64][68];
  __shared__ float w16sh[1024];
  __shared__ float scsh[64], shsh[64];
  const int tid = threadIdx.x;
  if (tid < 64) { scsh[tid] = sc[tid]; shsh[tid] = sh[tid]; }
  for (int i2 = tid; i2 < 1024; i2 += 256) w16sh[i2] = w16[i2];
  __syncthreads();
  const int row0 = blockIdx.x * 64;
  for (int idx = tid; idx < 4096; idx += 256) {
    int r = idx >> 6, c = idx & 63;
    float v = in[(size_t)(row0 + r) * 64 + c];
    xn[r][c] = fmaxf(fmaf(v, scsh[c], shsh[c]), 0.f);
  }
  __syncthreads();

  const int lane = tid & 63;
  const int wave = tid >> 6;
  float wreg[64];
  #pragma unroll
  for (int k = 0; k < 64; ++k) wreg[k] = w[k * 64 + lane];
  const float bz = bias[lane];
  for (int r = wave * 16; r < wave * 16 + 16; ++r) {
    float acc = bz;
    #pragma unroll
    for (int k = 0; k < 64; k += 4) {
      float4 xv = *(const float4*)(&xn[r][k]);
      acc = fmaf(xv.x, wreg[k + 0], acc);
      acc = fmaf(xv.y, wreg[k + 1], acc);
      acc = fmaf(xv.z, wreg[k + 2], acc);
      acc = fmaf(xv.w, wreg[k + 3], acc);
    }
    outz[(size_t)(row0 + r) * 64 + lane] = bf16r(acc);
  }
  for (int idx = tid; idx < 1024; idx += 256) {
    int r = idx >> 4, t = idx & 15;
    float acc = 0.f;
    #pragma unroll
    for (int c = 0; c < 64; c += 4) {
      float4 xv = *(const float4*)(&xn[r][c]);
      acc = fmaf(xv.x, w16sh[(c + 0) * 16 + t], acc);
      acc = fmaf(xv.y, w16sh[(c + 1) * 16 + t], acc);
      acc = fmaf(xv.z, w16sh[(c + 2) * 16 + t], acc);
      acc = fmaf(xv.w, w16sh[(c + 3) * 16 + t], acc);
    }
    out16[(size_t)(row0 + r) * 16 + t] = acc;
  }
}

// ---------------- K1: lp partials, histogram + rank ----------------
__global__ __launch_bounds__(256) void k_prhist(
    const float* __restrict__ p, const int* __restrict__ knn,
    const float* __restrict__ lpw1, const float* __restrict__ lpb1,
    float* __restrict__ plp,
    int* __restrict__ cnt, int* __restrict__ rank)
{
  __shared__ float lpw1sh[9], lpb1sh[3];
  __shared__ float lpsh[4][8];
  const int tid = threadIdx.x;
  if (tid < 9) lpw1sh[tid] = lpw1[tid];
  if (tid < 3) lpb1sh[tid] = lpb1[tid];
  __syncthreads();

  const size_t g = (size_t)blockIdx.x * 256 + tid;
  const int i = (int)(g >> 4);
  const int j = knn[g];
  const float pr0 = p[j * 3 + 0] - p[i * 3 + 0];
  const float pr1 = p[j * 3 + 1] - p[i * 3 + 1];
  const float pr2 = p[j * 3 + 2] - p[i * 3 + 2];
  rank[g] = atomicAdd(&cnt[j], 1);

  float q0 = fmaf(pr2, lpw1sh[6], fmaf(pr1, lpw1sh[3], fmaf(pr0, lpw1sh[0], lpb1sh[0])));
  float q1 = fmaf(pr2, lpw1sh[7], fmaf(pr1, lpw1sh[4], fmaf(pr0, lpw1sh[1], lpb1sh[1])));
  float q2 = fmaf(pr2, lpw1sh[8], fmaf(pr1, lpw1sh[5], fmaf(pr0, lpw1sh[2], lpb1sh[2])));
  float s0 = q0, s1 = q1, s2 = q2, qq0 = q0 * q0, qq1 = q1 * q1, qq2 = q2 * q2;
  #pragma unroll
  for (int m = 1; m < 64; m <<= 1) {
    s0 += __shfl_xor(s0, m); s1 += __shfl_xor(s1, m); s2 += __shfl_xor(s2, m);
    qq0 += __shfl_xor(qq0, m); qq1 += __shfl_xor(qq1, m); qq2 += __shfl_xor(qq2, m);
  }
  if ((tid & 63) == 0) {
    const int w = tid >> 6;
    lpsh[w][0] = s0; lpsh[w][1] = s1; lpsh[w][2] = s2; lpsh[w][3] = 0.f;
    lpsh[w][4] = qq0; lpsh[w][5] = qq1; lpsh[w][6] = qq2; lpsh[w][7] = 0.f;
  }
  __syncthreads();
  if (tid < 8) {
    float v = lpsh[0][tid] + lpsh[1][tid] + lpsh[2][tid] + lpsh[3][tid];
    plp[(size_t)tid * gridDim.x + blockIdx.x] = v;
  }
}

// ---------------- merged: CSR scan + lp finalize + weight folding ----------------
__global__ __launch_bounds__(1024) void k_scan_mid(
    const int* __restrict__ cnt, int* __restrict__ rowstart, int n,
    const float* __restrict__ plp, int nbplp,
    const float* __restrict__ lpg, const float* __restrict__ lpbt,
    const float* __restrict__ lpw1, const float* __restrict__ lpb1,
    const float* __restrict__ lpw2, const float* __restrict__ lpb2,
    const float* __restrict__ m1w2, const float* __restrict__ m2w1,
    const float* __restrict__ m1b2,
    float* __restrict__ cst, float inv_count)
{
  __shared__ int tsum[1024];
  __shared__ float Ssh[8];
  const int tid = threadIdx.x;
  const int per = n >> 10;
  const int base = tid * per;
  int local[32];
  int s = 0;
  for (int u = 0; u < per; ++u) { local[u] = cnt[base + u]; s += local[u]; }
  tsum[tid] = s;
  __syncthreads();
  for (int off = 1; off < 1024; off <<= 1) {
    int v = (tid >= off) ? tsum[tid - off] : 0;
    __syncthreads();
    tsum[tid] += v;
    __syncthreads();
  }
  int run = tsum[tid] - s;
  for (int u = 0; u < per; ++u) { rowstart[base + u] = run; run += local[u]; }
  if (tid == 1023) rowstart[n] = run;

  if (tid < 256) {
    const int row = tid >> 5, l32 = tid & 31;
    float ls = 0.f;
    for (int i = l32; i < nbplp; i += 32) ls += plp[(size_t)row * nbplp + i];
    #pragma unroll
    for (int m = 1; m < 32; m <<= 1) ls += __shfl_xor(ls, m);
    if (l32 == 0) Ssh[row] = ls;
  }
  __syncthreads();
  if (tid < 3) {
    float m = Ssh[tid] * inv_count;
    float v = Ssh[4 + tid] * inv_count - m * m;
    float rs = rsqrtf(v + 1e-5f);
    float sc = lpg[tid] * rs;
    cst[S_LPSC + tid] = sc;
    cst[S_LPSH + tid] = fmaf(-m, sc, lpbt[tid]);
  }
  __syncthreads();
  if (tid < 9)  cst[S_QW + tid] = lpw1[tid] * cst[S_LPSC + (tid % 3)];
  if (tid < 3)  cst[S_QB + tid] = fmaf(lpb1[tid], cst[S_LPSC + tid], cst[S_LPSH + tid]);
  if (tid < 16) {
    float b = 0.f;
    for (int c2 = 0; c2 < 4; ++c2) b += lpb2[c2 * 16 + tid];
    cst[S_LPB2S + tid] = b;
    for (int r = 0; r < 3; ++r) {
      float w = 0.f;
      for (int c2 = 0; c2 < 4; ++c2) w += lpw2[r * 64 + c2 * 16 + tid];
      cst[S_LPW2S + r * 16 + tid] = w;
    }
  }
  __syncthreads();
  if (tid < 256) {
    #pragma unroll
    for (int q = 0; q < 4; ++q) {
      int ee = tid * 4 + q;
      int c = ee >> 4, u = ee & 15;
      float sg = 0.f;
      #pragma unroll
      for (int t = 0; t < 16; ++t) sg = fmaf(m1w2[u * 16 + t], m2w1[t * 64 + c], sg);
      cst[S_G + c * 16 + u] = sg;
    }
  }
  if (tid < 192) {
    int c = tid / 3, r = tid - c * 3;
    float sh = 0.f;
    #pragma unroll
    for (int t = 0; t < 16; ++t) sh = fmaf(cst[S_LPW2S + r * 16 + t], m2w1[(16 + t) * 64 + c], sh);
    cst[S_HC + c * 4 + r] = sh;
  }
  if (tid < 64) {
    cst[S_HC + tid * 4 + 3] = 0.f;
    float sb = 0.f;
    #pragma unroll
    for (int t = 0; t < 16; ++t) {
      sb = fmaf(m1b2[t], m2w1[t * 64 + tid], sb);
      sb = fmaf(cst[S_LPB2S + t], m2w1[(16 + t) * 64 + tid], sb);
    }
    cst[S_HB + tid] = sb;
  }
}

// ---------------- K2: u-moment accumulation + uq/uqn/pos store ----------------
__global__ __launch_bounds__(256) void k_moment(
    const float* __restrict__ y16, const float* __restrict__ p,
    const int* __restrict__ knn, const float* __restrict__ m1w1,
    const float* __restrict__ m1b1, const float* __restrict__ cst,
    const int* __restrict__ rowstart, const int* __restrict__ rank,
    float* __restrict__ pmom,   // [210 * gridDim.x] channel-major
    unsigned* __restrict__ uq,  // [nk * 8] packed fp16 t1[16]
    unsigned* __restrict__ uqn, // [nk * 2] packed fp16 qn[3]
    int* __restrict__ posbuf)   // [nk]
{
  __shared__ float ush[256 * 21];
  const int tid = threadIdx.x;
  const size_t g = (size_t)blockIdx.x * 256 + tid;
  const int i = (int)(g >> 4);
  const int j = knn[g];
  const float pr0 = p[j * 3 + 0] - p[i * 3 + 0];
  const float pr1 = p[j * 3 + 1] - p[i * 3 + 1];
  const float pr2 = p[j * 3 + 2] - p[i * 3 + 2];
  const float* yj = y16 + (size_t)j * 16;
  float4 ya = *(const float4*)(yj);
  float4 yb = *(const float4*)(yj + 4);
  float4 yc = *(const float4*)(yj + 8);
  float4 yd = *(const float4*)(yj + 12);
  float t1[16] = {ya.x, ya.y, ya.z, ya.w, yb.x, yb.y, yb.z, yb.w,
                  yc.x, yc.y, yc.z, yc.w, yd.x, yd.y, yd.z, yd.w};
  #pragma unroll
  for (int u = 0; u < 16; ++u)
    t1[u] = fmaxf(fmaf(pr2, m1w1[32 + u], fmaf(pr1, m1w1[16 + u],
                  fmaf(pr0, m1w1[u], t1[u] + m1b1[u]))), 0.f);
  const float qn0 = fmaxf(fmaf(pr2, cst[S_QW + 6], fmaf(pr1, cst[S_QW + 3], fmaf(pr0, cst[S_QW + 0], cst[S_QB + 0]))), 0.f);
  const float qn1 = fmaxf(fmaf(pr2, cst[S_QW + 7], fmaf(pr1, cst[S_QW + 4], fmaf(pr0, cst[S_QW + 1], cst[S_QB + 1]))), 0.f);
  const float qn2 = fmaxf(fmaf(pr2, cst[S_QW + 8], fmaf(pr1, cst[S_QW + 5], fmaf(pr0, cst[S_QW + 2], cst[S_QB + 2]))), 0.f);

  posbuf[g] = rowstart[j] + rank[g];

  uint4 ua, ub;
  ua.x = packh2(t1[0], t1[1]);   ua.y = packh2(t1[2], t1[3]);
  ua.z = packh2(t1[4], t1[5]);   ua.w = packh2(t1[6], t1[7]);
  ub.x = packh2(t1[8], t1[9]);   ub.y = packh2(t1[10], t1[11]);
  ub.z = packh2(t1[12], t1[13]); ub.w = packh2(t1[14], t1[15]);
  *(uint4*)(uq + g * 8)     = ua;
  *(uint4*)(uq + g * 8 + 4) = ub;
  uint2 uc;
  uc.x = packh2(qn0, qn1);
  uc.y = packh2(qn2, 0.f);
  *(uint2*)(uqn + g * 2) = uc;

  float* ur = ush + tid * 21;
  #pragma unroll
  for (int u = 0; u < 16; ++u) ur[u] = t1[u];
  ur[16] = qn0; ur[17] = qn1; ur[18] = qn2; ur[19] = 1.f;
  __syncthreads();

  if (tid < 210) {
    int a = 0, t = tid;
    while (t >= 20 - a) { t -= 20 - a; ++a; }
    const int b = a + t;
    float s = 0.f;
    // unstaggered: all lanes read row r (broadcast + <=20 consecutive addrs -> conflict-free)
    for (int r = 0; r < 256; ++r) {
      const float* u = ush + r * 21;
      s = fmaf(u[a], u[b], s);
    }
    pmom[(size_t)tid * gridDim.x + blockIdx.x] = s;
  }
}

// ---------------- parallel moment reduce ----------------
__global__ __launch_bounds__(256) void k_mred(
    const float* __restrict__ pmom, float* __restrict__ S2, int nb)
{
  const int c = blockIdx.x;
  const int tid = threadIdx.x;
  float s = 0.f;
  for (int i = tid; i < nb; i += 256) s += pmom[(size_t)c * nb + i];
  #pragma unroll
  for (int m = 1; m < 64; m <<= 1) s += __shfl_xor(s, m);
  __shared__ float ws[4];
  if ((tid & 63) == 0) ws[tid >> 6] = s;
  __syncthreads();
  if (tid == 0) S2[c] = ws[0] + ws[1] + ws[2] + ws[3];
}

// ---------------- moment finalize ----------------
__global__ __launch_bounds__(64) void k_mfin(
    const float* __restrict__ S2in,
    const float* __restrict__ g, const float* __restrict__ b,
    float* __restrict__ cst, float inv_count)
{
  __shared__ float S2[210];
  const int tid = threadIdx.x;
  for (int i = tid; i < 210; i += 64) S2[i] = S2in[i];
  __syncthreads();
  const int c = tid;
  float w[20];
  #pragma unroll
  for (int u = 0; u < 16; ++u) w[u] = cst[S_G + c * 16 + u];
  w[16] = cst[S_HC + c * 4 + 0];
  w[17] = cst[S_HC + c * 4 + 1];
  w[18] = cst[S_HC + c * 4 + 2];
  w[19] = cst[S_HB + c];
  float m2 = 0.f, m1 = 0.f;
  for (int a = 0; a < 20; ++a) {
    const float wa = w[a];
    m2 = fmaf(wa * wa, S2[pidx(a, a)], m2);
    float cross = 0.f;
    for (int bb = a + 1; bb < 20; ++bb) cross = fmaf(w[bb], S2[pidx(a, bb)], cross);
    m2 = fmaf(2.f * wa, cross, m2);
    m1 = fmaf(wa, S2[pidx(a, 19)], m1);
  }
  const float mean = m1 * inv_count;
  const float var = m2 * inv_count - mean * mean;
  const float rs = rsqrtf(var + 1e-5f);
  const float sc = g[c] * rs;
  cst[S_M2S1 + c] = sc;
  cst[S_M2H1 + c] = fmaf(-mean, sc, b[c]);
}

// ---------------- K3: h2(bf16) from packed uq/uqn via folded G/H ----------------
__global__ __launch_bounds__(256) void k_h2(
    const unsigned* __restrict__ uq, const unsigned* __restrict__ uqn,
    const float* __restrict__ cst, const float* __restrict__ m2w2,
    unsigned short* __restrict__ h2out,
    float* __restrict__ partial)   // [16 * gridDim.x]
{
  __shared__ float Gsh[1024], Hsh[256], hbsh[64];
  __shared__ float w2m[512];
  __shared__ float scsh[64], shsh[64];
  __shared__ float redsh[4][16];
  const int tid = threadIdx.x;
  for (int i = tid; i < 1024; i += 256) Gsh[i] = cst[S_G + i];
  Hsh[tid] = cst[S_HC + tid];
  for (int i = tid; i < 512; i += 256) w2m[i] = m2w2[i];
  if (tid < 64) { hbsh[tid] = cst[S_HB + tid]; scsh[tid] = cst[S_M2S1 + tid]; shsh[tid] = cst[S_M2H1 + tid]; }
  __syncthreads();

  const size_t g0 = ((size_t)blockIdx.x * 256 + tid) * 2;
  float t1[2][16], qn[2][3];
  #pragma unroll
  for (int gg = 0; gg < 2; ++gg) {
    const size_t g = g0 + gg;
    uint4 ua = *(const uint4*)(uq + g * 8);
    uint4 ub = *(const uint4*)(uq + g * 8 + 4);
    uint2 uc = *(const uint2*)(uqn + g * 2);
    t1[gg][0] = lo16(ua.x);  t1[gg][1] = hi16(ua.x);
    t1[gg][2] = lo16(ua.y);  t1[gg][3] = hi16(ua.y);
    t1[gg][4] = lo16(ua.z);  t1[gg][5] = hi16(ua.z);
    t1[gg][6] = lo16(ua.w);  t1[gg][7] = hi16(ua.w);
    t1[gg][8] = lo16(ub.x);  t1[gg][9] = hi16(ub.x);
    t1[gg][10] = lo16(ub.y); t1[gg][11] = hi16(ub.y);
    t1[gg][12] = lo16(ub.z); t1[gg][13] = hi16(ub.z);
    t1[gg][14] = lo16(ub.w); t1[gg][15] = hi16(ub.w);
    qn[gg][0] = lo16(uc.x); qn[gg][1] = hi16(uc.x); qn[gg][2] = lo16(uc.y);
  }

  float a0[8], a1[8];
  #pragma unroll
  for (int t = 0; t < 8; ++t) { a0[t] = 0.f; a1[t] = 0.f; }
  for (int c = 0; c < 64; ++c) {
    float4 g0v = *(const float4*)(Gsh + c * 16);
    float4 g1v = *(const float4*)(Gsh + c * 16 + 4);
    float4 g2v = *(const float4*)(Gsh + c * 16 + 8);
    float4 g3v = *(const float4*)(Gsh + c * 16 + 12);
    float4 hv = *(const float4*)(Hsh + c * 4);
    float h_0 = hbsh[c], h_1 = hbsh[c];
    h_0 = fmaf(t1[0][0], g0v.x, h_0); h_0 = fmaf(t1[0][1], g0v.y, h_0); h_0 = fmaf(t1[0][2], g0v.z, h_0); h_0 = fmaf(t1[0][3], g0v.w, h_0);
    h_0 = fmaf(t1[0][4], g1v.x, h_0); h_0 = fmaf(t1[0][5], g1v.y, h_0); h_0 = fmaf(t1[0][6], g1v.z, h_0); h_0 = fmaf(t1[0][7], g1v.w, h_0);
    h_0 = fmaf(t1[0][8], g2v.x, h_0); h_0 = fmaf(t1[0][9], g2v.y, h_0); h_0 = fmaf(t1[0][10], g2v.z, h_0); h_0 = fmaf(t1[0][11], g2v.w, h_0);
    h_0 = fmaf(t1[0][12], g3v.x, h_0); h_0 = fmaf(t1[0][13], g3v.y, h_0); h_0 = fmaf(t1[0][14], g3v.z, h_0); h_0 = fmaf(t1[0][15], g3v.w, h_0);
    h_0 = fmaf(qn[0][0], hv.x, fmaf(qn[0][1], hv.y, fmaf(qn[0][2], hv.z, h_0)));
    h_1 = fmaf(t1[1][0], g0v.x, h_1); h_1 = fmaf(t1[1][1], g0v.y, h_1); h_1 = fmaf(t1[1][2], g0v.z, h_1); h_1 = fmaf(t1[1][3], g0v.w, h_1);
    h_1 = fmaf(t1[1][4], g1v.x, h_1); h_1 = fmaf(t1[1][5], g1v.y, h_1); h_1 = fmaf(t1[1][6], g1v.z, h_1); h_1 = fmaf(t1[1][7], g1v.w, h_1);
    h_1 = fmaf(t1[1][8], g2v.x, h_1); h_1 = fmaf(t1[1][9], g2v.y, h_1); h_1 = fmaf(t1[1][10], g2v.z, h_1); h_1 = fmaf(t1[1][11], g2v.w, h_1);
    h_1 = fmaf(t1[1][12], g3v.x, h_1); h_1 = fmaf(t1[1][13], g3v.y, h_1); h_1 = fmaf(t1[1][14], g3v.z, h_1); h_1 = fmaf(t1[1][15], g3v.w, h_1);
    h_1 = fmaf(qn[1][0], hv.x, fmaf(qn[1][1], hv.y, fmaf(qn[1][2], hv.z, h_1)));
    float x0 = fmaxf(fmaf(h_0, scsh[c], shsh[c]), 0.f);
    float x1 = fmaxf(fmaf(h_1, scsh[c], shsh[c]), 0.f);
    float4 wa = *(const float4*)(w2m + c * 8);
    float4 wb = *(const float4*)(w2m + c * 8 + 4);
    a0[0] = fmaf(x0, wa.x, a0[0]); a0[1] = fmaf(x0, wa.y, a0[1]); a0[2] = fmaf(x0, wa.z, a0[2]); a0[3] = fmaf(x0, wa.w, a0[3]);
    a0[4] = fmaf(x0, wb.x, a0[4]); a0[5] = fmaf(x0, wb.y, a0[5]); a0[6] = fmaf(x0, wb.z, a0[6]); a0[7] = fmaf(x0, wb.w, a0[7]);
    a1[0] = fmaf(x1, wa.x, a1[0]); a1[1] = fmaf(x1, wa.y, a1[1]); a1[2] = fmaf(x1, wa.z, a1[2]); a1[3] = fmaf(x1, wa.w, a1[3]);
    a1[4] = fmaf(x1, wb.x, a1[4]); a1[5] = fmaf(x1, wb.y, a1[5]); a1[6] = fmaf(x1, wb.z, a1[6]); a1[7] = fmaf(x1, wb.w, a1[7]);
  }
  uint4 pa, pb;
  pa.x = bf16r(a0[0]) | ((unsigned)bf16r(a0[1]) << 16);
  pa.y = bf16r(a0[2]) | ((unsigned)bf16r(a0[3]) << 16);
  pa.z = bf16r(a0[4]) | ((unsigned)bf16r(a0[5]) << 16);
  pa.w = bf16r(a0[6]) | ((unsigned)bf16r(a0[7]) << 16);
  pb.x = bf16r(a1[0]) | ((unsigned)bf16r(a1[1]) << 16);
  pb.y = bf16r(a1[2]) | ((unsigned)bf16r(a1[3]) << 16);
  pb.z = bf16r(a1[4]) | ((unsigned)bf16r(a1[5]) << 16);
  pb.w = bf16r(a1[6]) | ((unsigned)bf16r(a1[7]) << 16);
  *(uint4*)(h2out + g0 * 8) = pa;
  *(uint4*)(h2out + g0 * 8 + 8) = pb;

  float st[8], sq[8];
  #pragma unroll
  for (int t = 0; t < 8; ++t) {
    st[t] = a0[t] + a1[t];
    sq[t] = fmaf(a0[t], a0[t], a1[t] * a1[t]);
  }
  #pragma unroll
  for (int m = 1; m < 64; m <<= 1) {
    #pragma unroll
    for (int t = 0; t < 8; ++t) { st[t] += __shfl_xor(st[t], m); sq[t] += __shfl_xor(sq[t], m); }
  }
  if ((tid & 63) == 0) {
    const int w = tid >> 6;
    #pragma unroll
    for (int t = 0; t < 8; ++t) { redsh[w][t] = st[t]; redsh[w][8 + t] = sq[t]; }
  }
  __syncthreads();
  if (tid < 16) {
    float v = redsh[0][tid] + redsh[1][tid] + redsh[2][tid] + redsh[3][tid];
    partial[(size_t)tid * gridDim.x + blockIdx.x] = v;
  }
}

// ---------------- K4: fused softmax + xk + x_intra (LDS reduce) + exv(fp16) ----------------
__global__ __launch_bounds__(256) void k_intra(
    const unsigned short* __restrict__ zb, const unsigned* __restrict__ uqn,
    const int* __restrict__ knn, const float* __restrict__ cst,
    const float* __restrict__ lpw2, const float* __restrict__ lpb2,
    const float* __restrict__ iw, const float* __restrict__ ib,
    const float* __restrict__ ixw, const float* __restrict__ ixb,
    const unsigned short* __restrict__ h2b, const float* __restrict__ m2w3,
    const float* __restrict__ m2b3,
    const int* __restrict__ posbuf,
    float* __restrict__ x_intra, unsigned* __restrict__ exv)
{
  __shared__ uint2 xksh[256][17];   // 64 fp16 per row (16 quads), padded row = 34 dwords
  __shared__ float lpw2sh[192], lpb2sh[64];
  __shared__ h2 iwsh2[256], ixwsh2[256];   // packed fp16 pairs of output channels
  __shared__ float ibsh[8], ixbsh[8];
  __shared__ float w3sh[64], b3sh[8], s2sh[8], h2ssh[8];
  const int tid = threadIdx.x;
  if (tid < 192) lpw2sh[tid] = lpw2[tid];
  if (tid < 64) { lpb2sh[tid] = lpb2[tid]; w3sh[tid] = m2w3[tid]; }
  iwsh2[tid]  = mkh2(iw[2 * tid], iw[2 * tid + 1]);
  ixwsh2[tid] = mkh2(ixw[2 * tid], ixw[2 * tid + 1]);
  if (tid < 8) {
    ibsh[tid] = ib[tid]; ixbsh[tid] = ixb[tid];
    b3sh[tid] = m2b3[tid]; s2sh[tid] = cst[S_M2S2 + tid]; h2ssh[tid] = cst[S_M2H2 + tid];
  }
  __syncthreads();

  const size_t g = (size_t)blockIdx.x * 256 + tid;
  const int j = knn[g];
  const unsigned* zr = (const unsigned*)(zb + (size_t)j * 64);
  const int pos = posbuf[g];

  uint2 uc = *(const uint2*)(uqn + g * 2);
  const float qn0 = lo16(uc.x), qn1 = hi16(uc.x), qn2 = lo16(uc.y);

  // fused k-softmax from bf16 h2
  uint4 hu = *(const uint4*)(h2b + g * 8);
  float hn[8];
  hn[0] = fmaxf(fmaf(__uint_as_float(hu.x << 16),        s2sh[0], h2ssh[0]), 0.f);
  hn[1] = fmaxf(fmaf(__uint_as_float(hu.x & 0xffff0000u), s2sh[1], h2ssh[1]), 0.f);
  hn[2] = fmaxf(fmaf(__uint_as_float(hu.y << 16),        s2sh[2], h2ssh[2]), 0.f);
  hn[3] = fmaxf(fmaf(__uint_as_float(hu.y & 0xffff0000u), s2sh[3], h2ssh[3]), 0.f);
  hn[4] = fmaxf(fmaf(__uint_as_float(hu.z << 16),        s2sh[4], h2ssh[4]), 0.f);
  hn[5] = fmaxf(fmaf(__uint_as_float(hu.z & 0xffff0000u), s2sh[5], h2ssh[5]), 0.f);
  hn[6] = fmaxf(fmaf(__uint_as_float(hu.w << 16),        s2sh[6], h2ssh[6]), 0.f);
  hn[7] = fmaxf(fmaf(__uint_as_float(hu.w & 0xffff0000u), s2sh[7], h2ssh[7]), 0.f);
  float wk[8];
  #pragma unroll
  for (int t = 0; t < 8; ++t) {
    float a = b3sh[t];
    #pragma unroll
    for (int u = 0; u < 8; ++u) a = fmaf(hn[u], w3sh[u * 8 + t], a);
    wk[t] = a;
  }
  #pragma unroll
  for (int t = 0; t < 8; ++t) {
    float m = wk[t];
    m = fmaxf(m, __shfl_xor(m, 1));
    m = fmaxf(m, __shfl_xor(m, 2));
    m = fmaxf(m, __shfl_xor(m, 4));
    m = fmaxf(m, __shfl_xor(m, 8));
    float ex = __expf(wk[t] - m);
    float s = ex;
    s += __shfl_xor(s, 1);
    s += __shfl_xor(s, 2);
    s += __shfl_xor(s, 4);
    s += __shfl_xor(s, 8);
    wk[t] = ex / s;
  }

  h2 sacc2[4], vacc2[4];
  sacc2[0] = mkh2(ibsh[0], ibsh[1]); sacc2[1] = mkh2(ibsh[2], ibsh[3]);
  sacc2[2] = mkh2(ibsh[4], ibsh[5]); sacc2[3] = mkh2(ibsh[6], ibsh[7]);
  vacc2[0] = mkh2(ixbsh[0], ixbsh[1]); vacc2[1] = mkh2(ixbsh[2], ixbsh[3]);
  vacc2[2] = mkh2(ixbsh[4], ixbsh[5]); vacc2[3] = mkh2(ixbsh[6], ixbsh[7]);
  uint4 zq;
  #pragma unroll
  for (int c = 0; c < 64; c += 4) {
    if ((c & 7) == 0) zq = *(const uint4*)(zr + (c >> 1));
    const unsigned u0 = ((c & 7) == 0) ? zq.x : zq.z;
    const unsigned u1 = ((c & 7) == 0) ? zq.y : zq.w;
    const float z0 = __uint_as_float(u0 << 16);
    const float z1 = __uint_as_float(u0 & 0xffff0000u);
    const float z2 = __uint_as_float(u1 << 16);
    const float z3 = __uint_as_float(u1 & 0xffff0000u);
    float4 l0 = *(const float4*)(lpw2sh + c);
    float4 l1 = *(const float4*)(lpw2sh + 64 + c);
    float4 l2 = *(const float4*)(lpw2sh + 128 + c);
    float4 lb = *(const float4*)(lpb2sh + c);
    float xkv[4];
    xkv[0] = (z0 + fmaf(qn2, l2.x, fmaf(qn1, l1.x, fmaf(qn0, l0.x, lb.x)))) * wk[(c + 0) & 7];
    xkv[1] = (z1 + fmaf(qn2, l2.y, fmaf(qn1, l1.y, fmaf(qn0, l0.y, lb.y)))) * wk[(c + 1) & 7];
    xkv[2] = (z2 + fmaf(qn2, l2.z, fmaf(qn1, l1.z, fmaf(qn0, l0.z, lb.z)))) * wk[(c + 2) & 7];
    xkv[3] = (z3 + fmaf(qn2, l2.w, fmaf(qn1, l1.w, fmaf(qn0, l0.w, lb.w)))) * wk[(c + 3) & 7];
    xksh[tid][c >> 2] = make_uint2(packh2(xkv[0], xkv[1]), packh2(xkv[2], xkv[3]));
    #pragma unroll
    for (int d = 0; d < 4; ++d) {
      const _Float16 xh = (_Float16)xkv[d];
      h2 x2; x2[0] = xh; x2[1] = xh;
      const int cc = (c + d) * 4;
      #pragma unroll
      for (int q = 0; q < 4; ++q) {
        sacc2[q] = __builtin_elementwise_fma(x2, iwsh2[cc + q], sacc2[q]);
        vacc2[q] = __builtin_elementwise_fma(x2, ixwsh2[cc + q], vacc2[q]);
      }
    }
  }
  float sacc[8], vacc[8];
  #pragma unroll
  for (int q = 0; q < 4; ++q) {
    sacc[2 * q] = (float)sacc2[q][0]; sacc[2 * q + 1] = (float)sacc2[q][1];
    vacc[2 * q] = (float)vacc2[q][0]; vacc[2 * q + 1] = (float)vacc2[q][1];
  }
  float ex[8];
  #pragma unroll
  for (int t = 0; t < 8; ++t) ex[t] = __expf(sacc[t]);
  uint4 ea, eb;
  ea.x = packh2(ex[0], ex[1]); ea.y = packh2(ex[2], ex[3]);
  ea.z = packh2(ex[4], ex[5]); ea.w = packh2(ex[6], ex[7]);
  eb.x = packh2(ex[0] * vacc[0], ex[1] * vacc[1]);
  eb.y = packh2(ex[2] * vacc[2], ex[3] * vacc[3]);
  eb.z = packh2(ex[4] * vacc[4], ex[5] * vacc[5]);
  eb.w = packh2(ex[6] * vacc[6], ex[7] * vacc[7]);
  *(uint4*)(exv + (size_t)pos * 8) = ea;
  *(uint4*)(exv + (size_t)pos * 8 + 4) = eb;

  // x_intra: LDS-staged reduce over the 16 edges of each node
  __syncthreads();
  const int base = tid & ~15;
  const int own = tid & 15;
  float o0 = 0.f, o1 = 0.f, o2 = 0.f, o3 = 0.f;
  #pragma unroll
  for (int k = 0; k < 16; ++k) {
    uint2 v = xksh[base + k][own];
    o0 += lo16(v.x); o1 += hi16(v.x);
    o2 += lo16(v.y); o3 += hi16(v.y);
  }
  const size_t i = g >> 4;
  *(float4*)(x_intra + i * 64 + own * 4) = make_float4(o0, o1, o2, o3);
}

// ---------------- K5: streaming segment reduce (fp16) + x2 + bn2 partials ----------------
__global__ __launch_bounds__(256) void k_inter_x2(
    const int* __restrict__ rowstart, const unsigned* __restrict__ exv,
    float* __restrict__ xi, float* __restrict__ partial)
{
  __shared__ float bsum[64], bsq[64];
  const int tid = threadIdx.x;
  if (tid < 64) { bsum[tid] = 0.f; bsq[tid] = 0.f; }
  __syncthreads();
  const int t = tid & 15;
  const int j = blockIdx.x * 16 + (tid >> 4);
  const int s0 = rowstart[j];
  const int e0 = rowstart[j + 1];
  const unsigned short* eh = (const unsigned short*)exv;
  float acc = 0.f;
  for (int e = s0; e < e0; ++e) acc += h2f(eh[(size_t)e * 16 + t]);
  const float other = __shfl_xor(acc, 8);
  float r = (t < 8) ? ((acc > 0.f) ? other / acc : 0.f)
                    : ((other > 0.f) ? acc / other : 0.f);
  float4 xv = *(const float4*)(xi + (size_t)j * 64 + t * 4);
  float v0 = xv.x + __shfl(r, (4 * t + 0) & 7, 16);
  float v1 = xv.y + __shfl(r, (4 * t + 1) & 7, 16);
  float v2 = xv.z + __shfl(r, (4 * t + 2) & 7, 16);
  float v3 = xv.w + __shfl(r, (4 * t + 3) & 7, 16);
  *(float4*)(xi + (size_t)j * 64 + t * 4) = make_float4(v0, v1, v2, v3);
  float s_[4] = {v0, v1, v2, v3};
  float q_[4] = {v0 * v0, v1 * v1, v2 * v2, v3 * v3};
  #pragma unroll
  for (int d = 0; d < 4; ++d) {
    s_[d] += __shfl_xor(s_[d], 16); s_[d] += __shfl_xor(s_[d], 32);
    q_[d] += __shfl_xor(q_[d], 16); q_[d] += __shfl_xor(q_[d], 32);
  }
  if ((tid & 63) < 16) {
    #pragma unroll
    for (int d = 0; d < 4; ++d) {
      atomicAdd(&bsum[4 * t + d], s_[d]);
      atomicAdd(&bsq[4 * t + d], q_[d]);
    }
  }
  __syncthreads();
  if (tid < 64) {
    partial[(size_t)tid * gridDim.x + blockIdx.x] = bsum[tid];
    partial[(size_t)(tid + 64) * gridDim.x + blockIdx.x] = bsq[tid];
  }
}

// ---------------- K6: final bn3 + residual + relu ----------------
__global__ __launch_bounds__(256) void k_out(
    const float* __restrict__ y3, const float* __restrict__ x0,
    const float* __restrict__ cst, float* __restrict__ out)
{
  __shared__ float scsh[64], shsh[64];
  const int tid = threadIdx.x;
  if (tid < 64) { scsh[tid] = cst[S_SC3 + tid]; shsh[tid] = cst[S_SH3 + tid]; }
  __syncthreads();
  const size_t i = ((size_t)blockIdx.x * 256 + tid) * 4;
  float4 y = *(const float4*)(y3 + i);
  float4 x = *(const float4*)(x0 + i);
  const int c = (int)(i & 63);
  float4 o;
  o.x = fmaxf(fmaf(y.x, scsh[c + 0], shsh[c + 0]) + x.x, 0.f);
  o.y = fmaxf(fmaf(y.y, scsh[c + 1], shsh[c + 1]) + x.y, 0.f);
  o.z = fmaxf(fmaf(y.z, scsh[c + 2], shsh[c + 2]) + x.z, 0.f);
  o.w = fmaxf(fmaf(y.w, scsh[c + 3], shsh[c + 3]) + x.w, 0.f);
  *(float4*)(out + i) = o;
}

// ---------------- launch ----------------
extern "C" void kernel_launch(void* const* d_in, const int* in_sizes, int n_in,
                              void* d_out, int out_size, void* d_ws, size_t ws_size,
                              hipStream_t stream)
{
  (void)n_in; (void)out_size; (void)ws_size;
  const float* p    = (const float*)d_in[0];
  const float* x    = (const float*)d_in[1];
  const int*   knn  = (const int*)d_in[2];
  const float* w1   = (const float*)d_in[3];
  const float* g1   = (const float*)d_in[4];
  const float* b1   = (const float*)d_in[5];
  const float* m1w1 = (const float*)d_in[6];
  const float* m1b1 = (const float*)d_in[7];
  const float* m1w2 = (const float*)d_in[8];
  const float* m1b2 = (const float*)d_in[9];
  const float* lpw1 = (const float*)d_in[10];
  const float* lpb1 = (const float*)d_in[11];
  const float* lpg  = (const float*)d_in[12];
  const float* lpbt = (const float*)d_in[13];
  const float* lpw2 = (const float*)d_in[14];
  const float* lpb2 = (const float*)d_in[15];
  const float* m2w1 = (const float*)d_in[16];
  const float* m2g1 = (const float*)d_in[17];
  const float* m2bt1= (const float*)d_in[18];
  const float* m2w2 = (const float*)d_in[19];
  const float* m2g2 = (const float*)d_in[20];
  const float* m2bt2= (const float*)d_in[21];
  const float* m2w3 = (const float*)d_in[22];
  const float* m2b3 = (const float*)d_in[23];
  const float* m3w  = (const float*)d_in[24];
  const float* m3b  = (const float*)d_in[25];
  const float* iw   = (const float*)d_in[26];
  const float* ib   = (const float*)d_in[27];
  const float* ixw  = (const float*)d_in[28];
  const float* ixb  = (const float*)d_in[29];
  const float* g2   = (const float*)d_in[30];
  const float* b2   = (const float*)d_in[31];
  const float* w3   = (const float*)d_in[32];
  const float* g3   = (const float*)d_in[33];
  const float* b3   = (const float*)d_in[34];
  float* out = (float*)d_out;
  float* ws  = (float*)d_ws;

  const int n = in_sizes[1] / 64;                // 32768
  const long long nk = (long long)n * 16;        // 524288

  float* cst  = ws;
  int* cnt      = (int*)(ws + CONST_FLOATS);    // n ints (zeroed with cst)
  int* rowstart = cnt + n;                      // n+1 ints (+pad)
  int* rank     = rowstart + n + 16;            // nk ints
  int* posb     = rank + nk;                    // nk ints
  unsigned short* zb = (unsigned short*)(posb + nk);  // 64n bf16 = 32n words
  float* y1 = (float*)(zb + 64LL * n);          // 64n, reused as y3
  float* xi = y1 + 64LL * n;                    // 64n
  float* y16 = xi + 64LL * n;                   // 16n
  unsigned short* h2b = (unsigned short*)(y16 + 16LL * n);  // 128n ushorts
  unsigned* exv = (unsigned*)(h2b + 128LL * n); // 128n uints

  const int gB   = n / 64;            // 512
  const int nkB  = (int)(nk / 256);   // 2048
  const int nkB2 = (int)(nk / 512);   // 1024
  const int jB   = n / 16;            // 2048

  float* pbn1  = (float*)(exv + 128LL * n);      // 128 * gB
  float* plp   = pbn1 + 128LL * gB;              // 8 * nkB
  float* pmom  = plp + 8LL * nkB;                // 210 * nkB
  float* s2buf = pmom + 210LL * nkB;             // 256
  float* pm2b2 = s2buf + 256;                    // 16 * nkB2
  float* pbn2  = pm2b2 + 16LL * nkB2;            // 128 * jB
  float* pbn3  = pbn2 + 128LL * jB;              // 128 * gB
  unsigned* uq = (unsigned*)(pbn3 + 128LL * gB); // 8 * nk uints
  unsigned* uqn = uq + 8LL * nk;                 // 2 * nk uints

  hipMemsetAsync(d_ws, 0, (size_t)CONST_FLOATS * sizeof(float) + (size_t)n * sizeof(int), stream);

  k_prhist<<<nkB, 256, 0, stream>>>(p, knn, lpw1, lpb1, plp, cnt, rank);
  k_gemm64<<<gB, 256, 0, stream>>>(x, w1, nullptr, nullptr, nullptr, y1, pbn1, n);
  k_scan_mid<<<1, 1024, 0, stream>>>(cnt, rowstart, n, plp, nkB,
                                     lpg, lpbt, lpw1, lpb1, lpw2, lpb2,
                                     m1w2, m2w1, m1b2, cst, 1.f / (float)nk);
  k_rbn<<<64, 256, 0, stream>>>(pbn1, gB, 64, g1, b1, cst + S_SC1, cst + S_SH1, 1.f / (float)n);
  // z(bf16) + y16 in one pass
  k_gemmzy<<<gB, 256, 0, stream>>>(y1, m3w, m3b, m1w1 + 48, cst + S_SC1, cst + S_SH1, zb, y16);
  // h1 BN stats via u-moments; also emits uq/uqn/pos
  k_moment<<<nkB, 256, 0, stream>>>(y16, p, knn, m1w1, m1b1, cst, rowstart, rank,
                                    pmom, uq, uqn, posb);
  k_mred<<<210, 256, 0, stream>>>(pmom, s2buf, nkB);
  k_mfin<<<1, 64, 0, stream>>>(s2buf, m2g1, m2bt1, cst, 1.f / (float)nk);
  // h2 (bf16) from uq/uqn + stats
  k_h2<<<nkB2, 256, 0, stream>>>(uq, uqn, cst, m2w2, h2b, pm2b2);
  k_rbn<<<8, 256, 0, stream>>>(pm2b2, nkB2, 8, m2g2, m2bt2, cst + S_M2S2, cst + S_M2H2, 1.f / (float)nk);
  // fused softmax + xk + x_intra + exv
  k_intra<<<nkB, 256, 0, stream>>>(zb, uqn, knn, cst, lpw2, lpb2, iw, ib, ixw, ixb,
                                   h2b, m2w3, m2b3, posb, xi, exv);
  // streaming segment reduce + x2 + bn2 partials
  k_inter_x2<<<jB, 256, 0, stream>>>(rowstart, exv, xi, pbn2);
  k_rbn<<<64, 256, 0, stream>>>(pbn2, jB, 64, g2, b2, cst + S_SC2, cst + S_SH2, 1.f / (float)n);
  // y3 = relu(bn2(x2)) @ w3, bn3
  k_gemm64<<<gB, 256, 0, stream>>>(xi, w3, nullptr, cst + S_SC2, cst + S_SH2, y1, pbn3, n);
  k_rbn<<<64, 256, 0, stream>>>(pbn3, gB, 64, g3, b3, cst + S_SC3, cst + S_SH3, 1.f / (float)n);
  // out = relu(bn3(y3) + x)
  k_out<<<(int)((long long)n * 64 / 1024), 256, 0, stream>>>(y1, x, cst, out);
}

// Round 15
// 274.133 us; speedup vs baseline: 1.6404x; 1.0958x over previous
//
#include <hip/hip_runtime.h>

// N = 32768 (runtime), C = 64, K = 16, CS = 8, SHARE = 8

enum {
  S_SC1 = 0,    S_SH1 = 64,
  S_LPSC = 128, S_LPSH = 132,
  S_M2S1 = 136, S_M2H1 = 200,
  S_M2S2 = 264, S_M2H2 = 272,
  S_SC2 = 280,  S_SH2 = 344,
  S_SC3 = 408,  S_SH3 = 472,
  S_LPW2S = 536, S_LPB2S = 584,
  S_QW = 600, S_QB = 612,
  S_G = 640,        // 64x16 c-major
  S_HC = 1664,      // 64x4 c-major
  S_HB = 1920,      // 64
  CONST_FLOATS = 2048
};

typedef _Float16 h2 __attribute__((ext_vector_type(2)));

__device__ __forceinline__ int pidx(int a, int b) {  // a<=b, 20-dim sym
  return a * 20 - (a * (a - 1)) / 2 + (b - a);
}
__device__ __forceinline__ unsigned short bf16r(float f) {
  unsigned u = __float_as_uint(f);
  u = u + 0x7fffu + ((u >> 16) & 1u);
  return (unsigned short)(u >> 16);
}
__device__ __forceinline__ unsigned short f2h(float f) {
  _Float16 h = (_Float16)f;
  unsigned short u;
  __builtin_memcpy(&u, &h, 2);
  return u;
}
__device__ __forceinline__ float h2f(unsigned short u) {
  _Float16 h;
  __builtin_memcpy(&h, &u, 2);
  return (float)h;
}
__device__ __forceinline__ unsigned packh2(float a, float b) {
  return (unsigned)f2h(a) | ((unsigned)f2h(b) << 16);
}
__device__ __forceinline__ float lo16(unsigned u) { return h2f((unsigned short)(u & 0xffffu)); }
__device__ __forceinline__ float hi16(unsigned u) { return h2f((unsigned short)(u >> 16)); }
__device__ __forceinline__ h2 mkh2(float a, float b) {
  h2 v; v[0] = (_Float16)a; v[1] = (_Float16)b; return v;
}

// ---------------- fused partial-reduce + BN finalize ----------------
__global__ __launch_bounds__(256) void k_rbn(
    const float* __restrict__ partial, int nb, int nch,
    const float* __restrict__ g, const float* __restrict__ b,
    float* __restrict__ scale, float* __restrict__ shift, float inv_count)
{
  const int c = blockIdx.x;
  const int tid = threadIdx.x;
  float s = 0.f, q = 0.f;
  for (int i = tid; i < nb; i += 256) {
    s += partial[(size_t)c * nb + i];
    q += partial[(size_t)(c + nch) * nb + i];
  }
  #pragma unroll
  for (int m = 1; m < 64; m <<= 1) { s += __shfl_xor(s, m); q += __shfl_xor(q, m); }
  __shared__ float ws[4], wq[4];
  if ((tid & 63) == 0) { ws[tid >> 6] = s; wq[tid >> 6] = q; }
  __syncthreads();
  if (tid == 0) {
    float S = ws[0] + ws[1] + ws[2] + ws[3];
    float Q = wq[0] + wq[1] + wq[2] + wq[3];
    float m = S * inv_count;
    float v = Q * inv_count - m * m;
    float rs = rsqrtf(v + 1e-5f);
    float sc = g[c] * rs;
    scale[c] = sc;
    shift[c] = fmaf(-m, sc, b[c]);
  }
}

// ---------------- generic 64x64 GEMM (f32 out) ----------------
__global__ __launch_bounds__(256) void k_gemm64(
    const float* __restrict__ in, const float* __restrict__ w,
    const float* __restrict__ bias,
    const float* __restrict__ sc, const float* __restrict__ sh,
    float* __restrict__ out,
    float* __restrict__ partial, int n)
{
  __shared__ float scsh[64], shsh[64];
  __shared__ float bsum[64], bsq[64];
  const int tid = threadIdx.x;
  const int lane = tid & 63;
  const int wave = tid >> 6;
  if (sc != nullptr && tid < 64) { scsh[tid] = sc[tid]; shsh[tid] = sh[tid]; }
  if (tid < 64) { bsum[tid] = 0.f; bsq[tid] = 0.f; }
  __syncthreads();

  float wreg[64];
  #pragma unroll
  for (int k = 0; k < 64; ++k) wreg[k] = w[k * 64 + lane];
  const float bz = bias ? bias[lane] : 0.f;

  float lsum = 0.f, lsq = 0.f;
  const int row0 = (blockIdx.x * 4 + wave) * 16;
  for (int r = 0; r < 16; ++r) {
    const int row = row0 + r;
    const float* xr = in + (size_t)row * 64;
    float acc = bz;
    if (sc != nullptr) {
      #pragma unroll
      for (int k = 0; k < 64; k += 4) {
        float4 xv = *(const float4*)(xr + k);
        float x0 = fmaxf(fmaf(xv.x, scsh[k + 0], shsh[k + 0]), 0.f);
        float x1 = fmaxf(fmaf(xv.y, scsh[k + 1], shsh[k + 1]), 0.f);
        float x2 = fmaxf(fmaf(xv.z, scsh[k + 2], shsh[k + 2]), 0.f);
        float x3 = fmaxf(fmaf(xv.w, scsh[k + 3], shsh[k + 3]), 0.f);
        acc = fmaf(x0, wreg[k + 0], acc);
        acc = fmaf(x1, wreg[k + 1], acc);
        acc = fmaf(x2, wreg[k + 2], acc);
        acc = fmaf(x3, wreg[k + 3], acc);
      }
    } else {
      #pragma unroll
      for (int k = 0; k < 64; k += 4) {
        float4 xv = *(const float4*)(xr + k);
        acc = fmaf(xv.x, wreg[k + 0], acc);
        acc = fmaf(xv.y, wreg[k + 1], acc);
        acc = fmaf(xv.z, wreg[k + 2], acc);
        acc = fmaf(xv.w, wreg[k + 3], acc);
      }
    }
    out[(size_t)row * 64 + lane] = acc;
    lsum += acc;
    lsq = fmaf(acc, acc, lsq);
  }
  if (partial != nullptr) {
    atomicAdd(&bsum[lane], lsum);
    atomicAdd(&bsq[lane], lsq);
    __syncthreads();
    if (tid < 64) {
      partial[(size_t)tid * gridDim.x + blockIdx.x] = bsum[tid];
      partial[(size_t)(tid + 64) * gridDim.x + blockIdx.x] = bsq[tid];
    }
  }
}

// ---------------- fused: z (bf16) = nr(y1)@m3w+m3b ; y16 = nr(y1)@m1w1[3:] ----------------
__global__ __launch_bounds__(256) void k_gemmzy(
    const float* __restrict__ in, const float* __restrict__ w,
    const float* __restrict__ bias, const float* __restrict__ w16,
    const float* __restrict__ sc, const float* __restrict__ sh,
    unsigned short* __restrict__ outz, float* __restrict__ out16)
{
  __shared__ float xn[64][68];
  __shared__ float w16sh[1024];
  __shared__ float scsh[64], shsh[64];
  const int tid = threadIdx.x;
  if (tid < 64) { scsh[tid] = sc[tid]; shsh[tid] = sh[tid]; }
  for (int i2 = tid; i2 < 1024; i2 += 256) w16sh[i2] = w16[i2];
  __syncthreads();
  const int row0 = blockIdx.x * 64;
  for (int idx = tid; idx < 4096; idx += 256) {
    int r = idx >> 6, c = idx & 63;
    float v = in[(size_t)(row0 + r) * 64 + c];
    xn[r][c] = fmaxf(fmaf(v, scsh[c], shsh[c]), 0.f);
  }
  __syncthreads();

  const int lane = tid & 63;
  const int wave = tid >> 6;
  float wreg[64];
  #pragma unroll
  for (int k = 0; k < 64; ++k) wreg[k] = w[k * 64 + lane];
  const float bz = bias[lane];
  for (int r = wave * 16; r < wave * 16 + 16; ++r) {
    float acc = bz;
    #pragma unroll
    for (int k = 0; k < 64; k += 4) {
      float4 xv = *(const float4*)(&xn[r][k]);
      acc = fmaf(xv.x, wreg[k + 0], acc);
      acc = fmaf(xv.y, wreg[k + 1], acc);
      acc = fmaf(xv.z, wreg[k + 2], acc);
      acc = fmaf(xv.w, wreg[k + 3], acc);
    }
    outz[(size_t)(row0 + r) * 64 + lane] = bf16r(acc);
  }
  for (int idx = tid; idx < 1024; idx += 256) {
    int r = idx >> 4, t = idx & 15;
    float acc = 0.f;
    #pragma unroll
    for (int c = 0; c < 64; c += 4) {
      float4 xv = *(const float4*)(&xn[r][c]);
      acc = fmaf(xv.x, w16sh[(c + 0) * 16 + t], acc);
      acc = fmaf(xv.y, w16sh[(c + 1) * 16 + t], acc);
      acc = fmaf(xv.z, w16sh[(c + 2) * 16 + t], acc);
      acc = fmaf(xv.w, w16sh[(c + 3) * 16 + t], acc);
    }
    out16[(size_t)(row0 + r) * 16 + t] = acc;
  }
}

// ---------------- K1: lp partials, histogram + rank ----------------
__global__ __launch_bounds__(256) void k_prhist(
    const float* __restrict__ p, const int* __restrict__ knn,
    const float* __restrict__ lpw1, const float* __restrict__ lpb1,
    float* __restrict__ plp,
    int* __restrict__ cnt, int* __restrict__ rank)
{
  __shared__ float lpw1sh[9], lpb1sh[3];
  __shared__ float lpsh[4][8];
  const int tid = threadIdx.x;
  if (tid < 9) lpw1sh[tid] = lpw1[tid];
  if (tid < 3) lpb1sh[tid] = lpb1[tid];
  __syncthreads();

  const size_t g = (size_t)blockIdx.x * 256 + tid;
  const int i = (int)(g >> 4);
  const int j = knn[g];
  const float pr0 = p[j * 3 + 0] - p[i * 3 + 0];
  const float pr1 = p[j * 3 + 1] - p[i * 3 + 1];
  const float pr2 = p[j * 3 + 2] - p[i * 3 + 2];
  rank[g] = atomicAdd(&cnt[j], 1);

  float q0 = fmaf(pr2, lpw1sh[6], fmaf(pr1, lpw1sh[3], fmaf(pr0, lpw1sh[0], lpb1sh[0])));
  float q1 = fmaf(pr2, lpw1sh[7], fmaf(pr1, lpw1sh[4], fmaf(pr0, lpw1sh[1], lpb1sh[1])));
  float q2 = fmaf(pr2, lpw1sh[8], fmaf(pr1, lpw1sh[5], fmaf(pr0, lpw1sh[2], lpb1sh[2])));
  float s0 = q0, s1 = q1, s2 = q2, qq0 = q0 * q0, qq1 = q1 * q1, qq2 = q2 * q2;
  #pragma unroll
  for (int m = 1; m < 64; m <<= 1) {
    s0 += __shfl_xor(s0, m); s1 += __shfl_xor(s1, m); s2 += __shfl_xor(s2, m);
    qq0 += __shfl_xor(qq0, m); qq1 += __shfl_xor(qq1, m); qq2 += __shfl_xor(qq2, m);
  }
  if ((tid & 63) == 0) {
    const int w = tid >> 6;
    lpsh[w][0] = s0; lpsh[w][1] = s1; lpsh[w][2] = s2; lpsh[w][3] = 0.f;
    lpsh[w][4] = qq0; lpsh[w][5] = qq1; lpsh[w][6] = qq2; lpsh[w][7] = 0.f;
  }
  __syncthreads();
  if (tid < 8) {
    float v = lpsh[0][tid] + lpsh[1][tid] + lpsh[2][tid] + lpsh[3][tid];
    plp[(size_t)tid * gridDim.x + blockIdx.x] = v;
  }
}

// ---------------- block sums of cnt (1024 counts per block) ----------------
__global__ __launch_bounds__(256) void k_bsum(
    const int* __restrict__ cnt, int* __restrict__ bsums)
{
  const int tid = threadIdx.x;
  int4 c4 = ((const int4*)cnt)[blockIdx.x * 256 + tid];
  int s = c4.x + c4.y + c4.z + c4.w;
  #pragma unroll
  for (int m = 1; m < 64; m <<= 1) s += __shfl_xor(s, m);
  __shared__ int ws[4];
  if ((tid & 63) == 0) ws[tid >> 6] = s;
  __syncthreads();
  if (tid == 0) bsums[blockIdx.x] = ws[0] + ws[1] + ws[2] + ws[3];
}

// ---------------- mid: block-sum scan + lp finalize + weight folding (LDS-staged) ----------------
__global__ __launch_bounds__(256) void k_mid2(
    const int* __restrict__ bsums, int* __restrict__ blockoff,
    int* __restrict__ rowstart, int n,
    const float* __restrict__ plp, int nbplp,
    const float* __restrict__ lpg, const float* __restrict__ lpbt,
    const float* __restrict__ lpw1, const float* __restrict__ lpb1,
    const float* __restrict__ lpw2, const float* __restrict__ lpb2,
    const float* __restrict__ m1w2, const float* __restrict__ m2w1,
    const float* __restrict__ m1b2,
    float* __restrict__ cst, float inv_count)
{
  __shared__ float w2sh_[2048];   // m2w1 staged
  __shared__ float w1sh_[256];    // m1w2 staged
  __shared__ int bsh[64];
  __shared__ float Ssh[8];
  const int tid = threadIdx.x;
  const int nb1024 = n >> 10;
  if (tid < nb1024) bsh[tid] = bsums[tid];
  for (int i = tid; i < 2048; i += 256) w2sh_[i] = m2w1[i];
  w1sh_[tid] = m1w2[tid];
  // lp stats reduce
  {
    const int row = tid >> 5, l32 = tid & 31;
    float ls = 0.f;
    for (int i = l32; i < nbplp; i += 32) ls += plp[(size_t)row * nbplp + i];
    #pragma unroll
    for (int m = 1; m < 32; m <<= 1) ls += __shfl_xor(ls, m);
    if (l32 == 0) Ssh[row] = ls;
  }
  __syncthreads();
  if (tid == 0) {
    int run = 0;
    for (int i = 0; i < nb1024; ++i) { blockoff[i] = run; run += bsh[i]; }
    rowstart[n] = run;
  }
  if (tid < 3) {
    float m = Ssh[tid] * inv_count;
    float v = Ssh[4 + tid] * inv_count - m * m;
    float rs = rsqrtf(v + 1e-5f);
    float sc = lpg[tid] * rs;
    cst[S_LPSC + tid] = sc;
    cst[S_LPSH + tid] = fmaf(-m, sc, lpbt[tid]);
  }
  __syncthreads();
  if (tid < 9)  cst[S_QW + tid] = lpw1[tid] * cst[S_LPSC + (tid % 3)];
  if (tid < 3)  cst[S_QB + tid] = fmaf(lpb1[tid], cst[S_LPSC + tid], cst[S_LPSH + tid]);
  if (tid < 16) {
    float b = 0.f;
    for (int c2 = 0; c2 < 4; ++c2) b += lpb2[c2 * 16 + tid];
    cst[S_LPB2S + tid] = b;
    for (int r = 0; r < 3; ++r) {
      float w = 0.f;
      for (int c2 = 0; c2 < 4; ++c2) w += lpw2[r * 64 + c2 * 16 + tid];
      cst[S_LPW2S + r * 16 + tid] = w;
    }
  }
  __syncthreads();
  // G fold (from LDS)
  #pragma unroll
  for (int q = 0; q < 4; ++q) {
    int ee = tid * 4 + q;
    int c = ee >> 4, u = ee & 15;
    float sg = 0.f;
    #pragma unroll
    for (int t = 0; t < 16; ++t) sg = fmaf(w1sh_[u * 16 + t], w2sh_[t * 64 + c], sg);
    cst[S_G + c * 16 + u] = sg;
  }
  if (tid < 192) {
    int c = tid / 3, r = tid - c * 3;
    float sh = 0.f;
    #pragma unroll
    for (int t = 0; t < 16; ++t) sh = fmaf(cst[S_LPW2S + r * 16 + t], w2sh_[(16 + t) * 64 + c], sh);
    cst[S_HC + c * 4 + r] = sh;
  }
  if (tid < 64) {
    cst[S_HC + tid * 4 + 3] = 0.f;
    float sb = 0.f;
    #pragma unroll
    for (int t = 0; t < 16; ++t) {
      sb = fmaf(m1b2[t], w2sh_[t * 64 + tid], sb);
      sb = fmaf(cst[S_LPB2S + t], w2sh_[(16 + t) * 64 + tid], sb);
    }
    cst[S_HB + tid] = sb;
  }
}

// ---------------- final scan: per-block local scan + offset ----------------
__global__ __launch_bounds__(256) void k_scan3(
    const int* __restrict__ cnt, const int* __restrict__ blockoff,
    int* __restrict__ rowstart)
{
  const int tid = threadIdx.x;
  const int b = blockIdx.x;
  int4 c4 = ((const int4*)cnt)[b * 256 + tid];
  int tsum = c4.x + c4.y + c4.z + c4.w;
  const int lane = tid & 63, w = tid >> 6;
  int inc = tsum;
  #pragma unroll
  for (int d = 1; d < 64; d <<= 1) {
    int v = __shfl_up(inc, d);
    if (lane >= d) inc += v;
  }
  __shared__ int wsum[4];
  if (lane == 63) wsum[w] = inc;
  __syncthreads();
  int woff = 0;
  for (int u = 0; u < w; ++u) woff += wsum[u];
  int g0 = blockoff[b] + woff + inc - tsum;
  const int base = b * 1024 + tid * 4;
  int4 o;
  o.x = g0;
  o.y = g0 + c4.x;
  o.z = g0 + c4.x + c4.y;
  o.w = g0 + c4.x + c4.y + c4.z;
  *(int4*)(rowstart + base) = o;
}

// ---------------- K2: u-moment accumulation + uq/uqn/pos store ----------------
__global__ __launch_bounds__(256) void k_moment(
    const float* __restrict__ y16, const float* __restrict__ p,
    const int* __restrict__ knn, const float* __restrict__ m1w1,
    const float* __restrict__ m1b1, const float* __restrict__ cst,
    const int* __restrict__ rowstart, const int* __restrict__ rank,
    float* __restrict__ pmom,   // [210 * gridDim.x] channel-major
    unsigned* __restrict__ uq,  // [nk * 8] packed fp16 t1[16]
    unsigned* __restrict__ uqn, // [nk * 2] packed fp16 qn[3]
    int* __restrict__ posbuf)   // [nk]
{
  __shared__ float ush[256 * 21];
  const int tid = threadIdx.x;
  const size_t g = (size_t)blockIdx.x * 256 + tid;
  const int i = (int)(g >> 4);
  const int j = knn[g];
  const float pr0 = p[j * 3 + 0] - p[i * 3 + 0];
  const float pr1 = p[j * 3 + 1] - p[i * 3 + 1];
  const float pr2 = p[j * 3 + 2] - p[i * 3 + 2];
  const float* yj = y16 + (size_t)j * 16;
  float4 ya = *(const float4*)(yj);
  float4 yb = *(const float4*)(yj + 4);
  float4 yc = *(const float4*)(yj + 8);
  float4 yd = *(const float4*)(yj + 12);
  float t1[16] = {ya.x, ya.y, ya.z, ya.w, yb.x, yb.y, yb.z, yb.w,
                  yc.x, yc.y, yc.z, yc.w, yd.x, yd.y, yd.z, yd.w};
  #pragma unroll
  for (int u = 0; u < 16; ++u)
    t1[u] = fmaxf(fmaf(pr2, m1w1[32 + u], fmaf(pr1, m1w1[16 + u],
                  fmaf(pr0, m1w1[u], t1[u] + m1b1[u]))), 0.f);
  const float qn0 = fmaxf(fmaf(pr2, cst[S_QW + 6], fmaf(pr1, cst[S_QW + 3], fmaf(pr0, cst[S_QW + 0], cst[S_QB + 0]))), 0.f);
  const float qn1 = fmaxf(fmaf(pr2, cst[S_QW + 7], fmaf(pr1, cst[S_QW + 4], fmaf(pr0, cst[S_QW + 1], cst[S_QB + 1]))), 0.f);
  const float qn2 = fmaxf(fmaf(pr2, cst[S_QW + 8], fmaf(pr1, cst[S_QW + 5], fmaf(pr0, cst[S_QW + 2], cst[S_QB + 2]))), 0.f);

  posbuf[g] = rowstart[j] + rank[g];

  uint4 ua, ub;
  ua.x = packh2(t1[0], t1[1]);   ua.y = packh2(t1[2], t1[3]);
  ua.z = packh2(t1[4], t1[5]);   ua.w = packh2(t1[6], t1[7]);
  ub.x = packh2(t1[8], t1[9]);   ub.y = packh2(t1[10], t1[11]);
  ub.z = packh2(t1[12], t1[13]); ub.w = packh2(t1[14], t1[15]);
  *(uint4*)(uq + g * 8)     = ua;
  *(uint4*)(uq + g * 8 + 4) = ub;
  uint2 uc;
  uc.x = packh2(qn0, qn1);
  uc.y = packh2(qn2, 0.f);
  *(uint2*)(uqn + g * 2) = uc;

  float* ur = ush + tid * 21;
  #pragma unroll
  for (int u = 0; u < 16; ++u) ur[u] = t1[u];
  ur[16] = qn0; ur[17] = qn1; ur[18] = qn2; ur[19] = 1.f;
  __syncthreads();

  if (tid < 210) {
    int a = 0, t = tid;
    while (t >= 20 - a) { t -= 20 - a; ++a; }
    const int b = a + t;
    float s = 0.f;
    for (int r = 0; r < 256; ++r) {
      const float* u = ush + r * 21;
      s = fmaf(u[a], u[b], s);
    }
    pmom[(size_t)tid * gridDim.x + blockIdx.x] = s;
  }
}

// ---------------- parallel moment reduce ----------------
__global__ __launch_bounds__(256) void k_mred(
    const float* __restrict__ pmom, float* __restrict__ S2, int nb)
{
  const int c = blockIdx.x;
  const int tid = threadIdx.x;
  float s = 0.f;
  for (int i = tid; i < nb; i += 256) s += pmom[(size_t)c * nb + i];
  #pragma unroll
  for (int m = 1; m < 64; m <<= 1) s += __shfl_xor(s, m);
  __shared__ float ws[4];
  if ((tid & 63) == 0) ws[tid >> 6] = s;
  __syncthreads();
  if (tid == 0) S2[c] = ws[0] + ws[1] + ws[2] + ws[3];
}

// ---------------- moment finalize ----------------
__global__ __launch_bounds__(64) void k_mfin(
    const float* __restrict__ S2in,
    const float* __restrict__ g, const float* __restrict__ b,
    float* __restrict__ cst, float inv_count)
{
  __shared__ float S2[210];
  const int tid = threadIdx.x;
  for (int i = tid; i < 210; i += 64) S2[i] = S2in[i];
  __syncthreads();
  const int c = tid;
  float w[20];
  #pragma unroll
  for (int u = 0; u < 16; ++u) w[u] = cst[S_G + c * 16 + u];
  w[16] = cst[S_HC + c * 4 + 0];
  w[17] = cst[S_HC + c * 4 + 1];
  w[18] = cst[S_HC + c * 4 + 2];
  w[19] = cst[S_HB + c];
  float m2 = 0.f, m1 = 0.f;
  for (int a = 0; a < 20; ++a) {
    const float wa = w[a];
    m2 = fmaf(wa * wa, S2[pidx(a, a)], m2);
    float cross = 0.f;
    for (int bb = a + 1; bb < 20; ++bb) cross = fmaf(w[bb], S2[pidx(a, bb)], cross);
    m2 = fmaf(2.f * wa, cross, m2);
    m1 = fmaf(wa, S2[pidx(a, 19)], m1);
  }
  const float mean = m1 * inv_count;
  const float var = m2 * inv_count - mean * mean;
  const float rs = rsqrtf(var + 1e-5f);
  const float sc = g[c] * rs;
  cst[S_M2S1 + c] = sc;
  cst[S_M2H1 + c] = fmaf(-mean, sc, b[c]);
}

// ---------------- K3: h2(bf16) from packed uq/uqn via folded G/H ----------------
__global__ __launch_bounds__(256) void k_h2(
    const unsigned* __restrict__ uq, const unsigned* __restrict__ uqn,
    const float* __restrict__ cst, const float* __restrict__ m2w2,
    unsigned short* __restrict__ h2out,
    float* __restrict__ partial)   // [16 * gridDim.x]
{
  __shared__ float Gsh[1024], Hsh[256], hbsh[64];
  __shared__ float w2m[512];
  __shared__ float scsh[64], shsh[64];
  __shared__ float redsh[4][16];
  const int tid = threadIdx.x;
  for (int i = tid; i < 1024; i += 256) Gsh[i] = cst[S_G + i];
  Hsh[tid] = cst[S_HC + tid];
  for (int i = tid; i < 512; i += 256) w2m[i] = m2w2[i];
  if (tid < 64) { hbsh[tid] = cst[S_HB + tid]; scsh[tid] = cst[S_M2S1 + tid]; shsh[tid] = cst[S_M2H1 + tid]; }
  __syncthreads();

  const size_t g0 = ((size_t)blockIdx.x * 256 + tid) * 2;
  float t1[2][16], qn[2][3];
  #pragma unroll
  for (int gg = 0; gg < 2; ++gg) {
    const size_t g = g0 + gg;
    uint4 ua = *(const uint4*)(uq + g * 8);
    uint4 ub = *(const uint4*)(uq + g * 8 + 4);
    uint2 uc = *(const uint2*)(uqn + g * 2);
    t1[gg][0] = lo16(ua.x);  t1[gg][1] = hi16(ua.x);
    t1[gg][2] = lo16(ua.y);  t1[gg][3] = hi16(ua.y);
    t1[gg][4] = lo16(ua.z);  t1[gg][5] = hi16(ua.z);
    t1[gg][6] = lo16(ua.w);  t1[gg][7] = hi16(ua.w);
    t1[gg][8] = lo16(ub.x);  t1[gg][9] = hi16(ub.x);
    t1[gg][10] = lo16(ub.y); t1[gg][11] = hi16(ub.y);
    t1[gg][12] = lo16(ub.z); t1[gg][13] = hi16(ub.z);
    t1[gg][14] = lo16(ub.w); t1[gg][15] = hi16(ub.w);
    qn[gg][0] = lo16(uc.x); qn[gg][1] = hi16(uc.x); qn[gg][2] = lo16(uc.y);
  }

  float a0[8], a1[8];
  #pragma unroll
  for (int t = 0; t < 8; ++t) { a0[t] = 0.f; a1[t] = 0.f; }
  for (int c = 0; c < 64; ++c) {
    float4 g0v = *(const float4*)(Gsh + c * 16);
    float4 g1v = *(const float4*)(Gsh + c * 16 + 4);
    float4 g2v = *(const float4*)(Gsh + c * 16 + 8);
    float4 g3v = *(const float4*)(Gsh + c * 16 + 12);
    float4 hv = *(const float4*)(Hsh + c * 4);
    float h_0 = hbsh[c], h_1 = hbsh[c];
    h_0 = fmaf(t1[0][0], g0v.x, h_0); h_0 = fmaf(t1[0][1], g0v.y, h_0); h_0 = fmaf(t1[0][2], g0v.z, h_0); h_0 = fmaf(t1[0][3], g0v.w, h_0);
    h_0 = fmaf(t1[0][4], g1v.x, h_0); h_0 = fmaf(t1[0][5], g1v.y, h_0); h_0 = fmaf(t1[0][6], g1v.z, h_0); h_0 = fmaf(t1[0][7], g1v.w, h_0);
    h_0 = fmaf(t1[0][8], g2v.x, h_0); h_0 = fmaf(t1[0][9], g2v.y, h_0); h_0 = fmaf(t1[0][10], g2v.z, h_0); h_0 = fmaf(t1[0][11], g2v.w, h_0);
    h_0 = fmaf(t1[0][12], g3v.x, h_0); h_0 = fmaf(t1[0][13], g3v.y, h_0); h_0 = fmaf(t1[0][14], g3v.z, h_0); h_0 = fmaf(t1[0][15], g3v.w, h_0);
    h_0 = fmaf(qn[0][0], hv.x, fmaf(qn[0][1], hv.y, fmaf(qn[0][2], hv.z, h_0)));
    h_1 = fmaf(t1[1][0], g0v.x, h_1); h_1 = fmaf(t1[1][1], g0v.y, h_1); h_1 = fmaf(t1[1][2], g0v.z, h_1); h_1 = fmaf(t1[1][3], g0v.w, h_1);
    h_1 = fmaf(t1[1][4], g1v.x, h_1); h_1 = fmaf(t1[1][5], g1v.y, h_1); h_1 = fmaf(t1[1][6], g1v.z, h_1); h_1 = fmaf(t1[1][7], g1v.w, h_1);
    h_1 = fmaf(t1[1][8], g2v.x, h_1); h_1 = fmaf(t1[1][9], g2v.y, h_1); h_1 = fmaf(t1[1][10], g2v.z, h_1); h_1 = fmaf(t1[1][11], g2v.w, h_1);
    h_1 = fmaf(t1[1][12], g3v.x, h_1); h_1 = fmaf(t1[1][13], g3v.y, h_1); h_1 = fmaf(t1[1][14], g3v.z, h_1); h_1 = fmaf(t1[1][15], g3v.w, h_1);
    h_1 = fmaf(qn[1][0], hv.x, fmaf(qn[1][1], hv.y, fmaf(qn[1][2], hv.z, h_1)));
    float x0 = fmaxf(fmaf(h_0, scsh[c], shsh[c]), 0.f);
    float x1 = fmaxf(fmaf(h_1, scsh[c], shsh[c]), 0.f);
    float4 wa = *(const float4*)(w2m + c * 8);
    float4 wb = *(const float4*)(w2m + c * 8 + 4);
    a0[0] = fmaf(x0, wa.x, a0[0]); a0[1] = fmaf(x0, wa.y, a0[1]); a0[2] = fmaf(x0, wa.z, a0[2]); a0[3] = fmaf(x0, wa.w, a0[3]);
    a0[4] = fmaf(x0, wb.x, a0[4]); a0[5] = fmaf(x0, wb.y, a0[5]); a0[6] = fmaf(x0, wb.z, a0[6]); a0[7] = fmaf(x0, wb.w, a0[7]);
    a1[0] = fmaf(x1, wa.x, a1[0]); a1[1] = fmaf(x1, wa.y, a1[1]); a1[2] = fmaf(x1, wa.z, a1[2]); a1[3] = fmaf(x1, wa.w, a1[3]);
    a1[4] = fmaf(x1, wb.x, a1[4]); a1[5] = fmaf(x1, wb.y, a1[5]); a1[6] = fmaf(x1, wb.z, a1[6]); a1[7] = fmaf(x1, wb.w, a1[7]);
  }
  uint4 pa, pb;
  pa.x = bf16r(a0[0]) | ((unsigned)bf16r(a0[1]) << 16);
  pa.y = bf16r(a0[2]) | ((unsigned)bf16r(a0[3]) << 16);
  pa.z = bf16r(a0[4]) | ((unsigned)bf16r(a0[5]) << 16);
  pa.w = bf16r(a0[6]) | ((unsigned)bf16r(a0[7]) << 16);
  pb.x = bf16r(a1[0]) | ((unsigned)bf16r(a1[1]) << 16);
  pb.y = bf16r(a1[2]) | ((unsigned)bf16r(a1[3]) << 16);
  pb.z = bf16r(a1[4]) | ((unsigned)bf16r(a1[5]) << 16);
  pb.w = bf16r(a1[6]) | ((unsigned)bf16r(a1[7]) << 16);
  *(uint4*)(h2out + g0 * 8) = pa;
  *(uint4*)(h2out + g0 * 8 + 8) = pb;

  float st[8], sq[8];
  #pragma unroll
  for (int t = 0; t < 8; ++t) {
    st[t] = a0[t] + a1[t];
    sq[t] = fmaf(a0[t], a0[t], a1[t] * a1[t]);
  }
  #pragma unroll
  for (int m = 1; m < 64; m <<= 1) {
    #pragma unroll
    for (int t = 0; t < 8; ++t) { st[t] += __shfl_xor(st[t], m); sq[t] += __shfl_xor(sq[t], m); }
  }
  if ((tid & 63) == 0) {
    const int w = tid >> 6;
    #pragma unroll
    for (int t = 0; t < 8; ++t) { redsh[w][t] = st[t]; redsh[w][8 + t] = sq[t]; }
  }
  __syncthreads();
  if (tid < 16) {
    float v = redsh[0][tid] + redsh[1][tid] + redsh[2][tid] + redsh[3][tid];
    partial[(size_t)tid * gridDim.x + blockIdx.x] = v;
  }
}

// ---------------- K4: fused softmax + xk + x_intra (LDS reduce) + exv(fp16) ----------------
__global__ __launch_bounds__(256) void k_intra(
    const unsigned short* __restrict__ zb, const unsigned* __restrict__ uqn,
    const int* __restrict__ knn, const float* __restrict__ cst,
    const float* __restrict__ lpw2, const float* __restrict__ lpb2,
    const float* __restrict__ iw, const float* __restrict__ ib,
    const float* __restrict__ ixw, const float* __restrict__ ixb,
    const unsigned short* __restrict__ h2b, const float* __restrict__ m2w3,
    const float* __restrict__ m2b3,
    const int* __restrict__ posbuf,
    float* __restrict__ x_intra, unsigned* __restrict__ exv)
{
  __shared__ uint2 xksh[256][17];   // 64 fp16 per row (16 quads), padded row = 34 dwords
  __shared__ float lpw2sh[192], lpb2sh[64];
  __shared__ h2 iwsh2[256], ixwsh2[256];   // packed fp16 pairs of output channels
  __shared__ float ibsh[8], ixbsh[8];
  __shared__ float w3sh[64], b3sh[8], s2sh[8], h2ssh[8];
  const int tid = threadIdx.x;
  if (tid < 192) lpw2sh[tid] = lpw2[tid];
  if (tid < 64) { lpb2sh[tid] = lpb2[tid]; w3sh[tid] = m2w3[tid]; }
  iwsh2[tid]  = mkh2(iw[2 * tid], iw[2 * tid + 1]);
  ixwsh2[tid] = mkh2(ixw[2 * tid], ixw[2 * tid + 1]);
  if (tid < 8) {
    ibsh[tid] = ib[tid]; ixbsh[tid] = ixb[tid];
    b3sh[tid] = m2b3[tid]; s2sh[tid] = cst[S_M2S2 + tid]; h2ssh[tid] = cst[S_M2H2 + tid];
  }
  __syncthreads();

  const size_t g = (size_t)blockIdx.x * 256 + tid;
  const int j = knn[g];
  const unsigned* zr = (const unsigned*)(zb + (size_t)j * 64);
  const int pos = posbuf[g];

  uint2 uc = *(const uint2*)(uqn + g * 2);
  const float qn0 = lo16(uc.x), qn1 = hi16(uc.x), qn2 = lo16(uc.y);

  // fused k-softmax from bf16 h2
  uint4 hu = *(const uint4*)(h2b + g * 8);
  float hn[8];
  hn[0] = fmaxf(fmaf(__uint_as_float(hu.x << 16),        s2sh[0], h2ssh[0]), 0.f);
  hn[1] = fmaxf(fmaf(__uint_as_float(hu.x & 0xffff0000u), s2sh[1], h2ssh[1]), 0.f);
  hn[2] = fmaxf(fmaf(__uint_as_float(hu.y << 16),        s2sh[2], h2ssh[2]), 0.f);
  hn[3] = fmaxf(fmaf(__uint_as_float(hu.y & 0xffff0000u), s2sh[3], h2ssh[3]), 0.f);
  hn[4] = fmaxf(fmaf(__uint_as_float(hu.z << 16),        s2sh[4], h2ssh[4]), 0.f);
  hn[5] = fmaxf(fmaf(__uint_as_float(hu.z & 0xffff0000u), s2sh[5], h2ssh[5]), 0.f);
  hn[6] = fmaxf(fmaf(__uint_as_float(hu.w << 16),        s2sh[6], h2ssh[6]), 0.f);
  hn[7] = fmaxf(fmaf(__uint_as_float(hu.w & 0xffff0000u), s2sh[7], h2ssh[7]), 0.f);
  float wk[8];
  #pragma unroll
  for (int t = 0; t < 8; ++t) {
    float a = b3sh[t];
    #pragma unroll
    for (int u = 0; u < 8; ++u) a = fmaf(hn[u], w3sh[u * 8 + t], a);
    wk[t] = a;
  }
  #pragma unroll
  for (int t = 0; t < 8; ++t) {
    float m = wk[t];
    m = fmaxf(m, __shfl_xor(m, 1));
    m = fmaxf(m, __shfl_xor(m, 2));
    m = fmaxf(m, __shfl_xor(m, 4));
    m = fmaxf(m, __shfl_xor(m, 8));
    float ex = __expf(wk[t] - m);
    float s = ex;
    s += __shfl_xor(s, 1);
    s += __shfl_xor(s, 2);
    s += __shfl_xor(s, 4);
    s += __shfl_xor(s, 8);
    wk[t] = ex / s;
  }

  h2 sacc2[4], vacc2[4];
  sacc2[0] = mkh2(ibsh[0], ibsh[1]); sacc2[1] = mkh2(ibsh[2], ibsh[3]);
  sacc2[2] = mkh2(ibsh[4], ibsh[5]); sacc2[3] = mkh2(ibsh[6], ibsh[7]);
  vacc2[0] = mkh2(ixbsh[0], ixbsh[1]); vacc2[1] = mkh2(ixbsh[2], ixbsh[3]);
  vacc2[2] = mkh2(ixbsh[4], ixbsh[5]); vacc2[3] = mkh2(ixbsh[6], ixbsh[7]);
  uint4 zq;
  #pragma unroll
  for (int c = 0; c < 64; c += 4) {
    if ((c & 7) == 0) zq = *(const uint4*)(zr + (c >> 1));
    const unsigned u0 = ((c & 7) == 0) ? zq.x : zq.z;
    const unsigned u1 = ((c & 7) == 0) ? zq.y : zq.w;
    const float z0 = __uint_as_float(u0 << 16);
    const float z1 = __uint_as_float(u0 & 0xffff0000u);
    const float z2 = __uint_as_float(u1 << 16);
    const float z3 = __uint_as_float(u1 & 0xffff0000u);
    float4 l0 = *(const float4*)(lpw2sh + c);
    float4 l1 = *(const float4*)(lpw2sh + 64 + c);
    float4 l2 = *(const float4*)(lpw2sh + 128 + c);
    float4 lb = *(const float4*)(lpb2sh + c);
    float xkv[4];
    xkv[0] = (z0 + fmaf(qn2, l2.x, fmaf(qn1, l1.x, fmaf(qn0, l0.x, lb.x)))) * wk[(c + 0) & 7];
    xkv[1] = (z1 + fmaf(qn2, l2.y, fmaf(qn1, l1.y, fmaf(qn0, l0.y, lb.y)))) * wk[(c + 1) & 7];
    xkv[2] = (z2 + fmaf(qn2, l2.z, fmaf(qn1, l1.z, fmaf(qn0, l0.z, lb.z)))) * wk[(c + 2) & 7];
    xkv[3] = (z3 + fmaf(qn2, l2.w, fmaf(qn1, l1.w, fmaf(qn0, l0.w, lb.w)))) * wk[(c + 3) & 7];
    xksh[tid][c >> 2] = make_uint2(packh2(xkv[0], xkv[1]), packh2(xkv[2], xkv[3]));
    #pragma unroll
    for (int d = 0; d < 4; ++d) {
      const _Float16 xh = (_Float16)xkv[d];
      h2 x2; x2[0] = xh; x2[1] = xh;
      const int cc = (c + d) * 4;
      #pragma unroll
      for (int q = 0; q < 4; ++q) {
        sacc2[q] = __builtin_elementwise_fma(x2, iwsh2[cc + q], sacc2[q]);
        vacc2[q] = __builtin_elementwise_fma(x2, ixwsh2[cc + q], vacc2[q]);
      }
    }
  }
  float sacc[8], vacc[8];
  #pragma unroll
  for (int q = 0; q < 4; ++q) {
    sacc[2 * q] = (float)sacc2[q][0]; sacc[2 * q + 1] = (float)sacc2[q][1];
    vacc[2 * q] = (float)vacc2[q][0]; vacc[2 * q + 1] = (float)vacc2[q][1];
  }
  float ex[8];
  #pragma unroll
  for (int t = 0; t < 8; ++t) ex[t] = __expf(sacc[t]);
  uint4 ea, eb;
  ea.x = packh2(ex[0], ex[1]); ea.y = packh2(ex[2], ex[3]);
  ea.z = packh2(ex[4], ex[5]); ea.w = packh2(ex[6], ex[7]);
  eb.x = packh2(ex[0] * vacc[0], ex[1] * vacc[1]);
  eb.y = packh2(ex[2] * vacc[2], ex[3] * vacc[3]);
  eb.z = packh2(ex[4] * vacc[4], ex[5] * vacc[5]);
  eb.w = packh2(ex[6] * vacc[6], ex[7] * vacc[7]);
  *(uint4*)(exv + (size_t)pos * 8) = ea;
  *(uint4*)(exv + (size_t)pos * 8 + 4) = eb;

  // x_intra: LDS-staged reduce over the 16 edges of each node
  __syncthreads();
  const int base = tid & ~15;
  const int own = tid & 15;
  float o0 = 0.f, o1 = 0.f, o2 = 0.f, o3 = 0.f;
  #pragma unroll
  for (int k = 0; k < 16; ++k) {
    uint2 v = xksh[base + k][own];
    o0 += lo16(v.x); o1 += hi16(v.x);
    o2 += lo16(v.y); o3 += hi16(v.y);
  }
  const size_t i = g >> 4;
  *(float4*)(x_intra + i * 64 + own * 4) = make_float4(o0, o1, o2, o3);
}

// ---------------- K5: streaming segment reduce (fp16) + x2 + bn2 partials ----------------
__global__ __launch_bounds__(256) void k_inter_x2(
    const int* __restrict__ rowstart, const unsigned* __restrict__ exv,
    float* __restrict__ xi, float* __restrict__ partial)
{
  __shared__ float bsum[64], bsq[64];
  const int tid = threadIdx.x;
  if (tid < 64) { bsum[tid] = 0.f; bsq[tid] = 0.f; }
  __syncthreads();
  const int t = tid & 15;
  const int j = blockIdx.x * 16 + (tid >> 4);
  const int s0 = rowstart[j];
  const int e0 = rowstart[j + 1];
  const unsigned short* eh = (const unsigned short*)exv;
  float acc = 0.f;
  for (int e = s0; e < e0; ++e) acc += h2f(eh[(size_t)e * 16 + t]);
  const float other = __shfl_xor(acc, 8);
  float r = (t < 8) ? ((acc > 0.f) ? other / acc : 0.f)
                    : ((other > 0.f) ? acc / other : 0.f);
  float4 xv = *(const float4*)(xi + (size_t)j * 64 + t * 4);
  float v0 = xv.x + __shfl(r, (4 * t + 0) & 7, 16);
  float v1 = xv.y + __shfl(r, (4 * t + 1) & 7, 16);
  float v2 = xv.z + __shfl(r, (4 * t + 2) & 7, 16);
  float v3 = xv.w + __shfl(r, (4 * t + 3) & 7, 16);
  *(float4*)(xi + (size_t)j * 64 + t * 4) = make_float4(v0, v1, v2, v3);
  float s_[4] = {v0, v1, v2, v3};
  float q_[4] = {v0 * v0, v1 * v1, v2 * v2, v3 * v3};
  #pragma unroll
  for (int d = 0; d < 4; ++d) {
    s_[d] += __shfl_xor(s_[d], 16); s_[d] += __shfl_xor(s_[d], 32);
    q_[d] += __shfl_xor(q_[d], 16); q_[d] += __shfl_xor(q_[d], 32);
  }
  if ((tid & 63) < 16) {
    #pragma unroll
    for (int d = 0; d < 4; ++d) {
      atomicAdd(&bsum[4 * t + d], s_[d]);
      atomicAdd(&bsq[4 * t + d], q_[d]);
    }
  }
  __syncthreads();
  if (tid < 64) {
    partial[(size_t)tid * gridDim.x + blockIdx.x] = bsum[tid];
    partial[(size_t)(tid + 64) * gridDim.x + blockIdx.x] = bsq[tid];
  }
}

// ---------------- K6: final bn3 + residual + relu ----------------
__global__ __launch_bounds__(256) void k_out(
    const float* __restrict__ y3, const float* __restrict__ x0,
    const float* __restrict__ cst, float* __restrict__ out)
{
  __shared__ float scsh[64], shsh[64];
  const int tid = threadIdx.x;
  if (tid < 64) { scsh[tid] = cst[S_SC3 + tid]; shsh[tid] = cst[S_SH3 + tid]; }
  __syncthreads();
  const size_t i = ((size_t)blockIdx.x * 256 + tid) * 4;
  float4 y = *(const float4*)(y3 + i);
  float4 x = *(const float4*)(x0 + i);
  const int c = (int)(i & 63);
  float4 o;
  o.x = fmaxf(fmaf(y.x, scsh[c + 0], shsh[c + 0]) + x.x, 0.f);
  o.y = fmaxf(fmaf(y.y, scsh[c + 1], shsh[c + 1]) + x.y, 0.f);
  o.z = fmaxf(fmaf(y.z, scsh[c + 2], shsh[c + 2]) + x.z, 0.f);
  o.w = fmaxf(fmaf(y.w, scsh[c + 3], shsh[c + 3]) + x.w, 0.f);
  *(float4*)(out + i) = o;
}

// ---------------- launch ----------------
extern "C" void kernel_launch(void* const* d_in, const int* in_sizes, int n_in,
                              void* d_out, int out_size, void* d_ws, size_t ws_size,
                              hipStream_t stream)
{
  (void)n_in; (void)out_size; (void)ws_size;
  const float* p    = (const float*)d_in[0];
  const float* x    = (const float*)d_in[1];
  const int*   knn  = (const int*)d_in[2];
  const float* w1   = (const float*)d_in[3];
  const float* g1   = (const float*)d_in[4];
  const float* b1   = (const float*)d_in[5];
  const float* m1w1 = (const float*)d_in[6];
  const float* m1b1 = (const float*)d_in[7];
  const float* m1w2 = (const float*)d_in[8];
  const float* m1b2 = (const float*)d_in[9];
  const float* lpw1 = (const float*)d_in[10];
  const float* lpb1 = (const float*)d_in[11];
  const float* lpg  = (const float*)d_in[12];
  const float* lpbt = (const float*)d_in[13];
  const float* lpw2 = (const float*)d_in[14];
  const float* lpb2 = (const float*)d_in[15];
  const float* m2w1 = (const float*)d_in[16];
  const float* m2g1 = (const float*)d_in[17];
  const float* m2bt1= (const float*)d_in[18];
  const float* m2w2 = (const float*)d_in[19];
  const float* m2g2 = (const float*)d_in[20];
  const float* m2bt2= (const float*)d_in[21];
  const float* m2w3 = (const float*)d_in[22];
  const float* m2b3 = (const float*)d_in[23];
  const float* m3w  = (const float*)d_in[24];
  const float* m3b  = (const float*)d_in[25];
  const float* iw   = (const float*)d_in[26];
  const float* ib   = (const float*)d_in[27];
  const float* ixw  = (const float*)d_in[28];
  const float* ixb  = (const float*)d_in[29];
  const float* g2   = (const float*)d_in[30];
  const float* b2   = (const float*)d_in[31];
  const float* w3   = (const float*)d_in[32];
  const float* g3   = (const float*)d_in[33];
  const float* b3   = (const float*)d_in[34];
  float* out = (float*)d_out;
  float* ws  = (float*)d_ws;

  const int n = in_sizes[1] / 64;                // 32768
  const long long nk = (long long)n * 16;        // 524288
  const int nb1024 = n >> 10;                    // 32

  float* cst  = ws;
  int* cnt      = (int*)(ws + CONST_FLOATS);    // n ints (zeroed with cst)
  int* rowstart = cnt + n;                      // n+1 ints (+pad)
  int* rank     = rowstart + n + 16;            // nk ints
  int* posb     = rank + nk;                    // nk ints
  int* bsums    = posb + nk;                    // nb1024 ints
  int* blockoff = bsums + 64;                   // nb1024 ints
  unsigned short* zb = (unsigned short*)(blockoff + 64);  // 64n bf16
  float* y1 = (float*)(zb + 64LL * n);          // 64n, reused as y3
  float* xi = y1 + 64LL * n;                    // 64n
  float* y16 = xi + 64LL * n;                   // 16n
  unsigned short* h2b = (unsigned short*)(y16 + 16LL * n);  // 128n ushorts
  unsigned* exv = (unsigned*)(h2b + 128LL * n); // 128n uints

  const int gB   = n / 64;            // 512
  const int nkB  = (int)(nk / 256);   // 2048
  const int nkB2 = (int)(nk / 512);   // 1024
  const int jB   = n / 16;            // 2048

  float* pbn1  = (float*)(exv + 128LL * n);      // 128 * gB
  float* plp   = pbn1 + 128LL * gB;              // 8 * nkB
  float* pmom  = plp + 8LL * nkB;                // 210 * nkB
  float* s2buf = pmom + 210LL * nkB;             // 256
  float* pm2b2 = s2buf + 256;                    // 16 * nkB2
  float* pbn2  = pm2b2 + 16LL * nkB2;            // 128 * jB
  float* pbn3  = pbn2 + 128LL * jB;              // 128 * gB
  unsigned* uq = (unsigned*)(pbn3 + 128LL * gB); // 8 * nk uints
  unsigned* uqn = uq + 8LL * nk;                 // 2 * nk uints

  hipMemsetAsync(d_ws, 0, (size_t)CONST_FLOATS * sizeof(float) + (size_t)n * sizeof(int), stream);

  k_prhist<<<nkB, 256, 0, stream>>>(p, knn, lpw1, lpb1, plp, cnt, rank);
  k_gemm64<<<gB, 256, 0, stream>>>(x, w1, nullptr, nullptr, nullptr, y1, pbn1, n);
  k_bsum<<<nb1024, 256, 0, stream>>>(cnt, bsums);
  k_mid2<<<1, 256, 0, stream>>>(bsums, blockoff, rowstart, n, plp, nkB,
                                lpg, lpbt, lpw1, lpb1, lpw2, lpb2,
                                m1w2, m2w1, m1b2, cst, 1.f / (float)nk);
  k_rbn<<<64, 256, 0, stream>>>(pbn1, gB, 64, g1, b1, cst + S_SC1, cst + S_SH1, 1.f / (float)n);
  k_scan3<<<nb1024, 256, 0, stream>>>(cnt, blockoff, rowstart);
  // z(bf16) + y16 in one pass
  k_gemmzy<<<gB, 256, 0, stream>>>(y1, m3w, m3b, m1w1 + 48, cst + S_SC1, cst + S_SH1, zb, y16);
  // h1 BN stats via u-moments; also emits uq/uqn/pos
  k_moment<<<nkB, 256, 0, stream>>>(y16, p, knn, m1w1, m1b1, cst, rowstart, rank,
                                    pmom, uq, uqn, posb);
  k_mred<<<210, 256, 0, stream>>>(pmom, s2buf, nkB);
  k_mfin<<<1, 64, 0, stream>>>(s2buf, m2g1, m2bt1, cst, 1.f / (float)nk);
  // h2 (bf16) from uq/uqn + stats
  k_h2<<<nkB2, 256, 0, stream>>>(uq, uqn, cst, m2w2, h2b, pm2b2);
  k_rbn<<<8, 256, 0, stream>>>(pm2b2, nkB2, 8, m2g2, m2bt2, cst + S_M2S2, cst + S_M2H2, 1.f / (float)nk);
  // fused softmax + xk + x_intra + exv
  k_intra<<<nkB, 256, 0, stream>>>(zb, uqn, knn, cst, lpw2, lpb2, iw, ib, ixw, ixb,
                                   h2b, m2w3, m2b3, posb, xi, exv);
  // streaming segment reduce + x2 + bn2 partials
  k_inter_x2<<<jB, 256, 0, stream>>>(rowstart, exv, xi, pbn2);
  k_rbn<<<64, 256, 0, stream>>>(pbn2, jB, 64, g2, b2, cst + S_SC2, cst + S_SH2, 1.f / (float)n);
  // y3 = relu(bn2(x2)) @ w3, bn3
  k_gemm64<<<gB, 256, 0, stream>>>(xi, w3, nullptr, cst + S_SC2, cst + S_SH2, y1, pbn3, n);
  k_rbn<<<64, 256, 0, stream>>>(pbn3, gB, 64, g3, b3, cst + S_SC3, cst + S_SH3, 1.f / (float)n);
  // out = relu(bn3(y3) + x)
  k_out<<<(int)((long long)n * 64 / 1024), 256, 0, stream>>>(y1, x, cst, out);
}

// Round 16
// 260.635 us; speedup vs baseline: 1.7253x; 1.0518x over previous
//
#include <hip/hip_runtime.h>

// N = 32768 (runtime), C = 64, K = 16, CS = 8, SHARE = 8

enum {
  S_SC1 = 0,    S_SH1 = 64,
  S_LPSC = 128, S_LPSH = 132,
  S_M2S1 = 136, S_M2H1 = 200,
  S_M2S2 = 264, S_M2H2 = 272,
  S_SC2 = 280,  S_SH2 = 344,
  S_SC3 = 408,  S_SH3 = 472,
  S_LPW2S = 536, S_LPB2S = 584,
  S_QW = 600, S_QB = 612,
  S_G = 640,        // 64x16 c-major
  S_HC = 1664,      // 64x4 c-major
  S_HB = 1920,      // 64
  CONST_FLOATS = 2048
};

typedef _Float16 h2 __attribute__((ext_vector_type(2)));

__device__ __forceinline__ int pidx(int a, int b) {  // a<=b, 20-dim sym
  return a * 20 - (a * (a - 1)) / 2 + (b - a);
}
__device__ __forceinline__ unsigned short bf16r(float f) {
  unsigned u = __float_as_uint(f);
  u = u + 0x7fffu + ((u >> 16) & 1u);
  return (unsigned short)(u >> 16);
}
__device__ __forceinline__ unsigned short f2h(float f) {
  _Float16 h = (_Float16)f;
  unsigned short u;
  __builtin_memcpy(&u, &h, 2);
  return u;
}
__device__ __forceinline__ float h2f(unsigned short u) {
  _Float16 h;
  __builtin_memcpy(&h, &u, 2);
  return (float)h;
}
__device__ __forceinline__ unsigned packh2(float a, float b) {
  return (unsigned)f2h(a) | ((unsigned)f2h(b) << 16);
}
__device__ __forceinline__ float lo16(unsigned u) { return h2f((unsigned short)(u & 0xffffu)); }
__device__ __forceinline__ float hi16(unsigned u) { return h2f((unsigned short)(u >> 16)); }
__device__ __forceinline__ h2 mkh2(float a, float b) {
  h2 v; v[0] = (_Float16)a; v[1] = (_Float16)b; return v;
}

// ---------------- fused partial-reduce + BN finalize ----------------
__global__ __launch_bounds__(256) void k_rbn(
    const float* __restrict__ partial, int nb, int nch,
    const float* __restrict__ g, const float* __restrict__ b,
    float* __restrict__ scale, float* __restrict__ shift, float inv_count)
{
  const int c = blockIdx.x;
  const int tid = threadIdx.x;
  float s = 0.f, q = 0.f;
  for (int i = tid; i < nb; i += 256) {
    s += partial[(size_t)c * nb + i];
    q += partial[(size_t)(c + nch) * nb + i];
  }
  #pragma unroll
  for (int m = 1; m < 64; m <<= 1) { s += __shfl_xor(s, m); q += __shfl_xor(q, m); }
  __shared__ float ws[4], wq[4];
  if ((tid & 63) == 0) { ws[tid >> 6] = s; wq[tid >> 6] = q; }
  __syncthreads();
  if (tid == 0) {
    float S = ws[0] + ws[1] + ws[2] + ws[3];
    float Q = wq[0] + wq[1] + wq[2] + wq[3];
    float m = S * inv_count;
    float v = Q * inv_count - m * m;
    float rs = rsqrtf(v + 1e-5f);
    float sc = g[c] * rs;
    scale[c] = sc;
    shift[c] = fmaf(-m, sc, b[c]);
  }
}

// ---------------- 64x64 GEMM, 16 rows/block (high TLP) ----------------
__global__ __launch_bounds__(256) void k_gemm64(
    const float* __restrict__ in, const float* __restrict__ w,
    const float* __restrict__ bias,
    const float* __restrict__ sc, const float* __restrict__ sh,
    float* __restrict__ out,
    float* __restrict__ partial, int n)
{
  __shared__ float scsh[64], shsh[64];
  __shared__ float bsum[64], bsq[64];
  const int tid = threadIdx.x;
  const int lane = tid & 63;
  const int wave = tid >> 6;
  if (sc != nullptr && tid < 64) { scsh[tid] = sc[tid]; shsh[tid] = sh[tid]; }
  if (tid < 64) { bsum[tid] = 0.f; bsq[tid] = 0.f; }
  __syncthreads();

  float wreg[64];
  #pragma unroll
  for (int k = 0; k < 64; ++k) wreg[k] = w[k * 64 + lane];
  const float bz = bias ? bias[lane] : 0.f;

  float lsum = 0.f, lsq = 0.f;
  const int row0 = blockIdx.x * 16 + wave * 4;
  #pragma unroll
  for (int r = 0; r < 4; ++r) {
    const int row = row0 + r;
    const float* xr = in + (size_t)row * 64;
    float acc0 = bz, acc1 = 0.f;
    if (sc != nullptr) {
      #pragma unroll
      for (int k = 0; k < 32; k += 4) {
        float4 xa = *(const float4*)(xr + k);
        float4 xb = *(const float4*)(xr + 32 + k);
        float a0 = fmaxf(fmaf(xa.x, scsh[k + 0], shsh[k + 0]), 0.f);
        float a1 = fmaxf(fmaf(xa.y, scsh[k + 1], shsh[k + 1]), 0.f);
        float a2 = fmaxf(fmaf(xa.z, scsh[k + 2], shsh[k + 2]), 0.f);
        float a3 = fmaxf(fmaf(xa.w, scsh[k + 3], shsh[k + 3]), 0.f);
        float b0 = fmaxf(fmaf(xb.x, scsh[k + 32], shsh[k + 32]), 0.f);
        float b1 = fmaxf(fmaf(xb.y, scsh[k + 33], shsh[k + 33]), 0.f);
        float b2 = fmaxf(fmaf(xb.z, scsh[k + 34], shsh[k + 34]), 0.f);
        float b3 = fmaxf(fmaf(xb.w, scsh[k + 35], shsh[k + 35]), 0.f);
        acc0 = fmaf(a0, wreg[k + 0], acc0);
        acc0 = fmaf(a1, wreg[k + 1], acc0);
        acc0 = fmaf(a2, wreg[k + 2], acc0);
        acc0 = fmaf(a3, wreg[k + 3], acc0);
        acc1 = fmaf(b0, wreg[k + 32], acc1);
        acc1 = fmaf(b1, wreg[k + 33], acc1);
        acc1 = fmaf(b2, wreg[k + 34], acc1);
        acc1 = fmaf(b3, wreg[k + 35], acc1);
      }
    } else {
      #pragma unroll
      for (int k = 0; k < 32; k += 4) {
        float4 xa = *(const float4*)(xr + k);
        float4 xb = *(const float4*)(xr + 32 + k);
        acc0 = fmaf(xa.x, wreg[k + 0], acc0);
        acc0 = fmaf(xa.y, wreg[k + 1], acc0);
        acc0 = fmaf(xa.z, wreg[k + 2], acc0);
        acc0 = fmaf(xa.w, wreg[k + 3], acc0);
        acc1 = fmaf(xb.x, wreg[k + 32], acc1);
        acc1 = fmaf(xb.y, wreg[k + 33], acc1);
        acc1 = fmaf(xb.z, wreg[k + 34], acc1);
        acc1 = fmaf(xb.w, wreg[k + 35], acc1);
      }
    }
    float acc = acc0 + acc1;
    out[(size_t)row * 64 + lane] = acc;
    lsum += acc;
    lsq = fmaf(acc, acc, lsq);
  }
  if (partial != nullptr) {
    atomicAdd(&bsum[lane], lsum);
    atomicAdd(&bsq[lane], lsq);
    __syncthreads();
    if (tid < 64) {
      partial[(size_t)tid * gridDim.x + blockIdx.x] = bsum[tid];
      partial[(size_t)(tid + 64) * gridDim.x + blockIdx.x] = bsq[tid];
    }
  }
}

// ---------------- fused: z (bf16) = nr(y1)@m3w+m3b ; y16 = nr(y1)@m1w1[3:] ----------------
__global__ __launch_bounds__(256) void k_gemmzy(
    const float* __restrict__ in, const float* __restrict__ w,
    const float* __restrict__ bias, const float* __restrict__ w16,
    const float* __restrict__ sc, const float* __restrict__ sh,
    unsigned short* __restrict__ outz, float* __restrict__ out16)
{
  __shared__ float xn[64][68];
  __shared__ float w16sh[1024];
  __shared__ float scsh[64], shsh[64];
  const int tid = threadIdx.x;
  if (tid < 64) { scsh[tid] = sc[tid]; shsh[tid] = sh[tid]; }
  for (int i2 = tid; i2 < 1024; i2 += 256) w16sh[i2] = w16[i2];
  __syncthreads();
  const int row0 = blockIdx.x * 64;
  for (int idx = tid; idx < 4096; idx += 256) {
    int r = idx >> 6, c = idx & 63;
    float v = in[(size_t)(row0 + r) * 64 + c];
    xn[r][c] = fmaxf(fmaf(v, scsh[c], shsh[c]), 0.f);
  }
  __syncthreads();

  const int lane = tid & 63;
  const int wave = tid >> 6;
  float wreg[64];
  #pragma unroll
  for (int k = 0; k < 64; ++k) wreg[k] = w[k * 64 + lane];
  const float bz = bias[lane];
  for (int r = wave * 16; r < wave * 16 + 16; ++r) {
    float acc = bz;
    #pragma unroll
    for (int k = 0; k < 64; k += 4) {
      float4 xv = *(const float4*)(&xn[r][k]);
      acc = fmaf(xv.x, wreg[k + 0], acc);
      acc = fmaf(xv.y, wreg[k + 1], acc);
      acc = fmaf(xv.z, wreg[k + 2], acc);
      acc = fmaf(xv.w, wreg[k + 3], acc);
    }
    outz[(size_t)(row0 + r) * 64 + lane] = bf16r(acc);
  }
  for (int idx = tid; idx < 1024; idx += 256) {
    int r = idx >> 4, t = idx & 15;
    float acc = 0.f;
    #pragma unroll
    for (int c = 0; c < 64; c += 4) {
      float4 xv = *(const float4*)(&xn[r][c]);
      acc = fmaf(xv.x, w16sh[(c + 0) * 16 + t], acc);
      acc = fmaf(xv.y, w16sh[(c + 1) * 16 + t], acc);
      acc = fmaf(xv.z, w16sh[(c + 2) * 16 + t], acc);
      acc = fmaf(xv.w, w16sh[(c + 3) * 16 + t], acc);
    }
    out16[(size_t)(row0 + r) * 16 + t] = acc;
  }
}

// ---------------- K1: lp partials, histogram + rank ----------------
__global__ __launch_bounds__(256) void k_prhist(
    const float* __restrict__ p, const int* __restrict__ knn,
    const float* __restrict__ lpw1, const float* __restrict__ lpb1,
    float* __restrict__ plp,
    int* __restrict__ cnt, int* __restrict__ rank)
{
  __shared__ float lpw1sh[9], lpb1sh[3];
  __shared__ float lpsh[4][8];
  const int tid = threadIdx.x;
  if (tid < 9) lpw1sh[tid] = lpw1[tid];
  if (tid < 3) lpb1sh[tid] = lpb1[tid];
  __syncthreads();

  const size_t g = (size_t)blockIdx.x * 256 + tid;
  const int i = (int)(g >> 4);
  const int j = knn[g];
  const float pr0 = p[j * 3 + 0] - p[i * 3 + 0];
  const float pr1 = p[j * 3 + 1] - p[i * 3 + 1];
  const float pr2 = p[j * 3 + 2] - p[i * 3 + 2];
  rank[g] = atomicAdd(&cnt[j], 1);

  float q0 = fmaf(pr2, lpw1sh[6], fmaf(pr1, lpw1sh[3], fmaf(pr0, lpw1sh[0], lpb1sh[0])));
  float q1 = fmaf(pr2, lpw1sh[7], fmaf(pr1, lpw1sh[4], fmaf(pr0, lpw1sh[1], lpb1sh[1])));
  float q2 = fmaf(pr2, lpw1sh[8], fmaf(pr1, lpw1sh[5], fmaf(pr0, lpw1sh[2], lpb1sh[2])));
  float s0 = q0, s1 = q1, s2 = q2, qq0 = q0 * q0, qq1 = q1 * q1, qq2 = q2 * q2;
  #pragma unroll
  for (int m = 1; m < 64; m <<= 1) {
    s0 += __shfl_xor(s0, m); s1 += __shfl_xor(s1, m); s2 += __shfl_xor(s2, m);
    qq0 += __shfl_xor(qq0, m); qq1 += __shfl_xor(qq1, m); qq2 += __shfl_xor(qq2, m);
  }
  if ((tid & 63) == 0) {
    const int w = tid >> 6;
    lpsh[w][0] = s0; lpsh[w][1] = s1; lpsh[w][2] = s2; lpsh[w][3] = 0.f;
    lpsh[w][4] = qq0; lpsh[w][5] = qq1; lpsh[w][6] = qq2; lpsh[w][7] = 0.f;
  }
  __syncthreads();
  if (tid < 8) {
    float v = lpsh[0][tid] + lpsh[1][tid] + lpsh[2][tid] + lpsh[3][tid];
    plp[(size_t)tid * gridDim.x + blockIdx.x] = v;
  }
}

// ---------------- block sums of cnt (1024 counts per block) ----------------
__global__ __launch_bounds__(256) void k_bsum(
    const int* __restrict__ cnt, int* __restrict__ bsums)
{
  const int tid = threadIdx.x;
  int4 c4 = ((const int4*)cnt)[blockIdx.x * 256 + tid];
  int s = c4.x + c4.y + c4.z + c4.w;
  #pragma unroll
  for (int m = 1; m < 64; m <<= 1) s += __shfl_xor(s, m);
  __shared__ int ws[4];
  if ((tid & 63) == 0) ws[tid >> 6] = s;
  __syncthreads();
  if (tid == 0) bsums[blockIdx.x] = ws[0] + ws[1] + ws[2] + ws[3];
}

// ---------------- mid: block-sum scan + lp finalize + weight folding (LDS-staged) ----------------
__global__ __launch_bounds__(256) void k_mid2(
    const int* __restrict__ bsums, int* __restrict__ blockoff,
    int* __restrict__ rowstart, int n,
    const float* __restrict__ plp, int nbplp,
    const float* __restrict__ lpg, const float* __restrict__ lpbt,
    const float* __restrict__ lpw1, const float* __restrict__ lpb1,
    const float* __restrict__ lpw2, const float* __restrict__ lpb2,
    const float* __restrict__ m1w2, const float* __restrict__ m2w1,
    const float* __restrict__ m1b2,
    float* __restrict__ cst, float inv_count)
{
  __shared__ float w2sh_[2048];   // m2w1 staged
  __shared__ float w1sh_[256];    // m1w2 staged
  __shared__ int bsh[64];
  __shared__ float Ssh[8];
  const int tid = threadIdx.x;
  const int nb1024 = n >> 10;
  if (tid < nb1024) bsh[tid] = bsums[tid];
  for (int i = tid; i < 2048; i += 256) w2sh_[i] = m2w1[i];
  w1sh_[tid] = m1w2[tid];
  // lp stats reduce
  {
    const int row = tid >> 5, l32 = tid & 31;
    float ls = 0.f;
    for (int i = l32; i < nbplp; i += 32) ls += plp[(size_t)row * nbplp + i];
    #pragma unroll
    for (int m = 1; m < 32; m <<= 1) ls += __shfl_xor(ls, m);
    if (l32 == 0) Ssh[row] = ls;
  }
  __syncthreads();
  if (tid == 0) {
    int run = 0;
    for (int i = 0; i < nb1024; ++i) { blockoff[i] = run; run += bsh[i]; }
    rowstart[n] = run;
  }
  if (tid < 3) {
    float m = Ssh[tid] * inv_count;
    float v = Ssh[4 + tid] * inv_count - m * m;
    float rs = rsqrtf(v + 1e-5f);
    float sc = lpg[tid] * rs;
    cst[S_LPSC + tid] = sc;
    cst[S_LPSH + tid] = fmaf(-m, sc, lpbt[tid]);
  }
  __syncthreads();
  if (tid < 9)  cst[S_QW + tid] = lpw1[tid] * cst[S_LPSC + (tid % 3)];
  if (tid < 3)  cst[S_QB + tid] = fmaf(lpb1[tid], cst[S_LPSC + tid], cst[S_LPSH + tid]);
  if (tid < 16) {
    float b = 0.f;
    for (int c2 = 0; c2 < 4; ++c2) b += lpb2[c2 * 16 + tid];
    cst[S_LPB2S + tid] = b;
    for (int r = 0; r < 3; ++r) {
      float w = 0.f;
      for (int c2 = 0; c2 < 4; ++c2) w += lpw2[r * 64 + c2 * 16 + tid];
      cst[S_LPW2S + r * 16 + tid] = w;
    }
  }
  __syncthreads();
  // G fold (from LDS)
  #pragma unroll
  for (int q = 0; q < 4; ++q) {
    int ee = tid * 4 + q;
    int c = ee >> 4, u = ee & 15;
    float sg = 0.f;
    #pragma unroll
    for (int t = 0; t < 16; ++t) sg = fmaf(w1sh_[u * 16 + t], w2sh_[t * 64 + c], sg);
    cst[S_G + c * 16 + u] = sg;
  }
  if (tid < 192) {
    int c = tid / 3, r = tid - c * 3;
    float sh = 0.f;
    #pragma unroll
    for (int t = 0; t < 16; ++t) sh = fmaf(cst[S_LPW2S + r * 16 + t], w2sh_[(16 + t) * 64 + c], sh);
    cst[S_HC + c * 4 + r] = sh;
  }
  if (tid < 64) {
    cst[S_HC + tid * 4 + 3] = 0.f;
    float sb = 0.f;
    #pragma unroll
    for (int t = 0; t < 16; ++t) {
      sb = fmaf(m1b2[t], w2sh_[t * 64 + tid], sb);
      sb = fmaf(cst[S_LPB2S + t], w2sh_[(16 + t) * 64 + tid], sb);
    }
    cst[S_HB + tid] = sb;
  }
}

// ---------------- final scan: per-block local scan + offset ----------------
__global__ __launch_bounds__(256) void k_scan3(
    const int* __restrict__ cnt, const int* __restrict__ blockoff,
    int* __restrict__ rowstart)
{
  const int tid = threadIdx.x;
  const int b = blockIdx.x;
  int4 c4 = ((const int4*)cnt)[b * 256 + tid];
  int tsum = c4.x + c4.y + c4.z + c4.w;
  const int lane = tid & 63, w = tid >> 6;
  int inc = tsum;
  #pragma unroll
  for (int d = 1; d < 64; d <<= 1) {
    int v = __shfl_up(inc, d);
    if (lane >= d) inc += v;
  }
  __shared__ int wsum[4];
  if (lane == 63) wsum[w] = inc;
  __syncthreads();
  int woff = 0;
  for (int u = 0; u < w; ++u) woff += wsum[u];
  int g0 = blockoff[b] + woff + inc - tsum;
  const int base = b * 1024 + tid * 4;
  int4 o;
  o.x = g0;
  o.y = g0 + c4.x;
  o.z = g0 + c4.x + c4.y;
  o.w = g0 + c4.x + c4.y + c4.z;
  *(int4*)(rowstart + base) = o;
}

// ---------------- K2: u-moment accumulation + uq/uqn/pos store ----------------
__global__ __launch_bounds__(256) void k_moment(
    const float* __restrict__ y16, const float* __restrict__ p,
    const int* __restrict__ knn, const float* __restrict__ m1w1,
    const float* __restrict__ m1b1, const float* __restrict__ cst,
    const int* __restrict__ rowstart, const int* __restrict__ rank,
    float* __restrict__ pmom,   // [210 * gridDim.x] channel-major
    unsigned* __restrict__ uq,  // [nk * 8] packed fp16 t1[16]
    unsigned* __restrict__ uqn, // [nk * 2] packed fp16 qn[3]
    int* __restrict__ posbuf)   // [nk]
{
  __shared__ float ush[256 * 21];
  const int tid = threadIdx.x;
  const size_t g = (size_t)blockIdx.x * 256 + tid;
  const int i = (int)(g >> 4);
  const int j = knn[g];
  const float pr0 = p[j * 3 + 0] - p[i * 3 + 0];
  const float pr1 = p[j * 3 + 1] - p[i * 3 + 1];
  const float pr2 = p[j * 3 + 2] - p[i * 3 + 2];
  const float* yj = y16 + (size_t)j * 16;
  float4 ya = *(const float4*)(yj);
  float4 yb = *(const float4*)(yj + 4);
  float4 yc = *(const float4*)(yj + 8);
  float4 yd = *(const float4*)(yj + 12);
  float t1[16] = {ya.x, ya.y, ya.z, ya.w, yb.x, yb.y, yb.z, yb.w,
                  yc.x, yc.y, yc.z, yc.w, yd.x, yd.y, yd.z, yd.w};
  #pragma unroll
  for (int u = 0; u < 16; ++u)
    t1[u] = fmaxf(fmaf(pr2, m1w1[32 + u], fmaf(pr1, m1w1[16 + u],
                  fmaf(pr0, m1w1[u], t1[u] + m1b1[u]))), 0.f);
  const float qn0 = fmaxf(fmaf(pr2, cst[S_QW + 6], fmaf(pr1, cst[S_QW + 3], fmaf(pr0, cst[S_QW + 0], cst[S_QB + 0]))), 0.f);
  const float qn1 = fmaxf(fmaf(pr2, cst[S_QW + 7], fmaf(pr1, cst[S_QW + 4], fmaf(pr0, cst[S_QW + 1], cst[S_QB + 1]))), 0.f);
  const float qn2 = fmaxf(fmaf(pr2, cst[S_QW + 8], fmaf(pr1, cst[S_QW + 5], fmaf(pr0, cst[S_QW + 2], cst[S_QB + 2]))), 0.f);

  posbuf[g] = rowstart[j] + rank[g];

  uint4 ua, ub;
  ua.x = packh2(t1[0], t1[1]);   ua.y = packh2(t1[2], t1[3]);
  ua.z = packh2(t1[4], t1[5]);   ua.w = packh2(t1[6], t1[7]);
  ub.x = packh2(t1[8], t1[9]);   ub.y = packh2(t1[10], t1[11]);
  ub.z = packh2(t1[12], t1[13]); ub.w = packh2(t1[14], t1[15]);
  *(uint4*)(uq + g * 8)     = ua;
  *(uint4*)(uq + g * 8 + 4) = ub;
  uint2 uc;
  uc.x = packh2(qn0, qn1);
  uc.y = packh2(qn2, 0.f);
  *(uint2*)(uqn + g * 2) = uc;

  float* ur = ush + tid * 21;
  #pragma unroll
  for (int u = 0; u < 16; ++u) ur[u] = t1[u];
  ur[16] = qn0; ur[17] = qn1; ur[18] = qn2; ur[19] = 1.f;
  __syncthreads();

  if (tid < 210) {
    int a = 0, t = tid;
    while (t >= 20 - a) { t -= 20 - a; ++a; }
    const int b = a + t;
    float s = 0.f;
    for (int r = 0; r < 256; ++r) {
      const float* u = ush + r * 21;
      s = fmaf(u[a], u[b], s);
    }
    pmom[(size_t)tid * gridDim.x + blockIdx.x] = s;
  }
}

// ---------------- parallel moment reduce ----------------
__global__ __launch_bounds__(256) void k_mred(
    const float* __restrict__ pmom, float* __restrict__ S2, int nb)
{
  const int c = blockIdx.x;
  const int tid = threadIdx.x;
  float s = 0.f;
  for (int i = tid; i < nb; i += 256) s += pmom[(size_t)c * nb + i];
  #pragma unroll
  for (int m = 1; m < 64; m <<= 1) s += __shfl_xor(s, m);
  __shared__ float ws[4];
  if ((tid & 63) == 0) ws[tid >> 6] = s;
  __syncthreads();
  if (tid == 0) S2[c] = ws[0] + ws[1] + ws[2] + ws[3];
}

// ---------------- moment finalize ----------------
__global__ __launch_bounds__(64) void k_mfin(
    const float* __restrict__ S2in,
    const float* __restrict__ g, const float* __restrict__ b,
    float* __restrict__ cst, float inv_count)
{
  __shared__ float S2[210];
  const int tid = threadIdx.x;
  for (int i = tid; i < 210; i += 64) S2[i] = S2in[i];
  __syncthreads();
  const int c = tid;
  float w[20];
  #pragma unroll
  for (int u = 0; u < 16; ++u) w[u] = cst[S_G + c * 16 + u];
  w[16] = cst[S_HC + c * 4 + 0];
  w[17] = cst[S_HC + c * 4 + 1];
  w[18] = cst[S_HC + c * 4 + 2];
  w[19] = cst[S_HB + c];
  float m2 = 0.f, m1 = 0.f;
  for (int a = 0; a < 20; ++a) {
    const float wa = w[a];
    m2 = fmaf(wa * wa, S2[pidx(a, a)], m2);
    float cross = 0.f;
    for (int bb = a + 1; bb < 20; ++bb) cross = fmaf(w[bb], S2[pidx(a, bb)], cross);
    m2 = fmaf(2.f * wa, cross, m2);
    m1 = fmaf(wa, S2[pidx(a, 19)], m1);
  }
  const float mean = m1 * inv_count;
  const float var = m2 * inv_count - mean * mean;
  const float rs = rsqrtf(var + 1e-5f);
  const float sc = g[c] * rs;
  cst[S_M2S1 + c] = sc;
  cst[S_M2H1 + c] = fmaf(-mean, sc, b[c]);
}

// ---------------- K3: h2(bf16) from packed uq/uqn via folded G/H ----------------
__global__ __launch_bounds__(256) void k_h2(
    const unsigned* __restrict__ uq, const unsigned* __restrict__ uqn,
    const float* __restrict__ cst, const float* __restrict__ m2w2,
    unsigned short* __restrict__ h2out,
    float* __restrict__ partial)   // [16 * gridDim.x]
{
  __shared__ float Gsh[1024], Hsh[256], hbsh[64];
  __shared__ float w2m[512];
  __shared__ float scsh[64], shsh[64];
  __shared__ float redsh[4][16];
  const int tid = threadIdx.x;
  for (int i = tid; i < 1024; i += 256) Gsh[i] = cst[S_G + i];
  Hsh[tid] = cst[S_HC + tid];
  for (int i = tid; i < 512; i += 256) w2m[i] = m2w2[i];
  if (tid < 64) { hbsh[tid] = cst[S_HB + tid]; scsh[tid] = cst[S_M2S1 + tid]; shsh[tid] = cst[S_M2H1 + tid]; }
  __syncthreads();

  const size_t g0 = ((size_t)blockIdx.x * 256 + tid) * 2;
  float t1[2][16], qn[2][3];
  #pragma unroll
  for (int gg = 0; gg < 2; ++gg) {
    const size_t g = g0 + gg;
    uint4 ua = *(const uint4*)(uq + g * 8);
    uint4 ub = *(const uint4*)(uq + g * 8 + 4);
    uint2 uc = *(const uint2*)(uqn + g * 2);
    t1[gg][0] = lo16(ua.x);  t1[gg][1] = hi16(ua.x);
    t1[gg][2] = lo16(ua.y);  t1[gg][3] = hi16(ua.y);
    t1[gg][4] = lo16(ua.z);  t1[gg][5] = hi16(ua.z);
    t1[gg][6] = lo16(ua.w);  t1[gg][7] = hi16(ua.w);
    t1[gg][8] = lo16(ub.x);  t1[gg][9] = hi16(ub.x);
    t1[gg][10] = lo16(ub.y); t1[gg][11] = hi16(ub.y);
    t1[gg][12] = lo16(ub.z); t1[gg][13] = hi16(ub.z);
    t1[gg][14] = lo16(ub.w); t1[gg][15] = hi16(ub.w);
    qn[gg][0] = lo16(uc.x); qn[gg][1] = hi16(uc.x); qn[gg][2] = lo16(uc.y);
  }

  float a0[8], a1[8];
  #pragma unroll
  for (int t = 0; t < 8; ++t) { a0[t] = 0.f; a1[t] = 0.f; }
  for (int c = 0; c < 64; ++c) {
    float4 g0v = *(const float4*)(Gsh + c * 16);
    float4 g1v = *(const float4*)(Gsh + c * 16 + 4);
    float4 g2v = *(const float4*)(Gsh + c * 16 + 8);
    float4 g3v = *(const float4*)(Gsh + c * 16 + 12);
    float4 hv = *(const float4*)(Hsh + c * 4);
    float h_0 = hbsh[c], h_1 = hbsh[c];
    h_0 = fmaf(t1[0][0], g0v.x, h_0); h_0 = fmaf(t1[0][1], g0v.y, h_0); h_0 = fmaf(t1[0][2], g0v.z, h_0); h_0 = fmaf(t1[0][3], g0v.w, h_0);
    h_0 = fmaf(t1[0][4], g1v.x, h_0); h_0 = fmaf(t1[0][5], g1v.y, h_0); h_0 = fmaf(t1[0][6], g1v.z, h_0); h_0 = fmaf(t1[0][7], g1v.w, h_0);
    h_0 = fmaf(t1[0][8], g2v.x, h_0); h_0 = fmaf(t1[0][9], g2v.y, h_0); h_0 = fmaf(t1[0][10], g2v.z, h_0); h_0 = fmaf(t1[0][11], g2v.w, h_0);
    h_0 = fmaf(t1[0][12], g3v.x, h_0); h_0 = fmaf(t1[0][13], g3v.y, h_0); h_0 = fmaf(t1[0][14], g3v.z, h_0); h_0 = fmaf(t1[0][15], g3v.w, h_0);
    h_0 = fmaf(qn[0][0], hv.x, fmaf(qn[0][1], hv.y, fmaf(qn[0][2], hv.z, h_0)));
    h_1 = fmaf(t1[1][0], g0v.x, h_1); h_1 = fmaf(t1[1][1], g0v.y, h_1); h_1 = fmaf(t1[1][2], g0v.z, h_1); h_1 = fmaf(t1[1][3], g0v.w, h_1);
    h_1 = fmaf(t1[1][4], g1v.x, h_1); h_1 = fmaf(t1[1][5], g1v.y, h_1); h_1 = fmaf(t1[1][6], g1v.z, h_1); h_1 = fmaf(t1[1][7], g1v.w, h_1);
    h_1 = fmaf(t1[1][8], g2v.x, h_1); h_1 = fmaf(t1[1][9], g2v.y, h_1); h_1 = fmaf(t1[1][10], g2v.z, h_1); h_1 = fmaf(t1[1][11], g2v.w, h_1);
    h_1 = fmaf(t1[1][12], g3v.x, h_1); h_1 = fmaf(t1[1][13], g3v.y, h_1); h_1 = fmaf(t1[1][14], g3v.z, h_1); h_1 = fmaf(t1[1][15], g3v.w, h_1);
    h_1 = fmaf(qn[1][0], hv.x, fmaf(qn[1][1], hv.y, fmaf(qn[1][2], hv.z, h_1)));
    float x0 = fmaxf(fmaf(h_0, scsh[c], shsh[c]), 0.f);
    float x1 = fmaxf(fmaf(h_1, scsh[c], shsh[c]), 0.f);
    float4 wa = *(const float4*)(w2m + c * 8);
    float4 wb = *(const float4*)(w2m + c * 8 + 4);
    a0[0] = fmaf(x0, wa.x, a0[0]); a0[1] = fmaf(x0, wa.y, a0[1]); a0[2] = fmaf(x0, wa.z, a0[2]); a0[3] = fmaf(x0, wa.w, a0[3]);
    a0[4] = fmaf(x0, wb.x, a0[4]); a0[5] = fmaf(x0, wb.y, a0[5]); a0[6] = fmaf(x0, wb.z, a0[6]); a0[7] = fmaf(x0, wb.w, a0[7]);
    a1[0] = fmaf(x1, wa.x, a1[0]); a1[1] = fmaf(x1, wa.y, a1[1]); a1[2] = fmaf(x1, wa.z, a1[2]); a1[3] = fmaf(x1, wa.w, a1[3]);
    a1[4] = fmaf(x1, wb.x, a1[4]); a1[5] = fmaf(x1, wb.y, a1[5]); a1[6] = fmaf(x1, wb.z, a1[6]); a1[7] = fmaf(x1, wb.w, a1[7]);
  }
  uint4 pa, pb;
  pa.x = bf16r(a0[0]) | ((unsigned)bf16r(a0[1]) << 16);
  pa.y = bf16r(a0[2]) | ((unsigned)bf16r(a0[3]) << 16);
  pa.z = bf16r(a0[4]) | ((unsigned)bf16r(a0[5]) << 16);
  pa.w = bf16r(a0[6]) | ((unsigned)bf16r(a0[7]) << 16);
  pb.x = bf16r(a1[0]) | ((unsigned)bf16r(a1[1]) << 16);
  pb.y = bf16r(a1[2]) | ((unsigned)bf16r(a1[3]) << 16);
  pb.z = bf16r(a1[4]) | ((unsigned)bf16r(a1[5]) << 16);
  pb.w = bf16r(a1[6]) | ((unsigned)bf16r(a1[7]) << 16);
  *(uint4*)(h2out + g0 * 8) = pa;
  *(uint4*)(h2out + g0 * 8 + 8) = pb;

  float st[8], sq[8];
  #pragma unroll
  for (int t = 0; t < 8; ++t) {
    st[t] = a0[t] + a1[t];
    sq[t] = fmaf(a0[t], a0[t], a1[t] * a1[t]);
  }
  #pragma unroll
  for (int m = 1; m < 64; m <<= 1) {
    #pragma unroll
    for (int t = 0; t < 8; ++t) { st[t] += __shfl_xor(st[t], m); sq[t] += __shfl_xor(sq[t], m); }
  }
  if ((tid & 63) == 0) {
    const int w = tid >> 6;
    #pragma unroll
    for (int t = 0; t < 8; ++t) { redsh[w][t] = st[t]; redsh[w][8 + t] = sq[t]; }
  }
  __syncthreads();
  if (tid < 16) {
    float v = redsh[0][tid] + redsh[1][tid] + redsh[2][tid] + redsh[3][tid];
    partial[(size_t)tid * gridDim.x + blockIdx.x] = v;
  }
}

// ---------------- K4: fused softmax + xk + x_intra (LDS reduce) + exv(fp16) ----------------
__global__ __launch_bounds__(256) void k_intra(
    const unsigned short* __restrict__ zb, const unsigned* __restrict__ uqn,
    const int* __restrict__ knn, const float* __restrict__ cst,
    const float* __restrict__ lpw2, const float* __restrict__ lpb2,
    const float* __restrict__ iw, const float* __restrict__ ib,
    const float* __restrict__ ixw, const float* __restrict__ ixb,
    const unsigned short* __restrict__ h2b, const float* __restrict__ m2w3,
    const float* __restrict__ m2b3,
    const int* __restrict__ posbuf,
    float* __restrict__ x_intra, unsigned* __restrict__ exv)
{
  __shared__ uint2 xksh[256][17];   // 64 fp16 per row (16 quads), padded row = 34 dwords
  __shared__ float lpw2sh[192], lpb2sh[64];
  __shared__ h2 iwsh2[256], ixwsh2[256];   // packed fp16 pairs of output channels
  __shared__ float ibsh[8], ixbsh[8];
  __shared__ float w3sh[64], b3sh[8], s2sh[8], h2ssh[8];
  const int tid = threadIdx.x;
  if (tid < 192) lpw2sh[tid] = lpw2[tid];
  if (tid < 64) { lpb2sh[tid] = lpb2[tid]; w3sh[tid] = m2w3[tid]; }
  iwsh2[tid]  = mkh2(iw[2 * tid], iw[2 * tid + 1]);
  ixwsh2[tid] = mkh2(ixw[2 * tid], ixw[2 * tid + 1]);
  if (tid < 8) {
    ibsh[tid] = ib[tid]; ixbsh[tid] = ixb[tid];
    b3sh[tid] = m2b3[tid]; s2sh[tid] = cst[S_M2S2 + tid]; h2ssh[tid] = cst[S_M2H2 + tid];
  }
  __syncthreads();

  const size_t g = (size_t)blockIdx.x * 256 + tid;
  const int j = knn[g];
  const unsigned* zr = (const unsigned*)(zb + (size_t)j * 64);
  const int pos = posbuf[g];

  uint2 uc = *(const uint2*)(uqn + g * 2);
  const float qn0 = lo16(uc.x), qn1 = hi16(uc.x), qn2 = lo16(uc.y);

  // fused k-softmax from bf16 h2
  uint4 hu = *(const uint4*)(h2b + g * 8);
  float hn[8];
  hn[0] = fmaxf(fmaf(__uint_as_float(hu.x << 16),        s2sh[0], h2ssh[0]), 0.f);
  hn[1] = fmaxf(fmaf(__uint_as_float(hu.x & 0xffff0000u), s2sh[1], h2ssh[1]), 0.f);
  hn[2] = fmaxf(fmaf(__uint_as_float(hu.y << 16),        s2sh[2], h2ssh[2]), 0.f);
  hn[3] = fmaxf(fmaf(__uint_as_float(hu.y & 0xffff0000u), s2sh[3], h2ssh[3]), 0.f);
  hn[4] = fmaxf(fmaf(__uint_as_float(hu.z << 16),        s2sh[4], h2ssh[4]), 0.f);
  hn[5] = fmaxf(fmaf(__uint_as_float(hu.z & 0xffff0000u), s2sh[5], h2ssh[5]), 0.f);
  hn[6] = fmaxf(fmaf(__uint_as_float(hu.w << 16),        s2sh[6], h2ssh[6]), 0.f);
  hn[7] = fmaxf(fmaf(__uint_as_float(hu.w & 0xffff0000u), s2sh[7], h2ssh[7]), 0.f);
  float wk[8];
  #pragma unroll
  for (int t = 0; t < 8; ++t) {
    float a = b3sh[t];
    #pragma unroll
    for (int u = 0; u < 8; ++u) a = fmaf(hn[u], w3sh[u * 8 + t], a);
    wk[t] = a;
  }
  #pragma unroll
  for (int t = 0; t < 8; ++t) {
    float m = wk[t];
    m = fmaxf(m, __shfl_xor(m, 1));
    m = fmaxf(m, __shfl_xor(m, 2));
    m = fmaxf(m, __shfl_xor(m, 4));
    m = fmaxf(m, __shfl_xor(m, 8));
    float ex = __expf(wk[t] - m);
    float s = ex;
    s += __shfl_xor(s, 1);
    s += __shfl_xor(s, 2);
    s += __shfl_xor(s, 4);
    s += __shfl_xor(s, 8);
    wk[t] = ex / s;
  }

  h2 sacc2[4], vacc2[4];
  sacc2[0] = mkh2(ibsh[0], ibsh[1]); sacc2[1] = mkh2(ibsh[2], ibsh[3]);
  sacc2[2] = mkh2(ibsh[4], ibsh[5]); sacc2[3] = mkh2(ibsh[6], ibsh[7]);
  vacc2[0] = mkh2(ixbsh[0], ixbsh[1]); vacc2[1] = mkh2(ixbsh[2], ixbsh[3]);
  vacc2[2] = mkh2(ixbsh[4], ixbsh[5]); vacc2[3] = mkh2(ixbsh[6], ixbsh[7]);
  uint4 zq;
  #pragma unroll
  for (int c = 0; c < 64; c += 4) {
    if ((c & 7) == 0) zq = *(const uint4*)(zr + (c >> 1));
    const unsigned u0 = ((c & 7) == 0) ? zq.x : zq.z;
    const unsigned u1 = ((c & 7) == 0) ? zq.y : zq.w;
    const float z0 = __uint_as_float(u0 << 16);
    const float z1 = __uint_as_float(u0 & 0xffff0000u);
    const float z2 = __uint_as_float(u1 << 16);
    const float z3 = __uint_as_float(u1 & 0xffff0000u);
    float4 l0 = *(const float4*)(lpw2sh + c);
    float4 l1 = *(const float4*)(lpw2sh + 64 + c);
    float4 l2 = *(const float4*)(lpw2sh + 128 + c);
    float4 lb = *(const float4*)(lpb2sh + c);
    float xkv[4];
    xkv[0] = (z0 + fmaf(qn2, l2.x, fmaf(qn1, l1.x, fmaf(qn0, l0.x, lb.x)))) * wk[(c + 0) & 7];
    xkv[1] = (z1 + fmaf(qn2, l2.y, fmaf(qn1, l1.y, fmaf(qn0, l0.y, lb.y)))) * wk[(c + 1) & 7];
    xkv[2] = (z2 + fmaf(qn2, l2.z, fmaf(qn1, l1.z, fmaf(qn0, l0.z, lb.z)))) * wk[(c + 2) & 7];
    xkv[3] = (z3 + fmaf(qn2, l2.w, fmaf(qn1, l1.w, fmaf(qn0, l0.w, lb.w)))) * wk[(c + 3) & 7];
    xksh[tid][c >> 2] = make_uint2(packh2(xkv[0], xkv[1]), packh2(xkv[2], xkv[3]));
    #pragma unroll
    for (int d = 0; d < 4; ++d) {
      const _Float16 xh = (_Float16)xkv[d];
      h2 x2; x2[0] = xh; x2[1] = xh;
      const int cc = (c + d) * 4;
      #pragma unroll
      for (int q = 0; q < 4; ++q) {
        sacc2[q] = __builtin_elementwise_fma(x2, iwsh2[cc + q], sacc2[q]);
        vacc2[q] = __builtin_elementwise_fma(x2, ixwsh2[cc + q], vacc2[q]);
      }
    }
  }
  float sacc[8], vacc[8];
  #pragma unroll
  for (int q = 0; q < 4; ++q) {
    sacc[2 * q] = (float)sacc2[q][0]; sacc[2 * q + 1] = (float)sacc2[q][1];
    vacc[2 * q] = (float)vacc2[q][0]; vacc[2 * q + 1] = (float)vacc2[q][1];
  }
  float ex[8];
  #pragma unroll
  for (int t = 0; t < 8; ++t) ex[t] = __expf(sacc[t]);
  uint4 ea, eb;
  ea.x = packh2(ex[0], ex[1]); ea.y = packh2(ex[2], ex[3]);
  ea.z = packh2(ex[4], ex[5]); ea.w = packh2(ex[6], ex[7]);
  eb.x = packh2(ex[0] * vacc[0], ex[1] * vacc[1]);
  eb.y = packh2(ex[2] * vacc[2], ex[3] * vacc[3]);
  eb.z = packh2(ex[4] * vacc[4], ex[5] * vacc[5]);
  eb.w = packh2(ex[6] * vacc[6], ex[7] * vacc[7]);
  *(uint4*)(exv + (size_t)pos * 8) = ea;
  *(uint4*)(exv + (size_t)pos * 8 + 4) = eb;

  // x_intra: LDS-staged reduce over the 16 edges of each node
  __syncthreads();
  const int base = tid & ~15;
  const int own = tid & 15;
  float o0 = 0.f, o1 = 0.f, o2 = 0.f, o3 = 0.f;
  #pragma unroll
  for (int k = 0; k < 16; ++k) {
    uint2 v = xksh[base + k][own];
    o0 += lo16(v.x); o1 += hi16(v.x);
    o2 += lo16(v.y); o3 += hi16(v.y);
  }
  const size_t i = g >> 4;
  *(float4*)(x_intra + i * 64 + own * 4) = make_float4(o0, o1, o2, o3);
}

// ---------------- K5: streaming segment reduce (fp16) + x2 + bn2 partials ----------------
__global__ __launch_bounds__(256) void k_inter_x2(
    const int* __restrict__ rowstart, const unsigned* __restrict__ exv,
    float* __restrict__ xi, float* __restrict__ partial)
{
  __shared__ float bsum[64], bsq[64];
  const int tid = threadIdx.x;
  if (tid < 64) { bsum[tid] = 0.f; bsq[tid] = 0.f; }
  __syncthreads();
  const int t = tid & 15;
  const int j = blockIdx.x * 16 + (tid >> 4);
  const int s0 = rowstart[j];
  const int e0 = rowstart[j + 1];
  const unsigned short* eh = (const unsigned short*)exv;
  float acc = 0.f;
  for (int e = s0; e < e0; ++e) acc += h2f(eh[(size_t)e * 16 + t]);
  const float other = __shfl_xor(acc, 8);
  float r = (t < 8) ? ((acc > 0.f) ? other / acc : 0.f)
                    : ((other > 0.f) ? acc / other : 0.f);
  float4 xv = *(const float4*)(xi + (size_t)j * 64 + t * 4);
  float v0 = xv.x + __shfl(r, (4 * t + 0) & 7, 16);
  float v1 = xv.y + __shfl(r, (4 * t + 1) & 7, 16);
  float v2 = xv.z + __shfl(r, (4 * t + 2) & 7, 16);
  float v3 = xv.w + __shfl(r, (4 * t + 3) & 7, 16);
  *(float4*)(xi + (size_t)j * 64 + t * 4) = make_float4(v0, v1, v2, v3);
  float s_[4] = {v0, v1, v2, v3};
  float q_[4] = {v0 * v0, v1 * v1, v2 * v2, v3 * v3};
  #pragma unroll
  for (int d = 0; d < 4; ++d) {
    s_[d] += __shfl_xor(s_[d], 16); s_[d] += __shfl_xor(s_[d], 32);
    q_[d] += __shfl_xor(q_[d], 16); q_[d] += __shfl_xor(q_[d], 32);
  }
  if ((tid & 63) < 16) {
    #pragma unroll
    for (int d = 0; d < 4; ++d) {
      atomicAdd(&bsum[4 * t + d], s_[d]);
      atomicAdd(&bsq[4 * t + d], q_[d]);
    }
  }
  __syncthreads();
  if (tid < 64) {
    partial[(size_t)tid * gridDim.x + blockIdx.x] = bsum[tid];
    partial[(size_t)(tid + 64) * gridDim.x + blockIdx.x] = bsq[tid];
  }
}

// ---------------- K6: final bn3 + residual + relu ----------------
__global__ __launch_bounds__(256) void k_out(
    const float* __restrict__ y3, const float* __restrict__ x0,
    const float* __restrict__ cst, float* __restrict__ out)
{
  __shared__ float scsh[64], shsh[64];
  const int tid = threadIdx.x;
  if (tid < 64) { scsh[tid] = cst[S_SC3 + tid]; shsh[tid] = cst[S_SH3 + tid]; }
  __syncthreads();
  const size_t i = ((size_t)blockIdx.x * 256 + tid) * 4;
  float4 y = *(const float4*)(y3 + i);
  float4 x = *(const float4*)(x0 + i);
  const int c = (int)(i & 63);
  float4 o;
  o.x = fmaxf(fmaf(y.x, scsh[c + 0], shsh[c + 0]) + x.x, 0.f);
  o.y = fmaxf(fmaf(y.y, scsh[c + 1], shsh[c + 1]) + x.y, 0.f);
  o.z = fmaxf(fmaf(y.z, scsh[c + 2], shsh[c + 2]) + x.z, 0.f);
  o.w = fmaxf(fmaf(y.w, scsh[c + 3], shsh[c + 3]) + x.w, 0.f);
  *(float4*)(out + i) = o;
}

// ---------------- launch ----------------
extern "C" void kernel_launch(void* const* d_in, const int* in_sizes, int n_in,
                              void* d_out, int out_size, void* d_ws, size_t ws_size,
                              hipStream_t stream)
{
  (void)n_in; (void)out_size; (void)ws_size;
  const float* p    = (const float*)d_in[0];
  const float* x    = (const float*)d_in[1];
  const int*   knn  = (const int*)d_in[2];
  const float* w1   = (const float*)d_in[3];
  const float* g1   = (const float*)d_in[4];
  const float* b1   = (const float*)d_in[5];
  const float* m1w1 = (const float*)d_in[6];
  const float* m1b1 = (const float*)d_in[7];
  const float* m1w2 = (const float*)d_in[8];
  const float* m1b2 = (const float*)d_in[9];
  const float* lpw1 = (const float*)d_in[10];
  const float* lpb1 = (const float*)d_in[11];
  const float* lpg  = (const float*)d_in[12];
  const float* lpbt = (const float*)d_in[13];
  const float* lpw2 = (const float*)d_in[14];
  const float* lpb2 = (const float*)d_in[15];
  const float* m2w1 = (const float*)d_in[16];
  const float* m2g1 = (const float*)d_in[17];
  const float* m2bt1= (const float*)d_in[18];
  const float* m2w2 = (const float*)d_in[19];
  const float* m2g2 = (const float*)d_in[20];
  const float* m2bt2= (const float*)d_in[21];
  const float* m2w3 = (const float*)d_in[22];
  const float* m2b3 = (const float*)d_in[23];
  const float* m3w  = (const float*)d_in[24];
  const float* m3b  = (const float*)d_in[25];
  const float* iw   = (const float*)d_in[26];
  const float* ib   = (const float*)d_in[27];
  const float* ixw  = (const float*)d_in[28];
  const float* ixb  = (const float*)d_in[29];
  const float* g2   = (const float*)d_in[30];
  const float* b2   = (const float*)d_in[31];
  const float* w3   = (const float*)d_in[32];
  const float* g3   = (const float*)d_in[33];
  const float* b3   = (const float*)d_in[34];
  float* out = (float*)d_out;
  float* ws  = (float*)d_ws;

  const int n = in_sizes[1] / 64;                // 32768
  const long long nk = (long long)n * 16;        // 524288
  const int nb1024 = n >> 10;                    // 32

  float* cst  = ws;
  int* cnt      = (int*)(ws + CONST_FLOATS);    // n ints (zeroed with cst)
  int* rowstart = cnt + n;                      // n+1 ints (+pad)
  int* rank     = rowstart + n + 16;            // nk ints
  int* posb     = rank + nk;                    // nk ints
  int* bsums    = posb + nk;                    // nb1024 ints
  int* blockoff = bsums + 64;                   // nb1024 ints
  unsigned short* zb = (unsigned short*)(blockoff + 64);  // 64n bf16
  float* y1 = (float*)(zb + 64LL * n);          // 64n, reused as y3
  float* xi = y1 + 64LL * n;                    // 64n
  float* y16 = xi + 64LL * n;                   // 16n
  unsigned short* h2b = (unsigned short*)(y16 + 16LL * n);  // 128n ushorts
  unsigned* exv = (unsigned*)(h2b + 128LL * n); // 128n uints

  const int gB2  = n / 16;            // 2048 (gemm64 grid)
  const int gB   = n / 64;            // 512 (gemmzy grid)
  const int nkB  = (int)(nk / 256);   // 2048
  const int nkB2 = (int)(nk / 512);   // 1024
  const int jB   = n / 16;            // 2048

  float* pbn1  = (float*)(exv + 128LL * n);      // 128 * gB2
  float* plp   = pbn1 + 128LL * gB2;             // 8 * nkB
  float* pmom  = plp + 8LL * nkB;                // 210 * nkB
  float* s2buf = pmom + 210LL * nkB;             // 256
  float* pm2b2 = s2buf + 256;                    // 16 * nkB2
  float* pbn2  = pm2b2 + 16LL * nkB2;            // 128 * jB
  float* pbn3  = pbn2 + 128LL * jB;              // 128 * gB2
  unsigned* uq = (unsigned*)(pbn3 + 128LL * gB2); // 8 * nk uints
  unsigned* uqn = uq + 8LL * nk;                 // 2 * nk uints

  hipMemsetAsync(d_ws, 0, (size_t)CONST_FLOATS * sizeof(float) + (size_t)n * sizeof(int), stream);

  k_prhist<<<nkB, 256, 0, stream>>>(p, knn, lpw1, lpb1, plp, cnt, rank);
  k_gemm64<<<gB2, 256, 0, stream>>>(x, w1, nullptr, nullptr, nullptr, y1, pbn1, n);
  k_bsum<<<nb1024, 256, 0, stream>>>(cnt, bsums);
  k_mid2<<<1, 256, 0, stream>>>(bsums, blockoff, rowstart, n, plp, nkB,
                                lpg, lpbt, lpw1, lpb1, lpw2, lpb2,
                                m1w2, m2w1, m1b2, cst, 1.f / (float)nk);
  k_rbn<<<64, 256, 0, stream>>>(pbn1, gB2, 64, g1, b1, cst + S_SC1, cst + S_SH1, 1.f / (float)n);
  k_scan3<<<nb1024, 256, 0, stream>>>(cnt, blockoff, rowstart);
  // z(bf16) + y16 in one pass
  k_gemmzy<<<gB, 256, 0, stream>>>(y1, m3w, m3b, m1w1 + 48, cst + S_SC1, cst + S_SH1, zb, y16);
  // h1 BN stats via u-moments; also emits uq/uqn/pos
  k_moment<<<nkB, 256, 0, stream>>>(y16, p, knn, m1w1, m1b1, cst, rowstart, rank,
                                    pmom, uq, uqn, posb);
  k_mred<<<210, 256, 0, stream>>>(pmom, s2buf, nkB);
  k_mfin<<<1, 64, 0, stream>>>(s2buf, m2g1, m2bt1, cst, 1.f / (float)nk);
  // h2 (bf16) from uq/uqn + stats
  k_h2<<<nkB2, 256, 0, stream>>>(uq, uqn, cst, m2w2, h2b, pm2b2);
  k_rbn<<<8, 256, 0, stream>>>(pm2b2, nkB2, 8, m2g2, m2bt2, cst + S_M2S2, cst + S_M2H2, 1.f / (float)nk);
  // fused softmax + xk + x_intra + exv
  k_intra<<<nkB, 256, 0, stream>>>(zb, uqn, knn, cst, lpw2, lpb2, iw, ib, ixw, ixb,
                                   h2b, m2w3, m2b3, posb, xi, exv);
  // streaming segment reduce + x2 + bn2 partials
  k_inter_x2<<<jB, 256, 0, stream>>>(rowstart, exv, xi, pbn2);
  k_rbn<<<64, 256, 0, stream>>>(pbn2, jB, 64, g2, b2, cst + S_SC2, cst + S_SH2, 1.f / (float)n);
  // y3 = relu(bn2(x2)) @ w3, bn3
  k_gemm64<<<gB2, 256, 0, stream>>>(xi, w3, nullptr, cst + S_SC2, cst + S_SH2, y1, pbn3, n);
  k_rbn<<<64, 256, 0, stream>>>(pbn3, gB2, 64, g3, b3, cst + S_SC3, cst + S_SH3, 1.f / (float)n);
  // out = relu(bn3(y3) + x)
  k_out<<<(int)((long long)n * 64 / 1024), 256, 0, stream>>>(y1, x, cst, out);
}

// Round 17
// 260.361 us; speedup vs baseline: 1.7271x; 1.0011x over previous
//
#include <hip/hip_runtime.h>

// N = 32768 (runtime), C = 64, K = 16, CS = 8, SHARE = 8

enum {
  S_SC1 = 0,    S_SH1 = 64,
  S_LPSC = 128, S_LPSH = 132,
  S_M2S1 = 136, S_M2H1 = 200,
  S_M2S2 = 264, S_M2H2 = 272,
  S_SC2 = 280,  S_SH2 = 344,
  S_SC3 = 408,  S_SH3 = 472,
  S_LPW2S = 536, S_LPB2S = 584,
  S_QW = 600, S_QB = 612,
  S_G = 640,        // 64x16 c-major
  S_HC = 1664,      // 64x4 c-major
  S_HB = 1920,      // 64
  CONST_FLOATS = 2048
};

typedef _Float16 h2 __attribute__((ext_vector_type(2)));

__device__ __forceinline__ int pidx(int a, int b) {  // a<=b, 20-dim sym
  return a * 20 - (a * (a - 1)) / 2 + (b - a);
}
__device__ __forceinline__ unsigned short bf16r(float f) {
  unsigned u = __float_as_uint(f);
  u = u + 0x7fffu + ((u >> 16) & 1u);
  return (unsigned short)(u >> 16);
}
__device__ __forceinline__ unsigned short f2h(float f) {
  _Float16 h = (_Float16)f;
  unsigned short u;
  __builtin_memcpy(&u, &h, 2);
  return u;
}
__device__ __forceinline__ float h2f(unsigned short u) {
  _Float16 h;
  __builtin_memcpy(&h, &u, 2);
  return (float)h;
}
__device__ __forceinline__ unsigned packh2(float a, float b) {
  return (unsigned)f2h(a) | ((unsigned)f2h(b) << 16);
}
__device__ __forceinline__ float lo16(unsigned u) { return h2f((unsigned short)(u & 0xffffu)); }
__device__ __forceinline__ float hi16(unsigned u) { return h2f((unsigned short)(u >> 16)); }
__device__ __forceinline__ h2 mkh2(float a, float b) {
  h2 v; v[0] = (_Float16)a; v[1] = (_Float16)b; return v;
}

// ---------------- zero the histogram counts (replaces slow runtime fill) ----------------
__global__ __launch_bounds__(256) void k_zero(int* __restrict__ cnt)
{
  ((int4*)cnt)[(size_t)blockIdx.x * 256 + threadIdx.x] = make_int4(0, 0, 0, 0);
}

// ---------------- fused partial-reduce + BN finalize ----------------
__global__ __launch_bounds__(256) void k_rbn(
    const float* __restrict__ partial, int nb, int nch,
    const float* __restrict__ g, const float* __restrict__ b,
    float* __restrict__ scale, float* __restrict__ shift, float inv_count)
{
  const int c = blockIdx.x;
  const int tid = threadIdx.x;
  float s = 0.f, q = 0.f;
  for (int i = tid; i < nb; i += 256) {
    s += partial[(size_t)c * nb + i];
    q += partial[(size_t)(c + nch) * nb + i];
  }
  #pragma unroll
  for (int m = 1; m < 64; m <<= 1) { s += __shfl_xor(s, m); q += __shfl_xor(q, m); }
  __shared__ float ws[4], wq[4];
  if ((tid & 63) == 0) { ws[tid >> 6] = s; wq[tid >> 6] = q; }
  __syncthreads();
  if (tid == 0) {
    float S = ws[0] + ws[1] + ws[2] + ws[3];
    float Q = wq[0] + wq[1] + wq[2] + wq[3];
    float m = S * inv_count;
    float v = Q * inv_count - m * m;
    float rs = rsqrtf(v + 1e-5f);
    float sc = g[c] * rs;
    scale[c] = sc;
    shift[c] = fmaf(-m, sc, b[c]);
  }
}

// ---------------- 64x64 GEMM, 16 rows/block (high TLP) ----------------
__global__ __launch_bounds__(256) void k_gemm64(
    const float* __restrict__ in, const float* __restrict__ w,
    const float* __restrict__ bias,
    const float* __restrict__ sc, const float* __restrict__ sh,
    float* __restrict__ out,
    float* __restrict__ partial, int n)
{
  __shared__ float scsh[64], shsh[64];
  __shared__ float bsum[64], bsq[64];
  const int tid = threadIdx.x;
  const int lane = tid & 63;
  const int wave = tid >> 6;
  if (sc != nullptr && tid < 64) { scsh[tid] = sc[tid]; shsh[tid] = sh[tid]; }
  if (tid < 64) { bsum[tid] = 0.f; bsq[tid] = 0.f; }
  __syncthreads();

  float wreg[64];
  #pragma unroll
  for (int k = 0; k < 64; ++k) wreg[k] = w[k * 64 + lane];
  const float bz = bias ? bias[lane] : 0.f;

  float lsum = 0.f, lsq = 0.f;
  const int row0 = blockIdx.x * 16 + wave * 4;
  #pragma unroll
  for (int r = 0; r < 4; ++r) {
    const int row = row0 + r;
    const float* xr = in + (size_t)row * 64;
    float acc0 = bz, acc1 = 0.f;
    if (sc != nullptr) {
      #pragma unroll
      for (int k = 0; k < 32; k += 4) {
        float4 xa = *(const float4*)(xr + k);
        float4 xb = *(const float4*)(xr + 32 + k);
        float a0 = fmaxf(fmaf(xa.x, scsh[k + 0], shsh[k + 0]), 0.f);
        float a1 = fmaxf(fmaf(xa.y, scsh[k + 1], shsh[k + 1]), 0.f);
        float a2 = fmaxf(fmaf(xa.z, scsh[k + 2], shsh[k + 2]), 0.f);
        float a3 = fmaxf(fmaf(xa.w, scsh[k + 3], shsh[k + 3]), 0.f);
        float b0 = fmaxf(fmaf(xb.x, scsh[k + 32], shsh[k + 32]), 0.f);
        float b1 = fmaxf(fmaf(xb.y, scsh[k + 33], shsh[k + 33]), 0.f);
        float b2 = fmaxf(fmaf(xb.z, scsh[k + 34], shsh[k + 34]), 0.f);
        float b3 = fmaxf(fmaf(xb.w, scsh[k + 35], shsh[k + 35]), 0.f);
        acc0 = fmaf(a0, wreg[k + 0], acc0);
        acc0 = fmaf(a1, wreg[k + 1], acc0);
        acc0 = fmaf(a2, wreg[k + 2], acc0);
        acc0 = fmaf(a3, wreg[k + 3], acc0);
        acc1 = fmaf(b0, wreg[k + 32], acc1);
        acc1 = fmaf(b1, wreg[k + 33], acc1);
        acc1 = fmaf(b2, wreg[k + 34], acc1);
        acc1 = fmaf(b3, wreg[k + 35], acc1);
      }
    } else {
      #pragma unroll
      for (int k = 0; k < 32; k += 4) {
        float4 xa = *(const float4*)(xr + k);
        float4 xb = *(const float4*)(xr + 32 + k);
        acc0 = fmaf(xa.x, wreg[k + 0], acc0);
        acc0 = fmaf(xa.y, wreg[k + 1], acc0);
        acc0 = fmaf(xa.z, wreg[k + 2], acc0);
        acc0 = fmaf(xa.w, wreg[k + 3], acc0);
        acc1 = fmaf(xb.x, wreg[k + 32], acc1);
        acc1 = fmaf(xb.y, wreg[k + 33], acc1);
        acc1 = fmaf(xb.z, wreg[k + 34], acc1);
        acc1 = fmaf(xb.w, wreg[k + 35], acc1);
      }
    }
    float acc = acc0 + acc1;
    out[(size_t)row * 64 + lane] = acc;
    lsum += acc;
    lsq = fmaf(acc, acc, lsq);
  }
  if (partial != nullptr) {
    atomicAdd(&bsum[lane], lsum);
    atomicAdd(&bsq[lane], lsq);
    __syncthreads();
    if (tid < 64) {
      partial[(size_t)tid * gridDim.x + blockIdx.x] = bsum[tid];
      partial[(size_t)(tid + 64) * gridDim.x + blockIdx.x] = bsq[tid];
    }
  }
}

// ---------------- fused: z (bf16) = nr(y1)@m3w+m3b ; y16 = nr(y1)@m1w1[3:] ----------------
__global__ __launch_bounds__(256) void k_gemmzy(
    const float* __restrict__ in, const float* __restrict__ w,
    const float* __restrict__ bias, const float* __restrict__ w16,
    const float* __restrict__ sc, const float* __restrict__ sh,
    unsigned short* __restrict__ outz, float* __restrict__ out16)
{
  __shared__ float xn[64][68];
  __shared__ float w16sh[1024];
  __shared__ float scsh[64], shsh[64];
  const int tid = threadIdx.x;
  if (tid < 64) { scsh[tid] = sc[tid]; shsh[tid] = sh[tid]; }
  for (int i2 = tid; i2 < 1024; i2 += 256) w16sh[i2] = w16[i2];
  __syncthreads();
  const int row0 = blockIdx.x * 64;
  for (int idx = tid; idx < 4096; idx += 256) {
    int r = idx >> 6, c = idx & 63;
    float v = in[(size_t)(row0 + r) * 64 + c];
    xn[r][c] = fmaxf(fmaf(v, scsh[c], shsh[c]), 0.f);
  }
  __syncthreads();

  const int lane = tid & 63;
  const int wave = tid >> 6;
  float wreg[64];
  #pragma unroll
  for (int k = 0; k < 64; ++k) wreg[k] = w[k * 64 + lane];
  const float bz = bias[lane];
  for (int r = wave * 16; r < wave * 16 + 16; ++r) {
    float acc = bz;
    #pragma unroll
    for (int k = 0; k < 64; k += 4) {
      float4 xv = *(const float4*)(&xn[r][k]);
      acc = fmaf(xv.x, wreg[k + 0], acc);
      acc = fmaf(xv.y, wreg[k + 1], acc);
      acc = fmaf(xv.z, wreg[k + 2], acc);
      acc = fmaf(xv.w, wreg[k + 3], acc);
    }
    outz[(size_t)(row0 + r) * 64 + lane] = bf16r(acc);
  }
  for (int idx = tid; idx < 1024; idx += 256) {
    int r = idx >> 4, t = idx & 15;
    float acc = 0.f;
    #pragma unroll
    for (int c = 0; c < 64; c += 4) {
      float4 xv = *(const float4*)(&xn[r][c]);
      acc = fmaf(xv.x, w16sh[(c + 0) * 16 + t], acc);
      acc = fmaf(xv.y, w16sh[(c + 1) * 16 + t], acc);
      acc = fmaf(xv.z, w16sh[(c + 2) * 16 + t], acc);
      acc = fmaf(xv.w, w16sh[(c + 3) * 16 + t], acc);
    }
    out16[(size_t)(row0 + r) * 16 + t] = acc;
  }
}

// ---------------- K1: lp partials, histogram + rank ----------------
__global__ __launch_bounds__(256) void k_prhist(
    const float* __restrict__ p, const int* __restrict__ knn,
    const float* __restrict__ lpw1, const float* __restrict__ lpb1,
    float* __restrict__ plp,
    int* __restrict__ cnt, int* __restrict__ rank)
{
  __shared__ float lpw1sh[9], lpb1sh[3];
  __shared__ float lpsh[4][8];
  const int tid = threadIdx.x;
  if (tid < 9) lpw1sh[tid] = lpw1[tid];
  if (tid < 3) lpb1sh[tid] = lpb1[tid];
  __syncthreads();

  const size_t g = (size_t)blockIdx.x * 256 + tid;
  const int i = (int)(g >> 4);
  const int j = knn[g];
  const float pr0 = p[j * 3 + 0] - p[i * 3 + 0];
  const float pr1 = p[j * 3 + 1] - p[i * 3 + 1];
  const float pr2 = p[j * 3 + 2] - p[i * 3 + 2];
  rank[g] = atomicAdd(&cnt[j], 1);

  float q0 = fmaf(pr2, lpw1sh[6], fmaf(pr1, lpw1sh[3], fmaf(pr0, lpw1sh[0], lpb1sh[0])));
  float q1 = fmaf(pr2, lpw1sh[7], fmaf(pr1, lpw1sh[4], fmaf(pr0, lpw1sh[1], lpb1sh[1])));
  float q2 = fmaf(pr2, lpw1sh[8], fmaf(pr1, lpw1sh[5], fmaf(pr0, lpw1sh[2], lpb1sh[2])));
  float s0 = q0, s1 = q1, s2 = q2, qq0 = q0 * q0, qq1 = q1 * q1, qq2 = q2 * q2;
  #pragma unroll
  for (int m = 1; m < 64; m <<= 1) {
    s0 += __shfl_xor(s0, m); s1 += __shfl_xor(s1, m); s2 += __shfl_xor(s2, m);
    qq0 += __shfl_xor(qq0, m); qq1 += __shfl_xor(qq1, m); qq2 += __shfl_xor(qq2, m);
  }
  if ((tid & 63) == 0) {
    const int w = tid >> 6;
    lpsh[w][0] = s0; lpsh[w][1] = s1; lpsh[w][2] = s2; lpsh[w][3] = 0.f;
    lpsh[w][4] = qq0; lpsh[w][5] = qq1; lpsh[w][6] = qq2; lpsh[w][7] = 0.f;
  }
  __syncthreads();
  if (tid < 8) {
    float v = lpsh[0][tid] + lpsh[1][tid] + lpsh[2][tid] + lpsh[3][tid];
    plp[(size_t)tid * gridDim.x + blockIdx.x] = v;
  }
}

// ---------------- block sums of cnt (1024 counts per block) ----------------
__global__ __launch_bounds__(256) void k_bsum(
    const int* __restrict__ cnt, int* __restrict__ bsums)
{
  const int tid = threadIdx.x;
  int4 c4 = ((const int4*)cnt)[blockIdx.x * 256 + tid];
  int s = c4.x + c4.y + c4.z + c4.w;
  #pragma unroll
  for (int m = 1; m < 64; m <<= 1) s += __shfl_xor(s, m);
  __shared__ int ws[4];
  if ((tid & 63) == 0) ws[tid >> 6] = s;
  __syncthreads();
  if (tid == 0) bsums[blockIdx.x] = ws[0] + ws[1] + ws[2] + ws[3];
}

// ---------------- mid: block-sum scan + lp finalize + weight folding (LDS-staged) ----------------
__global__ __launch_bounds__(256) void k_mid2(
    const int* __restrict__ bsums, int* __restrict__ blockoff,
    int* __restrict__ rowstart, int n,
    const float* __restrict__ plp, int nbplp,
    const float* __restrict__ lpg, const float* __restrict__ lpbt,
    const float* __restrict__ lpw1, const float* __restrict__ lpb1,
    const float* __restrict__ lpw2, const float* __restrict__ lpb2,
    const float* __restrict__ m1w2, const float* __restrict__ m2w1,
    const float* __restrict__ m1b2,
    float* __restrict__ cst, float inv_count)
{
  __shared__ float w2sh_[2048];   // m2w1 staged
  __shared__ float w1sh_[256];    // m1w2 staged
  __shared__ int bsh[64];
  __shared__ float Ssh[8];
  const int tid = threadIdx.x;
  const int nb1024 = n >> 10;
  if (tid < nb1024) bsh[tid] = bsums[tid];
  for (int i = tid; i < 2048; i += 256) w2sh_[i] = m2w1[i];
  w1sh_[tid] = m1w2[tid];
  // lp stats reduce
  {
    const int row = tid >> 5, l32 = tid & 31;
    float ls = 0.f;
    for (int i = l32; i < nbplp; i += 32) ls += plp[(size_t)row * nbplp + i];
    #pragma unroll
    for (int m = 1; m < 32; m <<= 1) ls += __shfl_xor(ls, m);
    if (l32 == 0) Ssh[row] = ls;
  }
  __syncthreads();
  if (tid == 0) {
    int run = 0;
    for (int i = 0; i < nb1024; ++i) { blockoff[i] = run; run += bsh[i]; }
    rowstart[n] = run;
  }
  if (tid < 3) {
    float m = Ssh[tid] * inv_count;
    float v = Ssh[4 + tid] * inv_count - m * m;
    float rs = rsqrtf(v + 1e-5f);
    float sc = lpg[tid] * rs;
    cst[S_LPSC + tid] = sc;
    cst[S_LPSH + tid] = fmaf(-m, sc, lpbt[tid]);
  }
  __syncthreads();
  if (tid < 9)  cst[S_QW + tid] = lpw1[tid] * cst[S_LPSC + (tid % 3)];
  if (tid < 3)  cst[S_QB + tid] = fmaf(lpb1[tid], cst[S_LPSC + tid], cst[S_LPSH + tid]);
  if (tid < 16) {
    float b = 0.f;
    for (int c2 = 0; c2 < 4; ++c2) b += lpb2[c2 * 16 + tid];
    cst[S_LPB2S + tid] = b;
    for (int r = 0; r < 3; ++r) {
      float w = 0.f;
      for (int c2 = 0; c2 < 4; ++c2) w += lpw2[r * 64 + c2 * 16 + tid];
      cst[S_LPW2S + r * 16 + tid] = w;
    }
  }
  __syncthreads();
  // G fold (from LDS)
  #pragma unroll
  for (int q = 0; q < 4; ++q) {
    int ee = tid * 4 + q;
    int c = ee >> 4, u = ee & 15;
    float sg = 0.f;
    #pragma unroll
    for (int t = 0; t < 16; ++t) sg = fmaf(w1sh_[u * 16 + t], w2sh_[t * 64 + c], sg);
    cst[S_G + c * 16 + u] = sg;
  }
  if (tid < 192) {
    int c = tid / 3, r = tid - c * 3;
    float sh = 0.f;
    #pragma unroll
    for (int t = 0; t < 16; ++t) sh = fmaf(cst[S_LPW2S + r * 16 + t], w2sh_[(16 + t) * 64 + c], sh);
    cst[S_HC + c * 4 + r] = sh;
  }
  if (tid < 64) {
    cst[S_HC + tid * 4 + 3] = 0.f;
    float sb = 0.f;
    #pragma unroll
    for (int t = 0; t < 16; ++t) {
      sb = fmaf(m1b2[t], w2sh_[t * 64 + tid], sb);
      sb = fmaf(cst[S_LPB2S + t], w2sh_[(16 + t) * 64 + tid], sb);
    }
    cst[S_HB + tid] = sb;
  }
}

// ---------------- final scan: per-block local scan + offset ----------------
__global__ __launch_bounds__(256) void k_scan3(
    const int* __restrict__ cnt, const int* __restrict__ blockoff,
    int* __restrict__ rowstart)
{
  const int tid = threadIdx.x;
  const int b = blockIdx.x;
  int4 c4 = ((const int4*)cnt)[b * 256 + tid];
  int tsum = c4.x + c4.y + c4.z + c4.w;
  const int lane = tid & 63, w = tid >> 6;
  int inc = tsum;
  #pragma unroll
  for (int d = 1; d < 64; d <<= 1) {
    int v = __shfl_up(inc, d);
    if (lane >= d) inc += v;
  }
  __shared__ int wsum[4];
  if (lane == 63) wsum[w] = inc;
  __syncthreads();
  int woff = 0;
  for (int u = 0; u < w; ++u) woff += wsum[u];
  int g0 = blockoff[b] + woff + inc - tsum;
  const int base = b * 1024 + tid * 4;
  int4 o;
  o.x = g0;
  o.y = g0 + c4.x;
  o.z = g0 + c4.x + c4.y;
  o.w = g0 + c4.x + c4.y + c4.z;
  *(int4*)(rowstart + base) = o;
}

// ---------------- K2: u-moment accumulation + uq/uqn/pos store ----------------
__global__ __launch_bounds__(256) void k_moment(
    const float* __restrict__ y16, const float* __restrict__ p,
    const int* __restrict__ knn, const float* __restrict__ m1w1,
    const float* __restrict__ m1b1, const float* __restrict__ cst,
    const int* __restrict__ rowstart, const int* __restrict__ rank,
    float* __restrict__ pmom,   // [210 * gridDim.x] channel-major
    unsigned* __restrict__ uq,  // [nk * 8] packed fp16 t1[16]
    unsigned* __restrict__ uqn, // [nk * 2] packed fp16 qn[3]
    int* __restrict__ posbuf)   // [nk]
{
  __shared__ float ush[256 * 21];
  const int tid = threadIdx.x;
  const size_t g = (size_t)blockIdx.x * 256 + tid;
  const int i = (int)(g >> 4);
  const int j = knn[g];
  const float pr0 = p[j * 3 + 0] - p[i * 3 + 0];
  const float pr1 = p[j * 3 + 1] - p[i * 3 + 1];
  const float pr2 = p[j * 3 + 2] - p[i * 3 + 2];
  const float* yj = y16 + (size_t)j * 16;
  float4 ya = *(const float4*)(yj);
  float4 yb = *(const float4*)(yj + 4);
  float4 yc = *(const float4*)(yj + 8);
  float4 yd = *(const float4*)(yj + 12);
  float t1[16] = {ya.x, ya.y, ya.z, ya.w, yb.x, yb.y, yb.z, yb.w,
                  yc.x, yc.y, yc.z, yc.w, yd.x, yd.y, yd.z, yd.w};
  #pragma unroll
  for (int u = 0; u < 16; ++u)
    t1[u] = fmaxf(fmaf(pr2, m1w1[32 + u], fmaf(pr1, m1w1[16 + u],
                  fmaf(pr0, m1w1[u], t1[u] + m1b1[u]))), 0.f);
  const float qn0 = fmaxf(fmaf(pr2, cst[S_QW + 6], fmaf(pr1, cst[S_QW + 3], fmaf(pr0, cst[S_QW + 0], cst[S_QB + 0]))), 0.f);
  const float qn1 = fmaxf(fmaf(pr2, cst[S_QW + 7], fmaf(pr1, cst[S_QW + 4], fmaf(pr0, cst[S_QW + 1], cst[S_QB + 1]))), 0.f);
  const float qn2 = fmaxf(fmaf(pr2, cst[S_QW + 8], fmaf(pr1, cst[S_QW + 5], fmaf(pr0, cst[S_QW + 2], cst[S_QB + 2]))), 0.f);

  posbuf[g] = rowstart[j] + rank[g];

  uint4 ua, ub;
  ua.x = packh2(t1[0], t1[1]);   ua.y = packh2(t1[2], t1[3]);
  ua.z = packh2(t1[4], t1[5]);   ua.w = packh2(t1[6], t1[7]);
  ub.x = packh2(t1[8], t1[9]);   ub.y = packh2(t1[10], t1[11]);
  ub.z = packh2(t1[12], t1[13]); ub.w = packh2(t1[14], t1[15]);
  *(uint4*)(uq + g * 8)     = ua;
  *(uint4*)(uq + g * 8 + 4) = ub;
  uint2 uc;
  uc.x = packh2(qn0, qn1);
  uc.y = packh2(qn2, 0.f);
  *(uint2*)(uqn + g * 2) = uc;

  float* ur = ush + tid * 21;
  #pragma unroll
  for (int u = 0; u < 16; ++u) ur[u] = t1[u];
  ur[16] = qn0; ur[17] = qn1; ur[18] = qn2; ur[19] = 1.f;
  __syncthreads();

  if (tid < 210) {
    int a = 0, t = tid;
    while (t >= 20 - a) { t -= 20 - a; ++a; }
    const int b = a + t;
    float s = 0.f;
    for (int r = 0; r < 256; ++r) {
      const float* u = ush + r * 21;
      s = fmaf(u[a], u[b], s);
    }
    pmom[(size_t)tid * gridDim.x + blockIdx.x] = s;
  }
}

// ---------------- parallel moment reduce ----------------
__global__ __launch_bounds__(256) void k_mred(
    const float* __restrict__ pmom, float* __restrict__ S2, int nb)
{
  const int c = blockIdx.x;
  const int tid = threadIdx.x;
  float s = 0.f;
  for (int i = tid; i < nb; i += 256) s += pmom[(size_t)c * nb + i];
  #pragma unroll
  for (int m = 1; m < 64; m <<= 1) s += __shfl_xor(s, m);
  __shared__ float ws[4];
  if ((tid & 63) == 0) ws[tid >> 6] = s;
  __syncthreads();
  if (tid == 0) S2[c] = ws[0] + ws[1] + ws[2] + ws[3];
}

// ---------------- moment finalize ----------------
__global__ __launch_bounds__(64) void k_mfin(
    const float* __restrict__ S2in,
    const float* __restrict__ g, const float* __restrict__ b,
    float* __restrict__ cst, float inv_count)
{
  __shared__ float S2[210];
  const int tid = threadIdx.x;
  for (int i = tid; i < 210; i += 64) S2[i] = S2in[i];
  __syncthreads();
  const int c = tid;
  float w[20];
  #pragma unroll
  for (int u = 0; u < 16; ++u) w[u] = cst[S_G + c * 16 + u];
  w[16] = cst[S_HC + c * 4 + 0];
  w[17] = cst[S_HC + c * 4 + 1];
  w[18] = cst[S_HC + c * 4 + 2];
  w[19] = cst[S_HB + c];
  float m2 = 0.f, m1 = 0.f;
  for (int a = 0; a < 20; ++a) {
    const float wa = w[a];
    m2 = fmaf(wa * wa, S2[pidx(a, a)], m2);
    float cross = 0.f;
    for (int bb = a + 1; bb < 20; ++bb) cross = fmaf(w[bb], S2[pidx(a, bb)], cross);
    m2 = fmaf(2.f * wa, cross, m2);
    m1 = fmaf(wa, S2[pidx(a, 19)], m1);
  }
  const float mean = m1 * inv_count;
  const float var = m2 * inv_count - mean * mean;
  const float rs = rsqrtf(var + 1e-5f);
  const float sc = g[c] * rs;
  cst[S_M2S1 + c] = sc;
  cst[S_M2H1 + c] = fmaf(-mean, sc, b[c]);
}

// ---------------- K3: h2(bf16) from packed uq/uqn via folded G/H ----------------
__global__ __launch_bounds__(256) void k_h2(
    const unsigned* __restrict__ uq, const unsigned* __restrict__ uqn,
    const float* __restrict__ cst, const float* __restrict__ m2w2,
    unsigned short* __restrict__ h2out,
    float* __restrict__ partial)   // [16 * gridDim.x]
{
  __shared__ float Gsh[1024], Hsh[256], hbsh[64];
  __shared__ float w2m[512];
  __shared__ float scsh[64], shsh[64];
  __shared__ float redsh[4][16];
  const int tid = threadIdx.x;
  for (int i = tid; i < 1024; i += 256) Gsh[i] = cst[S_G + i];
  Hsh[tid] = cst[S_HC + tid];
  for (int i = tid; i < 512; i += 256) w2m[i] = m2w2[i];
  if (tid < 64) { hbsh[tid] = cst[S_HB + tid]; scsh[tid] = cst[S_M2S1 + tid]; shsh[tid] = cst[S_M2H1 + tid]; }
  __syncthreads();

  const size_t g0 = ((size_t)blockIdx.x * 256 + tid) * 2;
  float t1[2][16], qn[2][3];
  #pragma unroll
  for (int gg = 0; gg < 2; ++gg) {
    const size_t g = g0 + gg;
    uint4 ua = *(const uint4*)(uq + g * 8);
    uint4 ub = *(const uint4*)(uq + g * 8 + 4);
    uint2 uc = *(const uint2*)(uqn + g * 2);
    t1[gg][0] = lo16(ua.x);  t1[gg][1] = hi16(ua.x);
    t1[gg][2] = lo16(ua.y);  t1[gg][3] = hi16(ua.y);
    t1[gg][4] = lo16(ua.z);  t1[gg][5] = hi16(ua.z);
    t1[gg][6] = lo16(ua.w);  t1[gg][7] = hi16(ua.w);
    t1[gg][8] = lo16(ub.x);  t1[gg][9] = hi16(ub.x);
    t1[gg][10] = lo16(ub.y); t1[gg][11] = hi16(ub.y);
    t1[gg][12] = lo16(ub.z); t1[gg][13] = hi16(ub.z);
    t1[gg][14] = lo16(ub.w); t1[gg][15] = hi16(ub.w);
    qn[gg][0] = lo16(uc.x); qn[gg][1] = hi16(uc.x); qn[gg][2] = lo16(uc.y);
  }

  float a0[8], a1[8];
  #pragma unroll
  for (int t = 0; t < 8; ++t) { a0[t] = 0.f; a1[t] = 0.f; }
  for (int c = 0; c < 64; ++c) {
    float4 g0v = *(const float4*)(Gsh + c * 16);
    float4 g1v = *(const float4*)(Gsh + c * 16 + 4);
    float4 g2v = *(const float4*)(Gsh + c * 16 + 8);
    float4 g3v = *(const float4*)(Gsh + c * 16 + 12);
    float4 hv = *(const float4*)(Hsh + c * 4);
    float h_0 = hbsh[c], h_1 = hbsh[c];
    h_0 = fmaf(t1[0][0], g0v.x, h_0); h_0 = fmaf(t1[0][1], g0v.y, h_0); h_0 = fmaf(t1[0][2], g0v.z, h_0); h_0 = fmaf(t1[0][3], g0v.w, h_0);
    h_0 = fmaf(t1[0][4], g1v.x, h_0); h_0 = fmaf(t1[0][5], g1v.y, h_0); h_0 = fmaf(t1[0][6], g1v.z, h_0); h_0 = fmaf(t1[0][7], g1v.w, h_0);
    h_0 = fmaf(t1[0][8], g2v.x, h_0); h_0 = fmaf(t1[0][9], g2v.y, h_0); h_0 = fmaf(t1[0][10], g2v.z, h_0); h_0 = fmaf(t1[0][11], g2v.w, h_0);
    h_0 = fmaf(t1[0][12], g3v.x, h_0); h_0 = fmaf(t1[0][13], g3v.y, h_0); h_0 = fmaf(t1[0][14], g3v.z, h_0); h_0 = fmaf(t1[0][15], g3v.w, h_0);
    h_0 = fmaf(qn[0][0], hv.x, fmaf(qn[0][1], hv.y, fmaf(qn[0][2], hv.z, h_0)));
    h_1 = fmaf(t1[1][0], g0v.x, h_1); h_1 = fmaf(t1[1][1], g0v.y, h_1); h_1 = fmaf(t1[1][2], g0v.z, h_1); h_1 = fmaf(t1[1][3], g0v.w, h_1);
    h_1 = fmaf(t1[1][4], g1v.x, h_1); h_1 = fmaf(t1[1][5], g1v.y, h_1); h_1 = fmaf(t1[1][6], g1v.z, h_1); h_1 = fmaf(t1[1][7], g1v.w, h_1);
    h_1 = fmaf(t1[1][8], g2v.x, h_1); h_1 = fmaf(t1[1][9], g2v.y, h_1); h_1 = fmaf(t1[1][10], g2v.z, h_1); h_1 = fmaf(t1[1][11], g2v.w, h_1);
    h_1 = fmaf(t1[1][12], g3v.x, h_1); h_1 = fmaf(t1[1][13], g3v.y, h_1); h_1 = fmaf(t1[1][14], g3v.z, h_1); h_1 = fmaf(t1[1][15], g3v.w, h_1);
    h_1 = fmaf(qn[1][0], hv.x, fmaf(qn[1][1], hv.y, fmaf(qn[1][2], hv.z, h_1)));
    float x0 = fmaxf(fmaf(h_0, scsh[c], shsh[c]), 0.f);
    float x1 = fmaxf(fmaf(h_1, scsh[c], shsh[c]), 0.f);
    float4 wa = *(const float4*)(w2m + c * 8);
    float4 wb = *(const float4*)(w2m + c * 8 + 4);
    a0[0] = fmaf(x0, wa.x, a0[0]); a0[1] = fmaf(x0, wa.y, a0[1]); a0[2] = fmaf(x0, wa.z, a0[2]); a0[3] = fmaf(x0, wa.w, a0[3]);
    a0[4] = fmaf(x0, wb.x, a0[4]); a0[5] = fmaf(x0, wb.y, a0[5]); a0[6] = fmaf(x0, wb.z, a0[6]); a0[7] = fmaf(x0, wb.w, a0[7]);
    a1[0] = fmaf(x1, wa.x, a1[0]); a1[1] = fmaf(x1, wa.y, a1[1]); a1[2] = fmaf(x1, wa.z, a1[2]); a1[3] = fmaf(x1, wa.w, a1[3]);
    a1[4] = fmaf(x1, wb.x, a1[4]); a1[5] = fmaf(x1, wb.y, a1[5]); a1[6] = fmaf(x1, wb.z, a1[6]); a1[7] = fmaf(x1, wb.w, a1[7]);
  }
  uint4 pa, pb;
  pa.x = bf16r(a0[0]) | ((unsigned)bf16r(a0[1]) << 16);
  pa.y = bf16r(a0[2]) | ((unsigned)bf16r(a0[3]) << 16);
  pa.z = bf16r(a0[4]) | ((unsigned)bf16r(a0[5]) << 16);
  pa.w = bf16r(a0[6]) | ((unsigned)bf16r(a0[7]) << 16);
  pb.x = bf16r(a1[0]) | ((unsigned)bf16r(a1[1]) << 16);
  pb.y = bf16r(a1[2]) | ((unsigned)bf16r(a1[3]) << 16);
  pb.z = bf16r(a1[4]) | ((unsigned)bf16r(a1[5]) << 16);
  pb.w = bf16r(a1[6]) | ((unsigned)bf16r(a1[7]) << 16);
  *(uint4*)(h2out + g0 * 8) = pa;
  *(uint4*)(h2out + g0 * 8 + 8) = pb;

  float st[8], sq[8];
  #pragma unroll
  for (int t = 0; t < 8; ++t) {
    st[t] = a0[t] + a1[t];
    sq[t] = fmaf(a0[t], a0[t], a1[t] * a1[t]);
  }
  #pragma unroll
  for (int m = 1; m < 64; m <<= 1) {
    #pragma unroll
    for (int t = 0; t < 8; ++t) { st[t] += __shfl_xor(st[t], m); sq[t] += __shfl_xor(sq[t], m); }
  }
  if ((tid & 63) == 0) {
    const int w = tid >> 6;
    #pragma unroll
    for (int t = 0; t < 8; ++t) { redsh[w][t] = st[t]; redsh[w][8 + t] = sq[t]; }
  }
  __syncthreads();
  if (tid < 16) {
    float v = redsh[0][tid] + redsh[1][tid] + redsh[2][tid] + redsh[3][tid];
    partial[(size_t)tid * gridDim.x + blockIdx.x] = v;
  }
}

// ---------------- K4: fused softmax + xk + x_intra (LDS reduce) + exv(fp16) ----------------
__global__ __launch_bounds__(256) void k_intra(
    const unsigned short* __restrict__ zb, const unsigned* __restrict__ uqn,
    const int* __restrict__ knn, const float* __restrict__ cst,
    const float* __restrict__ lpw2, const float* __restrict__ lpb2,
    const float* __restrict__ iw, const float* __restrict__ ib,
    const float* __restrict__ ixw, const float* __restrict__ ixb,
    const unsigned short* __restrict__ h2b, const float* __restrict__ m2w3,
    const float* __restrict__ m2b3,
    const int* __restrict__ posbuf,
    float* __restrict__ x_intra, unsigned* __restrict__ exv)
{
  __shared__ uint2 xksh[256][17];   // 64 fp16 per row (16 quads), padded row = 34 dwords
  __shared__ float lpw2sh[192], lpb2sh[64];
  __shared__ h2 iwsh2[256], ixwsh2[256];   // packed fp16 pairs of output channels
  __shared__ float ibsh[8], ixbsh[8];
  __shared__ float w3sh[64], b3sh[8], s2sh[8], h2ssh[8];
  const int tid = threadIdx.x;
  if (tid < 192) lpw2sh[tid] = lpw2[tid];
  if (tid < 64) { lpb2sh[tid] = lpb2[tid]; w3sh[tid] = m2w3[tid]; }
  iwsh2[tid]  = mkh2(iw[2 * tid], iw[2 * tid + 1]);
  ixwsh2[tid] = mkh2(ixw[2 * tid], ixw[2 * tid + 1]);
  if (tid < 8) {
    ibsh[tid] = ib[tid]; ixbsh[tid] = ixb[tid];
    b3sh[tid] = m2b3[tid]; s2sh[tid] = cst[S_M2S2 + tid]; h2ssh[tid] = cst[S_M2H2 + tid];
  }
  __syncthreads();

  const size_t g = (size_t)blockIdx.x * 256 + tid;
  const int j = knn[g];
  const unsigned* zr = (const unsigned*)(zb + (size_t)j * 64);
  const int pos = posbuf[g];

  uint2 uc = *(const uint2*)(uqn + g * 2);
  const float qn0 = lo16(uc.x), qn1 = hi16(uc.x), qn2 = lo16(uc.y);

  // fused k-softmax from bf16 h2
  uint4 hu = *(const uint4*)(h2b + g * 8);
  float hn[8];
  hn[0] = fmaxf(fmaf(__uint_as_float(hu.x << 16),        s2sh[0], h2ssh[0]), 0.f);
  hn[1] = fmaxf(fmaf(__uint_as_float(hu.x & 0xffff0000u), s2sh[1], h2ssh[1]), 0.f);
  hn[2] = fmaxf(fmaf(__uint_as_float(hu.y << 16),        s2sh[2], h2ssh[2]), 0.f);
  hn[3] = fmaxf(fmaf(__uint_as_float(hu.y & 0xffff0000u), s2sh[3], h2ssh[3]), 0.f);
  hn[4] = fmaxf(fmaf(__uint_as_float(hu.z << 16),        s2sh[4], h2ssh[4]), 0.f);
  hn[5] = fmaxf(fmaf(__uint_as_float(hu.z & 0xffff0000u), s2sh[5], h2ssh[5]), 0.f);
  hn[6] = fmaxf(fmaf(__uint_as_float(hu.w << 16),        s2sh[6], h2ssh[6]), 0.f);
  hn[7] = fmaxf(fmaf(__uint_as_float(hu.w & 0xffff0000u), s2sh[7], h2ssh[7]), 0.f);
  float wk[8];
  #pragma unroll
  for (int t = 0; t < 8; ++t) {
    float a = b3sh[t];
    #pragma unroll
    for (int u = 0; u < 8; ++u) a = fmaf(hn[u], w3sh[u * 8 + t], a);
    wk[t] = a;
  }
  #pragma unroll
  for (int t = 0; t < 8; ++t) {
    float m = wk[t];
    m = fmaxf(m, __shfl_xor(m, 1));
    m = fmaxf(m, __shfl_xor(m, 2));
    m = fmaxf(m, __shfl_xor(m, 4));
    m = fmaxf(m, __shfl_xor(m, 8));
    float ex = __expf(wk[t] - m);
    float s = ex;
    s += __shfl_xor(s, 1);
    s += __shfl_xor(s, 2);
    s += __shfl_xor(s, 4);
    s += __shfl_xor(s, 8);
    wk[t] = ex / s;
  }

  h2 sacc2[4], vacc2[4];
  sacc2[0] = mkh2(ibsh[0], ibsh[1]); sacc2[1] = mkh2(ibsh[2], ibsh[3]);
  sacc2[2] = mkh2(ibsh[4], ibsh[5]); sacc2[3] = mkh2(ibsh[6], ibsh[7]);
  vacc2[0] = mkh2(ixbsh[0], ixbsh[1]); vacc2[1] = mkh2(ixbsh[2], ixbsh[3]);
  vacc2[2] = mkh2(ixbsh[4], ixbsh[5]); vacc2[3] = mkh2(ixbsh[6], ixbsh[7]);
  uint4 zq;
  #pragma unroll
  for (int c = 0; c < 64; c += 4) {
    if ((c & 7) == 0) zq = *(const uint4*)(zr + (c >> 1));
    const unsigned u0 = ((c & 7) == 0) ? zq.x : zq.z;
    const unsigned u1 = ((c & 7) == 0) ? zq.y : zq.w;
    const float z0 = __uint_as_float(u0 << 16);
    const float z1 = __uint_as_float(u0 & 0xffff0000u);
    const float z2 = __uint_as_float(u1 << 16);
    const float z3 = __uint_as_float(u1 & 0xffff0000u);
    float4 l0 = *(const float4*)(lpw2sh + c);
    float4 l1 = *(const float4*)(lpw2sh + 64 + c);
    float4 l2 = *(const float4*)(lpw2sh + 128 + c);
    float4 lb = *(const float4*)(lpb2sh + c);
    float xkv[4];
    xkv[0] = (z0 + fmaf(qn2, l2.x, fmaf(qn1, l1.x, fmaf(qn0, l0.x, lb.x)))) * wk[(c + 0) & 7];
    xkv[1] = (z1 + fmaf(qn2, l2.y, fmaf(qn1, l1.y, fmaf(qn0, l0.y, lb.y)))) * wk[(c + 1) & 7];
    xkv[2] = (z2 + fmaf(qn2, l2.z, fmaf(qn1, l1.z, fmaf(qn0, l0.z, lb.z)))) * wk[(c + 2) & 7];
    xkv[3] = (z3 + fmaf(qn2, l2.w, fmaf(qn1, l1.w, fmaf(qn0, l0.w, lb.w)))) * wk[(c + 3) & 7];
    xksh[tid][c >> 2] = make_uint2(packh2(xkv[0], xkv[1]), packh2(xkv[2], xkv[3]));
    #pragma unroll
    for (int d = 0; d < 4; ++d) {
      const _Float16 xh = (_Float16)xkv[d];
      h2 x2; x2[0] = xh; x2[1] = xh;
      const int cc = (c + d) * 4;
      #pragma unroll
      for (int q = 0; q < 4; ++q) {
        sacc2[q] = __builtin_elementwise_fma(x2, iwsh2[cc + q], sacc2[q]);
        vacc2[q] = __builtin_elementwise_fma(x2, ixwsh2[cc + q], vacc2[q]);
      }
    }
  }
  float sacc[8], vacc[8];
  #pragma unroll
  for (int q = 0; q < 4; ++q) {
    sacc[2 * q] = (float)sacc2[q][0]; sacc[2 * q + 1] = (float)sacc2[q][1];
    vacc[2 * q] = (float)vacc2[q][0]; vacc[2 * q + 1] = (float)vacc2[q][1];
  }
  float ex[8];
  #pragma unroll
  for (int t = 0; t < 8; ++t) ex[t] = __expf(sacc[t]);
  uint4 ea, eb;
  ea.x = packh2(ex[0], ex[1]); ea.y = packh2(ex[2], ex[3]);
  ea.z = packh2(ex[4], ex[5]); ea.w = packh2(ex[6], ex[7]);
  eb.x = packh2(ex[0] * vacc[0], ex[1] * vacc[1]);
  eb.y = packh2(ex[2] * vacc[2], ex[3] * vacc[3]);
  eb.z = packh2(ex[4] * vacc[4], ex[5] * vacc[5]);
  eb.w = packh2(ex[6] * vacc[6], ex[7] * vacc[7]);
  *(uint4*)(exv + (size_t)pos * 8) = ea;
  *(uint4*)(exv + (size_t)pos * 8 + 4) = eb;

  // x_intra: LDS-staged reduce over the 16 edges of each node
  __syncthreads();
  const int base = tid & ~15;
  const int own = tid & 15;
  float o0 = 0.f, o1 = 0.f, o2 = 0.f, o3 = 0.f;
  #pragma unroll
  for (int k = 0; k < 16; ++k) {
    uint2 v = xksh[base + k][own];
    o0 += lo16(v.x); o1 += hi16(v.x);
    o2 += lo16(v.y); o3 += hi16(v.y);
  }
  const size_t i = g >> 4;
  *(float4*)(x_intra + i * 64 + own * 4) = make_float4(o0, o1, o2, o3);
}

// ---------------- K5: streaming segment reduce (fp16) + x2 + bn2 partials ----------------
__global__ __launch_bounds__(256) void k_inter_x2(
    const int* __restrict__ rowstart, const unsigned* __restrict__ exv,
    float* __restrict__ xi, float* __restrict__ partial)
{
  __shared__ float bsum[64], bsq[64];
  const int tid = threadIdx.x;
  if (tid < 64) { bsum[tid] = 0.f; bsq[tid] = 0.f; }
  __syncthreads();
  const int t = tid & 15;
  const int j = blockIdx.x * 16 + (tid >> 4);
  const int s0 = rowstart[j];
  const int e0 = rowstart[j + 1];
  const unsigned short* eh = (const unsigned short*)exv;
  float acc = 0.f;
  for (int e = s0; e < e0; ++e) acc += h2f(eh[(size_t)e * 16 + t]);
  const float other = __shfl_xor(acc, 8);
  float r = (t < 8) ? ((acc > 0.f) ? other / acc : 0.f)
                    : ((other > 0.f) ? acc / other : 0.f);
  float4 xv = *(const float4*)(xi + (size_t)j * 64 + t * 4);
  float v0 = xv.x + __shfl(r, (4 * t + 0) & 7, 16);
  float v1 = xv.y + __shfl(r, (4 * t + 1) & 7, 16);
  float v2 = xv.z + __shfl(r, (4 * t + 2) & 7, 16);
  float v3 = xv.w + __shfl(r, (4 * t + 3) & 7, 16);
  *(float4*)(xi + (size_t)j * 64 + t * 4) = make_float4(v0, v1, v2, v3);
  float s_[4] = {v0, v1, v2, v3};
  float q_[4] = {v0 * v0, v1 * v1, v2 * v2, v3 * v3};
  #pragma unroll
  for (int d = 0; d < 4; ++d) {
    s_[d] += __shfl_xor(s_[d], 16); s_[d] += __shfl_xor(s_[d], 32);
    q_[d] += __shfl_xor(q_[d], 16); q_[d] += __shfl_xor(q_[d], 32);
  }
  if ((tid & 63) < 16) {
    #pragma unroll
    for (int d = 0; d < 4; ++d) {
      atomicAdd(&bsum[4 * t + d], s_[d]);
      atomicAdd(&bsq[4 * t + d], q_[d]);
    }
  }
  __syncthreads();
  if (tid < 64) {
    partial[(size_t)tid * gridDim.x + blockIdx.x] = bsum[tid];
    partial[(size_t)(tid + 64) * gridDim.x + blockIdx.x] = bsq[tid];
  }
}

// ---------------- K6: final bn3 + residual + relu ----------------
__global__ __launch_bounds__(256) void k_out(
    const float* __restrict__ y3, const float* __restrict__ x0,
    const float* __restrict__ cst, float* __restrict__ out)
{
  __shared__ float scsh[64], shsh[64];
  const int tid = threadIdx.x;
  if (tid < 64) { scsh[tid] = cst[S_SC3 + tid]; shsh[tid] = cst[S_SH3 + tid]; }
  __syncthreads();
  const size_t i = ((size_t)blockIdx.x * 256 + tid) * 4;
  float4 y = *(const float4*)(y3 + i);
  float4 x = *(const float4*)(x0 + i);
  const int c = (int)(i & 63);
  float4 o;
  o.x = fmaxf(fmaf(y.x, scsh[c + 0], shsh[c + 0]) + x.x, 0.f);
  o.y = fmaxf(fmaf(y.y, scsh[c + 1], shsh[c + 1]) + x.y, 0.f);
  o.z = fmaxf(fmaf(y.z, scsh[c + 2], shsh[c + 2]) + x.z, 0.f);
  o.w = fmaxf(fmaf(y.w, scsh[c + 3], shsh[c + 3]) + x.w, 0.f);
  *(float4*)(out + i) = o;
}

// ---------------- launch ----------------
extern "C" void kernel_launch(void* const* d_in, const int* in_sizes, int n_in,
                              void* d_out, int out_size, void* d_ws, size_t ws_size,
                              hipStream_t stream)
{
  (void)n_in; (void)out_size; (void)ws_size;
  const float* p    = (const float*)d_in[0];
  const float* x    = (const float*)d_in[1];
  const int*   knn  = (const int*)d_in[2];
  const float* w1   = (const float*)d_in[3];
  const float* g1   = (const float*)d_in[4];
  const float* b1   = (const float*)d_in[5];
  const float* m1w1 = (const float*)d_in[6];
  const float* m1b1 = (const float*)d_in[7];
  const float* m1w2 = (const float*)d_in[8];
  const float* m1b2 = (const float*)d_in[9];
  const float* lpw1 = (const float*)d_in[10];
  const float* lpb1 = (const float*)d_in[11];
  const float* lpg  = (const float*)d_in[12];
  const float* lpbt = (const float*)d_in[13];
  const float* lpw2 = (const float*)d_in[14];
  const float* lpb2 = (const float*)d_in[15];
  const float* m2w1 = (const float*)d_in[16];
  const float* m2g1 = (const float*)d_in[17];
  const float* m2bt1= (const float*)d_in[18];
  const float* m2w2 = (const float*)d_in[19];
  const float* m2g2 = (const float*)d_in[20];
  const float* m2bt2= (const float*)d_in[21];
  const float* m2w3 = (const float*)d_in[22];
  const float* m2b3 = (const float*)d_in[23];
  const float* m3w  = (const float*)d_in[24];
  const float* m3b  = (const float*)d_in[25];
  const float* iw   = (const float*)d_in[26];
  const float* ib   = (const float*)d_in[27];
  const float* ixw  = (const float*)d_in[28];
  const float* ixb  = (const float*)d_in[29];
  const float* g2   = (const float*)d_in[30];
  const float* b2   = (const float*)d_in[31];
  const float* w3   = (const float*)d_in[32];
  const float* g3   = (const float*)d_in[33];
  const float* b3   = (const float*)d_in[34];
  float* out = (float*)d_out;
  float* ws  = (float*)d_ws;

  const int n = in_sizes[1] / 64;                // 32768
  const long long nk = (long long)n * 16;        // 524288
  const int nb1024 = n >> 10;                    // 32

  float* cst  = ws;
  int* cnt      = (int*)(ws + CONST_FLOATS);    // n ints (zeroed by k_zero)
  int* rowstart = cnt + n;                      // n+1 ints (+pad)
  int* rank     = rowstart + n + 16;            // nk ints
  int* posb     = rank + nk;                    // nk ints
  int* bsums    = posb + nk;                    // nb1024 ints
  int* blockoff = bsums + 64;                   // nb1024 ints
  unsigned short* zb = (unsigned short*)(blockoff + 64);  // 64n bf16
  float* y1 = (float*)(zb + 64LL * n);          // 64n, reused as y3
  float* xi = y1 + 64LL * n;                    // 64n
  float* y16 = xi + 64LL * n;                   // 16n
  unsigned short* h2b = (unsigned short*)(y16 + 16LL * n);  // 128n ushorts
  unsigned* exv = (unsigned*)(h2b + 128LL * n); // 128n uints

  const int gB2  = n / 16;            // 2048 (gemm64 grid)
  const int gB   = n / 64;            // 512 (gemmzy grid)
  const int nkB  = (int)(nk / 256);   // 2048
  const int nkB2 = (int)(nk / 512);   // 1024
  const int jB   = n / 16;            // 2048

  float* pbn1  = (float*)(exv + 128LL * n);      // 128 * gB2
  float* plp   = pbn1 + 128LL * gB2;             // 8 * nkB
  float* pmom  = plp + 8LL * nkB;                // 210 * nkB
  float* s2buf = pmom + 210LL * nkB;             // 256
  float* pm2b2 = s2buf + 256;                    // 16 * nkB2
  float* pbn2  = pm2b2 + 16LL * nkB2;            // 128 * jB
  float* pbn3  = pbn2 + 128LL * jB;              // 128 * gB2
  unsigned* uq = (unsigned*)(pbn3 + 128LL * gB2); // 8 * nk uints
  unsigned* uqn = uq + 8LL * nk;                 // 2 * nk uints

  // zero histogram counts with a parallel kernel (runtime fill was 42 us)
  k_zero<<<n / 1024, 256, 0, stream>>>(cnt);

  k_prhist<<<nkB, 256, 0, stream>>>(p, knn, lpw1, lpb1, plp, cnt, rank);
  k_gemm64<<<gB2, 256, 0, stream>>>(x, w1, nullptr, nullptr, nullptr, y1, pbn1, n);
  k_bsum<<<nb1024, 256, 0, stream>>>(cnt, bsums);
  k_mid2<<<1, 256, 0, stream>>>(bsums, blockoff, rowstart, n, plp, nkB,
                                lpg, lpbt, lpw1, lpb1, lpw2, lpb2,
                                m1w2, m2w1, m1b2, cst, 1.f / (float)nk);
  k_rbn<<<64, 256, 0, stream>>>(pbn1, gB2, 64, g1, b1, cst + S_SC1, cst + S_SH1, 1.f / (float)n);
  k_scan3<<<nb1024, 256, 0, stream>>>(cnt, blockoff, rowstart);
  // z(bf16) + y16 in one pass
  k_gemmzy<<<gB, 256, 0, stream>>>(y1, m3w, m3b, m1w1 + 48, cst + S_SC1, cst + S_SH1, zb, y16);
  // h1 BN stats via u-moments; also emits uq/uqn/pos
  k_moment<<<nkB, 256, 0, stream>>>(y16, p, knn, m1w1, m1b1, cst, rowstart, rank,
                                    pmom, uq, uqn, posb);
  k_mred<<<210, 256, 0, stream>>>(pmom, s2buf, nkB);
  k_mfin<<<1, 64, 0, stream>>>(s2buf, m2g1, m2bt1, cst, 1.f / (float)nk);
  // h2 (bf16) from uq/uqn + stats
  k_h2<<<nkB2, 256, 0, stream>>>(uq, uqn, cst, m2w2, h2b, pm2b2);
  k_rbn<<<8, 256, 0, stream>>>(pm2b2, nkB2, 8, m2g2, m2bt2, cst + S_M2S2, cst + S_M2H2, 1.f / (float)nk);
  // fused softmax + xk + x_intra + exv
  k_intra<<<nkB, 256, 0, stream>>>(zb, uqn, knn, cst, lpw2, lpb2, iw, ib, ixw, ixb,
                                   h2b, m2w3, m2b3, posb, xi, exv);
  // streaming segment reduce + x2 + bn2 partials
  k_inter_x2<<<jB, 256, 0, stream>>>(rowstart, exv, xi, pbn2);
  k_rbn<<<64, 256, 0, stream>>>(pbn2, jB, 64, g2, b2, cst + S_SC2, cst + S_SH2, 1.f / (float)n);
  // y3 = relu(bn2(x2)) @ w3, bn3
  k_gemm64<<<gB2, 256, 0, stream>>>(xi, w3, nullptr, cst + S_SC2, cst + S_SH2, y1, pbn3, n);
  k_rbn<<<64, 256, 0, stream>>>(pbn3, gB2, 64, g3, b3, cst + S_SC3, cst + S_SH3, 1.f / (float)n);
  // out = relu(bn3(y3) + x)
  k_out<<<(int)((long long)n * 64 / 1024), 256, 0, stream>>>(y1, x, cst, out);
}

// Round 18
// 256.667 us; speedup vs baseline: 1.7520x; 1.0144x over previous
//
#include <hip/hip_runtime.h>

// N = 32768 (runtime), C = 64, K = 16, CS = 8, SHARE = 8

enum {
  S_SC1 = 0,    S_SH1 = 64,
  S_LPSC = 128, S_LPSH = 132,
  S_M2S1 = 136, S_M2H1 = 200,
  S_M2S2 = 264, S_M2H2 = 272,
  S_SC2 = 280,  S_SH2 = 344,
  S_SC3 = 408,  S_SH3 = 472,
  S_LPW2S = 536, S_LPB2S = 584,
  S_QW = 600, S_QB = 612,
  S_G = 640,        // 64x16 c-major
  S_HC = 1664,      // 64x4 c-major
  S_HB = 1920,      // 64
  CONST_FLOATS = 2048
};

typedef _Float16 h2 __attribute__((ext_vector_type(2)));

__device__ __forceinline__ int pidx(int a, int b) {  // a<=b, 20-dim sym
  return a * 20 - (a * (a - 1)) / 2 + (b - a);
}
__device__ __forceinline__ unsigned short bf16r(float f) {
  unsigned u = __float_as_uint(f);
  u = u + 0x7fffu + ((u >> 16) & 1u);
  return (unsigned short)(u >> 16);
}
__device__ __forceinline__ unsigned short f2h(float f) {
  _Float16 h = (_Float16)f;
  unsigned short u;
  __builtin_memcpy(&u, &h, 2);
  return u;
}
__device__ __forceinline__ float h2f(unsigned short u) {
  _Float16 h;
  __builtin_memcpy(&h, &u, 2);
  return (float)h;
}
__device__ __forceinline__ unsigned packh2(float a, float b) {
  return (unsigned)f2h(a) | ((unsigned)f2h(b) << 16);
}
__device__ __forceinline__ float lo16(unsigned u) { return h2f((unsigned short)(u & 0xffffu)); }
__device__ __forceinline__ float hi16(unsigned u) { return h2f((unsigned short)(u >> 16)); }
__device__ __forceinline__ h2 mkh2(float a, float b) {
  h2 v; v[0] = (_Float16)a; v[1] = (_Float16)b; return v;
}
__device__ __forceinline__ h2 u2h2(unsigned u) {
  h2 v; __builtin_memcpy(&v, &u, 4); return v;
}

// ---------------- zero the histogram counts ----------------
__global__ __launch_bounds__(256) void k_zero(int* __restrict__ cnt)
{
  ((int4*)cnt)[(size_t)blockIdx.x * 256 + threadIdx.x] = make_int4(0, 0, 0, 0);
}

// ---------------- fused partial-reduce + BN finalize ----------------
__global__ __launch_bounds__(256) void k_rbn(
    const float* __restrict__ partial, int nb, int nch,
    const float* __restrict__ g, const float* __restrict__ b,
    float* __restrict__ scale, float* __restrict__ shift, float inv_count)
{
  const int c = blockIdx.x;
  const int tid = threadIdx.x;
  float s = 0.f, q = 0.f;
  for (int i = tid; i < nb; i += 256) {
    s += partial[(size_t)c * nb + i];
    q += partial[(size_t)(c + nch) * nb + i];
  }
  #pragma unroll
  for (int m = 1; m < 64; m <<= 1) { s += __shfl_xor(s, m); q += __shfl_xor(q, m); }
  __shared__ float ws[4], wq[4];
  if ((tid & 63) == 0) { ws[tid >> 6] = s; wq[tid >> 6] = q; }
  __syncthreads();
  if (tid == 0) {
    float S = ws[0] + ws[1] + ws[2] + ws[3];
    float Q = wq[0] + wq[1] + wq[2] + wq[3];
    float m = S * inv_count;
    float v = Q * inv_count - m * m;
    float rs = rsqrtf(v + 1e-5f);
    float sc = g[c] * rs;
    scale[c] = sc;
    shift[c] = fmaf(-m, sc, b[c]);
  }
}

// ---------------- 64x64 GEMM, 16 rows/block (high TLP) ----------------
__global__ __launch_bounds__(256) void k_gemm64(
    const float* __restrict__ in, const float* __restrict__ w,
    const float* __restrict__ bias,
    const float* __restrict__ sc, const float* __restrict__ sh,
    float* __restrict__ out,
    float* __restrict__ partial, int n)
{
  __shared__ float scsh[64], shsh[64];
  __shared__ float bsum[64], bsq[64];
  const int tid = threadIdx.x;
  const int lane = tid & 63;
  const int wave = tid >> 6;
  if (sc != nullptr && tid < 64) { scsh[tid] = sc[tid]; shsh[tid] = sh[tid]; }
  if (tid < 64) { bsum[tid] = 0.f; bsq[tid] = 0.f; }
  __syncthreads();

  float wreg[64];
  #pragma unroll
  for (int k = 0; k < 64; ++k) wreg[k] = w[k * 64 + lane];
  const float bz = bias ? bias[lane] : 0.f;

  float lsum = 0.f, lsq = 0.f;
  const int row0 = blockIdx.x * 16 + wave * 4;
  #pragma unroll
  for (int r = 0; r < 4; ++r) {
    const int row = row0 + r;
    const float* xr = in + (size_t)row * 64;
    float acc0 = bz, acc1 = 0.f;
    if (sc != nullptr) {
      #pragma unroll
      for (int k = 0; k < 32; k += 4) {
        float4 xa = *(const float4*)(xr + k);
        float4 xb = *(const float4*)(xr + 32 + k);
        float a0 = fmaxf(fmaf(xa.x, scsh[k + 0], shsh[k + 0]), 0.f);
        float a1 = fmaxf(fmaf(xa.y, scsh[k + 1], shsh[k + 1]), 0.f);
        float a2 = fmaxf(fmaf(xa.z, scsh[k + 2], shsh[k + 2]), 0.f);
        float a3 = fmaxf(fmaf(xa.w, scsh[k + 3], shsh[k + 3]), 0.f);
        float b0 = fmaxf(fmaf(xb.x, scsh[k + 32], shsh[k + 32]), 0.f);
        float b1 = fmaxf(fmaf(xb.y, scsh[k + 33], shsh[k + 33]), 0.f);
        float b2 = fmaxf(fmaf(xb.z, scsh[k + 34], shsh[k + 34]), 0.f);
        float b3 = fmaxf(fmaf(xb.w, scsh[k + 35], shsh[k + 35]), 0.f);
        acc0 = fmaf(a0, wreg[k + 0], acc0);
        acc0 = fmaf(a1, wreg[k + 1], acc0);
        acc0 = fmaf(a2, wreg[k + 2], acc0);
        acc0 = fmaf(a3, wreg[k + 3], acc0);
        acc1 = fmaf(b0, wreg[k + 32], acc1);
        acc1 = fmaf(b1, wreg[k + 33], acc1);
        acc1 = fmaf(b2, wreg[k + 34], acc1);
        acc1 = fmaf(b3, wreg[k + 35], acc1);
      }
    } else {
      #pragma unroll
      for (int k = 0; k < 32; k += 4) {
        float4 xa = *(const float4*)(xr + k);
        float4 xb = *(const float4*)(xr + 32 + k);
        acc0 = fmaf(xa.x, wreg[k + 0], acc0);
        acc0 = fmaf(xa.y, wreg[k + 1], acc0);
        acc0 = fmaf(xa.z, wreg[k + 2], acc0);
        acc0 = fmaf(xa.w, wreg[k + 3], acc0);
        acc1 = fmaf(xb.x, wreg[k + 32], acc1);
        acc1 = fmaf(xb.y, wreg[k + 33], acc1);
        acc1 = fmaf(xb.z, wreg[k + 34], acc1);
        acc1 = fmaf(xb.w, wreg[k + 35], acc1);
      }
    }
    float acc = acc0 + acc1;
    out[(size_t)row * 64 + lane] = acc;
    lsum += acc;
    lsq = fmaf(acc, acc, lsq);
  }
  if (partial != nullptr) {
    atomicAdd(&bsum[lane], lsum);
    atomicAdd(&bsq[lane], lsq);
    __syncthreads();
    if (tid < 64) {
      partial[(size_t)tid * gridDim.x + blockIdx.x] = bsum[tid];
      partial[(size_t)(tid + 64) * gridDim.x + blockIdx.x] = bsq[tid];
    }
  }
}

// ---------------- fused: z (bf16) + y16, 16 rows/block (high TLP) ----------------
__global__ __launch_bounds__(256) void k_gemmzy(
    const float* __restrict__ in, const float* __restrict__ w,
    const float* __restrict__ bias, const float* __restrict__ w16,
    const float* __restrict__ sc, const float* __restrict__ sh,
    unsigned short* __restrict__ outz, float* __restrict__ out16)
{
  __shared__ float xn[16][68];
  __shared__ float w16sh[1024];
  __shared__ float scsh[64], shsh[64];
  const int tid = threadIdx.x;
  if (tid < 64) { scsh[tid] = sc[tid]; shsh[tid] = sh[tid]; }
  for (int i2 = tid; i2 < 1024; i2 += 256) w16sh[i2] = w16[i2];
  __syncthreads();
  const int row0 = blockIdx.x * 16;
  for (int idx = tid; idx < 1024; idx += 256) {
    int r = idx >> 6, c = idx & 63;
    float v = in[(size_t)(row0 + r) * 64 + c];
    xn[r][c] = fmaxf(fmaf(v, scsh[c], shsh[c]), 0.f);
  }
  __syncthreads();

  const int lane = tid & 63;
  const int wave = tid >> 6;
  float wreg[64];
  #pragma unroll
  for (int k = 0; k < 64; ++k) wreg[k] = w[k * 64 + lane];
  const float bz = bias[lane];
  #pragma unroll
  for (int rr = 0; rr < 4; ++rr) {
    const int r = wave * 4 + rr;
    float acc0 = bz, acc1 = 0.f;
    #pragma unroll
    for (int k = 0; k < 32; k += 4) {
      float4 xa = *(const float4*)(&xn[r][k]);
      float4 xb = *(const float4*)(&xn[r][32 + k]);
      acc0 = fmaf(xa.x, wreg[k + 0], acc0);
      acc0 = fmaf(xa.y, wreg[k + 1], acc0);
      acc0 = fmaf(xa.z, wreg[k + 2], acc0);
      acc0 = fmaf(xa.w, wreg[k + 3], acc0);
      acc1 = fmaf(xb.x, wreg[k + 32], acc1);
      acc1 = fmaf(xb.y, wreg[k + 33], acc1);
      acc1 = fmaf(xb.z, wreg[k + 34], acc1);
      acc1 = fmaf(xb.w, wreg[k + 35], acc1);
    }
    outz[(size_t)(row0 + r) * 64 + lane] = bf16r(acc0 + acc1);
  }
  // y16: one output per thread (16 rows x 16 outputs)
  {
    const int r = tid >> 4, t = tid & 15;
    float acc = 0.f;
    #pragma unroll
    for (int c = 0; c < 64; c += 4) {
      float4 xv = *(const float4*)(&xn[r][c]);
      acc = fmaf(xv.x, w16sh[(c + 0) * 16 + t], acc);
      acc = fmaf(xv.y, w16sh[(c + 1) * 16 + t], acc);
      acc = fmaf(xv.z, w16sh[(c + 2) * 16 + t], acc);
      acc = fmaf(xv.w, w16sh[(c + 3) * 16 + t], acc);
    }
    out16[(size_t)(row0 + r) * 16 + t] = acc;
  }
}

// ---------------- K1: lp partials, histogram + rank ----------------
__global__ __launch_bounds__(256) void k_prhist(
    const float* __restrict__ p, const int* __restrict__ knn,
    const float* __restrict__ lpw1, const float* __restrict__ lpb1,
    float* __restrict__ plp,
    int* __restrict__ cnt, int* __restrict__ rank)
{
  __shared__ float lpw1sh[9], lpb1sh[3];
  __shared__ float lpsh[4][8];
  const int tid = threadIdx.x;
  if (tid < 9) lpw1sh[tid] = lpw1[tid];
  if (tid < 3) lpb1sh[tid] = lpb1[tid];
  __syncthreads();

  const size_t g = (size_t)blockIdx.x * 256 + tid;
  const int i = (int)(g >> 4);
  const int j = knn[g];
  const float pr0 = p[j * 3 + 0] - p[i * 3 + 0];
  const float pr1 = p[j * 3 + 1] - p[i * 3 + 1];
  const float pr2 = p[j * 3 + 2] - p[i * 3 + 2];
  rank[g] = atomicAdd(&cnt[j], 1);

  float q0 = fmaf(pr2, lpw1sh[6], fmaf(pr1, lpw1sh[3], fmaf(pr0, lpw1sh[0], lpb1sh[0])));
  float q1 = fmaf(pr2, lpw1sh[7], fmaf(pr1, lpw1sh[4], fmaf(pr0, lpw1sh[1], lpb1sh[1])));
  float q2 = fmaf(pr2, lpw1sh[8], fmaf(pr1, lpw1sh[5], fmaf(pr0, lpw1sh[2], lpb1sh[2])));
  float s0 = q0, s1 = q1, s2 = q2, qq0 = q0 * q0, qq1 = q1 * q1, qq2 = q2 * q2;
  #pragma unroll
  for (int m = 1; m < 64; m <<= 1) {
    s0 += __shfl_xor(s0, m); s1 += __shfl_xor(s1, m); s2 += __shfl_xor(s2, m);
    qq0 += __shfl_xor(qq0, m); qq1 += __shfl_xor(qq1, m); qq2 += __shfl_xor(qq2, m);
  }
  if ((tid & 63) == 0) {
    const int w = tid >> 6;
    lpsh[w][0] = s0; lpsh[w][1] = s1; lpsh[w][2] = s2; lpsh[w][3] = 0.f;
    lpsh[w][4] = qq0; lpsh[w][5] = qq1; lpsh[w][6] = qq2; lpsh[w][7] = 0.f;
  }
  __syncthreads();
  if (tid < 8) {
    float v = lpsh[0][tid] + lpsh[1][tid] + lpsh[2][tid] + lpsh[3][tid];
    plp[(size_t)tid * gridDim.x + blockIdx.x] = v;
  }
}

// ---------------- block sums of cnt ----------------
__global__ __launch_bounds__(256) void k_bsum(
    const int* __restrict__ cnt, int* __restrict__ bsums)
{
  const int tid = threadIdx.x;
  int4 c4 = ((const int4*)cnt)[blockIdx.x * 256 + tid];
  int s = c4.x + c4.y + c4.z + c4.w;
  #pragma unroll
  for (int m = 1; m < 64; m <<= 1) s += __shfl_xor(s, m);
  __shared__ int ws[4];
  if ((tid & 63) == 0) ws[tid >> 6] = s;
  __syncthreads();
  if (tid == 0) bsums[blockIdx.x] = ws[0] + ws[1] + ws[2] + ws[3];
}

// ---------------- mid: block-sum scan + lp finalize + weight folding ----------------
__global__ __launch_bounds__(256) void k_mid2(
    const int* __restrict__ bsums, int* __restrict__ blockoff,
    int* __restrict__ rowstart, int n,
    const float* __restrict__ plp, int nbplp,
    const float* __restrict__ lpg, const float* __restrict__ lpbt,
    const float* __restrict__ lpw1, const float* __restrict__ lpb1,
    const float* __restrict__ lpw2, const float* __restrict__ lpb2,
    const float* __restrict__ m1w2, const float* __restrict__ m2w1,
    const float* __restrict__ m1b2,
    float* __restrict__ cst, float inv_count)
{
  __shared__ float w2sh_[2048];   // m2w1 staged
  __shared__ float w1sh_[256];    // m1w2 staged
  __shared__ int bsh[64];
  __shared__ float Ssh[8];
  const int tid = threadIdx.x;
  const int nb1024 = n >> 10;
  if (tid < nb1024) bsh[tid] = bsums[tid];
  for (int i = tid; i < 2048; i += 256) w2sh_[i] = m2w1[i];
  w1sh_[tid] = m1w2[tid];
  {
    const int row = tid >> 5, l32 = tid & 31;
    float ls = 0.f;
    for (int i = l32; i < nbplp; i += 32) ls += plp[(size_t)row * nbplp + i];
    #pragma unroll
    for (int m = 1; m < 32; m <<= 1) ls += __shfl_xor(ls, m);
    if (l32 == 0) Ssh[row] = ls;
  }
  __syncthreads();
  if (tid == 0) {
    int run = 0;
    for (int i = 0; i < nb1024; ++i) { blockoff[i] = run; run += bsh[i]; }
    rowstart[n] = run;
  }
  if (tid < 3) {
    float m = Ssh[tid] * inv_count;
    float v = Ssh[4 + tid] * inv_count - m * m;
    float rs = rsqrtf(v + 1e-5f);
    float sc = lpg[tid] * rs;
    cst[S_LPSC + tid] = sc;
    cst[S_LPSH + tid] = fmaf(-m, sc, lpbt[tid]);
  }
  __syncthreads();
  if (tid < 9)  cst[S_QW + tid] = lpw1[tid] * cst[S_LPSC + (tid % 3)];
  if (tid < 3)  cst[S_QB + tid] = fmaf(lpb1[tid], cst[S_LPSC + tid], cst[S_LPSH + tid]);
  if (tid < 16) {
    float b = 0.f;
    for (int c2 = 0; c2 < 4; ++c2) b += lpb2[c2 * 16 + tid];
    cst[S_LPB2S + tid] = b;
    for (int r = 0; r < 3; ++r) {
      float w = 0.f;
      for (int c2 = 0; c2 < 4; ++c2) w += lpw2[r * 64 + c2 * 16 + tid];
      cst[S_LPW2S + r * 16 + tid] = w;
    }
  }
  __syncthreads();
  #pragma unroll
  for (int q = 0; q < 4; ++q) {
    int ee = tid * 4 + q;
    int c = ee >> 4, u = ee & 15;
    float sg = 0.f;
    #pragma unroll
    for (int t = 0; t < 16; ++t) sg = fmaf(w1sh_[u * 16 + t], w2sh_[t * 64 + c], sg);
    cst[S_G + c * 16 + u] = sg;
  }
  if (tid < 192) {
    int c = tid / 3, r = tid - c * 3;
    float sh = 0.f;
    #pragma unroll
    for (int t = 0; t < 16; ++t) sh = fmaf(cst[S_LPW2S + r * 16 + t], w2sh_[(16 + t) * 64 + c], sh);
    cst[S_HC + c * 4 + r] = sh;
  }
  if (tid < 64) {
    cst[S_HC + tid * 4 + 3] = 0.f;
    float sb = 0.f;
    #pragma unroll
    for (int t = 0; t < 16; ++t) {
      sb = fmaf(m1b2[t], w2sh_[t * 64 + tid], sb);
      sb = fmaf(cst[S_LPB2S + t], w2sh_[(16 + t) * 64 + tid], sb);
    }
    cst[S_HB + tid] = sb;
  }
}

// ---------------- final scan ----------------
__global__ __launch_bounds__(256) void k_scan3(
    const int* __restrict__ cnt, const int* __restrict__ blockoff,
    int* __restrict__ rowstart)
{
  const int tid = threadIdx.x;
  const int b = blockIdx.x;
  int4 c4 = ((const int4*)cnt)[b * 256 + tid];
  int tsum = c4.x + c4.y + c4.z + c4.w;
  const int lane = tid & 63, w = tid >> 6;
  int inc = tsum;
  #pragma unroll
  for (int d = 1; d < 64; d <<= 1) {
    int v = __shfl_up(inc, d);
    if (lane >= d) inc += v;
  }
  __shared__ int wsum[4];
  if (lane == 63) wsum[w] = inc;
  __syncthreads();
  int woff = 0;
  for (int u = 0; u < w; ++u) woff += wsum[u];
  int g0 = blockoff[b] + woff + inc - tsum;
  const int base = b * 1024 + tid * 4;
  int4 o;
  o.x = g0;
  o.y = g0 + c4.x;
  o.z = g0 + c4.x + c4.y;
  o.w = g0 + c4.x + c4.y + c4.z;
  *(int4*)(rowstart + base) = o;
}

// ---------------- K2: u-moment accumulation + uq/uqn/pos store ----------------
__global__ __launch_bounds__(256) void k_moment(
    const float* __restrict__ y16, const float* __restrict__ p,
    const int* __restrict__ knn, const float* __restrict__ m1w1,
    const float* __restrict__ m1b1, const float* __restrict__ cst,
    const int* __restrict__ rowstart, const int* __restrict__ rank,
    float* __restrict__ pmom,
    unsigned* __restrict__ uq,
    unsigned* __restrict__ uqn,
    int* __restrict__ posbuf)
{
  __shared__ float ush[256 * 21];
  const int tid = threadIdx.x;
  const size_t g = (size_t)blockIdx.x * 256 + tid;
  const int i = (int)(g >> 4);
  const int j = knn[g];
  const float pr0 = p[j * 3 + 0] - p[i * 3 + 0];
  const float pr1 = p[j * 3 + 1] - p[i * 3 + 1];
  const float pr2 = p[j * 3 + 2] - p[i * 3 + 2];
  const float* yj = y16 + (size_t)j * 16;
  float4 ya = *(const float4*)(yj);
  float4 yb = *(const float4*)(yj + 4);
  float4 yc = *(const float4*)(yj + 8);
  float4 yd = *(const float4*)(yj + 12);
  float t1[16] = {ya.x, ya.y, ya.z, ya.w, yb.x, yb.y, yb.z, yb.w,
                  yc.x, yc.y, yc.z, yc.w, yd.x, yd.y, yd.z, yd.w};
  #pragma unroll
  for (int u = 0; u < 16; ++u)
    t1[u] = fmaxf(fmaf(pr2, m1w1[32 + u], fmaf(pr1, m1w1[16 + u],
                  fmaf(pr0, m1w1[u], t1[u] + m1b1[u]))), 0.f);
  const float qn0 = fmaxf(fmaf(pr2, cst[S_QW + 6], fmaf(pr1, cst[S_QW + 3], fmaf(pr0, cst[S_QW + 0], cst[S_QB + 0]))), 0.f);
  const float qn1 = fmaxf(fmaf(pr2, cst[S_QW + 7], fmaf(pr1, cst[S_QW + 4], fmaf(pr0, cst[S_QW + 1], cst[S_QB + 1]))), 0.f);
  const float qn2 = fmaxf(fmaf(pr2, cst[S_QW + 8], fmaf(pr1, cst[S_QW + 5], fmaf(pr0, cst[S_QW + 2], cst[S_QB + 2]))), 0.f);

  posbuf[g] = rowstart[j] + rank[g];

  uint4 ua, ub;
  ua.x = packh2(t1[0], t1[1]);   ua.y = packh2(t1[2], t1[3]);
  ua.z = packh2(t1[4], t1[5]);   ua.w = packh2(t1[6], t1[7]);
  ub.x = packh2(t1[8], t1[9]);   ub.y = packh2(t1[10], t1[11]);
  ub.z = packh2(t1[12], t1[13]); ub.w = packh2(t1[14], t1[15]);
  *(uint4*)(uq + g * 8)     = ua;
  *(uint4*)(uq + g * 8 + 4) = ub;
  uint2 uc;
  uc.x = packh2(qn0, qn1);
  uc.y = packh2(qn2, 0.f);
  *(uint2*)(uqn + g * 2) = uc;

  float* ur = ush + tid * 21;
  #pragma unroll
  for (int u = 0; u < 16; ++u) ur[u] = t1[u];
  ur[16] = qn0; ur[17] = qn1; ur[18] = qn2; ur[19] = 1.f;
  __syncthreads();

  if (tid < 210) {
    int a = 0, t = tid;
    while (t >= 20 - a) { t -= 20 - a; ++a; }
    const int b = a + t;
    float s = 0.f;
    for (int r = 0; r < 256; ++r) {
      const float* u = ush + r * 21;
      s = fmaf(u[a], u[b], s);
    }
    pmom[(size_t)tid * gridDim.x + blockIdx.x] = s;
  }
}

// ---------------- parallel moment reduce ----------------
__global__ __launch_bounds__(256) void k_mred(
    const float* __restrict__ pmom, float* __restrict__ S2, int nb)
{
  const int c = blockIdx.x;
  const int tid = threadIdx.x;
  float s = 0.f;
  for (int i = tid; i < nb; i += 256) s += pmom[(size_t)c * nb + i];
  #pragma unroll
  for (int m = 1; m < 64; m <<= 1) s += __shfl_xor(s, m);
  __shared__ float ws[4];
  if ((tid & 63) == 0) ws[tid >> 6] = s;
  __syncthreads();
  if (tid == 0) S2[c] = ws[0] + ws[1] + ws[2] + ws[3];
}

// ---------------- moment finalize ----------------
__global__ __launch_bounds__(64) void k_mfin(
    const float* __restrict__ S2in,
    const float* __restrict__ g, const float* __restrict__ b,
    float* __restrict__ cst, float inv_count)
{
  __shared__ float S2[210];
  const int tid = threadIdx.x;
  for (int i = tid; i < 210; i += 64) S2[i] = S2in[i];
  __syncthreads();
  const int c = tid;
  float w[20];
  #pragma unroll
  for (int u = 0; u < 16; ++u) w[u] = cst[S_G + c * 16 + u];
  w[16] = cst[S_HC + c * 4 + 0];
  w[17] = cst[S_HC + c * 4 + 1];
  w[18] = cst[S_HC + c * 4 + 2];
  w[19] = cst[S_HB + c];
  float m2 = 0.f, m1 = 0.f;
  for (int a = 0; a < 20; ++a) {
    const float wa = w[a];
    m2 = fmaf(wa * wa, S2[pidx(a, a)], m2);
    float cross = 0.f;
    for (int bb = a + 1; bb < 20; ++bb) cross = fmaf(w[bb], S2[pidx(a, bb)], cross);
    m2 = fmaf(2.f * wa, cross, m2);
    m1 = fmaf(wa, S2[pidx(a, 19)], m1);
  }
  const float mean = m1 * inv_count;
  const float var = m2 * inv_count - mean * mean;
  const float rs = rsqrtf(var + 1e-5f);
  const float sc = g[c] * rs;
  cst[S_M2S1 + c] = sc;
  cst[S_M2H1 + c] = fmaf(-mean, sc, b[c]);
}

// ---------------- K3: h2(bf16) from packed uq/uqn via fp16 G/H ----------------
__global__ __launch_bounds__(256) void k_h2(
    const unsigned* __restrict__ uq, const unsigned* __restrict__ uqn,
    const float* __restrict__ cst, const float* __restrict__ m2w2,
    unsigned short* __restrict__ h2out,
    float* __restrict__ partial)   // [16 * gridDim.x]
{
  __shared__ h2 Gh2[512];          // G as fp16 pairs: [c][q] over u-pairs
  __shared__ h2 Hp[64];            // (H0,H1) per channel
  __shared__ float Hs[64], hbsh[64];
  __shared__ float w2m[512];
  __shared__ float scsh[64], shsh[64];
  __shared__ float redsh[4][16];
  const int tid = threadIdx.x;
  for (int i = tid; i < 512; i += 256) {
    int c = i >> 3, q = i & 7;
    Gh2[i] = mkh2(cst[S_G + c * 16 + 2 * q], cst[S_G + c * 16 + 2 * q + 1]);
  }
  for (int i = tid; i < 512; i += 256) w2m[i] = m2w2[i];
  if (tid < 64) {
    Hp[tid] = mkh2(cst[S_HC + tid * 4 + 0], cst[S_HC + tid * 4 + 1]);
    Hs[tid] = cst[S_HC + tid * 4 + 2];
    hbsh[tid] = cst[S_HB + tid];
    scsh[tid] = cst[S_M2S1 + tid];
    shsh[tid] = cst[S_M2H1 + tid];
  }
  __syncthreads();

  const size_t g0 = ((size_t)blockIdx.x * 256 + tid) * 2;
  h2 tp[2][8], qp[2];
  float q2f[2];
  #pragma unroll
  for (int gg = 0; gg < 2; ++gg) {
    const size_t g = g0 + gg;
    uint4 ua = *(const uint4*)(uq + g * 8);
    uint4 ub = *(const uint4*)(uq + g * 8 + 4);
    uint2 uc = *(const uint2*)(uqn + g * 2);
    tp[gg][0] = u2h2(ua.x); tp[gg][1] = u2h2(ua.y); tp[gg][2] = u2h2(ua.z); tp[gg][3] = u2h2(ua.w);
    tp[gg][4] = u2h2(ub.x); tp[gg][5] = u2h2(ub.y); tp[gg][6] = u2h2(ub.z); tp[gg][7] = u2h2(ub.w);
    qp[gg] = u2h2(uc.x);
    q2f[gg] = lo16(uc.y);
  }

  float a0[8], a1[8];
  #pragma unroll
  for (int t = 0; t < 8; ++t) { a0[t] = 0.f; a1[t] = 0.f; }
  for (int c = 0; c < 64; ++c) {
    const h2* Gc = Gh2 + c * 8;
    h2 acc0 = qp[0] * Hp[c];
    h2 acc1 = qp[1] * Hp[c];
    #pragma unroll
    for (int q = 0; q < 8; ++q) {
      h2 gq = Gc[q];
      acc0 = __builtin_elementwise_fma(tp[0][q], gq, acc0);
      acc1 = __builtin_elementwise_fma(tp[1][q], gq, acc1);
    }
    float base = fmaf(0.f, 0.f, hbsh[c]);
    float h_0 = (float)acc0[0] + (float)acc0[1] + fmaf(q2f[0], Hs[c], base);
    float h_1 = (float)acc1[0] + (float)acc1[1] + fmaf(q2f[1], Hs[c], base);
    float x0 = fmaxf(fmaf(h_0, scsh[c], shsh[c]), 0.f);
    float x1 = fmaxf(fmaf(h_1, scsh[c], shsh[c]), 0.f);
    float4 wa = *(const float4*)(w2m + c * 8);
    float4 wb = *(const float4*)(w2m + c * 8 + 4);
    a0[0] = fmaf(x0, wa.x, a0[0]); a0[1] = fmaf(x0, wa.y, a0[1]); a0[2] = fmaf(x0, wa.z, a0[2]); a0[3] = fmaf(x0, wa.w, a0[3]);
    a0[4] = fmaf(x0, wb.x, a0[4]); a0[5] = fmaf(x0, wb.y, a0[5]); a0[6] = fmaf(x0, wb.z, a0[6]); a0[7] = fmaf(x0, wb.w, a0[7]);
    a1[0] = fmaf(x1, wa.x, a1[0]); a1[1] = fmaf(x1, wa.y, a1[1]); a1[2] = fmaf(x1, wa.z, a1[2]); a1[3] = fmaf(x1, wa.w, a1[3]);
    a1[4] = fmaf(x1, wb.x, a1[4]); a1[5] = fmaf(x1, wb.y, a1[5]); a1[6] = fmaf(x1, wb.z, a1[6]); a1[7] = fmaf(x1, wb.w, a1[7]);
  }
  uint4 pa, pb;
  pa.x = bf16r(a0[0]) | ((unsigned)bf16r(a0[1]) << 16);
  pa.y = bf16r(a0[2]) | ((unsigned)bf16r(a0[3]) << 16);
  pa.z = bf16r(a0[4]) | ((unsigned)bf16r(a0[5]) << 16);
  pa.w = bf16r(a0[6]) | ((unsigned)bf16r(a0[7]) << 16);
  pb.x = bf16r(a1[0]) | ((unsigned)bf16r(a1[1]) << 16);
  pb.y = bf16r(a1[2]) | ((unsigned)bf16r(a1[3]) << 16);
  pb.z = bf16r(a1[4]) | ((unsigned)bf16r(a1[5]) << 16);
  pb.w = bf16r(a1[6]) | ((unsigned)bf16r(a1[7]) << 16);
  *(uint4*)(h2out + g0 * 8) = pa;
  *(uint4*)(h2out + g0 * 8 + 8) = pb;

  float st[8], sq[8];
  #pragma unroll
  for (int t = 0; t < 8; ++t) {
    st[t] = a0[t] + a1[t];
    sq[t] = fmaf(a0[t], a0[t], a1[t] * a1[t]);
  }
  #pragma unroll
  for (int m = 1; m < 64; m <<= 1) {
    #pragma unroll
    for (int t = 0; t < 8; ++t) { st[t] += __shfl_xor(st[t], m); sq[t] += __shfl_xor(sq[t], m); }
  }
  if ((tid & 63) == 0) {
    const int w = tid >> 6;
    #pragma unroll
    for (int t = 0; t < 8; ++t) { redsh[w][t] = st[t]; redsh[w][8 + t] = sq[t]; }
  }
  __syncthreads();
  if (tid < 16) {
    float v = redsh[0][tid] + redsh[1][tid] + redsh[2][tid] + redsh[3][tid];
    partial[(size_t)tid * gridDim.x + blockIdx.x] = v;
  }
}

// ---------------- K4: fused softmax + xk + x_intra (LDS reduce) + exv(fp16) ----------------
__global__ __launch_bounds__(256) void k_intra(
    const unsigned short* __restrict__ zb, const unsigned* __restrict__ uqn,
    const int* __restrict__ knn, const float* __restrict__ cst,
    const float* __restrict__ lpw2, const float* __restrict__ lpb2,
    const float* __restrict__ iw, const float* __restrict__ ib,
    const float* __restrict__ ixw, const float* __restrict__ ixb,
    const unsigned short* __restrict__ h2b, const float* __restrict__ m2w3,
    const float* __restrict__ m2b3,
    const int* __restrict__ posbuf,
    float* __restrict__ x_intra, unsigned* __restrict__ exv)
{
  __shared__ uint2 xksh[256][17];
  __shared__ float lpw2sh[192], lpb2sh[64];
  __shared__ h2 iwsh2[256], ixwsh2[256];
  __shared__ float ibsh[8], ixbsh[8];
  __shared__ float w3sh[64], b3sh[8], s2sh[8], h2ssh[8];
  const int tid = threadIdx.x;
  if (tid < 192) lpw2sh[tid] = lpw2[tid];
  if (tid < 64) { lpb2sh[tid] = lpb2[tid]; w3sh[tid] = m2w3[tid]; }
  iwsh2[tid]  = mkh2(iw[2 * tid], iw[2 * tid + 1]);
  ixwsh2[tid] = mkh2(ixw[2 * tid], ixw[2 * tid + 1]);
  if (tid < 8) {
    ibsh[tid] = ib[tid]; ixbsh[tid] = ixb[tid];
    b3sh[tid] = m2b3[tid]; s2sh[tid] = cst[S_M2S2 + tid]; h2ssh[tid] = cst[S_M2H2 + tid];
  }
  __syncthreads();

  const size_t g = (size_t)blockIdx.x * 256 + tid;
  const int j = knn[g];
  const unsigned* zr = (const unsigned*)(zb + (size_t)j * 64);
  const int pos = posbuf[g];

  uint2 uc = *(const uint2*)(uqn + g * 2);
  const float qn0 = lo16(uc.x), qn1 = hi16(uc.x), qn2 = lo16(uc.y);

  uint4 hu = *(const uint4*)(h2b + g * 8);
  float hn[8];
  hn[0] = fmaxf(fmaf(__uint_as_float(hu.x << 16),        s2sh[0], h2ssh[0]), 0.f);
  hn[1] = fmaxf(fmaf(__uint_as_float(hu.x & 0xffff0000u), s2sh[1], h2ssh[1]), 0.f);
  hn[2] = fmaxf(fmaf(__uint_as_float(hu.y << 16),        s2sh[2], h2ssh[2]), 0.f);
  hn[3] = fmaxf(fmaf(__uint_as_float(hu.y & 0xffff0000u), s2sh[3], h2ssh[3]), 0.f);
  hn[4] = fmaxf(fmaf(__uint_as_float(hu.z << 16),        s2sh[4], h2ssh[4]), 0.f);
  hn[5] = fmaxf(fmaf(__uint_as_float(hu.z & 0xffff0000u), s2sh[5], h2ssh[5]), 0.f);
  hn[6] = fmaxf(fmaf(__uint_as_float(hu.w << 16),        s2sh[6], h2ssh[6]), 0.f);
  hn[7] = fmaxf(fmaf(__uint_as_float(hu.w & 0xffff0000u), s2sh[7], h2ssh[7]), 0.f);
  float wk[8];
  #pragma unroll
  for (int t = 0; t < 8; ++t) {
    float a = b3sh[t];
    #pragma unroll
    for (int u = 0; u < 8; ++u) a = fmaf(hn[u], w3sh[u * 8 + t], a);
    wk[t] = a;
  }
  #pragma unroll
  for (int t = 0; t < 8; ++t) {
    float m = wk[t];
    m = fmaxf(m, __shfl_xor(m, 1));
    m = fmaxf(m, __shfl_xor(m, 2));
    m = fmaxf(m, __shfl_xor(m, 4));
    m = fmaxf(m, __shfl_xor(m, 8));
    float ex = __expf(wk[t] - m);
    float s = ex;
    s += __shfl_xor(s, 1);
    s += __shfl_xor(s, 2);
    s += __shfl_xor(s, 4);
    s += __shfl_xor(s, 8);
    wk[t] = ex / s;
  }

  h2 sacc2[4], vacc2[4];
  sacc2[0] = mkh2(ibsh[0], ibsh[1]); sacc2[1] = mkh2(ibsh[2], ibsh[3]);
  sacc2[2] = mkh2(ibsh[4], ibsh[5]); sacc2[3] = mkh2(ibsh[6], ibsh[7]);
  vacc2[0] = mkh2(ixbsh[0], ixbsh[1]); vacc2[1] = mkh2(ixbsh[2], ixbsh[3]);
  vacc2[2] = mkh2(ixbsh[4], ixbsh[5]); vacc2[3] = mkh2(ixbsh[6], ixbsh[7]);
  uint4 zq;
  #pragma unroll
  for (int c = 0; c < 64; c += 4) {
    if ((c & 7) == 0) zq = *(const uint4*)(zr + (c >> 1));
    const unsigned u0 = ((c & 7) == 0) ? zq.x : zq.z;
    const unsigned u1 = ((c & 7) == 0) ? zq.y : zq.w;
    const float z0 = __uint_as_float(u0 << 16);
    const float z1 = __uint_as_float(u0 & 0xffff0000u);
    const float z2 = __uint_as_float(u1 << 16);
    const float z3 = __uint_as_float(u1 & 0xffff0000u);
    float4 l0 = *(const float4*)(lpw2sh + c);
    float4 l1 = *(const float4*)(lpw2sh + 64 + c);
    float4 l2 = *(const float4*)(lpw2sh + 128 + c);
    float4 lb = *(const float4*)(lpb2sh + c);
    float xkv[4];
    xkv[0] = (z0 + fmaf(qn2, l2.x, fmaf(qn1, l1.x, fmaf(qn0, l0.x, lb.x)))) * wk[(c + 0) & 7];
    xkv[1] = (z1 + fmaf(qn2, l2.y, fmaf(qn1, l1.y, fmaf(qn0, l0.y, lb.y)))) * wk[(c + 1) & 7];
    xkv[2] = (z2 + fmaf(qn2, l2.z, fmaf(qn1, l1.z, fmaf(qn0, l0.z, lb.z)))) * wk[(c + 2) & 7];
    xkv[3] = (z3 + fmaf(qn2, l2.w, fmaf(qn1, l1.w, fmaf(qn0, l0.w, lb.w)))) * wk[(c + 3) & 7];
    xksh[tid][c >> 2] = make_uint2(packh2(xkv[0], xkv[1]), packh2(xkv[2], xkv[3]));
    #pragma unroll
    for (int d = 0; d < 4; ++d) {
      const _Float16 xh = (_Float16)xkv[d];
      h2 x2; x2[0] = xh; x2[1] = xh;
      const int cc = (c + d) * 4;
      #pragma unroll
      for (int q = 0; q < 4; ++q) {
        sacc2[q] = __builtin_elementwise_fma(x2, iwsh2[cc + q], sacc2[q]);
        vacc2[q] = __builtin_elementwise_fma(x2, ixwsh2[cc + q], vacc2[q]);
      }
    }
  }
  float sacc[8], vacc[8];
  #pragma unroll
  for (int q = 0; q < 4; ++q) {
    sacc[2 * q] = (float)sacc2[q][0]; sacc[2 * q + 1] = (float)sacc2[q][1];
    vacc[2 * q] = (float)vacc2[q][0]; vacc[2 * q + 1] = (float)vacc2[q][1];
  }
  float ex[8];
  #pragma unroll
  for (int t = 0; t < 8; ++t) ex[t] = __expf(sacc[t]);
  uint4 ea, eb;
  ea.x = packh2(ex[0], ex[1]); ea.y = packh2(ex[2], ex[3]);
  ea.z = packh2(ex[4], ex[5]); ea.w = packh2(ex[6], ex[7]);
  eb.x = packh2(ex[0] * vacc[0], ex[1] * vacc[1]);
  eb.y = packh2(ex[2] * vacc[2], ex[3] * vacc[3]);
  eb.z = packh2(ex[4] * vacc[4], ex[5] * vacc[5]);
  eb.w = packh2(ex[6] * vacc[6], ex[7] * vacc[7]);
  *(uint4*)(exv + (size_t)pos * 8) = ea;
  *(uint4*)(exv + (size_t)pos * 8 + 4) = eb;

  __syncthreads();
  const int base = tid & ~15;
  const int own = tid & 15;
  float o0 = 0.f, o1 = 0.f, o2 = 0.f, o3 = 0.f;
  #pragma unroll
  for (int k = 0; k < 16; ++k) {
    uint2 v = xksh[base + k][own];
    o0 += lo16(v.x); o1 += hi16(v.x);
    o2 += lo16(v.y); o3 += hi16(v.y);
  }
  const size_t i = g >> 4;
  *(float4*)(x_intra + i * 64 + own * 4) = make_float4(o0, o1, o2, o3);
}

// ---------------- K5: streaming segment reduce (fp16) + x2 + bn2 partials ----------------
__global__ __launch_bounds__(256) void k_inter_x2(
    const int* __restrict__ rowstart, const unsigned* __restrict__ exv,
    float* __restrict__ xi, float* __restrict__ partial)
{
  __shared__ float bsum[64], bsq[64];
  const int tid = threadIdx.x;
  if (tid < 64) { bsum[tid] = 0.f; bsq[tid] = 0.f; }
  __syncthreads();
  const int t = tid & 15;
  const int j = blockIdx.x * 16 + (tid >> 4);
  const int s0 = rowstart[j];
  const int e0 = rowstart[j + 1];
  const unsigned short* eh = (const unsigned short*)exv;
  float acc = 0.f;
  for (int e = s0; e < e0; ++e) acc += h2f(eh[(size_t)e * 16 + t]);
  const float other = __shfl_xor(acc, 8);
  float r = (t < 8) ? ((acc > 0.f) ? other / acc : 0.f)
                    : ((other > 0.f) ? acc / other : 0.f);
  float4 xv = *(const float4*)(xi + (size_t)j * 64 + t * 4);
  float v0 = xv.x + __shfl(r, (4 * t + 0) & 7, 16);
  float v1 = xv.y + __shfl(r, (4 * t + 1) & 7, 16);
  float v2 = xv.z + __shfl(r, (4 * t + 2) & 7, 16);
  float v3 = xv.w + __shfl(r, (4 * t + 3) & 7, 16);
  *(float4*)(xi + (size_t)j * 64 + t * 4) = make_float4(v0, v1, v2, v3);
  float s_[4] = {v0, v1, v2, v3};
  float q_[4] = {v0 * v0, v1 * v1, v2 * v2, v3 * v3};
  #pragma unroll
  for (int d = 0; d < 4; ++d) {
    s_[d] += __shfl_xor(s_[d], 16); s_[d] += __shfl_xor(s_[d], 32);
    q_[d] += __shfl_xor(q_[d], 16); q_[d] += __shfl_xor(q_[d], 32);
  }
  if ((tid & 63) < 16) {
    #pragma unroll
    for (int d = 0; d < 4; ++d) {
      atomicAdd(&bsum[4 * t + d], s_[d]);
      atomicAdd(&bsq[4 * t + d], q_[d]);
    }
  }
  __syncthreads();
  if (tid < 64) {
    partial[(size_t)tid * gridDim.x + blockIdx.x] = bsum[tid];
    partial[(size_t)(tid + 64) * gridDim.x + blockIdx.x] = bsq[tid];
  }
}

// ---------------- K6: final bn3 + residual + relu ----------------
__global__ __launch_bounds__(256) void k_out(
    const float* __restrict__ y3, const float* __restrict__ x0,
    const float* __restrict__ cst, float* __restrict__ out)
{
  __shared__ float scsh[64], shsh[64];
  const int tid = threadIdx.x;
  if (tid < 64) { scsh[tid] = cst[S_SC3 + tid]; shsh[tid] = cst[S_SH3 + tid]; }
  __syncthreads();
  const size_t i = ((size_t)blockIdx.x * 256 + tid) * 4;
  float4 y = *(const float4*)(y3 + i);
  float4 x = *(const float4*)(x0 + i);
  const int c = (int)(i & 63);
  float4 o;
  o.x = fmaxf(fmaf(y.x, scsh[c + 0], shsh[c + 0]) + x.x, 0.f);
  o.y = fmaxf(fmaf(y.y, scsh[c + 1], shsh[c + 1]) + x.y, 0.f);
  o.z = fmaxf(fmaf(y.z, scsh[c + 2], shsh[c + 2]) + x.z, 0.f);
  o.w = fmaxf(fmaf(y.w, scsh[c + 3], shsh[c + 3]) + x.w, 0.f);
  *(float4*)(out + i) = o;
}

// ---------------- launch ----------------
extern "C" void kernel_launch(void* const* d_in, const int* in_sizes, int n_in,
                              void* d_out, int out_size, void* d_ws, size_t ws_size,
                              hipStream_t stream)
{
  (void)n_in; (void)out_size; (void)ws_size;
  const float* p    = (const float*)d_in[0];
  const float* x    = (const float*)d_in[1];
  const int*   knn  = (const int*)d_in[2];
  const float* w1   = (const float*)d_in[3];
  const float* g1   = (const float*)d_in[4];
  const float* b1   = (const float*)d_in[5];
  const float* m1w1 = (const float*)d_in[6];
  const float* m1b1 = (const float*)d_in[7];
  const float* m1w2 = (const float*)d_in[8];
  const float* m1b2 = (const float*)d_in[9];
  const float* lpw1 = (const float*)d_in[10];
  const float* lpb1 = (const float*)d_in[11];
  const float* lpg  = (const float*)d_in[12];
  const float* lpbt = (const float*)d_in[13];
  const float* lpw2 = (const float*)d_in[14];
  const float* lpb2 = (const float*)d_in[15];
  const float* m2w1 = (const float*)d_in[16];
  const float* m2g1 = (const float*)d_in[17];
  const float* m2bt1= (const float*)d_in[18];
  const float* m2w2 = (const float*)d_in[19];
  const float* m2g2 = (const float*)d_in[20];
  const float* m2bt2= (const float*)d_in[21];
  const float* m2w3 = (const float*)d_in[22];
  const float* m2b3 = (const float*)d_in[23];
  const float* m3w  = (const float*)d_in[24];
  const float* m3b  = (const float*)d_in[25];
  const float* iw   = (const float*)d_in[26];
  const float* ib   = (const float*)d_in[27];
  const float* ixw  = (const float*)d_in[28];
  const float* ixb  = (const float*)d_in[29];
  const float* g2   = (const float*)d_in[30];
  const float* b2   = (const float*)d_in[31];
  const float* w3   = (const float*)d_in[32];
  const float* g3   = (const float*)d_in[33];
  const float* b3   = (const float*)d_in[34];
  float* out = (float*)d_out;
  float* ws  = (float*)d_ws;

  const int n = in_sizes[1] / 64;                // 32768
  const long long nk = (long long)n * 16;        // 524288
  const int nb1024 = n >> 10;                    // 32

  float* cst  = ws;
  int* cnt      = (int*)(ws + CONST_FLOATS);    // n ints (zeroed by k_zero)
  int* rowstart = cnt + n;                      // n+1 ints (+pad)
  int* rank     = rowstart + n + 16;            // nk ints
  int* posb     = rank + nk;                    // nk ints
  int* bsums    = posb + nk;                    // nb1024 ints
  int* blockoff = bsums + 64;                   // nb1024 ints
  unsigned short* zb = (unsigned short*)(blockoff + 64);  // 64n bf16
  float* y1 = (float*)(zb + 64LL * n);          // 64n, reused as y3
  float* xi = y1 + 64LL * n;                    // 64n
  float* y16 = xi + 64LL * n;                   // 16n
  unsigned short* h2b = (unsigned short*)(y16 + 16LL * n);  // 128n ushorts
  unsigned* exv = (unsigned*)(h2b + 128LL * n); // 128n uints

  const int gB2  = n / 16;            // 2048 (gemm64/gemmzy grid)
  const int nkB  = (int)(nk / 256);   // 2048
  const int nkB2 = (int)(nk / 512);   // 1024
  const int jB   = n / 16;            // 2048

  float* pbn1  = (float*)(exv + 128LL * n);      // 128 * gB2
  float* plp   = pbn1 + 128LL * gB2;             // 8 * nkB
  float* pmom  = plp + 8LL * nkB;                // 210 * nkB
  float* s2buf = pmom + 210LL * nkB;             // 256
  float* pm2b2 = s2buf + 256;                    // 16 * nkB2
  float* pbn2  = pm2b2 + 16LL * nkB2;            // 128 * jB
  float* pbn3  = pbn2 + 128LL * jB;              // 128 * gB2
  unsigned* uq = (unsigned*)(pbn3 + 128LL * gB2); // 8 * nk uints
  unsigned* uqn = uq + 8LL * nk;                 // 2 * nk uints

  // zero histogram counts with a parallel kernel
  k_zero<<<n / 1024, 256, 0, stream>>>(cnt);

  k_prhist<<<nkB, 256, 0, stream>>>(p, knn, lpw1, lpb1, plp, cnt, rank);
  k_gemm64<<<gB2, 256, 0, stream>>>(x, w1, nullptr, nullptr, nullptr, y1, pbn1, n);
  k_bsum<<<nb1024, 256, 0, stream>>>(cnt, bsums);
  k_mid2<<<1, 256, 0, stream>>>(bsums, blockoff, rowstart, n, plp, nkB,
                                lpg, lpbt, lpw1, lpb1, lpw2, lpb2,
                                m1w2, m2w1, m1b2, cst, 1.f / (float)nk);
  k_rbn<<<64, 256, 0, stream>>>(pbn1, gB2, 64, g1, b1, cst + S_SC1, cst + S_SH1, 1.f / (float)n);
  k_scan3<<<nb1024, 256, 0, stream>>>(cnt, blockoff, rowstart);
  // z(bf16) + y16 in one pass (16 rows/block)
  k_gemmzy<<<gB2, 256, 0, stream>>>(y1, m3w, m3b, m1w1 + 48, cst + S_SC1, cst + S_SH1, zb, y16);
  // h1 BN stats via u-moments; also emits uq/uqn/pos
  k_moment<<<nkB, 256, 0, stream>>>(y16, p, knn, m1w1, m1b1, cst, rowstart, rank,
                                    pmom, uq, uqn, posb);
  k_mred<<<210, 256, 0, stream>>>(pmom, s2buf, nkB);
  k_mfin<<<1, 64, 0, stream>>>(s2buf, m2g1, m2bt1, cst, 1.f / (float)nk);
  // h2 (bf16) from uq/uqn + stats
  k_h2<<<nkB2, 256, 0, stream>>>(uq, uqn, cst, m2w2, h2b, pm2b2);
  k_rbn<<<8, 256, 0, stream>>>(pm2b2, nkB2, 8, m2g2, m2bt2, cst + S_M2S2, cst + S_M2H2, 1.f / (float)nk);
  // fused softmax + xk + x_intra + exv
  k_intra<<<nkB, 256, 0, stream>>>(zb, uqn, knn, cst, lpw2, lpb2, iw, ib, ixw, ixb,
                                   h2b, m2w3, m2b3, posb, xi, exv);
  // streaming segment reduce + x2 + bn2 partials
  k_inter_x2<<<jB, 256, 0, stream>>>(rowstart, exv, xi, pbn2);
  k_rbn<<<64, 256, 0, stream>>>(pbn2, jB, 64, g2, b2, cst + S_SC2, cst + S_SH2, 1.f / (float)n);
  // y3 = relu(bn2(x2)) @ w3, bn3
  k_gemm64<<<gB2, 256, 0, stream>>>(xi, w3, nullptr, cst + S_SC2, cst + S_SH2, y1, pbn3, n);
  k_rbn<<<64, 256, 0, stream>>>(pbn3, gB2, 64, g3, b3, cst + S_SC3, cst + S_SH3, 1.f / (float)n);
  // out = relu(bn3(y3) + x)
  k_out<<<(int)((long long)n * 64 / 1024), 256, 0, stream>>>(y1, x, cst, out);
}